// Round 11
// baseline (306.358 us; speedup 1.0000x reference)
//
#include <hip/hip_runtime.h>
#include <hip/hip_bf16.h>
#include <cstddef>

#define NTOK 2048
#define DMODEL 512
#define NHEAD 8
#define DHEAD 64
#define NWIN 254          // (2048-16)/8 + 1
#define CDIM 1024         // CB*DH
#define NEGV -1000000000.0f

typedef __attribute__((ext_vector_type(8))) __bf16 bf16x8;
typedef __attribute__((ext_vector_type(4))) float f32x4;
typedef __hip_bfloat16 bf16;

// ---------------- workspace layout (byte offsets) ----------------
static const size_t B_WQKV_H = 0;          // 1536*512*2
static const size_t B_WQKV_L = 1572864;
static const size_t B_KW1_H  = 3145728;    // 1024*1024*2
static const size_t B_KW1_L  = 5242880;
static const size_t B_KW2_H  = 7340032;    // 64*1024*2
static const size_t B_KW2_L  = 7471104;
static const size_t B_VW1_H  = 7602176;
static const size_t B_VW2_H  = 9699328;
static const size_t B_WOUT_H = 9830400;    // 512*512*2
static const size_t B_HB_H   = 10354688;   // 2048*512*2
static const size_t B_HB_L   = 12451840;
static const size_t B_QBH    = 14548992;   // 8*2048*64*2 (non-roped q, hi)
static const size_t B_QBL    = 16646144;   // (lo, 3rd term)
static const size_t B_KF     = 18743296;   // 8*2048*64*4 (k fp32, pre-rope; dead after k_post -> HIDV)
static const size_t B_VBH    = 22937600;   // 8*2048*64*2
static const size_t B_RQH    = 25034752;   // roped q hi/lo
static const size_t B_RQL    = 27131904;
static const size_t B_RKH    = 29229056;   // 8*2112*64*2 (roped k, 64 zero-pad rows front)
static const size_t B_RKL    = 31391744;
static const size_t B_VTB    = 33554432;   // 8*64*2112*2 (v^T, 64 zero-pad cols front)
static const size_t B_CKT_H  = 35717120;   // 8*256*64*2 (compressed k rows, j=0 mem)
static const size_t B_CKT_L  = 35979264;
static const size_t B_CVT    = 36241408;   // 8*64*256*2 (compressed v transposed)
static const size_t B_SEL    = 36700160;   // 8*2048*5*4
static const size_t B_COUT   = 37027840;   // 4194304 (overlays KW_H)
static const size_t B_FOUT   = 41222144;   // 4194304 (overlays KW_L)
static const size_t B_SOUT   = 45416448;   // 4194304 (overlays VW_H)
static const size_t B_KW_H   = B_COUT;     // 2032*1024*2 = 4161536
static const size_t B_KW_L   = B_FOUT;
static const size_t B_VW_H   = B_SOUT;
static const size_t B_HID_H  = 49610752;   // 4161536 (k hidden hi)
static const size_t B_HID_L  = 53772288;   // 4161536 (k hidden lo)
static const size_t B_QBM    = 57933824;   // 8*2048*64*2 (q mid term)
static const size_t B_CKT_M  = 60030976;   // 8*256*64*2
static const size_t B_RKF    = 60293120;   // 8*2048*64*4 (roped k fp32); end 64487424
static const size_t B_HIDV   = B_KF;       // v hidden hi (4161536 <= 4194304, KF dead)
static const size_t B_COMBB  = B_HID_H;    // 2097152 (after MLPs dead)

// ================= pipelined 32x32-per-wave core (reg double-buffered frags) ======
// Per-element accumulation order: hh(k0), [hl(k0), lh(k0)], hh(k0+32), ... -> matches
// all previous cores bit-exactly. Requires K % 64 == 0.
template <int COMP>
__device__ __forceinline__ void gemm_tile32p(
    const bf16* __restrict__ Ah, const bf16* __restrict__ Al,
    const bf16* __restrict__ Wh, const bf16* __restrict__ Wl,
    int M, int K, int row_base, int col_base, int lr, int kg,
    f32x4 (&acc)[2][2]) {
  size_t ao[2], bo[2];
#pragma unroll
  for (int mi = 0; mi < 2; ++mi) {
    int r = row_base + mi * 16 + lr; if (r > M - 1) r = M - 1;
    ao[mi] = (size_t)r * K + kg;
  }
#pragma unroll
  for (int ni = 0; ni < 2; ++ni)
    bo[ni] = (size_t)(col_base + ni * 16 + lr) * K + kg;

  bf16x8 a0[2], b0[2], a1[2], b1[2];
  bf16x8 c0[2], d0[2], c1[2], d1[2];
#pragma unroll
  for (int i = 0; i < 2; ++i) {
    a0[i] = *reinterpret_cast<const bf16x8*>(Ah + ao[i]);
    b0[i] = *reinterpret_cast<const bf16x8*>(Wh + bo[i]);
    if constexpr (COMP) {
      c0[i] = *reinterpret_cast<const bf16x8*>(Al + ao[i]);
      d0[i] = *reinterpret_cast<const bf16x8*>(Wl + bo[i]);
    }
  }
  for (int k0 = 0; k0 < K; k0 += 64) {
#pragma unroll
    for (int i = 0; i < 2; ++i) {
      a1[i] = *reinterpret_cast<const bf16x8*>(Ah + ao[i] + k0 + 32);
      b1[i] = *reinterpret_cast<const bf16x8*>(Wh + bo[i] + k0 + 32);
      if constexpr (COMP) {
        c1[i] = *reinterpret_cast<const bf16x8*>(Al + ao[i] + k0 + 32);
        d1[i] = *reinterpret_cast<const bf16x8*>(Wl + bo[i] + k0 + 32);
      }
    }
#pragma unroll
    for (int mi = 0; mi < 2; ++mi)
#pragma unroll
      for (int ni = 0; ni < 2; ++ni)
        acc[mi][ni] = __builtin_amdgcn_mfma_f32_16x16x32_bf16(a0[mi], b0[ni], acc[mi][ni], 0, 0, 0);
    if constexpr (COMP) {
#pragma unroll
      for (int mi = 0; mi < 2; ++mi)
#pragma unroll
        for (int ni = 0; ni < 2; ++ni) {
          acc[mi][ni] = __builtin_amdgcn_mfma_f32_16x16x32_bf16(a0[mi], d0[ni], acc[mi][ni], 0, 0, 0);
          acc[mi][ni] = __builtin_amdgcn_mfma_f32_16x16x32_bf16(c0[mi], b0[ni], acc[mi][ni], 0, 0, 0);
        }
    }
    if (k0 + 64 < K) {
#pragma unroll
      for (int i = 0; i < 2; ++i) {
        a0[i] = *reinterpret_cast<const bf16x8*>(Ah + ao[i] + k0 + 64);
        b0[i] = *reinterpret_cast<const bf16x8*>(Wh + bo[i] + k0 + 64);
        if constexpr (COMP) {
          c0[i] = *reinterpret_cast<const bf16x8*>(Al + ao[i] + k0 + 64);
          d0[i] = *reinterpret_cast<const bf16x8*>(Wl + bo[i] + k0 + 64);
        }
      }
    }
#pragma unroll
    for (int mi = 0; mi < 2; ++mi)
#pragma unroll
      for (int ni = 0; ni < 2; ++ni)
        acc[mi][ni] = __builtin_amdgcn_mfma_f32_16x16x32_bf16(a1[mi], b1[ni], acc[mi][ni], 0, 0, 0);
    if constexpr (COMP) {
#pragma unroll
      for (int mi = 0; mi < 2; ++mi)
#pragma unroll
        for (int ni = 0; ni < 2; ++ni) {
          acc[mi][ni] = __builtin_amdgcn_mfma_f32_16x16x32_bf16(a1[mi], d1[ni], acc[mi][ni], 0, 0, 0);
          acc[mi][ni] = __builtin_amdgcn_mfma_f32_16x16x32_bf16(c1[mi], b1[ni], acc[mi][ni], 0, 0, 0);
        }
    }
  }
}

// ================= 64x64-per-wave core, register double-buffered =================
template <int COMP>
__device__ __forceinline__ void gemm_tile64(
    const bf16* __restrict__ Ah, const bf16* __restrict__ Al,
    const bf16* __restrict__ Wh, const bf16* __restrict__ Wl,
    int M, int K, int row_base, int col_base, int lr, int kg,
    f32x4 (&acc)[4][4]) {
  size_t ao[4], bo[4];
#pragma unroll
  for (int mi = 0; mi < 4; ++mi) {
    int r = row_base + mi * 16 + lr; if (r > M - 1) r = M - 1;
    ao[mi] = (size_t)r * K + kg;
  }
#pragma unroll
  for (int ni = 0; ni < 4; ++ni)
    bo[ni] = (size_t)(col_base + ni * 16 + lr) * K + kg;

  bf16x8 a0[4], b0[4], a1[4], b1[4];
  bf16x8 c0[4], d0[4], c1[4], d1[4];
#pragma unroll
  for (int i = 0; i < 4; ++i) {
    a0[i] = *reinterpret_cast<const bf16x8*>(Ah + ao[i]);
    b0[i] = *reinterpret_cast<const bf16x8*>(Wh + bo[i]);
    if constexpr (COMP) {
      c0[i] = *reinterpret_cast<const bf16x8*>(Al + ao[i]);
      d0[i] = *reinterpret_cast<const bf16x8*>(Wl + bo[i]);
    }
  }
  for (int k0 = 0; k0 < K; k0 += 64) {
#pragma unroll
    for (int i = 0; i < 4; ++i) {
      a1[i] = *reinterpret_cast<const bf16x8*>(Ah + ao[i] + k0 + 32);
      b1[i] = *reinterpret_cast<const bf16x8*>(Wh + bo[i] + k0 + 32);
      if constexpr (COMP) {
        c1[i] = *reinterpret_cast<const bf16x8*>(Al + ao[i] + k0 + 32);
        d1[i] = *reinterpret_cast<const bf16x8*>(Wl + bo[i] + k0 + 32);
      }
    }
#pragma unroll
    for (int mi = 0; mi < 4; ++mi)
#pragma unroll
      for (int ni = 0; ni < 4; ++ni)
        acc[mi][ni] = __builtin_amdgcn_mfma_f32_16x16x32_bf16(a0[mi], b0[ni], acc[mi][ni], 0, 0, 0);
    if constexpr (COMP) {
#pragma unroll
      for (int mi = 0; mi < 4; ++mi)
#pragma unroll
        for (int ni = 0; ni < 4; ++ni) {
          acc[mi][ni] = __builtin_amdgcn_mfma_f32_16x16x32_bf16(a0[mi], d0[ni], acc[mi][ni], 0, 0, 0);
          acc[mi][ni] = __builtin_amdgcn_mfma_f32_16x16x32_bf16(c0[mi], b0[ni], acc[mi][ni], 0, 0, 0);
        }
    }
    if (k0 + 64 < K) {
#pragma unroll
      for (int i = 0; i < 4; ++i) {
        a0[i] = *reinterpret_cast<const bf16x8*>(Ah + ao[i] + k0 + 64);
        b0[i] = *reinterpret_cast<const bf16x8*>(Wh + bo[i] + k0 + 64);
        if constexpr (COMP) {
          c0[i] = *reinterpret_cast<const bf16x8*>(Al + ao[i] + k0 + 64);
          d0[i] = *reinterpret_cast<const bf16x8*>(Wl + bo[i] + k0 + 64);
        }
      }
    }
#pragma unroll
    for (int mi = 0; mi < 4; ++mi)
#pragma unroll
      for (int ni = 0; ni < 4; ++ni)
        acc[mi][ni] = __builtin_amdgcn_mfma_f32_16x16x32_bf16(a1[mi], b1[ni], acc[mi][ni], 0, 0, 0);
    if constexpr (COMP) {
#pragma unroll
      for (int mi = 0; mi < 4; ++mi)
#pragma unroll
        for (int ni = 0; ni < 4; ++ni) {
          acc[mi][ni] = __builtin_amdgcn_mfma_f32_16x16x32_bf16(a1[mi], d1[ni], acc[mi][ni], 0, 0, 0);
          acc[mi][ni] = __builtin_amdgcn_mfma_f32_16x16x32_bf16(c1[mi], b1[ni], acc[mi][ni], 0, 0, 0);
        }
    }
  }
}

// ---------------- generic GEMM kernel (fp32 out; out-proj), pipelined 32 core ----------------
template <int EPI, int COMP>
__global__ __launch_bounds__(256) void k_cgemm(
    const bf16* __restrict__ Ah, const bf16* __restrict__ Al,
    const bf16* __restrict__ Wh, const bf16* __restrict__ Wl,
    const float* __restrict__ bias, float* __restrict__ Cf,
    int M, int K, int N) {
  const int lane = threadIdx.x & 63;
  const int w = threadIdx.x >> 6;
  const int wr = w >> 1, wc = w & 1;
  const int row_base = (blockIdx.y << 6) + (wr << 5);
  const int col_base = (blockIdx.x << 6) + (wc << 5);
  const int lr = lane & 15;
  const int kg = (lane >> 4) << 3;
  const int crow = (lane >> 4) << 2;

  f32x4 accs[2][2];
#pragma unroll
  for (int a = 0; a < 2; ++a)
#pragma unroll
    for (int b = 0; b < 2; ++b) accs[a][b] = (f32x4){0.f, 0.f, 0.f, 0.f};
  gemm_tile32p<COMP>(Ah, Al, Wh, Wl, M, K, row_base, col_base, lr, kg, accs);

#pragma unroll
  for (int mi = 0; mi < 2; ++mi) {
#pragma unroll
    for (int ni = 0; ni < 2; ++ni) {
      int col = col_base + (ni << 4) + lr;
      float bv = bias ? bias[col] : 0.f;
#pragma unroll
      for (int r = 0; r < 4; ++r) {
        int row = row_base + (mi << 4) + crow + r;
        if (row < M) {
          float vv = accs[mi][ni][r] + bv;
          if (EPI == 1) vv = fmaxf(vv, 0.f);
          Cf[(size_t)row * N + col] = vv;
        }
      }
    }
  }
}

// ---------------- qkv GEMM (pipelined 32x32/wave, 768 blocks, fused split/scatter) --------
__global__ __launch_bounds__(256, 1) void k_qkv(
    const bf16* __restrict__ Ah, const bf16* __restrict__ Al,
    const bf16* __restrict__ Wh, const bf16* __restrict__ Wl,
    float* __restrict__ KFo, bf16* __restrict__ QH, bf16* __restrict__ QM,
    bf16* __restrict__ QL, bf16* __restrict__ VB) {
  const int lane = threadIdx.x & 63;
  const int w = threadIdx.x >> 6;
  const int wr = w >> 1, wc = w & 1;
  const int row_base = (blockIdx.y << 6) + (wr << 5);
  const int col_base = (blockIdx.x << 6) + (wc << 5);
  const int lr = lane & 15;
  const int kg = (lane >> 4) << 3;
  const int crow = (lane >> 4) << 2;

  f32x4 acc[2][2];
#pragma unroll
  for (int a = 0; a < 2; ++a)
#pragma unroll
    for (int b = 0; b < 2; ++b) acc[a][b] = (f32x4){0.f, 0.f, 0.f, 0.f};
  gemm_tile32p<1>(Ah, Al, Wh, Wl, NTOK, DMODEL, row_base, col_base, lr, kg, acc);

#pragma unroll
  for (int mi = 0; mi < 2; ++mi) {
#pragma unroll
    for (int ni = 0; ni < 2; ++ni) {
      int col = col_base + (ni << 4) + lr;
      int which = col >> 9, rem = col & 511;
      int hh = rem >> 6, dd = rem & 63;
#pragma unroll
      for (int r = 0; r < 4; ++r) {
        int row = row_base + (mi << 4) + crow + r;   // M=2048 exact
        float vv = acc[mi][ni][r];
        size_t o = ((size_t)hh * NTOK + row) * DHEAD + dd;
        if (which == 0) {
          bf16 h1 = __float2bfloat16(vv);
          float r1 = vv - __bfloat162float(h1);
          bf16 m1 = __float2bfloat16(r1);
          QH[o] = h1;
          QM[o] = m1;
          QL[o] = __float2bfloat16(r1 - __bfloat162float(m1));
        } else if (which == 1) {
          KFo[o] = vv;
        } else {
          VB[o] = __float2bfloat16(vv);
        }
      }
    }
  }
}

// ---------------- merged MLP1, work-balanced hybrid grid (640 blocks) ----------------
// id < 128: v-path (plain, 128x128 tile, 64x64/wave) -- 4 work-units each, dispatched first.
// id >= 128: k-path (compensated, 64x64 tile, 32x32/wave) -- 3 units each, 512 blocks.
__global__ __launch_bounds__(256, 1) void k_mlp1(
    const bf16* __restrict__ KWh, const bf16* __restrict__ KWl,
    const bf16* __restrict__ W1h, const bf16* __restrict__ W1l,
    const float* __restrict__ kb1,
    const bf16* __restrict__ VWh, const bf16* __restrict__ VW1h,
    const float* __restrict__ vb1,
    bf16* __restrict__ HKh, bf16* __restrict__ HKl, bf16* __restrict__ HVh) {
  const int lane = threadIdx.x & 63;
  const int w = threadIdx.x >> 6;
  const int wr = w >> 1, wc = w & 1;
  const int lr = lane & 15;
  const int kg = (lane >> 4) << 3;
  const int crow = (lane >> 4) << 2;
  const int M = NHEAD * NWIN;  // 2032
  const int id = blockIdx.x;

  if (id < 128) {
    // v-path: 128x128 tile, 16 row-tiles x 8 col-tiles
    const int tr = id >> 3, tc = id & 7;
    const int row_base = (tr << 7) + (wr << 6);
    const int col_base = (tc << 7) + (wc << 6);
    f32x4 acc[4][4];
#pragma unroll
    for (int a = 0; a < 4; ++a)
#pragma unroll
      for (int b = 0; b < 4; ++b) acc[a][b] = (f32x4){0.f, 0.f, 0.f, 0.f};
    gemm_tile64<0>(VWh, nullptr, VW1h, nullptr, M, CDIM, row_base, col_base, lr, kg, acc);
#pragma unroll
    for (int mi = 0; mi < 4; ++mi) {
#pragma unroll
      for (int ni = 0; ni < 4; ++ni) {
        int col = col_base + (ni << 4) + lr;
        float bv = vb1[col];
#pragma unroll
        for (int r = 0; r < 4; ++r) {
          int row = row_base + (mi << 4) + crow + r;
          if (row < M)
            HVh[(size_t)row * CDIM + col] = __float2bfloat16(fmaxf(acc[mi][ni][r] + bv, 0.f));
        }
      }
    }
  } else {
    // k-path: 64x64 tile, 32 row-tiles x 16 col-tiles
    const int u = id - 128;
    const int tr = u >> 4, tc = u & 15;
    const int row_base = (tr << 6) + (wr << 5);
    const int col_base = (tc << 6) + (wc << 5);
    f32x4 acc[2][2];
#pragma unroll
    for (int a = 0; a < 2; ++a)
#pragma unroll
      for (int b = 0; b < 2; ++b) acc[a][b] = (f32x4){0.f, 0.f, 0.f, 0.f};
    gemm_tile32p<1>(KWh, KWl, W1h, W1l, M, CDIM, row_base, col_base, lr, kg, acc);
#pragma unroll
    for (int mi = 0; mi < 2; ++mi) {
#pragma unroll
      for (int ni = 0; ni < 2; ++ni) {
        int col = col_base + (ni << 4) + lr;
        float bv = kb1[col];
#pragma unroll
        for (int r = 0; r < 4; ++r) {
          int row = row_base + (mi << 4) + crow + r;
          if (row < M) {
            float vv = fmaxf(acc[mi][ni][r] + bv, 0.f);
            size_t o = (size_t)row * CDIM + col;
            bf16 h1 = __float2bfloat16(vv);
            HKh[o] = h1;
            HKl[o] = __float2bfloat16(vv - __bfloat162float(h1));
          }
        }
      }
    }
  }
}

// ---------------- merged MLP2 (pipelined 32 core): z=0 k -> ckT, z=1 v -> cvT ----------------
__global__ __launch_bounds__(256) void k_mlp2(
    const bf16* __restrict__ HKh, const bf16* __restrict__ HKl,
    const bf16* __restrict__ W2h, const bf16* __restrict__ W2l,
    const float* __restrict__ kb2,
    const bf16* __restrict__ HVh, const bf16* __restrict__ VW2h,
    const float* __restrict__ vb2,
    bf16* __restrict__ ckh, bf16* __restrict__ ckm, bf16* __restrict__ ckl,
    bf16* __restrict__ cvtb) {
  const int lane = threadIdx.x & 63;
  const int w = threadIdx.x >> 6;
  const int wr = w >> 1, wc = w & 1;
  const int row_base = (blockIdx.y << 6) + (wr << 5);
  const int col_base = (wc << 5);
  const int lr = lane & 15;
  const int kg = (lane >> 4) << 3;
  const int crow = (lane >> 4) << 2;
  const int M = NHEAD * NWIN;

  f32x4 accs[2][2];
#pragma unroll
  for (int a = 0; a < 2; ++a)
#pragma unroll
    for (int b = 0; b < 2; ++b) accs[a][b] = (f32x4){0.f, 0.f, 0.f, 0.f};
  if (blockIdx.z == 0)
    gemm_tile32p<1>(HKh, HKl, W2h, W2l, M, CDIM, row_base, col_base, lr, kg, accs);
  else
    gemm_tile32p<0>(HVh, nullptr, VW2h, nullptr, M, CDIM, row_base, col_base, lr, kg, accs);

  const float* bias = (blockIdx.z == 0) ? kb2 : vb2;
#pragma unroll
  for (int mi = 0; mi < 2; ++mi) {
#pragma unroll
    for (int ni = 0; ni < 2; ++ni) {
      int col = col_base + (ni << 4) + lr;
      float bv = bias[col];
#pragma unroll
      for (int r = 0; r < 4; ++r) {
        int row = row_base + (mi << 4) + crow + r;
        if (row < M) {
          float vv = accs[mi][ni][r] + bv;
          int hh = row / NWIN, jj = row - hh * NWIN;
          if (blockIdx.z == 0) {
            size_t o = ((size_t)hh * 256 + 1 + jj) * 64 + col;
            bf16 h1 = __float2bfloat16(vv);
            float r1 = vv - __bfloat162float(h1);
            bf16 m1 = __float2bfloat16(r1);
            ckh[o] = h1;
            ckm[o] = m1;
            ckl[o] = __float2bfloat16(r1 - __bfloat162float(m1));
          } else {
            cvtb[((size_t)hh * 64 + col) * 256 + 1 + jj] = __float2bfloat16(vv);
          }
        }
      }
    }
  }
}

// ================= k_setup: 6 weight transposes + zpad + fillmem + rmsnorm =================
__device__ __forceinline__ void wt_tile(const float* __restrict__ W,
                                        bf16* __restrict__ WTh, bf16* __restrict__ WTl,
                                        int K, int N, int bx, int by,
                                        float (*tsh)[33]) {
  const int k0 = bx << 5, n0 = by << 5;
  const int tx = threadIdx.x & 31, ty = threadIdx.x >> 5;
#pragma unroll
  for (int r = 0; r < 4; ++r)
    tsh[ty + (r << 3)][tx] = W[(size_t)(k0 + ty + (r << 3)) * N + n0 + tx];
  __syncthreads();
#pragma unroll
  for (int r = 0; r < 4; ++r) {
    float val = tsh[tx][ty + (r << 3)];
    size_t o = (size_t)(n0 + ty + (r << 3)) * K + k0 + tx;
    bf16 h1 = __float2bfloat16(val);
    WTh[o] = h1;
    if (WTl) WTl[o] = __float2bfloat16(val - __bfloat162float(h1));
  }
}

__global__ __launch_bounds__(256) void k_setup(
    const float* __restrict__ x, const float* __restrict__ g,
    const float* __restrict__ w_qkv, const float* __restrict__ k_w1,
    const float* __restrict__ k_w2, const float* __restrict__ v_w1,
    const float* __restrict__ v_w2, const float* __restrict__ w_out,
    const float* __restrict__ memkv,
    bf16* __restrict__ WQKV_H, bf16* __restrict__ WQKV_L,
    bf16* __restrict__ KW1_H, bf16* __restrict__ KW1_L,
    bf16* __restrict__ KW2_H, bf16* __restrict__ KW2_L,
    bf16* __restrict__ VW1_H, bf16* __restrict__ VW2_H, bf16* __restrict__ WOUT_H,
    bf16* __restrict__ hbh, bf16* __restrict__ hbl,
    bf16* __restrict__ rkh, bf16* __restrict__ rkl, bf16* __restrict__ vtb,
    bf16* __restrict__ ckh, bf16* __restrict__ ckm, bf16* __restrict__ ckl,
    bf16* __restrict__ cvtb) {
  __shared__ float tsh[32][33];
  __shared__ float wsum[4];
  __shared__ float scale_s;
  const int id = blockIdx.x;
  const int t = threadIdx.x;

  if (id < 768) {
    wt_tile(w_qkv, WQKV_H, WQKV_L, DMODEL, 1536, id % 16, id / 16, tsh);
  } else if (id < 1792) {
    int u = id - 768;  wt_tile(k_w1, KW1_H, KW1_L, CDIM, CDIM, u % 32, u / 32, tsh);
  } else if (id < 1856) {
    int u = id - 1792; wt_tile(k_w2, KW2_H, KW2_L, CDIM, DHEAD, u % 32, u / 32, tsh);
  } else if (id < 2880) {
    int u = id - 1856; wt_tile(v_w1, VW1_H, nullptr, CDIM, CDIM, u % 32, u / 32, tsh);
  } else if (id < 2944) {
    int u = id - 2880; wt_tile(v_w2, VW2_H, nullptr, CDIM, DHEAD, u % 32, u / 32, tsh);
  } else if (id < 3200) {
    int u = id - 2944; wt_tile(w_out, WOUT_H, nullptr, DMODEL, DMODEL, u % 16, u / 16, tsh);
  } else if (id < 3328) {
    int idx = (id - 3200) * 256 + t;   // [0, 32768)
    int h = idx >> 12, r = (idx >> 6) & 63, c = idx & 63;
    bf16 z = __float2bfloat16(0.f);
    rkh[((size_t)h * 2112 + r) * 64 + c] = z;
    rkl[((size_t)h * 2112 + r) * 64 + c] = z;
    vtb[((size_t)h * 64 + r) * 2112 + c] = z;
  } else if (id < 3330) {
    int u = (id - 3328) * 256 + t;     // [0, 512)
    if (u < 512) {
      int h = u >> 6, e = u & 63;
      float kv = memkv[(size_t)h * DHEAD + e];
      bf16 h1 = __float2bfloat16(kv);
      float r1 = kv - __bfloat162float(h1);
      bf16 m1 = __float2bfloat16(r1);
      ckh[((size_t)h * 256) * 64 + e] = h1;
      ckm[((size_t)h * 256) * 64 + e] = m1;
      ckl[((size_t)h * 256) * 64 + e] = __float2bfloat16(r1 - __bfloat162float(m1));
      bf16 z = __float2bfloat16(0.f);
      ckh[((size_t)h * 256 + 255) * 64 + e] = z;
      ckm[((size_t)h * 256 + 255) * 64 + e] = z;
      ckl[((size_t)h * 256 + 255) * 64 + e] = z;
      float vv = memkv[(size_t)(NHEAD + h) * DHEAD + e];
      cvtb[((size_t)h * 64 + e) * 256 + 0] = __float2bfloat16(vv);
      cvtb[((size_t)h * 64 + e) * 256 + 255] = z;
    }
  } else {
    const int row = id - 3330;
    const float* xr = x + (size_t)row * DMODEL;
    float s = 0.f;
    for (int c = t; c < DMODEL; c += 256) { float v = xr[c]; s += v * v; }
    for (int o = 32; o > 0; o >>= 1) s += __shfl_down(s, o);
    if ((t & 63) == 0) wsum[t >> 6] = s;
    __syncthreads();
    if (t == 0) {
      float tot = wsum[0] + wsum[1] + wsum[2] + wsum[3];
      scale_s = rsqrtf(tot * (1.f / DMODEL) + 1e-6f);
    }
    __syncthreads();
    float sc = scale_s;
    for (int c = t; c < DMODEL; c += 256) {
      float v = xr[c] * sc * g[c];
      bf16 h1 = __float2bfloat16(v);
      hbh[(size_t)row * DMODEL + c] = h1;
      hbl[(size_t)row * DMODEL + c] = __float2bfloat16(v - __bfloat162float(h1));
    }
  }
}

// ================= k_post: rope + v-transpose + compression windows =================
__global__ __launch_bounds__(256) void k_post(
    const bf16* __restrict__ qbh, const bf16* __restrict__ qbm,
    const bf16* __restrict__ qbl, const float* __restrict__ kf,
    const bf16* __restrict__ vbh,
    const float* __restrict__ kpos, const float* __restrict__ vpos,
    bf16* __restrict__ rqh, bf16* __restrict__ rql,
    bf16* __restrict__ rkh, bf16* __restrict__ rkl, float* __restrict__ rkf,
    bf16* __restrict__ vtb,
    bf16* __restrict__ kwh, bf16* __restrict__ kwl, bf16* __restrict__ vwh) {
  __shared__ bf16 tile[64][65];
  const int id = blockIdx.x;
  const int t = threadIdx.x;

  if (id < 2048) {
    int idx = id * 256 + t;
    int i = idx & 31;
    int n = (idx >> 5) & (NTOK - 1);
    int h = idx >> 16;
    float ex = (float)(2 * i) * (1.f / 64.f);
    float inv = exp2f(-ex * 13.287712379549449f);
    float ang = (float)n * inv;
    float sn, cs;
    sincosf(ang, &sn, &cs);
    size_t base = ((size_t)h * NTOK + n) * DHEAD + 2 * i;
    float q1 = __bfloat162float(qbh[base]) + __bfloat162float(qbm[base]) + __bfloat162float(qbl[base]);
    float q2 = __bfloat162float(qbh[base + 1]) + __bfloat162float(qbm[base + 1]) + __bfloat162float(qbl[base + 1]);
    float r1 = q1 * cs - q2 * sn, r2 = q1 * sn + q2 * cs;
    bf16 h1 = __float2bfloat16(r1);
    rqh[base] = h1; rql[base] = __float2bfloat16(r1 - __bfloat162float(h1));
    h1 = __float2bfloat16(r2);
    rqh[base + 1] = h1; rql[base + 1] = __float2bfloat16(r2 - __bfloat162float(h1));
    float k1 = kf[base], k2 = kf[base + 1];
    float s1 = k1 * cs - k2 * sn, s2 = k1 * sn + k2 * cs;
    rkf[base] = s1;
    rkf[base + 1] = s2;
    size_t kb = ((size_t)h * 2112 + 64 + n) * DHEAD + 2 * i;
    h1 = __float2bfloat16(s1);
    rkh[kb] = h1; rkl[kb] = __float2bfloat16(s1 - __bfloat162float(h1));
    h1 = __float2bfloat16(s2);
    rkh[kb + 1] = h1; rkl[kb + 1] = __float2bfloat16(s2 - __bfloat162float(h1));
  } else if (id < 2304) {
    int u = id - 2048;
    int h = u >> 5, n0 = (u & 31) << 6;
    int tx = t & 63, ty = t >> 6;
    for (int r = ty; r < 64; r += 4)
      tile[r][tx] = vbh[((size_t)h * NTOK + n0 + r) * DHEAD + tx];
    __syncthreads();
    for (int r = ty; r < 64; r += 4)
      vtb[((size_t)h * 64 + r) * 2112 + 64 + n0 + tx] = tile[tx][r];
  } else {
    int idx = (id - 2304) * 256 + t;   // [0, 2080768)
    int d = idx & 63;
    int c = (idx >> 6) & 15;
    int j = (idx >> 10) % NWIN;
    int h = idx / (NWIN << 10);
    int srcpos = (j << 3) + c;
    size_t src = ((size_t)h * NTOK + srcpos) * DHEAD + d;
    size_t pp = ((size_t)h * 16 + c) * DHEAD + d;
    float kv = kf[src] + kpos[pp];
    bf16 h1 = __float2bfloat16(kv);
    kwh[idx] = h1;
    kwl[idx] = __float2bfloat16(kv - __bfloat162float(h1));
    vwh[idx] = __float2bfloat16(__bfloat162float(vbh[src]) + vpos[pp]);
  }
}

// ---------------- compression attention (MFMA, 32 queries/block) ----------------
__global__ __launch_bounds__(256) void k_comp_attn(
    const bf16* __restrict__ qbh, const bf16* __restrict__ qbm, const bf16* __restrict__ qbl,
    const bf16* __restrict__ ckh, const bf16* __restrict__ ckm, const bf16* __restrict__ ckl,
    const bf16* __restrict__ cvtb,
    float* __restrict__ c_out, int* __restrict__ sel) {
  const int h = blockIdx.y;
  const int i0 = blockIdx.x << 5;
  const int t = threadIdx.x;
  const int w = t >> 6, lane = t & 63;
  const int lr = lane & 15, kg = (lane >> 4) << 3;
  const int crow = (lane >> 4) << 2;

  __shared__ float p[32][260];

  bf16x8 aH[2][2], aM[2][2], aL[2][2];
#pragma unroll
  for (int mi = 0; mi < 2; ++mi) {
    size_t qo = ((size_t)h * NTOK + i0 + mi * 16 + lr) * DHEAD + kg;
#pragma unroll
    for (int ks = 0; ks < 2; ++ks) {
      aH[mi][ks] = *reinterpret_cast<const bf16x8*>(qbh + qo + ks * 32);
      aM[mi][ks] = *reinterpret_cast<const bf16x8*>(qbm + qo + ks * 32);
      aL[mi][ks] = *reinterpret_cast<const bf16x8*>(qbl + qo + ks * 32);
    }
  }
  f32x4 acc[2][4];
#pragma unroll
  for (int a = 0; a < 2; ++a)
#pragma unroll
    for (int b = 0; b < 4; ++b) acc[a][b] = (f32x4){0.f, 0.f, 0.f, 0.f};
#pragma unroll
  for (int ni = 0; ni < 4; ++ni) {
    int col = (w << 6) + (ni << 4) + lr;
    size_t ko = ((size_t)h * 256 + col) * 64 + kg;
#pragma unroll
    for (int ks = 0; ks < 2; ++ks) {
      bf16x8 bH = *reinterpret_cast<const bf16x8*>(ckh + ko + ks * 32);
      bf16x8 bM = *reinterpret_cast<const bf16x8*>(ckm + ko + ks * 32);
      bf16x8 bL = *reinterpret_cast<const bf16x8*>(ckl + ko + ks * 32);
#pragma unroll
      for (int mi = 0; mi < 2; ++mi) {
        acc[mi][ni] = __builtin_amdgcn_mfma_f32_16x16x32_bf16(aH[mi][ks], bH, acc[mi][ni], 0, 0, 0);
        acc[mi][ni] = __builtin_amdgcn_mfma_f32_16x16x32_bf16(aH[mi][ks], bM, acc[mi][ni], 0, 0, 0);
        acc[mi][ni] = __builtin_amdgcn_mfma_f32_16x16x32_bf16(aM[mi][ks], bH, acc[mi][ni], 0, 0, 0);
        acc[mi][ni] = __builtin_amdgcn_mfma_f32_16x16x32_bf16(aH[mi][ks], bL, acc[mi][ni], 0, 0, 0);
        acc[mi][ni] = __builtin_amdgcn_mfma_f32_16x16x32_bf16(aL[mi][ks], bH, acc[mi][ni], 0, 0, 0);
        acc[mi][ni] = __builtin_amdgcn_mfma_f32_16x16x32_bf16(aM[mi][ks], bM, acc[mi][ni], 0, 0, 0);
      }
    }
  }
#pragma unroll
  for (int mi = 0; mi < 2; ++mi)
#pragma unroll
    for (int ni = 0; ni < 4; ++ni) {
      int col = (w << 6) + (ni << 4) + lr;
      int wend = (col == 0) ? -1 : ((col - 1) << 3) + 15;
#pragma unroll
      for (int r = 0; r < 4; ++r) {
        int qi = mi * 16 + crow + r;
        bool ok = (col < 255) && (wend < i0 + qi);
        p[qi][col] = ok ? acc[mi][ni][r] * 0.125f : NEGV;
      }
    }
  __syncthreads();

  const int qi = t >> 3, s = t & 7;
  float ev[32];
  float mx = -3.0e38f;
#pragma unroll
  for (int u = 0; u < 32; ++u) { ev[u] = p[qi][s + (u << 3)]; mx = fmaxf(mx, ev[u]); }
  mx = fmaxf(mx, __shfl_xor(mx, 1));
  mx = fmaxf(mx, __shfl_xor(mx, 2));
  mx = fmaxf(mx, __shfl_xor(mx, 4));
  float sum = 0.f;
#pragma unroll
  for (int u = 0; u < 32; ++u) { float e = __expf(ev[u] - mx); ev[u] = e; sum += e; }
  sum += __shfl_xor(sum, 1); sum += __shfl_xor(sum, 2); sum += __shfl_xor(sum, 4);
  float invs = 1.f / sum;
#pragma unroll
  for (int u = 0; u < 32; ++u) p[qi][s + (u << 3)] = ev[u] * invs;

  int qblk = (i0 + qi) >> 4;
  float vals[16];
#pragma unroll
  for (int u = 0; u < 16; ++u) {
    int f = (s << 4) + u;
    float v;
    if (f >= qblk || f == 127) v = NEGV;
    else v = (p[qi][2 * f + 1] + p[qi][2 * f + 2]) * 0.5f;
    vals[u] = v;
  }
  int base = ((h << 11) | (i0 + qi)) * 5;
  for (int kk = 0; kk < 4; ++kk) {
    float bv = -3.0e38f; int bi = 0;
#pragma unroll
    for (int u = 0; u < 16; ++u) {
      if (vals[u] > bv) { bv = vals[u]; bi = (s << 4) + u; }
    }
#pragma unroll
    for (int o = 1; o < 8; o <<= 1) {
      float ov = __shfl_xor(bv, o);
      int oi = __shfl_xor(bi, o);
      if (ov > bv || (ov == bv && oi < bi)) { bv = ov; bi = oi; }
    }
    if (s == 0) sel[base + kk] = (bv > -5.0e8f) ? bi : -1;
    if ((bi >> 4) == s) vals[bi & 15] = -3.0e38f;
  }
  if (s == 0) sel[base + 4] = (i0 + qi) >> 4;
  __syncthreads();

  const int wm = w >> 1, wn = w & 1;
  const int arow = wm * 16 + lr;
  f32x4 pacc[2];
#pragma unroll
  for (int b = 0; b < 2; ++b) pacc[b] = (f32x4){0.f, 0.f, 0.f, 0.f};
#pragma unroll
  for (int ks = 0; ks < 8; ++ks) {
    int k0 = ks * 32 + kg;
    float4 x0 = *reinterpret_cast<const float4*>(&p[arow][k0]);
    float4 x1 = *reinterpret_cast<const float4*>(&p[arow][k0 + 4]);
    float xv[8] = {x0.x, x0.y, x0.z, x0.w, x1.x, x1.y, x1.z, x1.w};
    bf16x8 ph, pl;
#pragma unroll
    for (int e = 0; e < 8; ++e) {
      __bf16 hh = (__bf16)xv[e];
      ph[e] = hh;
      pl[e] = (__bf16)(xv[e] - (float)hh);
    }
#pragma unroll
    for (int ni = 0; ni < 2; ++ni) {
      int d = (wn << 5) + (ni << 4) + lr;
      bf16x8 bv = *reinterpret_cast<const bf16x8*>(cvtb + ((size_t)h * 64 + d) * 256 + k0);
      pacc[ni] = __builtin_amdgcn_mfma_f32_16x16x32_bf16(ph, bv, pacc[ni], 0, 0, 0);
      pacc[ni] = __builtin_amdgcn_mfma_f32_16x16x32_bf16(pl, bv, pacc[ni], 0, 0, 0);
    }
  }
#pragma unroll
  for (int ni = 0; ni < 2; ++ni) {
    int d = (wn << 5) + (ni << 4) + lr;
#pragma unroll
    for (int r = 0; r < 4; ++r) {
      int q2 = wm * 16 + crow + r;
      c_out[((size_t)h * NTOK + i0 + q2) * DHEAD + d] = pacc[ni][r];
    }
  }
}

// ---------------- fine attention: 1 wave per query, fp32 K via float4 ----------------
__global__ __launch_bounds__(256) void k_fine_attn(
    const bf16* __restrict__ rqh, const bf16* __restrict__ rql,
    const float* __restrict__ rkf, const bf16* __restrict__ vbh,
    const int* __restrict__ sel, float* __restrict__ f_out) {
  const int h = blockIdx.y;
  const int wid = threadIdx.x >> 6;
  const int lane = threadIdx.x & 63;
  const int i = (blockIdx.x << 2) | wid;

  __shared__ float qs[4][64];
  __shared__ float pb[4][80];
  __shared__ int selb[4][5];

  size_t qoff = ((size_t)h * NTOK + i) * DHEAD + lane;
  qs[wid][lane] = __bfloat162float(rqh[qoff]) + __bfloat162float(rql[qoff]);
  if (lane < 5) selb[wid][lane] = sel[((h << 11) | i) * 5 + lane];
  __syncthreads();

  float sim0 = NEGV, sim1 = NEGV;
  {
    int kb = selb[wid][lane >> 4];
    int pos = (kb << 4) + (lane & 15);
    if (kb >= 0 && pos <= i) {
      const float* kp = rkf + ((size_t)h * NTOK + pos) * DHEAD;
      float d = 0.f;
#pragma unroll
      for (int e4 = 0; e4 < 16; ++e4) {
        float4 kv = *reinterpret_cast<const float4*>(kp + e4 * 4);
        d = fmaf(qs[wid][e4 * 4 + 0], kv.x, d);
        d = fmaf(qs[wid][e4 * 4 + 1], kv.y, d);
        d = fmaf(qs[wid][e4 * 4 + 2], kv.z, d);
        d = fmaf(qs[wid][e4 * 4 + 3], kv.w, d);
      }
      sim0 = d * 0.125f;
    }
  }
  if (lane < 16) {
    int kb = selb[wid][4];
    int pos = (kb << 4) + lane;
    if (pos <= i) {
      const float* kp = rkf + ((size_t)h * NTOK + pos) * DHEAD;
      float d = 0.f;
#pragma unroll
      for (int e4 = 0; e4 < 16; ++e4) {
        float4 kv = *reinterpret_cast<const float4*>(kp + e4 * 4);
        d = fmaf(qs[wid][e4 * 4 + 0], kv.x, d);
        d = fmaf(qs[wid][e4 * 4 + 1], kv.y, d);
        d = fmaf(qs[wid][e4 * 4 + 2], kv.z, d);
        d = fmaf(qs[wid][e4 * 4 + 3], kv.w, d);
      }
      sim1 = d * 0.125f;
    }
  }

  float mx = fmaxf(sim0, sim1);
#pragma unroll
  for (int o = 32; o > 0; o >>= 1) mx = fmaxf(mx, __shfl_xor(mx, o));
  float e0 = __expf(sim0 - mx);
  float e1 = __expf(sim1 - mx);
  float sum = e0 + e1;
#pragma unroll
  for (int o = 32; o > 0; o >>= 1) sum += __shfl_xor(sum, o);
  float invs = 1.f / sum;
  pb[wid][lane] = e0 * invs;
  if (lane < 16) pb[wid][64 + lane] = e1 * invs;

  float acc = 0.f;
#pragma unroll
  for (int b = 0; b < 5; ++b) {
    int kb = selb[wid][b];
    if (kb < 0) continue;
    const bf16* vr = vbh + ((size_t)h * NTOK + ((size_t)kb << 4)) * DHEAD + lane;
#pragma unroll
    for (int u = 0; u < 16; ++u)
      acc = fmaf(pb[wid][b * 16 + u], __bfloat162float(vr[(size_t)u * DHEAD]), acc);
  }
  f_out[((size_t)h * NTOK + i) * DHEAD + lane] = acc;
}

// ---------------- sliding-window attention (MFMA, 64 queries/block) ----------------
__global__ __launch_bounds__(256) void k_slide_attn(
    const bf16* __restrict__ rqh, const bf16* __restrict__ rql,
    const bf16* __restrict__ rkh, const bf16* __restrict__ rkl,
    const bf16* __restrict__ vtb, float* __restrict__ s_out) {
  const int h = blockIdx.y, nb = blockIdx.x;
  const int t = threadIdx.x, w = t >> 6, lane = t & 63;
  const int lr = lane & 15, kg = (lane >> 4) << 3;
  const int crow = (lane >> 4) << 2;
  const int wm = w >> 1, wn = w & 1;
  __shared__ float p[64][132];

  bf16x8 aH[2][2], aL[2][2];
#pragma unroll
  for (int mi = 0; mi < 2; ++mi) {
    size_t qo = ((size_t)h * NTOK + nb * 64 + wm * 32 + mi * 16 + lr) * DHEAD + kg;
#pragma unroll
    for (int ks = 0; ks < 2; ++ks) {
      aH[mi][ks] = *reinterpret_cast<const bf16x8*>(rqh + qo + ks * 32);
      aL[mi][ks] = *reinterpret_cast<const bf16x8*>(rql + qo + ks * 32);
    }
  }
  f32x4 acc[2][4];
#pragma unroll
  for (int a = 0; a < 2; ++a)
#pragma unroll
    for (int b = 0; b < 4; ++b) acc[a][b] = (f32x4){0.f, 0.f, 0.f, 0.f};
#pragma unroll
  for (int ni = 0; ni < 4; ++ni) {
    int col = (wn << 6) + (ni << 4) + lr;
    size_t ko = ((size_t)h * 2112 + nb * 64 + col) * 64 + kg;
#pragma unroll
    for (int ks = 0; ks < 2; ++ks) {
      bf16x8 bH = *reinterpret_cast<const bf16x8*>(rkh + ko + ks * 32);
      bf16x8 bL = *reinterpret_cast<const bf16x8*>(rkl + ko + ks * 32);
#pragma unroll
      for (int mi = 0; mi < 2; ++mi) {
        acc[mi][ni] = __builtin_amdgcn_mfma_f32_16x16x32_bf16(aH[mi][ks], bH, acc[mi][ni], 0, 0, 0);
        acc[mi][ni] = __builtin_amdgcn_mfma_f32_16x16x32_bf16(aL[mi][ks], bH, acc[mi][ni], 0, 0, 0);
        acc[mi][ni] = __builtin_amdgcn_mfma_f32_16x16x32_bf16(aH[mi][ks], bL, acc[mi][ni], 0, 0, 0);
      }
    }
  }
#pragma unroll
  for (int mi = 0; mi < 2; ++mi)
#pragma unroll
    for (int ni = 0; ni < 4; ++ni) {
      int col = (wn << 6) + (ni << 4) + lr;
#pragma unroll
      for (int r = 0; r < 4; ++r) {
        int qi2 = wm * 32 + mi * 16 + crow + r;
        bool ok = (col >= qi2 + 1) && (col <= qi2 + 64) && (nb > 0 || col >= 64);
        p[qi2][col] = ok ? acc[mi][ni][r] * 0.125f : NEGV;
      }
    }
  __syncthreads();

  const int qi = t >> 2, s = t & 3;
  float ev[32];
  float mx = -3.0e38f;
#pragma unroll
  for (int u = 0; u < 32; ++u) { ev[u] = p[qi][s + (u << 2)]; mx = fmaxf(mx, ev[u]); }
  mx = fmaxf(mx, __shfl_xor(mx, 1));
  mx = fmaxf(mx, __shfl_xor(mx, 2));
  float sum = 0.f;
#pragma unroll
  for (int u = 0; u < 32; ++u) { float e = __expf(ev[u] - mx); ev[u] = e; sum += e; }
  sum += __shfl_xor(sum, 1); sum += __shfl_xor(sum, 2);
  float invs = 1.f / sum;
#pragma unroll
  for (int u = 0; u < 32; ++u) p[qi][s + (u << 2)] = ev[u] * invs;
  __syncthreads();

  f32x4 pacc[2][2];
#pragma unroll
  for (int a = 0; a < 2; ++a)
#pragma unroll
    for (int b = 0; b < 2; ++b) pacc[a][b] = (f32x4){0.f, 0.f, 0.f, 0.f};
#pragma unroll
  for (int ks = 0; ks < 4; ++ks) {
    int k0 = ks * 32 + kg;
    bf16x8 ph[2], pl[2];
#pragma unroll
    for (int mi = 0; mi < 2; ++mi) {
      int arow = wm * 32 + mi * 16 + lr;
      float4 x0 = *reinterpret_cast<const float4*>(&p[arow][k0]);
      float4 x1 = *reinterpret_cast<const float4*>(&p[arow][k0 + 4]);
      float xv[8] = {x0.x, x0.y, x0.z, x0.w, x1.x, x1.y, x1.z, x1.w};
#pragma unroll
      for (int e = 0; e < 8; ++e) {
        __bf16 hh = (__bf16)xv[e];
        ph[mi][e] = hh;
        pl[mi][e] = (__bf16)(xv[e] - (float)hh);
      }
    }
#pragma unroll
    for (int ni = 0; ni < 2; ++ni) {
      int d = (wn << 5) + (ni << 4) + lr;
      bf16x8 bv = *reinterpret_cast<const bf16x8*>(vtb + ((size_t)h * 64 + d) * 2112 + nb * 64 + k0);
#pragma unroll
      for (int mi = 0; mi < 2; ++mi) {
        pacc[mi][ni] = __builtin_amdgcn_mfma_f32_16x16x32_bf16(ph[mi], bv, pacc[mi][ni], 0, 0, 0);
        pacc[mi][ni] = __builtin_amdgcn_mfma_f32_16x16x32_bf16(pl[mi], bv, pacc[mi][ni], 0, 0, 0);
      }
    }
  }
#pragma unroll
  for (int mi = 0; mi < 2; ++mi)
#pragma unroll
    for (int ni = 0; ni < 2; ++ni) {
      int d = (wn << 5) + (ni << 4) + lr;
#pragma unroll
      for (int r = 0; r < 4; ++r) {
        int qi2 = wm * 32 + mi * 16 + crow + r;
        s_out[((size_t)h * NTOK + nb * 64 + qi2) * DHEAD + d] = pacc[mi][ni][r];
      }
    }
}

// ---------------- fused strat + combine: one block per token ----------------
__global__ __launch_bounds__(256) void k_combine2(
    const bf16* __restrict__ Ah, const bf16* __restrict__ Al,
    const float* __restrict__ W, const float* __restrict__ bias,
    const float* __restrict__ c_out, const float* __restrict__ f_out,
    const float* __restrict__ s_out, bf16* __restrict__ comb) {
  const int i = blockIdx.x;
  const int t = threadIdx.x;
  __shared__ float hs[DMODEL];
  __shared__ float st[24];
  size_t ro = (size_t)i * DMODEL;
#pragma unroll
  for (int u = 0; u < 2; ++u) {
    int c = t + u * 256;
    hs[c] = __bfloat162float(Ah[ro + c]) + __bfloat162float(Al[ro + c]);
  }
  __syncthreads();
  if (t < 192) {
    int c = t >> 3, s = t & 7;
    float acc = 0.f;
    for (int u = 0; u < 64; ++u) {
      int e = s * 64 + u;
      acc = fmaf(hs[e], W[(size_t)e * 24 + c], acc);
    }
    acc += __shfl_xor(acc, 1);
    acc += __shfl_xor(acc, 2);
    acc += __shfl_xor(acc, 4);
    if (s == 0) st[c] = 1.f / (1.f + expf(-(acc + bias[c])));
  }
  __syncthreads();
#pragma unroll
  for (int u = 0; u < 2; ++u) {
    int c = t + u * 256;
    int h = c >> 6, d = c & 63;
    size_t a = ((size_t)h * NTOK + i) * DHEAD + d;
    comb[ro + c] = __float2bfloat16(st[h * 3] * c_out[a] + st[h * 3 + 1] * f_out[a]
                                    + st[h * 3 + 2] * s_out[a]);
  }
}

extern "C" void kernel_launch(void* const* d_in, const int* in_sizes, int n_in,
                              void* d_out, int out_size, void* d_ws, size_t ws_size,
                              hipStream_t stream) {
  const float* x      = (const float*)d_in[0];
  const float* g_norm = (const float*)d_in[1];
  const float* w_qkv  = (const float*)d_in[2];
  const float* k_pos  = (const float*)d_in[3];
  const float* v_pos  = (const float*)d_in[4];
  const float* mem_kv = (const float*)d_in[5];
  const float* k_w1   = (const float*)d_in[6];
  const float* k_b1   = (const float*)d_in[7];
  const float* k_w2   = (const float*)d_in[8];
  const float* k_b2   = (const float*)d_in[9];
  const float* v_w1   = (const float*)d_in[10];
  const float* v_b1   = (const float*)d_in[11];
  const float* v_w2   = (const float*)d_in[12];
  const float* v_b2   = (const float*)d_in[13];
  const float* w_comb = (const float*)d_in[14];
  const float* b_comb = (const float*)d_in[15];
  const float* w_out  = (const float*)d_in[16];
  float* out = (float*)d_out;
  char* wsb = (char*)d_ws;

  bf16* WQKV_H = (bf16*)(wsb + B_WQKV_H);
  bf16* WQKV_L = (bf16*)(wsb + B_WQKV_L);
  bf16* KW1_H  = (bf16*)(wsb + B_KW1_H);
  bf16* KW1_L  = (bf16*)(wsb + B_KW1_L);
  bf16* KW2_H  = (bf16*)(wsb + B_KW2_H);
  bf16* KW2_L  = (bf16*)(wsb + B_KW2_L);
  bf16* VW1_H  = (bf16*)(wsb + B_VW1_H);
  bf16* VW2_H  = (bf16*)(wsb + B_VW2_H);
  bf16* WOUT_H = (bf16*)(wsb + B_WOUT_H);
  bf16* HB_H   = (bf16*)(wsb + B_HB_H);
  bf16* HB_L   = (bf16*)(wsb + B_HB_L);
  bf16* QBH    = (bf16*)(wsb + B_QBH);
  bf16* QBM    = (bf16*)(wsb + B_QBM);
  bf16* QBL    = (bf16*)(wsb + B_QBL);
  float* KF    = (float*)(wsb + B_KF);
  bf16* VBH    = (bf16*)(wsb + B_VBH);
  bf16* RQH    = (bf16*)(wsb + B_RQH);
  bf16* RQL    = (bf16*)(wsb + B_RQL);
  bf16* RKH    = (bf16*)(wsb + B_RKH);
  bf16* RKL    = (bf16*)(wsb + B_RKL);
  float* RKF   = (float*)(wsb + B_RKF);
  bf16* VTB    = (bf16*)(wsb + B_VTB);
  bf16* CKT_H  = (bf16*)(wsb + B_CKT_H);
  bf16* CKT_M  = (bf16*)(wsb + B_CKT_M);
  bf16* CKT_L  = (bf16*)(wsb + B_CKT_L);
  bf16* CVT    = (bf16*)(wsb + B_CVT);
  int*   SEL   = (int*)(wsb + B_SEL);
  float* COUT  = (float*)(wsb + B_COUT);
  float* FOUT  = (float*)(wsb + B_FOUT);
  float* SOUT  = (float*)(wsb + B_SOUT);
  bf16* KW_H   = (bf16*)(wsb + B_KW_H);
  bf16* KW_L   = (bf16*)(wsb + B_KW_L);
  bf16* VW_H   = (bf16*)(wsb + B_VW_H);
  bf16* HID_H  = (bf16*)(wsb + B_HID_H);
  bf16* HID_L  = (bf16*)(wsb + B_HID_L);
  bf16* HIDV   = (bf16*)(wsb + B_HIDV);
  bf16* COMBB  = (bf16*)(wsb + B_COMBB);

  // 1. setup: weight splits + pads + mem fill + rmsnorm
  k_setup<<<5378, 256, 0, stream>>>(x, g_norm, w_qkv, k_w1, k_w2, v_w1, v_w2, w_out, mem_kv,
                                    WQKV_H, WQKV_L, KW1_H, KW1_L, KW2_H, KW2_L,
                                    VW1_H, VW2_H, WOUT_H, HB_H, HB_L,
                                    RKH, RKL, VTB, CKT_H, CKT_M, CKT_L, CVT);
  // 2. qkv (compensated, pipelined 32x32/wave, 768 blocks) with fused split/scatter
  k_qkv<<<dim3(24, 32), 256, 0, stream>>>(HB_H, HB_L, WQKV_H, WQKV_L, KF, QBH, QBM, QBL, VBH);
  // 3. post: rope + v-transpose + windows
  k_post<<<10432, 256, 0, stream>>>(QBH, QBM, QBL, KF, VBH, k_pos, v_pos,
                                    RQH, RQL, RKH, RKL, RKF, VTB, KW_H, KW_L, VW_H);
  // 4. merged MLP1, balanced 640-block hybrid grid; HIDV overlays dead KF
  k_mlp1<<<640, 256, 0, stream>>>(KW_H, KW_L, KW1_H, KW1_L, k_b1,
                                  VW_H, VW1_H, v_b1, HID_H, HID_L, HIDV);
  // 5. merged MLP2 -> ckT hi/mid/lo + cvT
  k_mlp2<<<dim3(1, 32, 2), 256, 0, stream>>>(HID_H, HID_L, KW2_H, KW2_L, k_b2,
                                             HIDV, VW2_H, v_b2, CKT_H, CKT_M, CKT_L, CVT);
  // 6-8. attention branches
  k_comp_attn<<<dim3(64, 8), 256, 0, stream>>>(QBH, QBM, QBL, CKT_H, CKT_M, CKT_L, CVT, COUT, SEL);
  k_fine_attn<<<dim3(512, 8), 256, 0, stream>>>(RQH, RQL, RKF, VBH, SEL, FOUT);
  k_slide_attn<<<dim3(32, 8), 256, 0, stream>>>(RQH, RQL, RKH, RKL, VTB, SOUT);
  // 9. fused strat + combine
  k_combine2<<<NTOK, 256, 0, stream>>>(HB_H, HB_L, w_comb, b_comb, COUT, FOUT, SOUT, COMBB);
  // 10. output projection (pipelined 32 core)
  k_cgemm<0, 0><<<dim3(8, 32), 256, 0, stream>>>(
      COMBB, nullptr, WOUT_H, nullptr, nullptr, out, NTOK, DMODEL, DMODEL);
}

// Round 12
// 254.489 us; speedup vs baseline: 1.2038x; 1.2038x over previous
//
#include <hip/hip_runtime.h>
#include <hip/hip_bf16.h>
#include <cstddef>

#define NTOK 2048
#define DMODEL 512
#define NHEAD 8
#define DHEAD 64
#define NWIN 254          // (2048-16)/8 + 1
#define CDIM 1024         // CB*DH
#define NEGV -1000000000.0f

typedef __attribute__((ext_vector_type(8))) __bf16 bf16x8;
typedef __attribute__((ext_vector_type(4))) float f32x4;
typedef __hip_bfloat16 bf16;

// ---------------- workspace layout (byte offsets) ----------------
static const size_t B_WQKV_H = 0;          // 1536*512*2
static const size_t B_WQKV_L = 1572864;
static const size_t B_KW1_H  = 3145728;    // 1024*1024*2
static const size_t B_KW1_L  = 5242880;
static const size_t B_KW2_H  = 7340032;    // 64*1024*2
static const size_t B_KW2_L  = 7471104;
static const size_t B_VW1_H  = 7602176;
static const size_t B_VW2_H  = 9699328;
static const size_t B_WOUT_H = 9830400;    // 512*512*2
static const size_t B_HB_H   = 10354688;   // 2048*512*2
static const size_t B_HB_L   = 12451840;
static const size_t B_QBH    = 14548992;   // 8*2048*64*2 (non-roped q, hi)
static const size_t B_QBL    = 16646144;   // (lo, 3rd term)
static const size_t B_KF     = 18743296;   // 8*2048*64*4 (k fp32; dead after k_post -> HIDV)
static const size_t B_VBH    = 22937600;   // 8*2048*64*2
static const size_t B_RQH    = 25034752;   // roped q hi/lo
static const size_t B_RQL    = 27131904;
static const size_t B_RKH    = 29229056;   // 8*2112*64*2 (roped k, 64 zero-pad rows front)
static const size_t B_RKL    = 31391744;
static const size_t B_VTB    = 33554432;   // 8*64*2112*2 (v^T, 64 zero-pad cols front)
static const size_t B_CKT_H  = 35717120;   // 8*256*64*2 (compressed k rows, j=0 mem)
static const size_t B_CKT_L  = 35979264;
static const size_t B_CVT    = 36241408;   // 8*64*256*2 (compressed v transposed)
static const size_t B_SEL    = 36700160;   // 8*2048*5*4
static const size_t B_COUT   = 37027840;   // 4194304 (overlays KW_H)
static const size_t B_FOUT   = 41222144;   // 4194304 (overlays KW_L)
static const size_t B_SOUT   = 45416448;   // 4194304 (overlays VW_H)
static const size_t B_KW_H   = B_COUT;     // 2032*1024*2 = 4161536
static const size_t B_KW_L   = B_FOUT;
static const size_t B_VW_H   = B_SOUT;
static const size_t B_HID_H  = 49610752;   // 4161536 (k hidden hi)
static const size_t B_HID_L  = 53772288;   // 4161536 (k hidden lo)
static const size_t B_QBM    = 57933824;   // 8*2048*64*2 (q mid term)
static const size_t B_CKT_M  = 60030976;   // 8*256*64*2
static const size_t B_RKF    = 60293120;   // 8*2048*64*4 (roped k fp32); end 64487424
static const size_t B_HIDV   = B_KF;       // v hidden hi (4161536 <= 4194304, KF dead)
static const size_t B_COMBB  = B_HID_H;    // 2097152 (after MLPs dead)

// ================= 32x32-per-wave GEMM core (64x64 block tile) =================
template <int COMP>
__device__ __forceinline__ void gemm_tile(
    const bf16* __restrict__ Ah, const bf16* __restrict__ Al,
    const bf16* __restrict__ Wh, const bf16* __restrict__ Wl,
    int M, int K, int row_base, int col_base, int lr, int kg,
    f32x4 accs[2][2]) {
  int ar0 = row_base + lr;       if (ar0 > M - 1) ar0 = M - 1;
  int ar1 = row_base + 16 + lr;  if (ar1 > M - 1) ar1 = M - 1;
  const size_t a0o = (size_t)ar0 * K + kg;
  const size_t a1o = (size_t)ar1 * K + kg;
  const size_t b0o = (size_t)(col_base + lr) * K + kg;
  const size_t b1o = (size_t)(col_base + 16 + lr) * K + kg;
  f32x4 acc00 = {}, acc01 = {}, acc10 = {}, acc11 = {};
  for (int k0 = 0; k0 < K; k0 += 32) {
    bf16x8 ah0 = *reinterpret_cast<const bf16x8*>(Ah + a0o + k0);
    bf16x8 ah1 = *reinterpret_cast<const bf16x8*>(Ah + a1o + k0);
    bf16x8 bh0 = *reinterpret_cast<const bf16x8*>(Wh + b0o + k0);
    bf16x8 bh1 = *reinterpret_cast<const bf16x8*>(Wh + b1o + k0);
    acc00 = __builtin_amdgcn_mfma_f32_16x16x32_bf16(ah0, bh0, acc00, 0, 0, 0);
    acc01 = __builtin_amdgcn_mfma_f32_16x16x32_bf16(ah0, bh1, acc01, 0, 0, 0);
    acc10 = __builtin_amdgcn_mfma_f32_16x16x32_bf16(ah1, bh0, acc10, 0, 0, 0);
    acc11 = __builtin_amdgcn_mfma_f32_16x16x32_bf16(ah1, bh1, acc11, 0, 0, 0);
    if constexpr (COMP) {
      bf16x8 al0 = *reinterpret_cast<const bf16x8*>(Al + a0o + k0);
      bf16x8 al1 = *reinterpret_cast<const bf16x8*>(Al + a1o + k0);
      bf16x8 bl0 = *reinterpret_cast<const bf16x8*>(Wl + b0o + k0);
      bf16x8 bl1 = *reinterpret_cast<const bf16x8*>(Wl + b1o + k0);
      acc00 = __builtin_amdgcn_mfma_f32_16x16x32_bf16(ah0, bl0, acc00, 0, 0, 0);
      acc01 = __builtin_amdgcn_mfma_f32_16x16x32_bf16(ah0, bl1, acc01, 0, 0, 0);
      acc10 = __builtin_amdgcn_mfma_f32_16x16x32_bf16(ah1, bl0, acc10, 0, 0, 0);
      acc11 = __builtin_amdgcn_mfma_f32_16x16x32_bf16(ah1, bl1, acc11, 0, 0, 0);
      acc00 = __builtin_amdgcn_mfma_f32_16x16x32_bf16(al0, bh0, acc00, 0, 0, 0);
      acc01 = __builtin_amdgcn_mfma_f32_16x16x32_bf16(al0, bh1, acc01, 0, 0, 0);
      acc10 = __builtin_amdgcn_mfma_f32_16x16x32_bf16(al1, bh0, acc10, 0, 0, 0);
      acc11 = __builtin_amdgcn_mfma_f32_16x16x32_bf16(al1, bh1, acc11, 0, 0, 0);
    }
  }
  accs[0][0] = acc00; accs[0][1] = acc01; accs[1][0] = acc10; accs[1][1] = acc11;
}

// ================= 64x64-per-wave core, register double-buffered (qkv) =================
template <int COMP>
__device__ __forceinline__ void gemm_tile64(
    const bf16* __restrict__ Ah, const bf16* __restrict__ Al,
    const bf16* __restrict__ Wh, const bf16* __restrict__ Wl,
    int M, int K, int row_base, int col_base, int lr, int kg,
    f32x4 (&acc)[4][4]) {
  size_t ao[4], bo[4];
#pragma unroll
  for (int mi = 0; mi < 4; ++mi) {
    int r = row_base + mi * 16 + lr; if (r > M - 1) r = M - 1;
    ao[mi] = (size_t)r * K + kg;
  }
#pragma unroll
  for (int ni = 0; ni < 4; ++ni)
    bo[ni] = (size_t)(col_base + ni * 16 + lr) * K + kg;

  bf16x8 a0[4], b0[4], a1[4], b1[4];
  bf16x8 c0[4], d0[4], c1[4], d1[4];
#pragma unroll
  for (int i = 0; i < 4; ++i) {
    a0[i] = *reinterpret_cast<const bf16x8*>(Ah + ao[i]);
    b0[i] = *reinterpret_cast<const bf16x8*>(Wh + bo[i]);
    if constexpr (COMP) {
      c0[i] = *reinterpret_cast<const bf16x8*>(Al + ao[i]);
      d0[i] = *reinterpret_cast<const bf16x8*>(Wl + bo[i]);
    }
  }
  for (int k0 = 0; k0 < K; k0 += 64) {
#pragma unroll
    for (int i = 0; i < 4; ++i) {
      a1[i] = *reinterpret_cast<const bf16x8*>(Ah + ao[i] + k0 + 32);
      b1[i] = *reinterpret_cast<const bf16x8*>(Wh + bo[i] + k0 + 32);
      if constexpr (COMP) {
        c1[i] = *reinterpret_cast<const bf16x8*>(Al + ao[i] + k0 + 32);
        d1[i] = *reinterpret_cast<const bf16x8*>(Wl + bo[i] + k0 + 32);
      }
    }
#pragma unroll
    for (int mi = 0; mi < 4; ++mi)
#pragma unroll
      for (int ni = 0; ni < 4; ++ni)
        acc[mi][ni] = __builtin_amdgcn_mfma_f32_16x16x32_bf16(a0[mi], b0[ni], acc[mi][ni], 0, 0, 0);
    if constexpr (COMP) {
#pragma unroll
      for (int mi = 0; mi < 4; ++mi)
#pragma unroll
        for (int ni = 0; ni < 4; ++ni) {
          acc[mi][ni] = __builtin_amdgcn_mfma_f32_16x16x32_bf16(a0[mi], d0[ni], acc[mi][ni], 0, 0, 0);
          acc[mi][ni] = __builtin_amdgcn_mfma_f32_16x16x32_bf16(c0[mi], b0[ni], acc[mi][ni], 0, 0, 0);
        }
    }
    if (k0 + 64 < K) {
#pragma unroll
      for (int i = 0; i < 4; ++i) {
        a0[i] = *reinterpret_cast<const bf16x8*>(Ah + ao[i] + k0 + 64);
        b0[i] = *reinterpret_cast<const bf16x8*>(Wh + bo[i] + k0 + 64);
        if constexpr (COMP) {
          c0[i] = *reinterpret_cast<const bf16x8*>(Al + ao[i] + k0 + 64);
          d0[i] = *reinterpret_cast<const bf16x8*>(Wl + bo[i] + k0 + 64);
        }
      }
    }
#pragma unroll
    for (int mi = 0; mi < 4; ++mi)
#pragma unroll
      for (int ni = 0; ni < 4; ++ni)
        acc[mi][ni] = __builtin_amdgcn_mfma_f32_16x16x32_bf16(a1[mi], b1[ni], acc[mi][ni], 0, 0, 0);
    if constexpr (COMP) {
#pragma unroll
      for (int mi = 0; mi < 4; ++mi)
#pragma unroll
        for (int ni = 0; ni < 4; ++ni) {
          acc[mi][ni] = __builtin_amdgcn_mfma_f32_16x16x32_bf16(a1[mi], d1[ni], acc[mi][ni], 0, 0, 0);
          acc[mi][ni] = __builtin_amdgcn_mfma_f32_16x16x32_bf16(c1[mi], b1[ni], acc[mi][ni], 0, 0, 0);
        }
    }
  }
}

// ---------------- generic GEMM kernel (fp32 out; out-proj) ----------------
template <int EPI, int COMP>
__global__ __launch_bounds__(256) void k_cgemm(
    const bf16* __restrict__ Ah, const bf16* __restrict__ Al,
    const bf16* __restrict__ Wh, const bf16* __restrict__ Wl,
    const float* __restrict__ bias, float* __restrict__ Cf,
    int M, int K, int N) {
  const int lane = threadIdx.x & 63;
  const int w = threadIdx.x >> 6;
  const int wr = w >> 1, wc = w & 1;
  const int row_base = (blockIdx.y << 6) + (wr << 5);
  const int col_base = (blockIdx.x << 6) + (wc << 5);
  const int lr = lane & 15;
  const int kg = (lane >> 4) << 3;
  const int crow = (lane >> 4) << 2;

  f32x4 accs[2][2];
  gemm_tile<COMP>(Ah, Al, Wh, Wl, M, K, row_base, col_base, lr, kg, accs);

#pragma unroll
  for (int mi = 0; mi < 2; ++mi) {
#pragma unroll
    for (int ni = 0; ni < 2; ++ni) {
      int col = col_base + (ni << 4) + lr;
      float bv = bias ? bias[col] : 0.f;
#pragma unroll
      for (int r = 0; r < 4; ++r) {
        int row = row_base + (mi << 4) + crow + r;
        if (row < M) {
          float vv = accs[mi][ni][r] + bv;
          if (EPI == 1) vv = fmaxf(vv, 0.f);
          Cf[(size_t)row * N + col] = vv;
        }
      }
    }
  }
}

// ---------------- qkv GEMM (64x64/wave pipelined, compensated, fused split/scatter) ----------------
__global__ __launch_bounds__(256, 1) void k_qkv(
    const bf16* __restrict__ Ah, const bf16* __restrict__ Al,
    const bf16* __restrict__ Wh, const bf16* __restrict__ Wl,
    float* __restrict__ KFo, bf16* __restrict__ QH, bf16* __restrict__ QM,
    bf16* __restrict__ QL, bf16* __restrict__ VB) {
  const int lane = threadIdx.x & 63;
  const int w = threadIdx.x >> 6;
  const int wr = w >> 1, wc = w & 1;
  const int row_base = (blockIdx.y << 7) + (wr << 6);
  const int col_base = (blockIdx.x << 7) + (wc << 6);
  const int lr = lane & 15;
  const int kg = (lane >> 4) << 3;
  const int crow = (lane >> 4) << 2;

  f32x4 acc[4][4];
#pragma unroll
  for (int a = 0; a < 4; ++a)
#pragma unroll
    for (int b = 0; b < 4; ++b) acc[a][b] = (f32x4){0.f, 0.f, 0.f, 0.f};
  gemm_tile64<1>(Ah, Al, Wh, Wl, NTOK, DMODEL, row_base, col_base, lr, kg, acc);

#pragma unroll
  for (int mi = 0; mi < 4; ++mi) {
#pragma unroll
    for (int ni = 0; ni < 4; ++ni) {
      int col = col_base + (ni << 4) + lr;
      int which = col >> 9, rem = col & 511;
      int hh = rem >> 6, dd = rem & 63;
#pragma unroll
      for (int r = 0; r < 4; ++r) {
        int row = row_base + (mi << 4) + crow + r;   // M=2048 exact, no guard
        float vv = acc[mi][ni][r];
        size_t o = ((size_t)hh * NTOK + row) * DHEAD + dd;
        if (which == 0) {
          bf16 h1 = __float2bfloat16(vv);
          float r1 = vv - __bfloat162float(h1);
          bf16 m1 = __float2bfloat16(r1);
          QH[o] = h1;
          QM[o] = m1;
          QL[o] = __float2bfloat16(r1 - __bfloat162float(m1));
        } else if (which == 1) {
          KFo[o] = vv;
        } else {
          VB[o] = __float2bfloat16(vv);
        }
      }
    }
  }
}

// ---------------- merged MLP1, LDS-staged (128x64 tile, BK=32, padded LDS) ----------------
// Hybrid 1D grid: id<256 = k-path (compensated, hi/lo out); id>=256 = v-path (plain).
// 4 waves (2x2): wave tile 64x32 (4x2 frags). LDS stride 40 elems (80B -> <=2-way banks).
// Per-acc MFMA order per k0: hh, hl, lh  -- bit-identical to gemm_tile/gemm_tile64.
#define LDP 40
__global__ __launch_bounds__(256, 2) void k_mlp1(
    const bf16* __restrict__ KWh, const bf16* __restrict__ KWl,
    const bf16* __restrict__ W1h, const bf16* __restrict__ W1l,
    const float* __restrict__ kb1,
    const bf16* __restrict__ VWh, const bf16* __restrict__ VW1h,
    const float* __restrict__ vb1,
    bf16* __restrict__ HKh, bf16* __restrict__ HKl, bf16* __restrict__ HVh) {
  __shared__ bf16 sAh[128 * LDP];
  __shared__ bf16 sAl[128 * LDP];
  __shared__ bf16 sBh[64 * LDP];
  __shared__ bf16 sBl[64 * LDP];

  const int t = threadIdx.x;
  const int lane = t & 63, w = t >> 6;
  const int wr = w >> 1, wc = w & 1;
  const int lr = lane & 15;
  const int kg = (lane >> 4) << 3;
  const int crow = (lane >> 4) << 2;
  const int M = NHEAD * NWIN;  // 2032
  const int id = blockIdx.x;
  const bool kpath = (id < 256);
  const int u = kpath ? id : id - 256;
  const int row0 = (u >> 4) << 7;   // 16 row-tiles of 128
  const int col0 = (u & 15) << 6;   // 16 col-tiles of 64

  const bf16* Ah = kpath ? KWh : VWh;
  const bf16* Bh = kpath ? W1h : VW1h;

  // staging coords (A: 2 chunks/thread; B: 1 chunk/thread)
  const int ra0 = t >> 1;                 // A chunk 0: rows 0..127, sub = (t&1)*? -- use q scheme
  // A-tile: 512 chunks of 16B; q = t and t+256; row=q>>2, sub=q&3
  const int qa0 = t,        ar0s = qa0 >> 2, as0 = qa0 & 3;
  const int qa1 = t + 256,  ar1s = qa1 >> 2, as1 = qa1 & 3;
  int gr0 = row0 + ar0s; if (gr0 > M - 1) gr0 = M - 1;
  int gr1 = row0 + ar1s; if (gr1 > M - 1) gr1 = M - 1;
  const int br = t >> 2, bs = t & 3;      // B-tile: 256 chunks; rows 0..63
  const int gbr = col0 + br;              // always < 1024

  f32x4 acc[4][2];
#pragma unroll
  for (int a = 0; a < 4; ++a)
#pragma unroll
    for (int b = 0; b < 2; ++b) acc[a][b] = (f32x4){0.f, 0.f, 0.f, 0.f};

  for (int k0 = 0; k0 < CDIM; k0 += 32) {
    // ---- stage tiles
    *reinterpret_cast<bf16x8*>(&sAh[ar0s * LDP + as0 * 8]) =
        *reinterpret_cast<const bf16x8*>(Ah + (size_t)gr0 * CDIM + k0 + as0 * 8);
    *reinterpret_cast<bf16x8*>(&sAh[ar1s * LDP + as1 * 8]) =
        *reinterpret_cast<const bf16x8*>(Ah + (size_t)gr1 * CDIM + k0 + as1 * 8);
    *reinterpret_cast<bf16x8*>(&sBh[br * LDP + bs * 8]) =
        *reinterpret_cast<const bf16x8*>(Bh + (size_t)gbr * CDIM + k0 + bs * 8);
    if (kpath) {
      *reinterpret_cast<bf16x8*>(&sAl[ar0s * LDP + as0 * 8]) =
          *reinterpret_cast<const bf16x8*>(KWl + (size_t)gr0 * CDIM + k0 + as0 * 8);
      *reinterpret_cast<bf16x8*>(&sAl[ar1s * LDP + as1 * 8]) =
          *reinterpret_cast<const bf16x8*>(KWl + (size_t)gr1 * CDIM + k0 + as1 * 8);
      *reinterpret_cast<bf16x8*>(&sBl[br * LDP + bs * 8]) =
          *reinterpret_cast<const bf16x8*>(W1l + (size_t)gbr * CDIM + k0 + bs * 8);
    }
    __syncthreads();

    // ---- fragments from LDS
    bf16x8 fAh[4], fBh[2], fAl[4], fBl[2];
#pragma unroll
    for (int mi = 0; mi < 4; ++mi)
      fAh[mi] = *reinterpret_cast<const bf16x8*>(&sAh[(wr * 64 + mi * 16 + lr) * LDP + kg]);
#pragma unroll
    for (int ni = 0; ni < 2; ++ni)
      fBh[ni] = *reinterpret_cast<const bf16x8*>(&sBh[(wc * 32 + ni * 16 + lr) * LDP + kg]);
    if (kpath) {
#pragma unroll
      for (int mi = 0; mi < 4; ++mi)
        fAl[mi] = *reinterpret_cast<const bf16x8*>(&sAl[(wr * 64 + mi * 16 + lr) * LDP + kg]);
#pragma unroll
      for (int ni = 0; ni < 2; ++ni)
        fBl[ni] = *reinterpret_cast<const bf16x8*>(&sBl[(wc * 32 + ni * 16 + lr) * LDP + kg]);
    }

    // ---- MFMAs: hh for all accs, then (hl, lh) per acc -- preserves per-acc order
#pragma unroll
    for (int mi = 0; mi < 4; ++mi)
#pragma unroll
      for (int ni = 0; ni < 2; ++ni)
        acc[mi][ni] = __builtin_amdgcn_mfma_f32_16x16x32_bf16(fAh[mi], fBh[ni], acc[mi][ni], 0, 0, 0);
    if (kpath) {
#pragma unroll
      for (int mi = 0; mi < 4; ++mi)
#pragma unroll
        for (int ni = 0; ni < 2; ++ni) {
          acc[mi][ni] = __builtin_amdgcn_mfma_f32_16x16x32_bf16(fAh[mi], fBl[ni], acc[mi][ni], 0, 0, 0);
          acc[mi][ni] = __builtin_amdgcn_mfma_f32_16x16x32_bf16(fAl[mi], fBh[ni], acc[mi][ni], 0, 0, 0);
        }
    }
    __syncthreads();
  }

  // ---- epilogue
#pragma unroll
  for (int mi = 0; mi < 4; ++mi) {
#pragma unroll
    for (int ni = 0; ni < 2; ++ni) {
      int col = col0 + wc * 32 + ni * 16 + lr;
      float bv = kpath ? kb1[col] : vb1[col];
#pragma unroll
      for (int r = 0; r < 4; ++r) {
        int row = row0 + wr * 64 + mi * 16 + crow + r;
        if (row < M) {
          float vv = fmaxf(acc[mi][ni][r] + bv, 0.f);
          size_t o = (size_t)row * CDIM + col;
          if (kpath) {
            bf16 h1 = __float2bfloat16(vv);
            HKh[o] = h1;
            HKl[o] = __float2bfloat16(vv - __bfloat162float(h1));
          } else {
            HVh[o] = __float2bfloat16(vv);
          }
        }
      }
    }
  }
}

// ---------------- merged MLP2: z=0 k-path -> ckT hi/mid/lo, z=1 v-path -> cvT ----------------
__global__ __launch_bounds__(256) void k_mlp2(
    const bf16* __restrict__ HKh, const bf16* __restrict__ HKl,
    const bf16* __restrict__ W2h, const bf16* __restrict__ W2l,
    const float* __restrict__ kb2,
    const bf16* __restrict__ HVh, const bf16* __restrict__ VW2h,
    const float* __restrict__ vb2,
    bf16* __restrict__ ckh, bf16* __restrict__ ckm, bf16* __restrict__ ckl,
    bf16* __restrict__ cvtb) {
  const int lane = threadIdx.x & 63;
  const int w = threadIdx.x >> 6;
  const int wr = w >> 1, wc = w & 1;
  const int row_base = (blockIdx.y << 6) + (wr << 5);
  const int col_base = (wc << 5);
  const int lr = lane & 15;
  const int kg = (lane >> 4) << 3;
  const int crow = (lane >> 4) << 2;
  const int M = NHEAD * NWIN;

  f32x4 accs[2][2];
  if (blockIdx.z == 0)
    gemm_tile<1>(HKh, HKl, W2h, W2l, M, CDIM, row_base, col_base, lr, kg, accs);
  else
    gemm_tile<0>(HVh, nullptr, VW2h, nullptr, M, CDIM, row_base, col_base, lr, kg, accs);

  const float* bias = (blockIdx.z == 0) ? kb2 : vb2;
#pragma unroll
  for (int mi = 0; mi < 2; ++mi) {
#pragma unroll
    for (int ni = 0; ni < 2; ++ni) {
      int col = col_base + (ni << 4) + lr;
      float bv = bias[col];
#pragma unroll
      for (int r = 0; r < 4; ++r) {
        int row = row_base + (mi << 4) + crow + r;
        if (row < M) {
          float vv = accs[mi][ni][r] + bv;
          int hh = row / NWIN, jj = row - hh * NWIN;
          if (blockIdx.z == 0) {
            size_t o = ((size_t)hh * 256 + 1 + jj) * 64 + col;
            bf16 h1 = __float2bfloat16(vv);
            float r1 = vv - __bfloat162float(h1);
            bf16 m1 = __float2bfloat16(r1);
            ckh[o] = h1;
            ckm[o] = m1;
            ckl[o] = __float2bfloat16(r1 - __bfloat162float(m1));
          } else {
            cvtb[((size_t)hh * 64 + col) * 256 + 1 + jj] = __float2bfloat16(vv);
          }
        }
      }
    }
  }
}

// ================= k_setup: 6 weight transposes + zpad + fillmem + rmsnorm =================
__device__ __forceinline__ void wt_tile(const float* __restrict__ W,
                                        bf16* __restrict__ WTh, bf16* __restrict__ WTl,
                                        int K, int N, int bx, int by,
                                        float (*tsh)[33]) {
  const int k0 = bx << 5, n0 = by << 5;
  const int tx = threadIdx.x & 31, ty = threadIdx.x >> 5;
#pragma unroll
  for (int r = 0; r < 4; ++r)
    tsh[ty + (r << 3)][tx] = W[(size_t)(k0 + ty + (r << 3)) * N + n0 + tx];
  __syncthreads();
#pragma unroll
  for (int r = 0; r < 4; ++r) {
    float val = tsh[tx][ty + (r << 3)];
    size_t o = (size_t)(n0 + ty + (r << 3)) * K + k0 + tx;
    bf16 h1 = __float2bfloat16(val);
    WTh[o] = h1;
    if (WTl) WTl[o] = __float2bfloat16(val - __bfloat162float(h1));
  }
}

__global__ __launch_bounds__(256) void k_setup(
    const float* __restrict__ x, const float* __restrict__ g,
    const float* __restrict__ w_qkv, const float* __restrict__ k_w1,
    const float* __restrict__ k_w2, const float* __restrict__ v_w1,
    const float* __restrict__ v_w2, const float* __restrict__ w_out,
    const float* __restrict__ memkv,
    bf16* __restrict__ WQKV_H, bf16* __restrict__ WQKV_L,
    bf16* __restrict__ KW1_H, bf16* __restrict__ KW1_L,
    bf16* __restrict__ KW2_H, bf16* __restrict__ KW2_L,
    bf16* __restrict__ VW1_H, bf16* __restrict__ VW2_H, bf16* __restrict__ WOUT_H,
    bf16* __restrict__ hbh, bf16* __restrict__ hbl,
    bf16* __restrict__ rkh, bf16* __restrict__ rkl, bf16* __restrict__ vtb,
    bf16* __restrict__ ckh, bf16* __restrict__ ckm, bf16* __restrict__ ckl,
    bf16* __restrict__ cvtb) {
  __shared__ float tsh[32][33];
  __shared__ float wsum[4];
  __shared__ float scale_s;
  const int id = blockIdx.x;
  const int t = threadIdx.x;

  if (id < 768) {
    wt_tile(w_qkv, WQKV_H, WQKV_L, DMODEL, 1536, id % 16, id / 16, tsh);
  } else if (id < 1792) {
    int u = id - 768;  wt_tile(k_w1, KW1_H, KW1_L, CDIM, CDIM, u % 32, u / 32, tsh);
  } else if (id < 1856) {
    int u = id - 1792; wt_tile(k_w2, KW2_H, KW2_L, CDIM, DHEAD, u % 32, u / 32, tsh);
  } else if (id < 2880) {
    int u = id - 1856; wt_tile(v_w1, VW1_H, nullptr, CDIM, CDIM, u % 32, u / 32, tsh);
  } else if (id < 2944) {
    int u = id - 2880; wt_tile(v_w2, VW2_H, nullptr, CDIM, DHEAD, u % 32, u / 32, tsh);
  } else if (id < 3200) {
    int u = id - 2944; wt_tile(w_out, WOUT_H, nullptr, DMODEL, DMODEL, u % 16, u / 16, tsh);
  } else if (id < 3328) {
    int idx = (id - 3200) * 256 + t;   // [0, 32768)
    int h = idx >> 12, r = (idx >> 6) & 63, c = idx & 63;
    bf16 z = __float2bfloat16(0.f);
    rkh[((size_t)h * 2112 + r) * 64 + c] = z;
    rkl[((size_t)h * 2112 + r) * 64 + c] = z;
    vtb[((size_t)h * 64 + r) * 2112 + c] = z;
  } else if (id < 3330) {
    int u = (id - 3328) * 256 + t;     // [0, 512)
    if (u < 512) {
      int h = u >> 6, e = u & 63;
      float kv = memkv[(size_t)h * DHEAD + e];
      bf16 h1 = __float2bfloat16(kv);
      float r1 = kv - __bfloat162float(h1);
      bf16 m1 = __float2bfloat16(r1);
      ckh[((size_t)h * 256) * 64 + e] = h1;
      ckm[((size_t)h * 256) * 64 + e] = m1;
      ckl[((size_t)h * 256) * 64 + e] = __float2bfloat16(r1 - __bfloat162float(m1));
      bf16 z = __float2bfloat16(0.f);
      ckh[((size_t)h * 256 + 255) * 64 + e] = z;
      ckm[((size_t)h * 256 + 255) * 64 + e] = z;
      ckl[((size_t)h * 256 + 255) * 64 + e] = z;
      float vv = memkv[(size_t)(NHEAD + h) * DHEAD + e];
      cvtb[((size_t)h * 64 + e) * 256 + 0] = __float2bfloat16(vv);
      cvtb[((size_t)h * 64 + e) * 256 + 255] = z;
    }
  } else {
    const int row = id - 3330;
    const float* xr = x + (size_t)row * DMODEL;
    float s = 0.f;
    for (int c = t; c < DMODEL; c += 256) { float v = xr[c]; s += v * v; }
    for (int o = 32; o > 0; o >>= 1) s += __shfl_down(s, o);
    if ((t & 63) == 0) wsum[t >> 6] = s;
    __syncthreads();
    if (t == 0) {
      float tot = wsum[0] + wsum[1] + wsum[2] + wsum[3];
      scale_s = rsqrtf(tot * (1.f / DMODEL) + 1e-6f);
    }
    __syncthreads();
    float sc = scale_s;
    for (int c = t; c < DMODEL; c += 256) {
      float v = xr[c] * sc * g[c];
      bf16 h1 = __float2bfloat16(v);
      hbh[(size_t)row * DMODEL + c] = h1;
      hbl[(size_t)row * DMODEL + c] = __float2bfloat16(v - __bfloat162float(h1));
    }
  }
}

// ================= k_post: rope + v-transpose + compression windows =================
__global__ __launch_bounds__(256) void k_post(
    const bf16* __restrict__ qbh, const bf16* __restrict__ qbm,
    const bf16* __restrict__ qbl, const float* __restrict__ kf,
    const bf16* __restrict__ vbh,
    const float* __restrict__ kpos, const float* __restrict__ vpos,
    bf16* __restrict__ rqh, bf16* __restrict__ rql,
    bf16* __restrict__ rkh, bf16* __restrict__ rkl, float* __restrict__ rkf,
    bf16* __restrict__ vtb,
    bf16* __restrict__ kwh, bf16* __restrict__ kwl, bf16* __restrict__ vwh) {
  __shared__ bf16 tile[64][65];
  const int id = blockIdx.x;
  const int t = threadIdx.x;

  if (id < 2048) {
    int idx = id * 256 + t;
    int i = idx & 31;
    int n = (idx >> 5) & (NTOK - 1);
    int h = idx >> 16;
    float ex = (float)(2 * i) * (1.f / 64.f);
    float inv = exp2f(-ex * 13.287712379549449f);
    float ang = (float)n * inv;
    float sn, cs;
    sincosf(ang, &sn, &cs);
    size_t base = ((size_t)h * NTOK + n) * DHEAD + 2 * i;
    float q1 = __bfloat162float(qbh[base]) + __bfloat162float(qbm[base]) + __bfloat162float(qbl[base]);
    float q2 = __bfloat162float(qbh[base + 1]) + __bfloat162float(qbm[base + 1]) + __bfloat162float(qbl[base + 1]);
    float r1 = q1 * cs - q2 * sn, r2 = q1 * sn + q2 * cs;
    bf16 h1 = __float2bfloat16(r1);
    rqh[base] = h1; rql[base] = __float2bfloat16(r1 - __bfloat162float(h1));
    h1 = __float2bfloat16(r2);
    rqh[base + 1] = h1; rql[base + 1] = __float2bfloat16(r2 - __bfloat162float(h1));
    float k1 = kf[base], k2 = kf[base + 1];
    float s1 = k1 * cs - k2 * sn, s2 = k1 * sn + k2 * cs;
    rkf[base] = s1;
    rkf[base + 1] = s2;
    size_t kb = ((size_t)h * 2112 + 64 + n) * DHEAD + 2 * i;
    h1 = __float2bfloat16(s1);
    rkh[kb] = h1; rkl[kb] = __float2bfloat16(s1 - __bfloat162float(h1));
    h1 = __float2bfloat16(s2);
    rkh[kb + 1] = h1; rkl[kb + 1] = __float2bfloat16(s2 - __bfloat162float(h1));
  } else if (id < 2304) {
    int u = id - 2048;
    int h = u >> 5, n0 = (u & 31) << 6;
    int tx = t & 63, ty = t >> 6;
    for (int r = ty; r < 64; r += 4)
      tile[r][tx] = vbh[((size_t)h * NTOK + n0 + r) * DHEAD + tx];
    __syncthreads();
    for (int r = ty; r < 64; r += 4)
      vtb[((size_t)h * 64 + r) * 2112 + 64 + n0 + tx] = tile[tx][r];
  } else {
    int idx = (id - 2304) * 256 + t;   // [0, 2080768)
    int d = idx & 63;
    int c = (idx >> 6) & 15;
    int j = (idx >> 10) % NWIN;
    int h = idx / (NWIN << 10);
    int srcpos = (j << 3) + c;
    size_t src = ((size_t)h * NTOK + srcpos) * DHEAD + d;
    size_t pp = ((size_t)h * 16 + c) * DHEAD + d;
    float kv = kf[src] + kpos[pp];
    bf16 h1 = __float2bfloat16(kv);
    kwh[idx] = h1;
    kwl[idx] = __float2bfloat16(kv - __bfloat162float(h1));
    vwh[idx] = __float2bfloat16(__bfloat162float(vbh[src]) + vpos[pp]);
  }
}

// ---------------- compression attention (MFMA, 32 queries/block) ----------------
__global__ __launch_bounds__(256) void k_comp_attn(
    const bf16* __restrict__ qbh, const bf16* __restrict__ qbm, const bf16* __restrict__ qbl,
    const bf16* __restrict__ ckh, const bf16* __restrict__ ckm, const bf16* __restrict__ ckl,
    const bf16* __restrict__ cvtb,
    float* __restrict__ c_out, int* __restrict__ sel) {
  const int h = blockIdx.y;
  const int i0 = blockIdx.x << 5;
  const int t = threadIdx.x;
  const int w = t >> 6, lane = t & 63;
  const int lr = lane & 15, kg = (lane >> 4) << 3;
  const int crow = (lane >> 4) << 2;

  __shared__ float p[32][260];

  bf16x8 aH[2][2], aM[2][2], aL[2][2];
#pragma unroll
  for (int mi = 0; mi < 2; ++mi) {
    size_t qo = ((size_t)h * NTOK + i0 + mi * 16 + lr) * DHEAD + kg;
#pragma unroll
    for (int ks = 0; ks < 2; ++ks) {
      aH[mi][ks] = *reinterpret_cast<const bf16x8*>(qbh + qo + ks * 32);
      aM[mi][ks] = *reinterpret_cast<const bf16x8*>(qbm + qo + ks * 32);
      aL[mi][ks] = *reinterpret_cast<const bf16x8*>(qbl + qo + ks * 32);
    }
  }
  f32x4 acc[2][4];
#pragma unroll
  for (int a = 0; a < 2; ++a)
#pragma unroll
    for (int b = 0; b < 4; ++b) acc[a][b] = (f32x4){0.f, 0.f, 0.f, 0.f};
#pragma unroll
  for (int ni = 0; ni < 4; ++ni) {
    int col = (w << 6) + (ni << 4) + lr;
    size_t ko = ((size_t)h * 256 + col) * 64 + kg;
#pragma unroll
    for (int ks = 0; ks < 2; ++ks) {
      bf16x8 bH = *reinterpret_cast<const bf16x8*>(ckh + ko + ks * 32);
      bf16x8 bM = *reinterpret_cast<const bf16x8*>(ckm + ko + ks * 32);
      bf16x8 bL = *reinterpret_cast<const bf16x8*>(ckl + ko + ks * 32);
#pragma unroll
      for (int mi = 0; mi < 2; ++mi) {
        acc[mi][ni] = __builtin_amdgcn_mfma_f32_16x16x32_bf16(aH[mi][ks], bH, acc[mi][ni], 0, 0, 0);
        acc[mi][ni] = __builtin_amdgcn_mfma_f32_16x16x32_bf16(aH[mi][ks], bM, acc[mi][ni], 0, 0, 0);
        acc[mi][ni] = __builtin_amdgcn_mfma_f32_16x16x32_bf16(aM[mi][ks], bH, acc[mi][ni], 0, 0, 0);
        acc[mi][ni] = __builtin_amdgcn_mfma_f32_16x16x32_bf16(aH[mi][ks], bL, acc[mi][ni], 0, 0, 0);
        acc[mi][ni] = __builtin_amdgcn_mfma_f32_16x16x32_bf16(aL[mi][ks], bH, acc[mi][ni], 0, 0, 0);
        acc[mi][ni] = __builtin_amdgcn_mfma_f32_16x16x32_bf16(aM[mi][ks], bM, acc[mi][ni], 0, 0, 0);
      }
    }
  }
#pragma unroll
  for (int mi = 0; mi < 2; ++mi)
#pragma unroll
    for (int ni = 0; ni < 4; ++ni) {
      int col = (w << 6) + (ni << 4) + lr;
      int wend = (col == 0) ? -1 : ((col - 1) << 3) + 15;
#pragma unroll
      for (int r = 0; r < 4; ++r) {
        int qi = mi * 16 + crow + r;
        bool ok = (col < 255) && (wend < i0 + qi);
        p[qi][col] = ok ? acc[mi][ni][r] * 0.125f : NEGV;
      }
    }
  __syncthreads();

  const int qi = t >> 3, s = t & 7;
  float ev[32];
  float mx = -3.0e38f;
#pragma unroll
  for (int u = 0; u < 32; ++u) { ev[u] = p[qi][s + (u << 3)]; mx = fmaxf(mx, ev[u]); }
  mx = fmaxf(mx, __shfl_xor(mx, 1));
  mx = fmaxf(mx, __shfl_xor(mx, 2));
  mx = fmaxf(mx, __shfl_xor(mx, 4));
  float sum = 0.f;
#pragma unroll
  for (int u = 0; u < 32; ++u) { float e = __expf(ev[u] - mx); ev[u] = e; sum += e; }
  sum += __shfl_xor(sum, 1); sum += __shfl_xor(sum, 2); sum += __shfl_xor(sum, 4);
  float invs = 1.f / sum;
#pragma unroll
  for (int u = 0; u < 32; ++u) p[qi][s + (u << 3)] = ev[u] * invs;

  int qblk = (i0 + qi) >> 4;
  float vals[16];
#pragma unroll
  for (int u = 0; u < 16; ++u) {
    int f = (s << 4) + u;
    float v;
    if (f >= qblk || f == 127) v = NEGV;
    else v = (p[qi][2 * f + 1] + p[qi][2 * f + 2]) * 0.5f;
    vals[u] = v;
  }
  int base = ((h << 11) | (i0 + qi)) * 5;
  for (int kk = 0; kk < 4; ++kk) {
    float bv = -3.0e38f; int bi = 0;
#pragma unroll
    for (int u = 0; u < 16; ++u) {
      if (vals[u] > bv) { bv = vals[u]; bi = (s << 4) + u; }
    }
#pragma unroll
    for (int o = 1; o < 8; o <<= 1) {
      float ov = __shfl_xor(bv, o);
      int oi = __shfl_xor(bi, o);
      if (ov > bv || (ov == bv && oi < bi)) { bv = ov; bi = oi; }
    }
    if (s == 0) sel[base + kk] = (bv > -5.0e8f) ? bi : -1;
    if ((bi >> 4) == s) vals[bi & 15] = -3.0e38f;
  }
  if (s == 0) sel[base + 4] = (i0 + qi) >> 4;
  __syncthreads();

  const int wm = w >> 1, wn = w & 1;
  const int arow = wm * 16 + lr;
  f32x4 pacc[2];
#pragma unroll
  for (int b = 0; b < 2; ++b) pacc[b] = (f32x4){0.f, 0.f, 0.f, 0.f};
#pragma unroll
  for (int ks = 0; ks < 8; ++ks) {
    int k0 = ks * 32 + kg;
    float4 x0 = *reinterpret_cast<const float4*>(&p[arow][k0]);
    float4 x1 = *reinterpret_cast<const float4*>(&p[arow][k0 + 4]);
    float xv[8] = {x0.x, x0.y, x0.z, x0.w, x1.x, x1.y, x1.z, x1.w};
    bf16x8 ph, pl;
#pragma unroll
    for (int e = 0; e < 8; ++e) {
      __bf16 hh = (__bf16)xv[e];
      ph[e] = hh;
      pl[e] = (__bf16)(xv[e] - (float)hh);
    }
#pragma unroll
    for (int ni = 0; ni < 2; ++ni) {
      int d = (wn << 5) + (ni << 4) + lr;
      bf16x8 bv = *reinterpret_cast<const bf16x8*>(cvtb + ((size_t)h * 64 + d) * 256 + k0);
      pacc[ni] = __builtin_amdgcn_mfma_f32_16x16x32_bf16(ph, bv, pacc[ni], 0, 0, 0);
      pacc[ni] = __builtin_amdgcn_mfma_f32_16x16x32_bf16(pl, bv, pacc[ni], 0, 0, 0);
    }
  }
#pragma unroll
  for (int ni = 0; ni < 2; ++ni) {
    int d = (wn << 5) + (ni << 4) + lr;
#pragma unroll
    for (int r = 0; r < 4; ++r) {
      int q2 = wm * 16 + crow + r;
      c_out[((size_t)h * NTOK + i0 + q2) * DHEAD + d] = pacc[ni][r];
    }
  }
}

// ---------------- fine attention: 1 wave per query, fp32 K via float4 ----------------
__global__ __launch_bounds__(256) void k_fine_attn(
    const bf16* __restrict__ rqh, const bf16* __restrict__ rql,
    const float* __restrict__ rkf, const bf16* __restrict__ vbh,
    const int* __restrict__ sel, float* __restrict__ f_out) {
  const int h = blockIdx.y;
  const int wid = threadIdx.x >> 6;
  const int lane = threadIdx.x & 63;
  const int i = (blockIdx.x << 2) | wid;

  __shared__ float qs[4][64];
  __shared__ float pb[4][80];
  __shared__ int selb[4][5];

  size_t qoff = ((size_t)h * NTOK + i) * DHEAD + lane;
  qs[wid][lane] = __bfloat162float(rqh[qoff]) + __bfloat162float(rql[qoff]);
  if (lane < 5) selb[wid][lane] = sel[((h << 11) | i) * 5 + lane];
  __syncthreads();

  float sim0 = NEGV, sim1 = NEGV;
  {
    int kb = selb[wid][lane >> 4];
    int pos = (kb << 4) + (lane & 15);
    if (kb >= 0 && pos <= i) {
      const float* kp = rkf + ((size_t)h * NTOK + pos) * DHEAD;
      float d = 0.f;
#pragma unroll
      for (int e4 = 0; e4 < 16; ++e4) {
        float4 kv = *reinterpret_cast<const float4*>(kp + e4 * 4);
        d = fmaf(qs[wid][e4 * 4 + 0], kv.x, d);
        d = fmaf(qs[wid][e4 * 4 + 1], kv.y, d);
        d = fmaf(qs[wid][e4 * 4 + 2], kv.z, d);
        d = fmaf(qs[wid][e4 * 4 + 3], kv.w, d);
      }
      sim0 = d * 0.125f;
    }
  }
  if (lane < 16) {
    int kb = selb[wid][4];
    int pos = (kb << 4) + lane;
    if (pos <= i) {
      const float* kp = rkf + ((size_t)h * NTOK + pos) * DHEAD;
      float d = 0.f;
#pragma unroll
      for (int e4 = 0; e4 < 16; ++e4) {
        float4 kv = *reinterpret_cast<const float4*>(kp + e4 * 4);
        d = fmaf(qs[wid][e4 * 4 + 0], kv.x, d);
        d = fmaf(qs[wid][e4 * 4 + 1], kv.y, d);
        d = fmaf(qs[wid][e4 * 4 + 2], kv.z, d);
        d = fmaf(qs[wid][e4 * 4 + 3], kv.w, d);
      }
      sim1 = d * 0.125f;
    }
  }

  float mx = fmaxf(sim0, sim1);
#pragma unroll
  for (int o = 32; o > 0; o >>= 1) mx = fmaxf(mx, __shfl_xor(mx, o));
  float e0 = __expf(sim0 - mx);
  float e1 = __expf(sim1 - mx);
  float sum = e0 + e1;
#pragma unroll
  for (int o = 32; o > 0; o >>= 1) sum += __shfl_xor(sum, o);
  float invs = 1.f / sum;
  pb[wid][lane] = e0 * invs;
  if (lane < 16) pb[wid][64 + lane] = e1 * invs;

  float acc = 0.f;
#pragma unroll
  for (int b = 0; b < 5; ++b) {
    int kb = selb[wid][b];
    if (kb < 0) continue;
    const bf16* vr = vbh + ((size_t)h * NTOK + ((size_t)kb << 4)) * DHEAD + lane;
#pragma unroll
    for (int u = 0; u < 16; ++u)
      acc = fmaf(pb[wid][b * 16 + u], __bfloat162float(vr[(size_t)u * DHEAD]), acc);
  }
  f_out[((size_t)h * NTOK + i) * DHEAD + lane] = acc;
}

// ---------------- sliding-window attention (MFMA, 64 queries/block) ----------------
__global__ __launch_bounds__(256) void k_slide_attn(
    const bf16* __restrict__ rqh, const bf16* __restrict__ rql,
    const bf16* __restrict__ rkh, const bf16* __restrict__ rkl,
    const bf16* __restrict__ vtb, float* __restrict__ s_out) {
  const int h = blockIdx.y, nb = blockIdx.x;
  const int t = threadIdx.x, w = t >> 6, lane = t & 63;
  const int lr = lane & 15, kg = (lane >> 4) << 3;
  const int crow = (lane >> 4) << 2;
  const int wm = w >> 1, wn = w & 1;
  __shared__ float p[64][132];

  bf16x8 aH[2][2], aL[2][2];
#pragma unroll
  for (int mi = 0; mi < 2; ++mi) {
    size_t qo = ((size_t)h * NTOK + nb * 64 + wm * 32 + mi * 16 + lr) * DHEAD + kg;
#pragma unroll
    for (int ks = 0; ks < 2; ++ks) {
      aH[mi][ks] = *reinterpret_cast<const bf16x8*>(rqh + qo + ks * 32);
      aL[mi][ks] = *reinterpret_cast<const bf16x8*>(rql + qo + ks * 32);
    }
  }
  f32x4 acc[2][4];
#pragma unroll
  for (int a = 0; a < 2; ++a)
#pragma unroll
    for (int b = 0; b < 4; ++b) acc[a][b] = (f32x4){0.f, 0.f, 0.f, 0.f};
#pragma unroll
  for (int ni = 0; ni < 4; ++ni) {
    int col = (wn << 6) + (ni << 4) + lr;
    size_t ko = ((size_t)h * 2112 + nb * 64 + col) * 64 + kg;
#pragma unroll
    for (int ks = 0; ks < 2; ++ks) {
      bf16x8 bH = *reinterpret_cast<const bf16x8*>(rkh + ko + ks * 32);
      bf16x8 bL = *reinterpret_cast<const bf16x8*>(rkl + ko + ks * 32);
#pragma unroll
      for (int mi = 0; mi < 2; ++mi) {
        acc[mi][ni] = __builtin_amdgcn_mfma_f32_16x16x32_bf16(aH[mi][ks], bH, acc[mi][ni], 0, 0, 0);
        acc[mi][ni] = __builtin_amdgcn_mfma_f32_16x16x32_bf16(aL[mi][ks], bH, acc[mi][ni], 0, 0, 0);
        acc[mi][ni] = __builtin_amdgcn_mfma_f32_16x16x32_bf16(aH[mi][ks], bL, acc[mi][ni], 0, 0, 0);
      }
    }
  }
#pragma unroll
  for (int mi = 0; mi < 2; ++mi)
#pragma unroll
    for (int ni = 0; ni < 4; ++ni) {
      int col = (wn << 6) + (ni << 4) + lr;
#pragma unroll
      for (int r = 0; r < 4; ++r) {
        int qi2 = wm * 32 + mi * 16 + crow + r;
        bool ok = (col >= qi2 + 1) && (col <= qi2 + 64) && (nb > 0 || col >= 64);
        p[qi2][col] = ok ? acc[mi][ni][r] * 0.125f : NEGV;
      }
    }
  __syncthreads();

  const int qi = t >> 2, s = t & 3;
  float ev[32];
  float mx = -3.0e38f;
#pragma unroll
  for (int u = 0; u < 32; ++u) { ev[u] = p[qi][s + (u << 2)]; mx = fmaxf(mx, ev[u]); }
  mx = fmaxf(mx, __shfl_xor(mx, 1));
  mx = fmaxf(mx, __shfl_xor(mx, 2));
  float sum = 0.f;
#pragma unroll
  for (int u = 0; u < 32; ++u) { float e = __expf(ev[u] - mx); ev[u] = e; sum += e; }
  sum += __shfl_xor(sum, 1); sum += __shfl_xor(sum, 2);
  float invs = 1.f / sum;
#pragma unroll
  for (int u = 0; u < 32; ++u) p[qi][s + (u << 2)] = ev[u] * invs;
  __syncthreads();

  f32x4 pacc[2][2];
#pragma unroll
  for (int a = 0; a < 2; ++a)
#pragma unroll
    for (int b = 0; b < 2; ++b) pacc[a][b] = (f32x4){0.f, 0.f, 0.f, 0.f};
#pragma unroll
  for (int ks = 0; ks < 4; ++ks) {
    int k0 = ks * 32 + kg;
    bf16x8 ph[2], pl[2];
#pragma unroll
    for (int mi = 0; mi < 2; ++mi) {
      int arow = wm * 32 + mi * 16 + lr;
      float4 x0 = *reinterpret_cast<const float4*>(&p[arow][k0]);
      float4 x1 = *reinterpret_cast<const float4*>(&p[arow][k0 + 4]);
      float xv[8] = {x0.x, x0.y, x0.z, x0.w, x1.x, x1.y, x1.z, x1.w};
#pragma unroll
      for (int e = 0; e < 8; ++e) {
        __bf16 hh = (__bf16)xv[e];
        ph[mi][e] = hh;
        pl[mi][e] = (__bf16)(xv[e] - (float)hh);
      }
    }
#pragma unroll
    for (int ni = 0; ni < 2; ++ni) {
      int d = (wn << 5) + (ni << 4) + lr;
      bf16x8 bv = *reinterpret_cast<const bf16x8*>(vtb + ((size_t)h * 64 + d) * 2112 + nb * 64 + k0);
#pragma unroll
      for (int mi = 0; mi < 2; ++mi) {
        pacc[mi][ni] = __builtin_amdgcn_mfma_f32_16x16x32_bf16(ph[mi], bv, pacc[mi][ni], 0, 0, 0);
        pacc[mi][ni] = __builtin_amdgcn_mfma_f32_16x16x32_bf16(pl[mi], bv, pacc[mi][ni], 0, 0, 0);
      }
    }
  }
#pragma unroll
  for (int mi = 0; mi < 2; ++mi)
#pragma unroll
    for (int ni = 0; ni < 2; ++ni) {
      int d = (wn << 5) + (ni << 4) + lr;
#pragma unroll
      for (int r = 0; r < 4; ++r) {
        int qi2 = wm * 32 + mi * 16 + crow + r;
        s_out[((size_t)h * NTOK + nb * 64 + qi2) * DHEAD + d] = pacc[mi][ni][r];
      }
    }
}

// ---------------- fused strat + combine: one block per token ----------------
__global__ __launch_bounds__(256) void k_combine2(
    const bf16* __restrict__ Ah, const bf16* __restrict__ Al,
    const float* __restrict__ W, const float* __restrict__ bias,
    const float* __restrict__ c_out, const float* __restrict__ f_out,
    const float* __restrict__ s_out, bf16* __restrict__ comb) {
  const int i = blockIdx.x;
  const int t = threadIdx.x;
  __shared__ float hs[DMODEL];
  __shared__ float st[24];
  size_t ro = (size_t)i * DMODEL;
#pragma unroll
  for (int u = 0; u < 2; ++u) {
    int c = t + u * 256;
    hs[c] = __bfloat162float(Ah[ro + c]) + __bfloat162float(Al[ro + c]);
  }
  __syncthreads();
  if (t < 192) {
    int c = t >> 3, s = t & 7;
    float acc = 0.f;
    for (int u = 0; u < 64; ++u) {
      int e = s * 64 + u;
      acc = fmaf(hs[e], W[(size_t)e * 24 + c], acc);
    }
    acc += __shfl_xor(acc, 1);
    acc += __shfl_xor(acc, 2);
    acc += __shfl_xor(acc, 4);
    if (s == 0) st[c] = 1.f / (1.f + expf(-(acc + bias[c])));
  }
  __syncthreads();
#pragma unroll
  for (int u = 0; u < 2; ++u) {
    int c = t + u * 256;
    int h = c >> 6, d = c & 63;
    size_t a = ((size_t)h * NTOK + i) * DHEAD + d;
    comb[ro + c] = __float2bfloat16(st[h * 3] * c_out[a] + st[h * 3 + 1] * f_out[a]
                                    + st[h * 3 + 2] * s_out[a]);
  }
}

extern "C" void kernel_launch(void* const* d_in, const int* in_sizes, int n_in,
                              void* d_out, int out_size, void* d_ws, size_t ws_size,
                              hipStream_t stream) {
  const float* x      = (const float*)d_in[0];
  const float* g_norm = (const float*)d_in[1];
  const float* w_qkv  = (const float*)d_in[2];
  const float* k_pos  = (const float*)d_in[3];
  const float* v_pos  = (const float*)d_in[4];
  const float* mem_kv = (const float*)d_in[5];
  const float* k_w1   = (const float*)d_in[6];
  const float* k_b1   = (const float*)d_in[7];
  const float* k_w2   = (const float*)d_in[8];
  const float* k_b2   = (const float*)d_in[9];
  const float* v_w1   = (const float*)d_in[10];
  const float* v_b1   = (const float*)d_in[11];
  const float* v_w2   = (const float*)d_in[12];
  const float* v_b2   = (const float*)d_in[13];
  const float* w_comb = (const float*)d_in[14];
  const float* b_comb = (const float*)d_in[15];
  const float* w_out  = (const float*)d_in[16];
  float* out = (float*)d_out;
  char* wsb = (char*)d_ws;

  bf16* WQKV_H = (bf16*)(wsb + B_WQKV_H);
  bf16* WQKV_L = (bf16*)(wsb + B_WQKV_L);
  bf16* KW1_H  = (bf16*)(wsb + B_KW1_H);
  bf16* KW1_L  = (bf16*)(wsb + B_KW1_L);
  bf16* KW2_H  = (bf16*)(wsb + B_KW2_H);
  bf16* KW2_L  = (bf16*)(wsb + B_KW2_L);
  bf16* VW1_H  = (bf16*)(wsb + B_VW1_H);
  bf16* VW2_H  = (bf16*)(wsb + B_VW2_H);
  bf16* WOUT_H = (bf16*)(wsb + B_WOUT_H);
  bf16* HB_H   = (bf16*)(wsb + B_HB_H);
  bf16* HB_L   = (bf16*)(wsb + B_HB_L);
  bf16* QBH    = (bf16*)(wsb + B_QBH);
  bf16* QBM    = (bf16*)(wsb + B_QBM);
  bf16* QBL    = (bf16*)(wsb + B_QBL);
  float* KF    = (float*)(wsb + B_KF);
  bf16* VBH    = (bf16*)(wsb + B_VBH);
  bf16* RQH    = (bf16*)(wsb + B_RQH);
  bf16* RQL    = (bf16*)(wsb + B_RQL);
  bf16* RKH    = (bf16*)(wsb + B_RKH);
  bf16* RKL    = (bf16*)(wsb + B_RKL);
  float* RKF   = (float*)(wsb + B_RKF);
  bf16* VTB    = (bf16*)(wsb + B_VTB);
  bf16* CKT_H  = (bf16*)(wsb + B_CKT_H);
  bf16* CKT_M  = (bf16*)(wsb + B_CKT_M);
  bf16* CKT_L  = (bf16*)(wsb + B_CKT_L);
  bf16* CVT    = (bf16*)(wsb + B_CVT);
  int*   SEL   = (int*)(wsb + B_SEL);
  float* COUT  = (float*)(wsb + B_COUT);
  float* FOUT  = (float*)(wsb + B_FOUT);
  float* SOUT  = (float*)(wsb + B_SOUT);
  bf16* KW_H   = (bf16*)(wsb + B_KW_H);
  bf16* KW_L   = (bf16*)(wsb + B_KW_L);
  bf16* VW_H   = (bf16*)(wsb + B_VW_H);
  bf16* HID_H  = (bf16*)(wsb + B_HID_H);
  bf16* HID_L  = (bf16*)(wsb + B_HID_L);
  bf16* HIDV   = (bf16*)(wsb + B_HIDV);
  bf16* COMBB  = (bf16*)(wsb + B_COMBB);

  // 1. setup: weight splits + pads + mem fill + rmsnorm
  k_setup<<<5378, 256, 0, stream>>>(x, g_norm, w_qkv, k_w1, k_w2, v_w1, v_w2, w_out, mem_kv,
                                    WQKV_H, WQKV_L, KW1_H, KW1_L, KW2_H, KW2_L,
                                    VW1_H, VW2_H, WOUT_H, HB_H, HB_L,
                                    RKH, RKL, VTB, CKT_H, CKT_M, CKT_L, CVT);
  // 2. qkv (compensated, pipelined 64x64/wave) with fused split/scatter
  k_qkv<<<dim3(12, 16), 256, 0, stream>>>(HB_H, HB_L, WQKV_H, WQKV_L, KF, QBH, QBM, QBL, VBH);
  // 3. post: rope + v-transpose + windows
  k_post<<<10432, 256, 0, stream>>>(QBH, QBM, QBL, KF, VBH, k_pos, v_pos,
                                    RQH, RQL, RKH, RKL, RKF, VTB, KW_H, KW_L, VW_H);
  // 4. merged MLP1: LDS-staged, 512 blocks (256 k + 256 v); HIDV overlays dead KF
  k_mlp1<<<512, 256, 0, stream>>>(KW_H, KW_L, KW1_H, KW1_L, k_b1,
                                  VW_H, VW1_H, v_b1, HID_H, HID_L, HIDV);
  // 5. merged MLP2 -> ckT hi/mid/lo + cvT
  k_mlp2<<<dim3(1, 32, 2), 256, 0, stream>>>(HID_H, HID_L, KW2_H, KW2_L, k_b2,
                                             HIDV, VW2_H, v_b2, CKT_H, CKT_M, CKT_L, CVT);
  // 6-8. attention branches
  k_comp_attn<<<dim3(64, 8), 256, 0, stream>>>(QBH, QBM, QBL, CKT_H, CKT_M, CKT_L, CVT, COUT, SEL);
  k_fine_attn<<<dim3(512, 8), 256, 0, stream>>>(RQH, RQL, RKF, VBH, SEL, FOUT);
  k_slide_attn<<<dim3(32, 8), 256, 0, stream>>>(RQH, RQL, RKH, RKL, VTB, SOUT);
  // 9. fused strat + combine
  k_combine2<<<NTOK, 256, 0, stream>>>(HB_H, HB_L, w_comb, b_comb, COUT, FOUT, SOUT, COMBB);
  // 10. output projection
  k_cgemm<0, 0><<<dim3(8, 32), 256, 0, stream>>>(
      COMBB, nullptr, WOUT_H, nullptr, nullptr, out, NTOK, DMODEL, DMODEL);
}

// Round 13
// 239.599 us; speedup vs baseline: 1.2786x; 1.0621x over previous
//
#include <hip/hip_runtime.h>
#include <hip/hip_bf16.h>
#include <cstddef>

#define NTOK 2048
#define DMODEL 512
#define NHEAD 8
#define DHEAD 64
#define NWIN 254          // (2048-16)/8 + 1
#define CDIM 1024         // CB*DH
#define NEGV -1000000000.0f

typedef __attribute__((ext_vector_type(8))) __bf16 bf16x8;
typedef __attribute__((ext_vector_type(4))) float f32x4;
typedef __hip_bfloat16 bf16;

// ---------------- workspace layout (byte offsets) ----------------
static const size_t B_WQKV_H = 0;          // 1536*512*2
static const size_t B_WQKV_L = 1572864;
static const size_t B_KW1_H  = 3145728;    // 1024*1024*2
static const size_t B_KW1_L  = 5242880;
static const size_t B_KW2_H  = 7340032;    // 64*1024*2
static const size_t B_KW2_L  = 7471104;
static const size_t B_VW1_H  = 7602176;
static const size_t B_VW2_H  = 9699328;
static const size_t B_WOUT_H = 9830400;    // 512*512*2
static const size_t B_HB_H   = 10354688;   // 2048*512*2
static const size_t B_HB_L   = 12451840;
static const size_t B_QBH    = 14548992;   // 8*2048*64*2 (non-roped q, hi)
static const size_t B_QBL    = 16646144;   // (lo, 3rd term)
static const size_t B_KF     = 18743296;   // 8*2048*64*4 (k fp32; dead after k_post -> HIDV)
static const size_t B_VBH    = 22937600;   // 8*2048*64*2
static const size_t B_RQH    = 25034752;   // roped q hi/lo
static const size_t B_RQL    = 27131904;
static const size_t B_RKH    = 29229056;   // 8*2112*64*2 (roped k, 64 zero-pad rows front)
static const size_t B_RKL    = 31391744;
static const size_t B_VTB    = 33554432;   // 8*64*2112*2 (v^T, 64 zero-pad cols front)
static const size_t B_CKT_H  = 35717120;   // 8*256*64*2 (compressed k rows, j=0 mem)
static const size_t B_CKT_L  = 35979264;
static const size_t B_CVT    = 36241408;   // 8*64*256*2 (compressed v transposed)
static const size_t B_SEL    = 36700160;   // 8*2048*5*4
static const size_t B_COUT   = 37027840;   // 4194304 (overlays KW_H)
static const size_t B_FOUT   = 41222144;   // 4194304 (overlays KW_L)
static const size_t B_SOUT   = 45416448;   // 4194304 (overlays VW_H)
static const size_t B_KW_H   = B_COUT;     // 2032*1024*2 = 4161536
static const size_t B_KW_L   = B_FOUT;
static const size_t B_VW_H   = B_SOUT;
static const size_t B_HID_H  = 49610752;   // 4161536 (k hidden hi)
static const size_t B_HID_L  = 53772288;   // 4161536 (k hidden lo)
static const size_t B_QBM    = 57933824;   // 8*2048*64*2 (q mid term)
static const size_t B_CKT_M  = 60030976;   // 8*256*64*2
static const size_t B_RKF    = 60293120;   // 8*2048*64*4 (roped k fp32); end 64487424
static const size_t B_HIDV   = B_KF;       // v hidden hi (4161536 <= 4194304, KF dead)
static const size_t B_COMBB  = B_HID_H;    // 2097152 (after MLPs dead)

// ================= 32x32-per-wave GEMM core (64x64 block tile) =================
template <int COMP>
__device__ __forceinline__ void gemm_tile(
    const bf16* __restrict__ Ah, const bf16* __restrict__ Al,
    const bf16* __restrict__ Wh, const bf16* __restrict__ Wl,
    int M, int K, int row_base, int col_base, int lr, int kg,
    f32x4 accs[2][2]) {
  int ar0 = row_base + lr;       if (ar0 > M - 1) ar0 = M - 1;
  int ar1 = row_base + 16 + lr;  if (ar1 > M - 1) ar1 = M - 1;
  const size_t a0o = (size_t)ar0 * K + kg;
  const size_t a1o = (size_t)ar1 * K + kg;
  const size_t b0o = (size_t)(col_base + lr) * K + kg;
  const size_t b1o = (size_t)(col_base + 16 + lr) * K + kg;
  f32x4 acc00 = {}, acc01 = {}, acc10 = {}, acc11 = {};
  for (int k0 = 0; k0 < K; k0 += 32) {
    bf16x8 ah0 = *reinterpret_cast<const bf16x8*>(Ah + a0o + k0);
    bf16x8 ah1 = *reinterpret_cast<const bf16x8*>(Ah + a1o + k0);
    bf16x8 bh0 = *reinterpret_cast<const bf16x8*>(Wh + b0o + k0);
    bf16x8 bh1 = *reinterpret_cast<const bf16x8*>(Wh + b1o + k0);
    acc00 = __builtin_amdgcn_mfma_f32_16x16x32_bf16(ah0, bh0, acc00, 0, 0, 0);
    acc01 = __builtin_amdgcn_mfma_f32_16x16x32_bf16(ah0, bh1, acc01, 0, 0, 0);
    acc10 = __builtin_amdgcn_mfma_f32_16x16x32_bf16(ah1, bh0, acc10, 0, 0, 0);
    acc11 = __builtin_amdgcn_mfma_f32_16x16x32_bf16(ah1, bh1, acc11, 0, 0, 0);
    if constexpr (COMP) {
      bf16x8 al0 = *reinterpret_cast<const bf16x8*>(Al + a0o + k0);
      bf16x8 al1 = *reinterpret_cast<const bf16x8*>(Al + a1o + k0);
      bf16x8 bl0 = *reinterpret_cast<const bf16x8*>(Wl + b0o + k0);
      bf16x8 bl1 = *reinterpret_cast<const bf16x8*>(Wl + b1o + k0);
      acc00 = __builtin_amdgcn_mfma_f32_16x16x32_bf16(ah0, bl0, acc00, 0, 0, 0);
      acc01 = __builtin_amdgcn_mfma_f32_16x16x32_bf16(ah0, bl1, acc01, 0, 0, 0);
      acc10 = __builtin_amdgcn_mfma_f32_16x16x32_bf16(ah1, bl0, acc10, 0, 0, 0);
      acc11 = __builtin_amdgcn_mfma_f32_16x16x32_bf16(ah1, bl1, acc11, 0, 0, 0);
      acc00 = __builtin_amdgcn_mfma_f32_16x16x32_bf16(al0, bh0, acc00, 0, 0, 0);
      acc01 = __builtin_amdgcn_mfma_f32_16x16x32_bf16(al0, bh1, acc01, 0, 0, 0);
      acc10 = __builtin_amdgcn_mfma_f32_16x16x32_bf16(al1, bh0, acc10, 0, 0, 0);
      acc11 = __builtin_amdgcn_mfma_f32_16x16x32_bf16(al1, bh1, acc11, 0, 0, 0);
    }
  }
  accs[0][0] = acc00; accs[0][1] = acc01; accs[1][0] = acc10; accs[1][1] = acc11;
}

// ---------------- generic GEMM kernel (fp32 out; out-proj) ----------------
template <int EPI, int COMP>
__global__ __launch_bounds__(256) void k_cgemm(
    const bf16* __restrict__ Ah, const bf16* __restrict__ Al,
    const bf16* __restrict__ Wh, const bf16* __restrict__ Wl,
    const float* __restrict__ bias, float* __restrict__ Cf,
    int M, int K, int N) {
  const int lane = threadIdx.x & 63;
  const int w = threadIdx.x >> 6;
  const int wr = w >> 1, wc = w & 1;
  const int row_base = (blockIdx.y << 6) + (wr << 5);
  const int col_base = (blockIdx.x << 6) + (wc << 5);
  const int lr = lane & 15;
  const int kg = (lane >> 4) << 3;
  const int crow = (lane >> 4) << 2;

  f32x4 accs[2][2];
  gemm_tile<COMP>(Ah, Al, Wh, Wl, M, K, row_base, col_base, lr, kg, accs);

#pragma unroll
  for (int mi = 0; mi < 2; ++mi) {
#pragma unroll
    for (int ni = 0; ni < 2; ++ni) {
      int col = col_base + (ni << 4) + lr;
      float bv = bias ? bias[col] : 0.f;
#pragma unroll
      for (int r = 0; r < 4; ++r) {
        int row = row_base + (mi << 4) + crow + r;
        if (row < M) {
          float vv = accs[mi][ni][r] + bv;
          if (EPI == 1) vv = fmaxf(vv, 0.f);
          Cf[(size_t)row * N + col] = vv;
        }
      }
    }
  }
}

#define LDP 40

// ---------------- qkv GEMM: LDS-staged 128x64 tile, compensated, fused scatter ----------------
// grid 384 blocks (16 row-tiles x 24 col-tiles), 2 blocks/CU.
// Per-acc MFMA order per k0: hh, hl, lh -- bit-identical to all prior cores.
__global__ __launch_bounds__(256, 2) void k_qkv(
    const bf16* __restrict__ Ah, const bf16* __restrict__ Al,
    const bf16* __restrict__ Wh, const bf16* __restrict__ Wl,
    float* __restrict__ KFo, bf16* __restrict__ QH, bf16* __restrict__ QM,
    bf16* __restrict__ QL, bf16* __restrict__ VB) {
  __shared__ bf16 sAh[128 * LDP];
  __shared__ bf16 sAl[128 * LDP];
  __shared__ bf16 sBh[64 * LDP];
  __shared__ bf16 sBl[64 * LDP];

  const int t = threadIdx.x;
  const int lane = t & 63, w = t >> 6;
  const int wr = w >> 1, wc = w & 1;
  const int lr = lane & 15;
  const int kg = (lane >> 4) << 3;
  const int crow = (lane >> 4) << 2;
  const int id = blockIdx.x;
  const int row0 = (id / 24) << 7;   // M=2048 exact: row0+127 <= 2047
  const int col0 = (id % 24) << 6;   // N=1536

  const int qa0 = t,        ar0s = qa0 >> 2, as0 = qa0 & 3;
  const int qa1 = t + 256,  ar1s = qa1 >> 2, as1 = qa1 & 3;
  const int gr0 = row0 + ar0s;
  const int gr1 = row0 + ar1s;
  const int br = t >> 2, bs = t & 3;
  const int gbr = col0 + br;

  f32x4 acc[4][2];
#pragma unroll
  for (int a = 0; a < 4; ++a)
#pragma unroll
    for (int b = 0; b < 2; ++b) acc[a][b] = (f32x4){0.f, 0.f, 0.f, 0.f};

  for (int k0 = 0; k0 < DMODEL; k0 += 32) {
    *reinterpret_cast<bf16x8*>(&sAh[ar0s * LDP + as0 * 8]) =
        *reinterpret_cast<const bf16x8*>(Ah + (size_t)gr0 * DMODEL + k0 + as0 * 8);
    *reinterpret_cast<bf16x8*>(&sAh[ar1s * LDP + as1 * 8]) =
        *reinterpret_cast<const bf16x8*>(Ah + (size_t)gr1 * DMODEL + k0 + as1 * 8);
    *reinterpret_cast<bf16x8*>(&sBh[br * LDP + bs * 8]) =
        *reinterpret_cast<const bf16x8*>(Wh + (size_t)gbr * DMODEL + k0 + bs * 8);
    *reinterpret_cast<bf16x8*>(&sAl[ar0s * LDP + as0 * 8]) =
        *reinterpret_cast<const bf16x8*>(Al + (size_t)gr0 * DMODEL + k0 + as0 * 8);
    *reinterpret_cast<bf16x8*>(&sAl[ar1s * LDP + as1 * 8]) =
        *reinterpret_cast<const bf16x8*>(Al + (size_t)gr1 * DMODEL + k0 + as1 * 8);
    *reinterpret_cast<bf16x8*>(&sBl[br * LDP + bs * 8]) =
        *reinterpret_cast<const bf16x8*>(Wl + (size_t)gbr * DMODEL + k0 + bs * 8);
    __syncthreads();

    bf16x8 fAh[4], fBh[2], fAl[4], fBl[2];
#pragma unroll
    for (int mi = 0; mi < 4; ++mi)
      fAh[mi] = *reinterpret_cast<const bf16x8*>(&sAh[(wr * 64 + mi * 16 + lr) * LDP + kg]);
#pragma unroll
    for (int ni = 0; ni < 2; ++ni)
      fBh[ni] = *reinterpret_cast<const bf16x8*>(&sBh[(wc * 32 + ni * 16 + lr) * LDP + kg]);
#pragma unroll
    for (int mi = 0; mi < 4; ++mi)
      fAl[mi] = *reinterpret_cast<const bf16x8*>(&sAl[(wr * 64 + mi * 16 + lr) * LDP + kg]);
#pragma unroll
    for (int ni = 0; ni < 2; ++ni)
      fBl[ni] = *reinterpret_cast<const bf16x8*>(&sBl[(wc * 32 + ni * 16 + lr) * LDP + kg]);

#pragma unroll
    for (int mi = 0; mi < 4; ++mi)
#pragma unroll
      for (int ni = 0; ni < 2; ++ni)
        acc[mi][ni] = __builtin_amdgcn_mfma_f32_16x16x32_bf16(fAh[mi], fBh[ni], acc[mi][ni], 0, 0, 0);
#pragma unroll
    for (int mi = 0; mi < 4; ++mi)
#pragma unroll
      for (int ni = 0; ni < 2; ++ni) {
        acc[mi][ni] = __builtin_amdgcn_mfma_f32_16x16x32_bf16(fAh[mi], fBl[ni], acc[mi][ni], 0, 0, 0);
        acc[mi][ni] = __builtin_amdgcn_mfma_f32_16x16x32_bf16(fAl[mi], fBh[ni], acc[mi][ni], 0, 0, 0);
      }
    __syncthreads();
  }

#pragma unroll
  for (int mi = 0; mi < 4; ++mi) {
#pragma unroll
    for (int ni = 0; ni < 2; ++ni) {
      int col = col0 + wc * 32 + ni * 16 + lr;
      int which = col >> 9, rem = col & 511;
      int hh = rem >> 6, dd = rem & 63;
#pragma unroll
      for (int r = 0; r < 4; ++r) {
        int row = row0 + wr * 64 + mi * 16 + crow + r;
        float vv = acc[mi][ni][r];
        size_t o = ((size_t)hh * NTOK + row) * DHEAD + dd;
        if (which == 0) {
          bf16 h1 = __float2bfloat16(vv);
          float r1 = vv - __bfloat162float(h1);
          bf16 m1 = __float2bfloat16(r1);
          QH[o] = h1;
          QM[o] = m1;
          QL[o] = __float2bfloat16(r1 - __bfloat162float(m1));
        } else if (which == 1) {
          KFo[o] = vv;
        } else {
          VB[o] = __float2bfloat16(vv);
        }
      }
    }
  }
}

// ---------------- merged MLP1, LDS-staged (128x64 tile, BK=32, padded LDS) ----------------
__global__ __launch_bounds__(256, 2) void k_mlp1(
    const bf16* __restrict__ KWh, const bf16* __restrict__ KWl,
    const bf16* __restrict__ W1h, const bf16* __restrict__ W1l,
    const float* __restrict__ kb1,
    const bf16* __restrict__ VWh, const bf16* __restrict__ VW1h,
    const float* __restrict__ vb1,
    bf16* __restrict__ HKh, bf16* __restrict__ HKl, bf16* __restrict__ HVh) {
  __shared__ bf16 sAh[128 * LDP];
  __shared__ bf16 sAl[128 * LDP];
  __shared__ bf16 sBh[64 * LDP];
  __shared__ bf16 sBl[64 * LDP];

  const int t = threadIdx.x;
  const int lane = t & 63, w = t >> 6;
  const int wr = w >> 1, wc = w & 1;
  const int lr = lane & 15;
  const int kg = (lane >> 4) << 3;
  const int crow = (lane >> 4) << 2;
  const int M = NHEAD * NWIN;  // 2032
  const int id = blockIdx.x;
  const bool kpath = (id < 256);
  const int u = kpath ? id : id - 256;
  const int row0 = (u >> 4) << 7;
  const int col0 = (u & 15) << 6;

  const bf16* Ah = kpath ? KWh : VWh;
  const bf16* Bh = kpath ? W1h : VW1h;

  const int qa0 = t,        ar0s = qa0 >> 2, as0 = qa0 & 3;
  const int qa1 = t + 256,  ar1s = qa1 >> 2, as1 = qa1 & 3;
  int gr0 = row0 + ar0s; if (gr0 > M - 1) gr0 = M - 1;
  int gr1 = row0 + ar1s; if (gr1 > M - 1) gr1 = M - 1;
  const int br = t >> 2, bs = t & 3;
  const int gbr = col0 + br;

  f32x4 acc[4][2];
#pragma unroll
  for (int a = 0; a < 4; ++a)
#pragma unroll
    for (int b = 0; b < 2; ++b) acc[a][b] = (f32x4){0.f, 0.f, 0.f, 0.f};

  for (int k0 = 0; k0 < CDIM; k0 += 32) {
    *reinterpret_cast<bf16x8*>(&sAh[ar0s * LDP + as0 * 8]) =
        *reinterpret_cast<const bf16x8*>(Ah + (size_t)gr0 * CDIM + k0 + as0 * 8);
    *reinterpret_cast<bf16x8*>(&sAh[ar1s * LDP + as1 * 8]) =
        *reinterpret_cast<const bf16x8*>(Ah + (size_t)gr1 * CDIM + k0 + as1 * 8);
    *reinterpret_cast<bf16x8*>(&sBh[br * LDP + bs * 8]) =
        *reinterpret_cast<const bf16x8*>(Bh + (size_t)gbr * CDIM + k0 + bs * 8);
    if (kpath) {
      *reinterpret_cast<bf16x8*>(&sAl[ar0s * LDP + as0 * 8]) =
          *reinterpret_cast<const bf16x8*>(KWl + (size_t)gr0 * CDIM + k0 + as0 * 8);
      *reinterpret_cast<bf16x8*>(&sAl[ar1s * LDP + as1 * 8]) =
          *reinterpret_cast<const bf16x8*>(KWl + (size_t)gr1 * CDIM + k0 + as1 * 8);
      *reinterpret_cast<bf16x8*>(&sBl[br * LDP + bs * 8]) =
          *reinterpret_cast<const bf16x8*>(W1l + (size_t)gbr * CDIM + k0 + bs * 8);
    }
    __syncthreads();

    bf16x8 fAh[4], fBh[2], fAl[4], fBl[2];
#pragma unroll
    for (int mi = 0; mi < 4; ++mi)
      fAh[mi] = *reinterpret_cast<const bf16x8*>(&sAh[(wr * 64 + mi * 16 + lr) * LDP + kg]);
#pragma unroll
    for (int ni = 0; ni < 2; ++ni)
      fBh[ni] = *reinterpret_cast<const bf16x8*>(&sBh[(wc * 32 + ni * 16 + lr) * LDP + kg]);
    if (kpath) {
#pragma unroll
      for (int mi = 0; mi < 4; ++mi)
        fAl[mi] = *reinterpret_cast<const bf16x8*>(&sAl[(wr * 64 + mi * 16 + lr) * LDP + kg]);
#pragma unroll
      for (int ni = 0; ni < 2; ++ni)
        fBl[ni] = *reinterpret_cast<const bf16x8*>(&sBl[(wc * 32 + ni * 16 + lr) * LDP + kg]);
    }

#pragma unroll
    for (int mi = 0; mi < 4; ++mi)
#pragma unroll
      for (int ni = 0; ni < 2; ++ni)
        acc[mi][ni] = __builtin_amdgcn_mfma_f32_16x16x32_bf16(fAh[mi], fBh[ni], acc[mi][ni], 0, 0, 0);
    if (kpath) {
#pragma unroll
      for (int mi = 0; mi < 4; ++mi)
#pragma unroll
        for (int ni = 0; ni < 2; ++ni) {
          acc[mi][ni] = __builtin_amdgcn_mfma_f32_16x16x32_bf16(fAh[mi], fBl[ni], acc[mi][ni], 0, 0, 0);
          acc[mi][ni] = __builtin_amdgcn_mfma_f32_16x16x32_bf16(fAl[mi], fBh[ni], acc[mi][ni], 0, 0, 0);
        }
    }
    __syncthreads();
  }

#pragma unroll
  for (int mi = 0; mi < 4; ++mi) {
#pragma unroll
    for (int ni = 0; ni < 2; ++ni) {
      int col = col0 + wc * 32 + ni * 16 + lr;
      float bv = kpath ? kb1[col] : vb1[col];
#pragma unroll
      for (int r = 0; r < 4; ++r) {
        int row = row0 + wr * 64 + mi * 16 + crow + r;
        if (row < M) {
          float vv = fmaxf(acc[mi][ni][r] + bv, 0.f);
          size_t o = (size_t)row * CDIM + col;
          if (kpath) {
            bf16 h1 = __float2bfloat16(vv);
            HKh[o] = h1;
            HKl[o] = __float2bfloat16(vv - __bfloat162float(h1));
          } else {
            HVh[o] = __float2bfloat16(vv);
          }
        }
      }
    }
  }
}

// ---------------- merged MLP2: z=0 k-path -> ckT hi/mid/lo, z=1 v-path -> cvT ----------------
__global__ __launch_bounds__(256) void k_mlp2(
    const bf16* __restrict__ HKh, const bf16* __restrict__ HKl,
    const bf16* __restrict__ W2h, const bf16* __restrict__ W2l,
    const float* __restrict__ kb2,
    const bf16* __restrict__ HVh, const bf16* __restrict__ VW2h,
    const float* __restrict__ vb2,
    bf16* __restrict__ ckh, bf16* __restrict__ ckm, bf16* __restrict__ ckl,
    bf16* __restrict__ cvtb) {
  const int lane = threadIdx.x & 63;
  const int w = threadIdx.x >> 6;
  const int wr = w >> 1, wc = w & 1;
  const int row_base = (blockIdx.y << 6) + (wr << 5);
  const int col_base = (wc << 5);
  const int lr = lane & 15;
  const int kg = (lane >> 4) << 3;
  const int crow = (lane >> 4) << 2;
  const int M = NHEAD * NWIN;

  f32x4 accs[2][2];
  if (blockIdx.z == 0)
    gemm_tile<1>(HKh, HKl, W2h, W2l, M, CDIM, row_base, col_base, lr, kg, accs);
  else
    gemm_tile<0>(HVh, nullptr, VW2h, nullptr, M, CDIM, row_base, col_base, lr, kg, accs);

  const float* bias = (blockIdx.z == 0) ? kb2 : vb2;
#pragma unroll
  for (int mi = 0; mi < 2; ++mi) {
#pragma unroll
    for (int ni = 0; ni < 2; ++ni) {
      int col = col_base + (ni << 4) + lr;
      float bv = bias[col];
#pragma unroll
      for (int r = 0; r < 4; ++r) {
        int row = row_base + (mi << 4) + crow + r;
        if (row < M) {
          float vv = accs[mi][ni][r] + bv;
          int hh = row / NWIN, jj = row - hh * NWIN;
          if (blockIdx.z == 0) {
            size_t o = ((size_t)hh * 256 + 1 + jj) * 64 + col;
            bf16 h1 = __float2bfloat16(vv);
            float r1 = vv - __bfloat162float(h1);
            bf16 m1 = __float2bfloat16(r1);
            ckh[o] = h1;
            ckm[o] = m1;
            ckl[o] = __float2bfloat16(r1 - __bfloat162float(m1));
          } else {
            cvtb[((size_t)hh * 64 + col) * 256 + 1 + jj] = __float2bfloat16(vv);
          }
        }
      }
    }
  }
}

// ================= k_setup: 6 weight transposes + zpad + fillmem + rmsnorm =================
__device__ __forceinline__ void wt_tile(const float* __restrict__ W,
                                        bf16* __restrict__ WTh, bf16* __restrict__ WTl,
                                        int K, int N, int bx, int by,
                                        float (*tsh)[33]) {
  const int k0 = bx << 5, n0 = by << 5;
  const int tx = threadIdx.x & 31, ty = threadIdx.x >> 5;
#pragma unroll
  for (int r = 0; r < 4; ++r)
    tsh[ty + (r << 3)][tx] = W[(size_t)(k0 + ty + (r << 3)) * N + n0 + tx];
  __syncthreads();
#pragma unroll
  for (int r = 0; r < 4; ++r) {
    float val = tsh[tx][ty + (r << 3)];
    size_t o = (size_t)(n0 + ty + (r << 3)) * K + k0 + tx;
    bf16 h1 = __float2bfloat16(val);
    WTh[o] = h1;
    if (WTl) WTl[o] = __float2bfloat16(val - __bfloat162float(h1));
  }
}

__global__ __launch_bounds__(256) void k_setup(
    const float* __restrict__ x, const float* __restrict__ g,
    const float* __restrict__ w_qkv, const float* __restrict__ k_w1,
    const float* __restrict__ k_w2, const float* __restrict__ v_w1,
    const float* __restrict__ v_w2, const float* __restrict__ w_out,
    const float* __restrict__ memkv,
    bf16* __restrict__ WQKV_H, bf16* __restrict__ WQKV_L,
    bf16* __restrict__ KW1_H, bf16* __restrict__ KW1_L,
    bf16* __restrict__ KW2_H, bf16* __restrict__ KW2_L,
    bf16* __restrict__ VW1_H, bf16* __restrict__ VW2_H, bf16* __restrict__ WOUT_H,
    bf16* __restrict__ hbh, bf16* __restrict__ hbl,
    bf16* __restrict__ rkh, bf16* __restrict__ rkl, bf16* __restrict__ vtb,
    bf16* __restrict__ ckh, bf16* __restrict__ ckm, bf16* __restrict__ ckl,
    bf16* __restrict__ cvtb) {
  __shared__ float tsh[32][33];
  __shared__ float wsum[4];
  __shared__ float scale_s;
  const int id = blockIdx.x;
  const int t = threadIdx.x;

  if (id < 768) {
    wt_tile(w_qkv, WQKV_H, WQKV_L, DMODEL, 1536, id % 16, id / 16, tsh);
  } else if (id < 1792) {
    int u = id - 768;  wt_tile(k_w1, KW1_H, KW1_L, CDIM, CDIM, u % 32, u / 32, tsh);
  } else if (id < 1856) {
    int u = id - 1792; wt_tile(k_w2, KW2_H, KW2_L, CDIM, DHEAD, u % 32, u / 32, tsh);
  } else if (id < 2880) {
    int u = id - 1856; wt_tile(v_w1, VW1_H, nullptr, CDIM, CDIM, u % 32, u / 32, tsh);
  } else if (id < 2944) {
    int u = id - 2880; wt_tile(v_w2, VW2_H, nullptr, CDIM, DHEAD, u % 32, u / 32, tsh);
  } else if (id < 3200) {
    int u = id - 2944; wt_tile(w_out, WOUT_H, nullptr, DMODEL, DMODEL, u % 16, u / 16, tsh);
  } else if (id < 3328) {
    int idx = (id - 3200) * 256 + t;   // [0, 32768)
    int h = idx >> 12, r = (idx >> 6) & 63, c = idx & 63;
    bf16 z = __float2bfloat16(0.f);
    rkh[((size_t)h * 2112 + r) * 64 + c] = z;
    rkl[((size_t)h * 2112 + r) * 64 + c] = z;
    vtb[((size_t)h * 64 + r) * 2112 + c] = z;
  } else if (id < 3330) {
    int u = (id - 3328) * 256 + t;     // [0, 512)
    if (u < 512) {
      int h = u >> 6, e = u & 63;
      float kv = memkv[(size_t)h * DHEAD + e];
      bf16 h1 = __float2bfloat16(kv);
      float r1 = kv - __bfloat162float(h1);
      bf16 m1 = __float2bfloat16(r1);
      ckh[((size_t)h * 256) * 64 + e] = h1;
      ckm[((size_t)h * 256) * 64 + e] = m1;
      ckl[((size_t)h * 256) * 64 + e] = __float2bfloat16(r1 - __bfloat162float(m1));
      bf16 z = __float2bfloat16(0.f);
      ckh[((size_t)h * 256 + 255) * 64 + e] = z;
      ckm[((size_t)h * 256 + 255) * 64 + e] = z;
      ckl[((size_t)h * 256 + 255) * 64 + e] = z;
      float vv = memkv[(size_t)(NHEAD + h) * DHEAD + e];
      cvtb[((size_t)h * 64 + e) * 256 + 0] = __float2bfloat16(vv);
      cvtb[((size_t)h * 64 + e) * 256 + 255] = z;
    }
  } else {
    const int row = id - 3330;
    const float* xr = x + (size_t)row * DMODEL;
    float s = 0.f;
    for (int c = t; c < DMODEL; c += 256) { float v = xr[c]; s += v * v; }
    for (int o = 32; o > 0; o >>= 1) s += __shfl_down(s, o);
    if ((t & 63) == 0) wsum[t >> 6] = s;
    __syncthreads();
    if (t == 0) {
      float tot = wsum[0] + wsum[1] + wsum[2] + wsum[3];
      scale_s = rsqrtf(tot * (1.f / DMODEL) + 1e-6f);
    }
    __syncthreads();
    float sc = scale_s;
    for (int c = t; c < DMODEL; c += 256) {
      float v = xr[c] * sc * g[c];
      bf16 h1 = __float2bfloat16(v);
      hbh[(size_t)row * DMODEL + c] = h1;
      hbl[(size_t)row * DMODEL + c] = __float2bfloat16(v - __bfloat162float(h1));
    }
  }
}

// ================= k_post: rope + v-transpose + compression windows =================
__global__ __launch_bounds__(256) void k_post(
    const bf16* __restrict__ qbh, const bf16* __restrict__ qbm,
    const bf16* __restrict__ qbl, const float* __restrict__ kf,
    const bf16* __restrict__ vbh,
    const float* __restrict__ kpos, const float* __restrict__ vpos,
    bf16* __restrict__ rqh, bf16* __restrict__ rql,
    bf16* __restrict__ rkh, bf16* __restrict__ rkl, float* __restrict__ rkf,
    bf16* __restrict__ vtb,
    bf16* __restrict__ kwh, bf16* __restrict__ kwl, bf16* __restrict__ vwh) {
  __shared__ bf16 tile[64][65];
  const int id = blockIdx.x;
  const int t = threadIdx.x;

  if (id < 2048) {
    int idx = id * 256 + t;
    int i = idx & 31;
    int n = (idx >> 5) & (NTOK - 1);
    int h = idx >> 16;
    float ex = (float)(2 * i) * (1.f / 64.f);
    float inv = exp2f(-ex * 13.287712379549449f);
    float ang = (float)n * inv;
    float sn, cs;
    sincosf(ang, &sn, &cs);
    size_t base = ((size_t)h * NTOK + n) * DHEAD + 2 * i;
    float q1 = __bfloat162float(qbh[base]) + __bfloat162float(qbm[base]) + __bfloat162float(qbl[base]);
    float q2 = __bfloat162float(qbh[base + 1]) + __bfloat162float(qbm[base + 1]) + __bfloat162float(qbl[base + 1]);
    float r1 = q1 * cs - q2 * sn, r2 = q1 * sn + q2 * cs;
    bf16 h1 = __float2bfloat16(r1);
    rqh[base] = h1; rql[base] = __float2bfloat16(r1 - __bfloat162float(h1));
    h1 = __float2bfloat16(r2);
    rqh[base + 1] = h1; rql[base + 1] = __float2bfloat16(r2 - __bfloat162float(h1));
    float k1 = kf[base], k2 = kf[base + 1];
    float s1 = k1 * cs - k2 * sn, s2 = k1 * sn + k2 * cs;
    rkf[base] = s1;
    rkf[base + 1] = s2;
    size_t kb = ((size_t)h * 2112 + 64 + n) * DHEAD + 2 * i;
    h1 = __float2bfloat16(s1);
    rkh[kb] = h1; rkl[kb] = __float2bfloat16(s1 - __bfloat162float(h1));
    h1 = __float2bfloat16(s2);
    rkh[kb + 1] = h1; rkl[kb + 1] = __float2bfloat16(s2 - __bfloat162float(h1));
  } else if (id < 2304) {
    int u = id - 2048;
    int h = u >> 5, n0 = (u & 31) << 6;
    int tx = t & 63, ty = t >> 6;
    for (int r = ty; r < 64; r += 4)
      tile[r][tx] = vbh[((size_t)h * NTOK + n0 + r) * DHEAD + tx];
    __syncthreads();
    for (int r = ty; r < 64; r += 4)
      vtb[((size_t)h * 64 + r) * 2112 + 64 + n0 + tx] = tile[tx][r];
  } else {
    int idx = (id - 2304) * 256 + t;   // [0, 2080768)
    int d = idx & 63;
    int c = (idx >> 6) & 15;
    int j = (idx >> 10) % NWIN;
    int h = idx / (NWIN << 10);
    int srcpos = (j << 3) + c;
    size_t src = ((size_t)h * NTOK + srcpos) * DHEAD + d;
    size_t pp = ((size_t)h * 16 + c) * DHEAD + d;
    float kv = kf[src] + kpos[pp];
    bf16 h1 = __float2bfloat16(kv);
    kwh[idx] = h1;
    kwl[idx] = __float2bfloat16(kv - __bfloat162float(h1));
    vwh[idx] = __float2bfloat16(__bfloat162float(vbh[src]) + vpos[pp]);
  }
}

// ---------------- compression attention (MFMA, 32 queries/block) ----------------
__global__ __launch_bounds__(256) void k_comp_attn(
    const bf16* __restrict__ qbh, const bf16* __restrict__ qbm, const bf16* __restrict__ qbl,
    const bf16* __restrict__ ckh, const bf16* __restrict__ ckm, const bf16* __restrict__ ckl,
    const bf16* __restrict__ cvtb,
    float* __restrict__ c_out, int* __restrict__ sel) {
  const int h = blockIdx.y;
  const int i0 = blockIdx.x << 5;
  const int t = threadIdx.x;
  const int w = t >> 6, lane = t & 63;
  const int lr = lane & 15, kg = (lane >> 4) << 3;
  const int crow = (lane >> 4) << 2;

  __shared__ float p[32][260];

  bf16x8 aH[2][2], aM[2][2], aL[2][2];
#pragma unroll
  for (int mi = 0; mi < 2; ++mi) {
    size_t qo = ((size_t)h * NTOK + i0 + mi * 16 + lr) * DHEAD + kg;
#pragma unroll
    for (int ks = 0; ks < 2; ++ks) {
      aH[mi][ks] = *reinterpret_cast<const bf16x8*>(qbh + qo + ks * 32);
      aM[mi][ks] = *reinterpret_cast<const bf16x8*>(qbm + qo + ks * 32);
      aL[mi][ks] = *reinterpret_cast<const bf16x8*>(qbl + qo + ks * 32);
    }
  }
  f32x4 acc[2][4];
#pragma unroll
  for (int a = 0; a < 2; ++a)
#pragma unroll
    for (int b = 0; b < 4; ++b) acc[a][b] = (f32x4){0.f, 0.f, 0.f, 0.f};
#pragma unroll
  for (int ni = 0; ni < 4; ++ni) {
    int col = (w << 6) + (ni << 4) + lr;
    size_t ko = ((size_t)h * 256 + col) * 64 + kg;
#pragma unroll
    for (int ks = 0; ks < 2; ++ks) {
      bf16x8 bH = *reinterpret_cast<const bf16x8*>(ckh + ko + ks * 32);
      bf16x8 bM = *reinterpret_cast<const bf16x8*>(ckm + ko + ks * 32);
      bf16x8 bL = *reinterpret_cast<const bf16x8*>(ckl + ko + ks * 32);
#pragma unroll
      for (int mi = 0; mi < 2; ++mi) {
        acc[mi][ni] = __builtin_amdgcn_mfma_f32_16x16x32_bf16(aH[mi][ks], bH, acc[mi][ni], 0, 0, 0);
        acc[mi][ni] = __builtin_amdgcn_mfma_f32_16x16x32_bf16(aH[mi][ks], bM, acc[mi][ni], 0, 0, 0);
        acc[mi][ni] = __builtin_amdgcn_mfma_f32_16x16x32_bf16(aM[mi][ks], bH, acc[mi][ni], 0, 0, 0);
        acc[mi][ni] = __builtin_amdgcn_mfma_f32_16x16x32_bf16(aH[mi][ks], bL, acc[mi][ni], 0, 0, 0);
        acc[mi][ni] = __builtin_amdgcn_mfma_f32_16x16x32_bf16(aL[mi][ks], bH, acc[mi][ni], 0, 0, 0);
        acc[mi][ni] = __builtin_amdgcn_mfma_f32_16x16x32_bf16(aM[mi][ks], bM, acc[mi][ni], 0, 0, 0);
      }
    }
  }
#pragma unroll
  for (int mi = 0; mi < 2; ++mi)
#pragma unroll
    for (int ni = 0; ni < 4; ++ni) {
      int col = (w << 6) + (ni << 4) + lr;
      int wend = (col == 0) ? -1 : ((col - 1) << 3) + 15;
#pragma unroll
      for (int r = 0; r < 4; ++r) {
        int qi = mi * 16 + crow + r;
        bool ok = (col < 255) && (wend < i0 + qi);
        p[qi][col] = ok ? acc[mi][ni][r] * 0.125f : NEGV;
      }
    }
  __syncthreads();

  const int qi = t >> 3, s = t & 7;
  float ev[32];
  float mx = -3.0e38f;
#pragma unroll
  for (int u = 0; u < 32; ++u) { ev[u] = p[qi][s + (u << 3)]; mx = fmaxf(mx, ev[u]); }
  mx = fmaxf(mx, __shfl_xor(mx, 1));
  mx = fmaxf(mx, __shfl_xor(mx, 2));
  mx = fmaxf(mx, __shfl_xor(mx, 4));
  float sum = 0.f;
#pragma unroll
  for (int u = 0; u < 32; ++u) { float e = __expf(ev[u] - mx); ev[u] = e; sum += e; }
  sum += __shfl_xor(sum, 1); sum += __shfl_xor(sum, 2); sum += __shfl_xor(sum, 4);
  float invs = 1.f / sum;
#pragma unroll
  for (int u = 0; u < 32; ++u) p[qi][s + (u << 3)] = ev[u] * invs;

  int qblk = (i0 + qi) >> 4;
  float vals[16];
#pragma unroll
  for (int u = 0; u < 16; ++u) {
    int f = (s << 4) + u;
    float v;
    if (f >= qblk || f == 127) v = NEGV;
    else v = (p[qi][2 * f + 1] + p[qi][2 * f + 2]) * 0.5f;
    vals[u] = v;
  }
  int base = ((h << 11) | (i0 + qi)) * 5;
  for (int kk = 0; kk < 4; ++kk) {
    float bv = -3.0e38f; int bi = 0;
#pragma unroll
    for (int u = 0; u < 16; ++u) {
      if (vals[u] > bv) { bv = vals[u]; bi = (s << 4) + u; }
    }
#pragma unroll
    for (int o = 1; o < 8; o <<= 1) {
      float ov = __shfl_xor(bv, o);
      int oi = __shfl_xor(bi, o);
      if (ov > bv || (ov == bv && oi < bi)) { bv = ov; bi = oi; }
    }
    if (s == 0) sel[base + kk] = (bv > -5.0e8f) ? bi : -1;
    if ((bi >> 4) == s) vals[bi & 15] = -3.0e38f;
  }
  if (s == 0) sel[base + 4] = (i0 + qi) >> 4;
  __syncthreads();

  const int wm = w >> 1, wn = w & 1;
  const int arow = wm * 16 + lr;
  f32x4 pacc[2];
#pragma unroll
  for (int b = 0; b < 2; ++b) pacc[b] = (f32x4){0.f, 0.f, 0.f, 0.f};
#pragma unroll
  for (int ks = 0; ks < 8; ++ks) {
    int k0 = ks * 32 + kg;
    float4 x0 = *reinterpret_cast<const float4*>(&p[arow][k0]);
    float4 x1 = *reinterpret_cast<const float4*>(&p[arow][k0 + 4]);
    float xv[8] = {x0.x, x0.y, x0.z, x0.w, x1.x, x1.y, x1.z, x1.w};
    bf16x8 ph, pl;
#pragma unroll
    for (int e = 0; e < 8; ++e) {
      __bf16 hh = (__bf16)xv[e];
      ph[e] = hh;
      pl[e] = (__bf16)(xv[e] - (float)hh);
    }
#pragma unroll
    for (int ni = 0; ni < 2; ++ni) {
      int d = (wn << 5) + (ni << 4) + lr;
      bf16x8 bv = *reinterpret_cast<const bf16x8*>(cvtb + ((size_t)h * 64 + d) * 256 + k0);
      pacc[ni] = __builtin_amdgcn_mfma_f32_16x16x32_bf16(ph, bv, pacc[ni], 0, 0, 0);
      pacc[ni] = __builtin_amdgcn_mfma_f32_16x16x32_bf16(pl, bv, pacc[ni], 0, 0, 0);
    }
  }
#pragma unroll
  for (int ni = 0; ni < 2; ++ni) {
    int d = (wn << 5) + (ni << 4) + lr;
#pragma unroll
    for (int r = 0; r < 4; ++r) {
      int q2 = wm * 16 + crow + r;
      c_out[((size_t)h * NTOK + i0 + q2) * DHEAD + d] = pacc[ni][r];
    }
  }
}

// ---------------- fine attention: 1 wave/query, V prefetched to regs (T14) ----------------
__global__ __launch_bounds__(256) void k_fine_attn(
    const bf16* __restrict__ rqh, const bf16* __restrict__ rql,
    const float* __restrict__ rkf, const bf16* __restrict__ vbh,
    const int* __restrict__ sel, float* __restrict__ f_out) {
  const int h = blockIdx.y;
  const int wid = threadIdx.x >> 6;
  const int lane = threadIdx.x & 63;
  const int i = (blockIdx.x << 2) | wid;

  __shared__ float qs[4][64];
  __shared__ float pb[4][80];
  __shared__ int selb[4][5];

  size_t qoff = ((size_t)h * NTOK + i) * DHEAD + lane;
  qs[wid][lane] = __bfloat162float(rqh[qoff]) + __bfloat162float(rql[qoff]);
  if (lane < 5) selb[wid][lane] = sel[((h << 11) | i) * 5 + lane];
  __syncthreads();

  int sblk[5];
#pragma unroll
  for (int b = 0; b < 5; ++b) sblk[b] = selb[wid][b];

  // ---- prefetch V into registers (addresses known from sel; latency hides under QK)
  // invalid block (kb<0) reads block 0 harmlessly; its p is 0.
  unsigned short vreg[80];
#pragma unroll
  for (int b = 0; b < 5; ++b) {
    int kb = sblk[b] < 0 ? 0 : sblk[b];
    const unsigned short* vr = reinterpret_cast<const unsigned short*>(
        vbh + ((size_t)h * NTOK + ((size_t)kb << 4)) * DHEAD + lane);
#pragma unroll
    for (int u = 0; u < 16; ++u)
      vreg[b * 16 + u] = vr[(size_t)u * DHEAD];
  }

  // ---- QK: lane -> key j=lane (blocks 0-3), j=64+lane (lane<16, own block)
  float sim0 = NEGV, sim1 = NEGV;
  {
    int kb = sblk[lane >> 4];
    int pos = (kb << 4) + (lane & 15);
    if (kb >= 0 && pos <= i) {
      const float* kp = rkf + ((size_t)h * NTOK + pos) * DHEAD;
      float d = 0.f;
#pragma unroll
      for (int e4 = 0; e4 < 16; ++e4) {
        float4 kv = *reinterpret_cast<const float4*>(kp + e4 * 4);
        d = fmaf(qs[wid][e4 * 4 + 0], kv.x, d);
        d = fmaf(qs[wid][e4 * 4 + 1], kv.y, d);
        d = fmaf(qs[wid][e4 * 4 + 2], kv.z, d);
        d = fmaf(qs[wid][e4 * 4 + 3], kv.w, d);
      }
      sim0 = d * 0.125f;
    }
  }
  if (lane < 16) {
    int kb = sblk[4];
    int pos = (kb << 4) + lane;
    if (pos <= i) {
      const float* kp = rkf + ((size_t)h * NTOK + pos) * DHEAD;
      float d = 0.f;
#pragma unroll
      for (int e4 = 0; e4 < 16; ++e4) {
        float4 kv = *reinterpret_cast<const float4*>(kp + e4 * 4);
        d = fmaf(qs[wid][e4 * 4 + 0], kv.x, d);
        d = fmaf(qs[wid][e4 * 4 + 1], kv.y, d);
        d = fmaf(qs[wid][e4 * 4 + 2], kv.z, d);
        d = fmaf(qs[wid][e4 * 4 + 3], kv.w, d);
      }
      sim1 = d * 0.125f;
    }
  }

  // ---- softmax over 80 (wave shuffles, no barriers)
  float mx = fmaxf(sim0, sim1);
#pragma unroll
  for (int o = 32; o > 0; o >>= 1) mx = fmaxf(mx, __shfl_xor(mx, o));
  float e0 = __expf(sim0 - mx);
  float e1 = __expf(sim1 - mx);        // lanes>=16: sim1=NEGV -> 0
  float sum = e0 + e1;
#pragma unroll
  for (int o = 32; o > 0; o >>= 1) sum += __shfl_xor(sum, o);
  float invs = 1.f / sum;
  pb[wid][lane] = e0 * invs;
  if (lane < 16) pb[wid][64 + lane] = e1 * invs;
  // same wave writes & reads pb[wid]: DS ops wave-ordered, no barrier needed

  // ---- PV: pure register FMAs (V already resident)
  float acc = 0.f;
#pragma unroll
  for (int j = 0; j < 80; ++j) {
    bf16 bv;
    *reinterpret_cast<unsigned short*>(&bv) = vreg[j];
    acc = fmaf(pb[wid][j], __bfloat162float(bv), acc);
  }
  f_out[((size_t)h * NTOK + i) * DHEAD + lane] = acc;
}

// ---------------- sliding-window attention (MFMA, 64 queries/block) ----------------
__global__ __launch_bounds__(256) void k_slide_attn(
    const bf16* __restrict__ rqh, const bf16* __restrict__ rql,
    const bf16* __restrict__ rkh, const bf16* __restrict__ rkl,
    const bf16* __restrict__ vtb, float* __restrict__ s_out) {
  const int h = blockIdx.y, nb = blockIdx.x;
  const int t = threadIdx.x, w = t >> 6, lane = t & 63;
  const int lr = lane & 15, kg = (lane >> 4) << 3;
  const int crow = (lane >> 4) << 2;
  const int wm = w >> 1, wn = w & 1;
  __shared__ float p[64][132];

  bf16x8 aH[2][2], aL[2][2];
#pragma unroll
  for (int mi = 0; mi < 2; ++mi) {
    size_t qo = ((size_t)h * NTOK + nb * 64 + wm * 32 + mi * 16 + lr) * DHEAD + kg;
#pragma unroll
    for (int ks = 0; ks < 2; ++ks) {
      aH[mi][ks] = *reinterpret_cast<const bf16x8*>(rqh + qo + ks * 32);
      aL[mi][ks] = *reinterpret_cast<const bf16x8*>(rql + qo + ks * 32);
    }
  }
  f32x4 acc[2][4];
#pragma unroll
  for (int a = 0; a < 2; ++a)
#pragma unroll
    for (int b = 0; b < 4; ++b) acc[a][b] = (f32x4){0.f, 0.f, 0.f, 0.f};
#pragma unroll
  for (int ni = 0; ni < 4; ++ni) {
    int col = (wn << 6) + (ni << 4) + lr;
    size_t ko = ((size_t)h * 2112 + nb * 64 + col) * 64 + kg;
#pragma unroll
    for (int ks = 0; ks < 2; ++ks) {
      bf16x8 bH = *reinterpret_cast<const bf16x8*>(rkh + ko + ks * 32);
      bf16x8 bL = *reinterpret_cast<const bf16x8*>(rkl + ko + ks * 32);
#pragma unroll
      for (int mi = 0; mi < 2; ++mi) {
        acc[mi][ni] = __builtin_amdgcn_mfma_f32_16x16x32_bf16(aH[mi][ks], bH, acc[mi][ni], 0, 0, 0);
        acc[mi][ni] = __builtin_amdgcn_mfma_f32_16x16x32_bf16(aL[mi][ks], bH, acc[mi][ni], 0, 0, 0);
        acc[mi][ni] = __builtin_amdgcn_mfma_f32_16x16x32_bf16(aH[mi][ks], bL, acc[mi][ni], 0, 0, 0);
      }
    }
  }
#pragma unroll
  for (int mi = 0; mi < 2; ++mi)
#pragma unroll
    for (int ni = 0; ni < 4; ++ni) {
      int col = (wn << 6) + (ni << 4) + lr;
#pragma unroll
      for (int r = 0; r < 4; ++r) {
        int qi2 = wm * 32 + mi * 16 + crow + r;
        bool ok = (col >= qi2 + 1) && (col <= qi2 + 64) && (nb > 0 || col >= 64);
        p[qi2][col] = ok ? acc[mi][ni][r] * 0.125f : NEGV;
      }
    }
  __syncthreads();

  const int qi = t >> 2, s = t & 3;
  float ev[32];
  float mx = -3.0e38f;
#pragma unroll
  for (int u = 0; u < 32; ++u) { ev[u] = p[qi][s + (u << 2)]; mx = fmaxf(mx, ev[u]); }
  mx = fmaxf(mx, __shfl_xor(mx, 1));
  mx = fmaxf(mx, __shfl_xor(mx, 2));
  float sum = 0.f;
#pragma unroll
  for (int u = 0; u < 32; ++u) { float e = __expf(ev[u] - mx); ev[u] = e; sum += e; }
  sum += __shfl_xor(sum, 1); sum += __shfl_xor(sum, 2);
  float invs = 1.f / sum;
#pragma unroll
  for (int u = 0; u < 32; ++u) p[qi][s + (u << 2)] = ev[u] * invs;
  __syncthreads();

  f32x4 pacc[2][2];
#pragma unroll
  for (int a = 0; a < 2; ++a)
#pragma unroll
    for (int b = 0; b < 2; ++b) pacc[a][b] = (f32x4){0.f, 0.f, 0.f, 0.f};
#pragma unroll
  for (int ks = 0; ks < 4; ++ks) {
    int k0 = ks * 32 + kg;
    bf16x8 ph[2], pl[2];
#pragma unroll
    for (int mi = 0; mi < 2; ++mi) {
      int arow = wm * 32 + mi * 16 + lr;
      float4 x0 = *reinterpret_cast<const float4*>(&p[arow][k0]);
      float4 x1 = *reinterpret_cast<const float4*>(&p[arow][k0 + 4]);
      float xv[8] = {x0.x, x0.y, x0.z, x0.w, x1.x, x1.y, x1.z, x1.w};
#pragma unroll
      for (int e = 0; e < 8; ++e) {
        __bf16 hh = (__bf16)xv[e];
        ph[mi][e] = hh;
        pl[mi][e] = (__bf16)(xv[e] - (float)hh);
      }
    }
#pragma unroll
    for (int ni = 0; ni < 2; ++ni) {
      int d = (wn << 5) + (ni << 4) + lr;
      bf16x8 bv = *reinterpret_cast<const bf16x8*>(vtb + ((size_t)h * 64 + d) * 2112 + nb * 64 + k0);
#pragma unroll
      for (int mi = 0; mi < 2; ++mi) {
        pacc[mi][ni] = __builtin_amdgcn_mfma_f32_16x16x32_bf16(ph[mi], bv, pacc[mi][ni], 0, 0, 0);
        pacc[mi][ni] = __builtin_amdgcn_mfma_f32_16x16x32_bf16(pl[mi], bv, pacc[mi][ni], 0, 0, 0);
      }
    }
  }
#pragma unroll
  for (int mi = 0; mi < 2; ++mi)
#pragma unroll
    for (int ni = 0; ni < 2; ++ni) {
      int d = (wn << 5) + (ni << 4) + lr;
#pragma unroll
      for (int r = 0; r < 4; ++r) {
        int qi2 = wm * 32 + mi * 16 + crow + r;
        s_out[((size_t)h * NTOK + nb * 64 + qi2) * DHEAD + d] = pacc[mi][ni][r];
      }
    }
}

// ---------------- fused strat + combine: one block per token ----------------
__global__ __launch_bounds__(256) void k_combine2(
    const bf16* __restrict__ Ah, const bf16* __restrict__ Al,
    const float* __restrict__ W, const float* __restrict__ bias,
    const float* __restrict__ c_out, const float* __restrict__ f_out,
    const float* __restrict__ s_out, bf16* __restrict__ comb) {
  const int i = blockIdx.x;
  const int t = threadIdx.x;
  __shared__ float hs[DMODEL];
  __shared__ float st[24];
  size_t ro = (size_t)i * DMODEL;
#pragma unroll
  for (int u = 0; u < 2; ++u) {
    int c = t + u * 256;
    hs[c] = __bfloat162float(Ah[ro + c]) + __bfloat162float(Al[ro + c]);
  }
  __syncthreads();
  if (t < 192) {
    int c = t >> 3, s = t & 7;
    float acc = 0.f;
    for (int u = 0; u < 64; ++u) {
      int e = s * 64 + u;
      acc = fmaf(hs[e], W[(size_t)e * 24 + c], acc);
    }
    acc += __shfl_xor(acc, 1);
    acc += __shfl_xor(acc, 2);
    acc += __shfl_xor(acc, 4);
    if (s == 0) st[c] = 1.f / (1.f + expf(-(acc + bias[c])));
  }
  __syncthreads();
#pragma unroll
  for (int u = 0; u < 2; ++u) {
    int c = t + u * 256;
    int h = c >> 6, d = c & 63;
    size_t a = ((size_t)h * NTOK + i) * DHEAD + d;
    comb[ro + c] = __float2bfloat16(st[h * 3] * c_out[a] + st[h * 3 + 1] * f_out[a]
                                    + st[h * 3 + 2] * s_out[a]);
  }
}

extern "C" void kernel_launch(void* const* d_in, const int* in_sizes, int n_in,
                              void* d_out, int out_size, void* d_ws, size_t ws_size,
                              hipStream_t stream) {
  const float* x      = (const float*)d_in[0];
  const float* g_norm = (const float*)d_in[1];
  const float* w_qkv  = (const float*)d_in[2];
  const float* k_pos  = (const float*)d_in[3];
  const float* v_pos  = (const float*)d_in[4];
  const float* mem_kv = (const float*)d_in[5];
  const float* k_w1   = (const float*)d_in[6];
  const float* k_b1   = (const float*)d_in[7];
  const float* k_w2   = (const float*)d_in[8];
  const float* k_b2   = (const float*)d_in[9];
  const float* v_w1   = (const float*)d_in[10];
  const float* v_b1   = (const float*)d_in[11];
  const float* v_w2   = (const float*)d_in[12];
  const float* v_b2   = (const float*)d_in[13];
  const float* w_comb = (const float*)d_in[14];
  const float* b_comb = (const float*)d_in[15];
  const float* w_out  = (const float*)d_in[16];
  float* out = (float*)d_out;
  char* wsb = (char*)d_ws;

  bf16* WQKV_H = (bf16*)(wsb + B_WQKV_H);
  bf16* WQKV_L = (bf16*)(wsb + B_WQKV_L);
  bf16* KW1_H  = (bf16*)(wsb + B_KW1_H);
  bf16* KW1_L  = (bf16*)(wsb + B_KW1_L);
  bf16* KW2_H  = (bf16*)(wsb + B_KW2_H);
  bf16* KW2_L  = (bf16*)(wsb + B_KW2_L);
  bf16* VW1_H  = (bf16*)(wsb + B_VW1_H);
  bf16* VW2_H  = (bf16*)(wsb + B_VW2_H);
  bf16* WOUT_H = (bf16*)(wsb + B_WOUT_H);
  bf16* HB_H   = (bf16*)(wsb + B_HB_H);
  bf16* HB_L   = (bf16*)(wsb + B_HB_L);
  bf16* QBH    = (bf16*)(wsb + B_QBH);
  bf16* QBM    = (bf16*)(wsb + B_QBM);
  bf16* QBL    = (bf16*)(wsb + B_QBL);
  float* KF    = (float*)(wsb + B_KF);
  bf16* VBH    = (bf16*)(wsb + B_VBH);
  bf16* RQH    = (bf16*)(wsb + B_RQH);
  bf16* RQL    = (bf16*)(wsb + B_RQL);
  bf16* RKH    = (bf16*)(wsb + B_RKH);
  bf16* RKL    = (bf16*)(wsb + B_RKL);
  float* RKF   = (float*)(wsb + B_RKF);
  bf16* VTB    = (bf16*)(wsb + B_VTB);
  bf16* CKT_H  = (bf16*)(wsb + B_CKT_H);
  bf16* CKT_M  = (bf16*)(wsb + B_CKT_M);
  bf16* CKT_L  = (bf16*)(wsb + B_CKT_L);
  bf16* CVT    = (bf16*)(wsb + B_CVT);
  int*   SEL   = (int*)(wsb + B_SEL);
  float* COUT  = (float*)(wsb + B_COUT);
  float* FOUT  = (float*)(wsb + B_FOUT);
  float* SOUT  = (float*)(wsb + B_SOUT);
  bf16* KW_H   = (bf16*)(wsb + B_KW_H);
  bf16* KW_L   = (bf16*)(wsb + B_KW_L);
  bf16* VW_H   = (bf16*)(wsb + B_VW_H);
  bf16* HID_H  = (bf16*)(wsb + B_HID_H);
  bf16* HID_L  = (bf16*)(wsb + B_HID_L);
  bf16* HIDV   = (bf16*)(wsb + B_HIDV);
  bf16* COMBB  = (bf16*)(wsb + B_COMBB);

  // 1. setup: weight splits + pads + mem fill + rmsnorm
  k_setup<<<5378, 256, 0, stream>>>(x, g_norm, w_qkv, k_w1, k_w2, v_w1, v_w2, w_out, mem_kv,
                                    WQKV_H, WQKV_L, KW1_H, KW1_L, KW2_H, KW2_L,
                                    VW1_H, VW2_H, WOUT_H, HB_H, HB_L,
                                    RKH, RKL, VTB, CKT_H, CKT_M, CKT_L, CVT);
  // 2. qkv: LDS-staged 128x64, 384 blocks, fused split/scatter
  k_qkv<<<384, 256, 0, stream>>>(HB_H, HB_L, WQKV_H, WQKV_L, KF, QBH, QBM, QBL, VBH);
  // 3. post: rope + v-transpose + windows
  k_post<<<10432, 256, 0, stream>>>(QBH, QBM, QBL, KF, VBH, k_pos, v_pos,
                                    RQH, RQL, RKH, RKL, RKF, VTB, KW_H, KW_L, VW_H);
  // 4. merged MLP1: LDS-staged, 512 blocks; HIDV overlays dead KF
  k_mlp1<<<512, 256, 0, stream>>>(KW_H, KW_L, KW1_H, KW1_L, k_b1,
                                  VW_H, VW1_H, v_b1, HID_H, HID_L, HIDV);
  // 5. merged MLP2 -> ckT hi/mid/lo + cvT
  k_mlp2<<<dim3(1, 32, 2), 256, 0, stream>>>(HID_H, HID_L, KW2_H, KW2_L, k_b2,
                                             HIDV, VW2_H, v_b2, CKT_H, CKT_M, CKT_L, CVT);
  // 6-8. attention branches
  k_comp_attn<<<dim3(64, 8), 256, 0, stream>>>(QBH, QBM, QBL, CKT_H, CKT_M, CKT_L, CVT, COUT, SEL);
  k_fine_attn<<<dim3(512, 8), 256, 0, stream>>>(RQH, RQL, RKF, VBH, SEL, FOUT);
  k_slide_attn<<<dim3(32, 8), 256, 0, stream>>>(RQH, RQL, RKH, RKL, VTB, SOUT);
  // 9. fused strat + combine
  k_combine2<<<NTOK, 256, 0, stream>>>(HB_H, HB_L, w_comb, b_comb, COUT, FOUT, SOUT, COMBB);
  // 10. output projection
  k_cgemm<0, 0><<<dim3(8, 32), 256, 0, stream>>>(
      COMBB, nullptr, WOUT_H, nullptr, nullptr, out, NTOK, DMODEL, DMODEL);
}

// Round 14
// 229.870 us; speedup vs baseline: 1.3327x; 1.0423x over previous
//
#include <hip/hip_runtime.h>
#include <hip/hip_bf16.h>
#include <cstddef>

#define NTOK 2048
#define DMODEL 512
#define NHEAD 8
#define DHEAD 64
#define NWIN 254          // (2048-16)/8 + 1
#define CDIM 1024         // CB*DH
#define NEGV -1000000000.0f

typedef __attribute__((ext_vector_type(8))) __bf16 bf16x8;
typedef __attribute__((ext_vector_type(4))) float f32x4;
typedef __hip_bfloat16 bf16;

// ---------------- workspace layout (byte offsets) ----------------
static const size_t B_WQKV_H = 0;          // 1536*512*2
static const size_t B_WQKV_L = 1572864;
static const size_t B_KW1_H  = 3145728;    // 1024*1024*2
static const size_t B_KW1_L  = 5242880;
static const size_t B_KW2_H  = 7340032;    // 64*1024*2
static const size_t B_KW2_L  = 7471104;
static const size_t B_VW1_H  = 7602176;
static const size_t B_VW2_H  = 9699328;
static const size_t B_WOUT_H = 9830400;    // 512*512*2
static const size_t B_HB_H   = 10354688;   // 2048*512*2
static const size_t B_HB_L   = 12451840;
static const size_t B_QBH    = 14548992;   // 8*2048*64*2 (non-roped q, hi)
static const size_t B_QBL    = 16646144;   // (lo, 3rd term)
static const size_t B_KF     = 18743296;   // 8*2048*64*4 (k fp32; dead after k_post -> HIDV)
static const size_t B_VBH    = 22937600;   // 8*2048*64*2
static const size_t B_RQH    = 25034752;   // roped q hi/lo
static const size_t B_RQL    = 27131904;
static const size_t B_RKH    = 29229056;   // 8*2112*64*2 (roped k, 64 zero-pad rows front)
static const size_t B_RKL    = 31391744;
static const size_t B_VTB    = 33554432;   // 8*64*2112*2 (v^T, 64 zero-pad cols front)
static const size_t B_CKT_H  = 35717120;   // 8*256*64*2 (compressed k rows, j=0 mem)
static const size_t B_CKT_L  = 35979264;
static const size_t B_CVT    = 36241408;   // 8*64*256*2 (compressed v transposed)
static const size_t B_SEL    = 36700160;   // 8*2048*5*4
static const size_t B_COUT   = 37027840;   // 4194304 (overlays KW_H)
static const size_t B_FOUT   = 41222144;   // 4194304 (overlays KW_L)
static const size_t B_SOUT   = 45416448;   // 4194304 (overlays VW_H)
static const size_t B_KW_H   = B_COUT;     // 2032*1024*2 = 4161536
static const size_t B_KW_L   = B_FOUT;
static const size_t B_VW_H   = B_SOUT;
static const size_t B_HID_H  = 49610752;   // 4161536 (k hidden hi)
static const size_t B_HID_L  = 53772288;   // 4161536 (k hidden lo)
static const size_t B_QBM    = 57933824;   // 8*2048*64*2 (q mid term)
static const size_t B_CKT_M  = 60030976;   // 8*256*64*2
static const size_t B_HIDV   = B_KF;       // v hidden hi (4161536 <= 4194304, KF dead)
static const size_t B_COMBB  = B_HID_H;    // 2097152 (after MLPs dead)

// ================= 32x32-per-wave GEMM core (64x64 block tile) =================
template <int COMP>
__device__ __forceinline__ void gemm_tile(
    const bf16* __restrict__ Ah, const bf16* __restrict__ Al,
    const bf16* __restrict__ Wh, const bf16* __restrict__ Wl,
    int M, int K, int row_base, int col_base, int lr, int kg,
    f32x4 accs[2][2]) {
  int ar0 = row_base + lr;       if (ar0 > M - 1) ar0 = M - 1;
  int ar1 = row_base + 16 + lr;  if (ar1 > M - 1) ar1 = M - 1;
  const size_t a0o = (size_t)ar0 * K + kg;
  const size_t a1o = (size_t)ar1 * K + kg;
  const size_t b0o = (size_t)(col_base + lr) * K + kg;
  const size_t b1o = (size_t)(col_base + 16 + lr) * K + kg;
  f32x4 acc00 = {}, acc01 = {}, acc10 = {}, acc11 = {};
  for (int k0 = 0; k0 < K; k0 += 32) {
    bf16x8 ah0 = *reinterpret_cast<const bf16x8*>(Ah + a0o + k0);
    bf16x8 ah1 = *reinterpret_cast<const bf16x8*>(Ah + a1o + k0);
    bf16x8 bh0 = *reinterpret_cast<const bf16x8*>(Wh + b0o + k0);
    bf16x8 bh1 = *reinterpret_cast<const bf16x8*>(Wh + b1o + k0);
    acc00 = __builtin_amdgcn_mfma_f32_16x16x32_bf16(ah0, bh0, acc00, 0, 0, 0);
    acc01 = __builtin_amdgcn_mfma_f32_16x16x32_bf16(ah0, bh1, acc01, 0, 0, 0);
    acc10 = __builtin_amdgcn_mfma_f32_16x16x32_bf16(ah1, bh0, acc10, 0, 0, 0);
    acc11 = __builtin_amdgcn_mfma_f32_16x16x32_bf16(ah1, bh1, acc11, 0, 0, 0);
    if constexpr (COMP) {
      bf16x8 al0 = *reinterpret_cast<const bf16x8*>(Al + a0o + k0);
      bf16x8 al1 = *reinterpret_cast<const bf16x8*>(Al + a1o + k0);
      bf16x8 bl0 = *reinterpret_cast<const bf16x8*>(Wl + b0o + k0);
      bf16x8 bl1 = *reinterpret_cast<const bf16x8*>(Wl + b1o + k0);
      acc00 = __builtin_amdgcn_mfma_f32_16x16x32_bf16(ah0, bl0, acc00, 0, 0, 0);
      acc01 = __builtin_amdgcn_mfma_f32_16x16x32_bf16(ah0, bl1, acc01, 0, 0, 0);
      acc10 = __builtin_amdgcn_mfma_f32_16x16x32_bf16(ah1, bl0, acc10, 0, 0, 0);
      acc11 = __builtin_amdgcn_mfma_f32_16x16x32_bf16(ah1, bl1, acc11, 0, 0, 0);
      acc00 = __builtin_amdgcn_mfma_f32_16x16x32_bf16(al0, bh0, acc00, 0, 0, 0);
      acc01 = __builtin_amdgcn_mfma_f32_16x16x32_bf16(al0, bh1, acc01, 0, 0, 0);
      acc10 = __builtin_amdgcn_mfma_f32_16x16x32_bf16(al1, bh0, acc10, 0, 0, 0);
      acc11 = __builtin_amdgcn_mfma_f32_16x16x32_bf16(al1, bh1, acc11, 0, 0, 0);
    }
  }
  accs[0][0] = acc00; accs[0][1] = acc01; accs[1][0] = acc10; accs[1][1] = acc11;
}

// ---------------- generic GEMM kernel (fp32 out; out-proj) ----------------
template <int EPI, int COMP>
__global__ __launch_bounds__(256) void k_cgemm(
    const bf16* __restrict__ Ah, const bf16* __restrict__ Al,
    const bf16* __restrict__ Wh, const bf16* __restrict__ Wl,
    const float* __restrict__ bias, float* __restrict__ Cf,
    int M, int K, int N) {
  const int lane = threadIdx.x & 63;
  const int w = threadIdx.x >> 6;
  const int wr = w >> 1, wc = w & 1;
  const int row_base = (blockIdx.y << 6) + (wr << 5);
  const int col_base = (blockIdx.x << 6) + (wc << 5);
  const int lr = lane & 15;
  const int kg = (lane >> 4) << 3;
  const int crow = (lane >> 4) << 2;

  f32x4 accs[2][2];
  gemm_tile<COMP>(Ah, Al, Wh, Wl, M, K, row_base, col_base, lr, kg, accs);

#pragma unroll
  for (int mi = 0; mi < 2; ++mi) {
#pragma unroll
    for (int ni = 0; ni < 2; ++ni) {
      int col = col_base + (ni << 4) + lr;
      float bv = bias ? bias[col] : 0.f;
#pragma unroll
      for (int r = 0; r < 4; ++r) {
        int row = row_base + (mi << 4) + crow + r;
        if (row < M) {
          float vv = accs[mi][ni][r] + bv;
          if (EPI == 1) vv = fmaxf(vv, 0.f);
          Cf[(size_t)row * N + col] = vv;
        }
      }
    }
  }
}

#define LDP 40

// ---------------- qkv GEMM: LDS-staged 128x64 tile, compensated, fused scatter ----------------
__global__ __launch_bounds__(256, 2) void k_qkv(
    const bf16* __restrict__ Ah, const bf16* __restrict__ Al,
    const bf16* __restrict__ Wh, const bf16* __restrict__ Wl,
    float* __restrict__ KFo, bf16* __restrict__ QH, bf16* __restrict__ QM,
    bf16* __restrict__ QL, bf16* __restrict__ VB) {
  __shared__ bf16 sAh[128 * LDP];
  __shared__ bf16 sAl[128 * LDP];
  __shared__ bf16 sBh[64 * LDP];
  __shared__ bf16 sBl[64 * LDP];

  const int t = threadIdx.x;
  const int lane = t & 63, w = t >> 6;
  const int wr = w >> 1, wc = w & 1;
  const int lr = lane & 15;
  const int kg = (lane >> 4) << 3;
  const int crow = (lane >> 4) << 2;
  const int id = blockIdx.x;
  const int row0 = (id / 24) << 7;
  const int col0 = (id % 24) << 6;

  const int qa0 = t,        ar0s = qa0 >> 2, as0 = qa0 & 3;
  const int qa1 = t + 256,  ar1s = qa1 >> 2, as1 = qa1 & 3;
  const int gr0 = row0 + ar0s;
  const int gr1 = row0 + ar1s;
  const int br = t >> 2, bs = t & 3;
  const int gbr = col0 + br;

  f32x4 acc[4][2];
#pragma unroll
  for (int a = 0; a < 4; ++a)
#pragma unroll
    for (int b = 0; b < 2; ++b) acc[a][b] = (f32x4){0.f, 0.f, 0.f, 0.f};

  for (int k0 = 0; k0 < DMODEL; k0 += 32) {
    *reinterpret_cast<bf16x8*>(&sAh[ar0s * LDP + as0 * 8]) =
        *reinterpret_cast<const bf16x8*>(Ah + (size_t)gr0 * DMODEL + k0 + as0 * 8);
    *reinterpret_cast<bf16x8*>(&sAh[ar1s * LDP + as1 * 8]) =
        *reinterpret_cast<const bf16x8*>(Ah + (size_t)gr1 * DMODEL + k0 + as1 * 8);
    *reinterpret_cast<bf16x8*>(&sBh[br * LDP + bs * 8]) =
        *reinterpret_cast<const bf16x8*>(Wh + (size_t)gbr * DMODEL + k0 + bs * 8);
    *reinterpret_cast<bf16x8*>(&sAl[ar0s * LDP + as0 * 8]) =
        *reinterpret_cast<const bf16x8*>(Al + (size_t)gr0 * DMODEL + k0 + as0 * 8);
    *reinterpret_cast<bf16x8*>(&sAl[ar1s * LDP + as1 * 8]) =
        *reinterpret_cast<const bf16x8*>(Al + (size_t)gr1 * DMODEL + k0 + as1 * 8);
    *reinterpret_cast<bf16x8*>(&sBl[br * LDP + bs * 8]) =
        *reinterpret_cast<const bf16x8*>(Wl + (size_t)gbr * DMODEL + k0 + bs * 8);
    __syncthreads();

    bf16x8 fAh[4], fBh[2], fAl[4], fBl[2];
#pragma unroll
    for (int mi = 0; mi < 4; ++mi)
      fAh[mi] = *reinterpret_cast<const bf16x8*>(&sAh[(wr * 64 + mi * 16 + lr) * LDP + kg]);
#pragma unroll
    for (int ni = 0; ni < 2; ++ni)
      fBh[ni] = *reinterpret_cast<const bf16x8*>(&sBh[(wc * 32 + ni * 16 + lr) * LDP + kg]);
#pragma unroll
    for (int mi = 0; mi < 4; ++mi)
      fAl[mi] = *reinterpret_cast<const bf16x8*>(&sAl[(wr * 64 + mi * 16 + lr) * LDP + kg]);
#pragma unroll
    for (int ni = 0; ni < 2; ++ni)
      fBl[ni] = *reinterpret_cast<const bf16x8*>(&sBl[(wc * 32 + ni * 16 + lr) * LDP + kg]);

#pragma unroll
    for (int mi = 0; mi < 4; ++mi)
#pragma unroll
      for (int ni = 0; ni < 2; ++ni)
        acc[mi][ni] = __builtin_amdgcn_mfma_f32_16x16x32_bf16(fAh[mi], fBh[ni], acc[mi][ni], 0, 0, 0);
#pragma unroll
    for (int mi = 0; mi < 4; ++mi)
#pragma unroll
      for (int ni = 0; ni < 2; ++ni) {
        acc[mi][ni] = __builtin_amdgcn_mfma_f32_16x16x32_bf16(fAh[mi], fBl[ni], acc[mi][ni], 0, 0, 0);
        acc[mi][ni] = __builtin_amdgcn_mfma_f32_16x16x32_bf16(fAl[mi], fBh[ni], acc[mi][ni], 0, 0, 0);
      }
    __syncthreads();
  }

#pragma unroll
  for (int mi = 0; mi < 4; ++mi) {
#pragma unroll
    for (int ni = 0; ni < 2; ++ni) {
      int col = col0 + wc * 32 + ni * 16 + lr;
      int which = col >> 9, rem = col & 511;
      int hh = rem >> 6, dd = rem & 63;
#pragma unroll
      for (int r = 0; r < 4; ++r) {
        int row = row0 + wr * 64 + mi * 16 + crow + r;
        float vv = acc[mi][ni][r];
        size_t o = ((size_t)hh * NTOK + row) * DHEAD + dd;
        if (which == 0) {
          bf16 h1 = __float2bfloat16(vv);
          float r1 = vv - __bfloat162float(h1);
          bf16 m1 = __float2bfloat16(r1);
          QH[o] = h1;
          QM[o] = m1;
          QL[o] = __float2bfloat16(r1 - __bfloat162float(m1));
        } else if (which == 1) {
          KFo[o] = vv;
        } else {
          VB[o] = __float2bfloat16(vv);
        }
      }
    }
  }
}

// ---------------- merged MLP1, LDS-staged (128x64 tile, BK=32, padded LDS) ----------------
__global__ __launch_bounds__(256, 2) void k_mlp1(
    const bf16* __restrict__ KWh, const bf16* __restrict__ KWl,
    const bf16* __restrict__ W1h, const bf16* __restrict__ W1l,
    const float* __restrict__ kb1,
    const bf16* __restrict__ VWh, const bf16* __restrict__ VW1h,
    const float* __restrict__ vb1,
    bf16* __restrict__ HKh, bf16* __restrict__ HKl, bf16* __restrict__ HVh) {
  __shared__ bf16 sAh[128 * LDP];
  __shared__ bf16 sAl[128 * LDP];
  __shared__ bf16 sBh[64 * LDP];
  __shared__ bf16 sBl[64 * LDP];

  const int t = threadIdx.x;
  const int lane = t & 63, w = t >> 6;
  const int wr = w >> 1, wc = w & 1;
  const int lr = lane & 15;
  const int kg = (lane >> 4) << 3;
  const int crow = (lane >> 4) << 2;
  const int M = NHEAD * NWIN;  // 2032
  const int id = blockIdx.x;
  const bool kpath = (id < 256);
  const int u = kpath ? id : id - 256;
  const int row0 = (u >> 4) << 7;
  const int col0 = (u & 15) << 6;

  const bf16* Ah = kpath ? KWh : VWh;
  const bf16* Bh = kpath ? W1h : VW1h;

  const int qa0 = t,        ar0s = qa0 >> 2, as0 = qa0 & 3;
  const int qa1 = t + 256,  ar1s = qa1 >> 2, as1 = qa1 & 3;
  int gr0 = row0 + ar0s; if (gr0 > M - 1) gr0 = M - 1;
  int gr1 = row0 + ar1s; if (gr1 > M - 1) gr1 = M - 1;
  const int br = t >> 2, bs = t & 3;
  const int gbr = col0 + br;

  f32x4 acc[4][2];
#pragma unroll
  for (int a = 0; a < 4; ++a)
#pragma unroll
    for (int b = 0; b < 2; ++b) acc[a][b] = (f32x4){0.f, 0.f, 0.f, 0.f};

  for (int k0 = 0; k0 < CDIM; k0 += 32) {
    *reinterpret_cast<bf16x8*>(&sAh[ar0s * LDP + as0 * 8]) =
        *reinterpret_cast<const bf16x8*>(Ah + (size_t)gr0 * CDIM + k0 + as0 * 8);
    *reinterpret_cast<bf16x8*>(&sAh[ar1s * LDP + as1 * 8]) =
        *reinterpret_cast<const bf16x8*>(Ah + (size_t)gr1 * CDIM + k0 + as1 * 8);
    *reinterpret_cast<bf16x8*>(&sBh[br * LDP + bs * 8]) =
        *reinterpret_cast<const bf16x8*>(Bh + (size_t)gbr * CDIM + k0 + bs * 8);
    if (kpath) {
      *reinterpret_cast<bf16x8*>(&sAl[ar0s * LDP + as0 * 8]) =
          *reinterpret_cast<const bf16x8*>(KWl + (size_t)gr0 * CDIM + k0 + as0 * 8);
      *reinterpret_cast<bf16x8*>(&sAl[ar1s * LDP + as1 * 8]) =
          *reinterpret_cast<const bf16x8*>(KWl + (size_t)gr1 * CDIM + k0 + as1 * 8);
      *reinterpret_cast<bf16x8*>(&sBl[br * LDP + bs * 8]) =
          *reinterpret_cast<const bf16x8*>(W1l + (size_t)gbr * CDIM + k0 + bs * 8);
    }
    __syncthreads();

    bf16x8 fAh[4], fBh[2], fAl[4], fBl[2];
#pragma unroll
    for (int mi = 0; mi < 4; ++mi)
      fAh[mi] = *reinterpret_cast<const bf16x8*>(&sAh[(wr * 64 + mi * 16 + lr) * LDP + kg]);
#pragma unroll
    for (int ni = 0; ni < 2; ++ni)
      fBh[ni] = *reinterpret_cast<const bf16x8*>(&sBh[(wc * 32 + ni * 16 + lr) * LDP + kg]);
    if (kpath) {
#pragma unroll
      for (int mi = 0; mi < 4; ++mi)
        fAl[mi] = *reinterpret_cast<const bf16x8*>(&sAl[(wr * 64 + mi * 16 + lr) * LDP + kg]);
#pragma unroll
      for (int ni = 0; ni < 2; ++ni)
        fBl[ni] = *reinterpret_cast<const bf16x8*>(&sBl[(wc * 32 + ni * 16 + lr) * LDP + kg]);
    }

#pragma unroll
    for (int mi = 0; mi < 4; ++mi)
#pragma unroll
      for (int ni = 0; ni < 2; ++ni)
        acc[mi][ni] = __builtin_amdgcn_mfma_f32_16x16x32_bf16(fAh[mi], fBh[ni], acc[mi][ni], 0, 0, 0);
    if (kpath) {
#pragma unroll
      for (int mi = 0; mi < 4; ++mi)
#pragma unroll
        for (int ni = 0; ni < 2; ++ni) {
          acc[mi][ni] = __builtin_amdgcn_mfma_f32_16x16x32_bf16(fAh[mi], fBl[ni], acc[mi][ni], 0, 0, 0);
          acc[mi][ni] = __builtin_amdgcn_mfma_f32_16x16x32_bf16(fAl[mi], fBh[ni], acc[mi][ni], 0, 0, 0);
        }
    }
    __syncthreads();
  }

#pragma unroll
  for (int mi = 0; mi < 4; ++mi) {
#pragma unroll
    for (int ni = 0; ni < 2; ++ni) {
      int col = col0 + wc * 32 + ni * 16 + lr;
      float bv = kpath ? kb1[col] : vb1[col];
#pragma unroll
      for (int r = 0; r < 4; ++r) {
        int row = row0 + wr * 64 + mi * 16 + crow + r;
        if (row < M) {
          float vv = fmaxf(acc[mi][ni][r] + bv, 0.f);
          size_t o = (size_t)row * CDIM + col;
          if (kpath) {
            bf16 h1 = __float2bfloat16(vv);
            HKh[o] = h1;
            HKl[o] = __float2bfloat16(vv - __bfloat162float(h1));
          } else {
            HVh[o] = __float2bfloat16(vv);
          }
        }
      }
    }
  }
}

// ---------------- merged MLP2: z=0 k-path -> ckT hi/mid/lo, z=1 v-path -> cvT ----------------
__global__ __launch_bounds__(256) void k_mlp2(
    const bf16* __restrict__ HKh, const bf16* __restrict__ HKl,
    const bf16* __restrict__ W2h, const bf16* __restrict__ W2l,
    const float* __restrict__ kb2,
    const bf16* __restrict__ HVh, const bf16* __restrict__ VW2h,
    const float* __restrict__ vb2,
    bf16* __restrict__ ckh, bf16* __restrict__ ckm, bf16* __restrict__ ckl,
    bf16* __restrict__ cvtb) {
  const int lane = threadIdx.x & 63;
  const int w = threadIdx.x >> 6;
  const int wr = w >> 1, wc = w & 1;
  const int row_base = (blockIdx.y << 6) + (wr << 5);
  const int col_base = (wc << 5);
  const int lr = lane & 15;
  const int kg = (lane >> 4) << 3;
  const int crow = (lane >> 4) << 2;
  const int M = NHEAD * NWIN;

  f32x4 accs[2][2];
  if (blockIdx.z == 0)
    gemm_tile<1>(HKh, HKl, W2h, W2l, M, CDIM, row_base, col_base, lr, kg, accs);
  else
    gemm_tile<0>(HVh, nullptr, VW2h, nullptr, M, CDIM, row_base, col_base, lr, kg, accs);

  const float* bias = (blockIdx.z == 0) ? kb2 : vb2;
#pragma unroll
  for (int mi = 0; mi < 2; ++mi) {
#pragma unroll
    for (int ni = 0; ni < 2; ++ni) {
      int col = col_base + (ni << 4) + lr;
      float bv = bias[col];
#pragma unroll
      for (int r = 0; r < 4; ++r) {
        int row = row_base + (mi << 4) + crow + r;
        if (row < M) {
          float vv = accs[mi][ni][r] + bv;
          int hh = row / NWIN, jj = row - hh * NWIN;
          if (blockIdx.z == 0) {
            size_t o = ((size_t)hh * 256 + 1 + jj) * 64 + col;
            bf16 h1 = __float2bfloat16(vv);
            float r1 = vv - __bfloat162float(h1);
            bf16 m1 = __float2bfloat16(r1);
            ckh[o] = h1;
            ckm[o] = m1;
            ckl[o] = __float2bfloat16(r1 - __bfloat162float(m1));
          } else {
            cvtb[((size_t)hh * 64 + col) * 256 + 1 + jj] = __float2bfloat16(vv);
          }
        }
      }
    }
  }
}

// ================= k_setup: 6 weight transposes + zpad + fillmem + rmsnorm =================
__device__ __forceinline__ void wt_tile(const float* __restrict__ W,
                                        bf16* __restrict__ WTh, bf16* __restrict__ WTl,
                                        int K, int N, int bx, int by,
                                        float (*tsh)[33]) {
  const int k0 = bx << 5, n0 = by << 5;
  const int tx = threadIdx.x & 31, ty = threadIdx.x >> 5;
#pragma unroll
  for (int r = 0; r < 4; ++r)
    tsh[ty + (r << 3)][tx] = W[(size_t)(k0 + ty + (r << 3)) * N + n0 + tx];
  __syncthreads();
#pragma unroll
  for (int r = 0; r < 4; ++r) {
    float val = tsh[tx][ty + (r << 3)];
    size_t o = (size_t)(n0 + ty + (r << 3)) * K + k0 + tx;
    bf16 h1 = __float2bfloat16(val);
    WTh[o] = h1;
    if (WTl) WTl[o] = __float2bfloat16(val - __bfloat162float(h1));
  }
}

__global__ __launch_bounds__(256) void k_setup(
    const float* __restrict__ x, const float* __restrict__ g,
    const float* __restrict__ w_qkv, const float* __restrict__ k_w1,
    const float* __restrict__ k_w2, const float* __restrict__ v_w1,
    const float* __restrict__ v_w2, const float* __restrict__ w_out,
    const float* __restrict__ memkv,
    bf16* __restrict__ WQKV_H, bf16* __restrict__ WQKV_L,
    bf16* __restrict__ KW1_H, bf16* __restrict__ KW1_L,
    bf16* __restrict__ KW2_H, bf16* __restrict__ KW2_L,
    bf16* __restrict__ VW1_H, bf16* __restrict__ VW2_H, bf16* __restrict__ WOUT_H,
    bf16* __restrict__ hbh, bf16* __restrict__ hbl,
    bf16* __restrict__ rkh, bf16* __restrict__ rkl, bf16* __restrict__ vtb,
    bf16* __restrict__ ckh, bf16* __restrict__ ckm, bf16* __restrict__ ckl,
    bf16* __restrict__ cvtb) {
  __shared__ float tsh[32][33];
  __shared__ float wsum[4];
  __shared__ float scale_s;
  const int id = blockIdx.x;
  const int t = threadIdx.x;

  if (id < 768) {
    wt_tile(w_qkv, WQKV_H, WQKV_L, DMODEL, 1536, id % 16, id / 16, tsh);
  } else if (id < 1792) {
    int u = id - 768;  wt_tile(k_w1, KW1_H, KW1_L, CDIM, CDIM, u % 32, u / 32, tsh);
  } else if (id < 1856) {
    int u = id - 1792; wt_tile(k_w2, KW2_H, KW2_L, CDIM, DHEAD, u % 32, u / 32, tsh);
  } else if (id < 2880) {
    int u = id - 1856; wt_tile(v_w1, VW1_H, nullptr, CDIM, CDIM, u % 32, u / 32, tsh);
  } else if (id < 2944) {
    int u = id - 2880; wt_tile(v_w2, VW2_H, nullptr, CDIM, DHEAD, u % 32, u / 32, tsh);
  } else if (id < 3200) {
    int u = id - 2944; wt_tile(w_out, WOUT_H, nullptr, DMODEL, DMODEL, u % 16, u / 16, tsh);
  } else if (id < 3328) {
    int idx = (id - 3200) * 256 + t;   // [0, 32768)
    int h = idx >> 12, r = (idx >> 6) & 63, c = idx & 63;
    bf16 z = __float2bfloat16(0.f);
    rkh[((size_t)h * 2112 + r) * 64 + c] = z;
    rkl[((size_t)h * 2112 + r) * 64 + c] = z;
    vtb[((size_t)h * 64 + r) * 2112 + c] = z;
  } else if (id < 3330) {
    int u = (id - 3328) * 256 + t;     // [0, 512)
    if (u < 512) {
      int h = u >> 6, e = u & 63;
      float kv = memkv[(size_t)h * DHEAD + e];
      bf16 h1 = __float2bfloat16(kv);
      float r1 = kv - __bfloat162float(h1);
      bf16 m1 = __float2bfloat16(r1);
      ckh[((size_t)h * 256) * 64 + e] = h1;
      ckm[((size_t)h * 256) * 64 + e] = m1;
      ckl[((size_t)h * 256) * 64 + e] = __float2bfloat16(r1 - __bfloat162float(m1));
      bf16 z = __float2bfloat16(0.f);
      ckh[((size_t)h * 256 + 255) * 64 + e] = z;
      ckm[((size_t)h * 256 + 255) * 64 + e] = z;
      ckl[((size_t)h * 256 + 255) * 64 + e] = z;
      float vv = memkv[(size_t)(NHEAD + h) * DHEAD + e];
      cvtb[((size_t)h * 64 + e) * 256 + 0] = __float2bfloat16(vv);
      cvtb[((size_t)h * 64 + e) * 256 + 255] = z;
    }
  } else {
    const int row = id - 3330;
    const float* xr = x + (size_t)row * DMODEL;
    float s = 0.f;
    for (int c = t; c < DMODEL; c += 256) { float v = xr[c]; s += v * v; }
    for (int o = 32; o > 0; o >>= 1) s += __shfl_down(s, o);
    if ((t & 63) == 0) wsum[t >> 6] = s;
    __syncthreads();
    if (t == 0) {
      float tot = wsum[0] + wsum[1] + wsum[2] + wsum[3];
      scale_s = rsqrtf(tot * (1.f / DMODEL) + 1e-6f);
    }
    __syncthreads();
    float sc = scale_s;
    for (int c = t; c < DMODEL; c += 256) {
      float v = xr[c] * sc * g[c];
      bf16 h1 = __float2bfloat16(v);
      hbh[(size_t)row * DMODEL + c] = h1;
      hbl[(size_t)row * DMODEL + c] = __float2bfloat16(v - __bfloat162float(h1));
    }
  }
}

// ================= k_post: rope + v-transpose + compression windows =================
__global__ __launch_bounds__(256) void k_post(
    const bf16* __restrict__ qbh, const bf16* __restrict__ qbm,
    const bf16* __restrict__ qbl, const float* __restrict__ kf,
    const bf16* __restrict__ vbh,
    const float* __restrict__ kpos, const float* __restrict__ vpos,
    bf16* __restrict__ rqh, bf16* __restrict__ rql,
    bf16* __restrict__ rkh, bf16* __restrict__ rkl,
    bf16* __restrict__ vtb,
    bf16* __restrict__ kwh, bf16* __restrict__ kwl, bf16* __restrict__ vwh) {
  __shared__ bf16 tile[64][65];
  const int id = blockIdx.x;
  const int t = threadIdx.x;

  if (id < 2048) {
    int idx = id * 256 + t;
    int i = idx & 31;
    int n = (idx >> 5) & (NTOK - 1);
    int h = idx >> 16;
    float ex = (float)(2 * i) * (1.f / 64.f);
    float inv = exp2f(-ex * 13.287712379549449f);
    float ang = (float)n * inv;
    float sn, cs;
    sincosf(ang, &sn, &cs);
    size_t base = ((size_t)h * NTOK + n) * DHEAD + 2 * i;
    float q1 = __bfloat162float(qbh[base]) + __bfloat162float(qbm[base]) + __bfloat162float(qbl[base]);
    float q2 = __bfloat162float(qbh[base + 1]) + __bfloat162float(qbm[base + 1]) + __bfloat162float(qbl[base + 1]);
    float r1 = q1 * cs - q2 * sn, r2 = q1 * sn + q2 * cs;
    bf16 h1 = __float2bfloat16(r1);
    rqh[base] = h1; rql[base] = __float2bfloat16(r1 - __bfloat162float(h1));
    h1 = __float2bfloat16(r2);
    rqh[base + 1] = h1; rql[base + 1] = __float2bfloat16(r2 - __bfloat162float(h1));
    float k1 = kf[base], k2 = kf[base + 1];
    float s1 = k1 * cs - k2 * sn, s2 = k1 * sn + k2 * cs;
    size_t kb = ((size_t)h * 2112 + 64 + n) * DHEAD + 2 * i;
    h1 = __float2bfloat16(s1);
    rkh[kb] = h1; rkl[kb] = __float2bfloat16(s1 - __bfloat162float(h1));
    h1 = __float2bfloat16(s2);
    rkh[kb + 1] = h1; rkl[kb + 1] = __float2bfloat16(s2 - __bfloat162float(h1));
  } else if (id < 2304) {
    int u = id - 2048;
    int h = u >> 5, n0 = (u & 31) << 6;
    int tx = t & 63, ty = t >> 6;
    for (int r = ty; r < 64; r += 4)
      tile[r][tx] = vbh[((size_t)h * NTOK + n0 + r) * DHEAD + tx];
    __syncthreads();
    for (int r = ty; r < 64; r += 4)
      vtb[((size_t)h * 64 + r) * 2112 + 64 + n0 + tx] = tile[tx][r];
  } else {
    int idx = (id - 2304) * 256 + t;   // [0, 2080768)
    int d = idx & 63;
    int c = (idx >> 6) & 15;
    int j = (idx >> 10) % NWIN;
    int h = idx / (NWIN << 10);
    int srcpos = (j << 3) + c;
    size_t src = ((size_t)h * NTOK + srcpos) * DHEAD + d;
    size_t pp = ((size_t)h * 16 + c) * DHEAD + d;
    float kv = kf[src] + kpos[pp];
    bf16 h1 = __float2bfloat16(kv);
    kwh[idx] = h1;
    kwl[idx] = __float2bfloat16(kv - __bfloat162float(h1));
    vwh[idx] = __float2bfloat16(__bfloat162float(vbh[src]) + vpos[pp]);
  }
}

// ---------------- compression attention (MFMA, 32 queries/block) ----------------
__global__ __launch_bounds__(256) void k_comp_attn(
    const bf16* __restrict__ qbh, const bf16* __restrict__ qbm, const bf16* __restrict__ qbl,
    const bf16* __restrict__ ckh, const bf16* __restrict__ ckm, const bf16* __restrict__ ckl,
    const bf16* __restrict__ cvtb,
    float* __restrict__ c_out, int* __restrict__ sel) {
  const int h = blockIdx.y;
  const int i0 = blockIdx.x << 5;
  const int t = threadIdx.x;
  const int w = t >> 6, lane = t & 63;
  const int lr = lane & 15, kg = (lane >> 4) << 3;
  const int crow = (lane >> 4) << 2;

  __shared__ float p[32][260];

  bf16x8 aH[2][2], aM[2][2], aL[2][2];
#pragma unroll
  for (int mi = 0; mi < 2; ++mi) {
    size_t qo = ((size_t)h * NTOK + i0 + mi * 16 + lr) * DHEAD + kg;
#pragma unroll
    for (int ks = 0; ks < 2; ++ks) {
      aH[mi][ks] = *reinterpret_cast<const bf16x8*>(qbh + qo + ks * 32);
      aM[mi][ks] = *reinterpret_cast<const bf16x8*>(qbm + qo + ks * 32);
      aL[mi][ks] = *reinterpret_cast<const bf16x8*>(qbl + qo + ks * 32);
    }
  }
  f32x4 acc[2][4];
#pragma unroll
  for (int a = 0; a < 2; ++a)
#pragma unroll
    for (int b = 0; b < 4; ++b) acc[a][b] = (f32x4){0.f, 0.f, 0.f, 0.f};
#pragma unroll
  for (int ni = 0; ni < 4; ++ni) {
    int col = (w << 6) + (ni << 4) + lr;
    size_t ko = ((size_t)h * 256 + col) * 64 + kg;
#pragma unroll
    for (int ks = 0; ks < 2; ++ks) {
      bf16x8 bH = *reinterpret_cast<const bf16x8*>(ckh + ko + ks * 32);
      bf16x8 bM = *reinterpret_cast<const bf16x8*>(ckm + ko + ks * 32);
      bf16x8 bL = *reinterpret_cast<const bf16x8*>(ckl + ko + ks * 32);
#pragma unroll
      for (int mi = 0; mi < 2; ++mi) {
        acc[mi][ni] = __builtin_amdgcn_mfma_f32_16x16x32_bf16(aH[mi][ks], bH, acc[mi][ni], 0, 0, 0);
        acc[mi][ni] = __builtin_amdgcn_mfma_f32_16x16x32_bf16(aH[mi][ks], bM, acc[mi][ni], 0, 0, 0);
        acc[mi][ni] = __builtin_amdgcn_mfma_f32_16x16x32_bf16(aM[mi][ks], bH, acc[mi][ni], 0, 0, 0);
        acc[mi][ni] = __builtin_amdgcn_mfma_f32_16x16x32_bf16(aH[mi][ks], bL, acc[mi][ni], 0, 0, 0);
        acc[mi][ni] = __builtin_amdgcn_mfma_f32_16x16x32_bf16(aL[mi][ks], bH, acc[mi][ni], 0, 0, 0);
        acc[mi][ni] = __builtin_amdgcn_mfma_f32_16x16x32_bf16(aM[mi][ks], bM, acc[mi][ni], 0, 0, 0);
      }
    }
  }
#pragma unroll
  for (int mi = 0; mi < 2; ++mi)
#pragma unroll
    for (int ni = 0; ni < 4; ++ni) {
      int col = (w << 6) + (ni << 4) + lr;
      int wend = (col == 0) ? -1 : ((col - 1) << 3) + 15;
#pragma unroll
      for (int r = 0; r < 4; ++r) {
        int qi = mi * 16 + crow + r;
        bool ok = (col < 255) && (wend < i0 + qi);
        p[qi][col] = ok ? acc[mi][ni][r] * 0.125f : NEGV;
      }
    }
  __syncthreads();

  const int qi = t >> 3, s = t & 7;
  float ev[32];
  float mx = -3.0e38f;
#pragma unroll
  for (int u = 0; u < 32; ++u) { ev[u] = p[qi][s + (u << 3)]; mx = fmaxf(mx, ev[u]); }
  mx = fmaxf(mx, __shfl_xor(mx, 1));
  mx = fmaxf(mx, __shfl_xor(mx, 2));
  mx = fmaxf(mx, __shfl_xor(mx, 4));
  float sum = 0.f;
#pragma unroll
  for (int u = 0; u < 32; ++u) { float e = __expf(ev[u] - mx); ev[u] = e; sum += e; }
  sum += __shfl_xor(sum, 1); sum += __shfl_xor(sum, 2); sum += __shfl_xor(sum, 4);
  float invs = 1.f / sum;
#pragma unroll
  for (int u = 0; u < 32; ++u) p[qi][s + (u << 3)] = ev[u] * invs;

  int qblk = (i0 + qi) >> 4;
  float vals[16];
#pragma unroll
  for (int u = 0; u < 16; ++u) {
    int f = (s << 4) + u;
    float v;
    if (f >= qblk || f == 127) v = NEGV;
    else v = (p[qi][2 * f + 1] + p[qi][2 * f + 2]) * 0.5f;
    vals[u] = v;
  }
  int base = ((h << 11) | (i0 + qi)) * 5;
  for (int kk = 0; kk < 4; ++kk) {
    float bv = -3.0e38f; int bi = 0;
#pragma unroll
    for (int u = 0; u < 16; ++u) {
      if (vals[u] > bv) { bv = vals[u]; bi = (s << 4) + u; }
    }
#pragma unroll
    for (int o = 1; o < 8; o <<= 1) {
      float ov = __shfl_xor(bv, o);
      int oi = __shfl_xor(bi, o);
      if (ov > bv || (ov == bv && oi < bi)) { bv = ov; bi = oi; }
    }
    if (s == 0) sel[base + kk] = (bv > -5.0e8f) ? bi : -1;
    if ((bi >> 4) == s) vals[bi & 15] = -3.0e38f;
  }
  if (s == 0) sel[base + 4] = (i0 + qi) >> 4;
  __syncthreads();

  const int wm = w >> 1, wn = w & 1;
  const int arow = wm * 16 + lr;
  f32x4 pacc[2];
#pragma unroll
  for (int b = 0; b < 2; ++b) pacc[b] = (f32x4){0.f, 0.f, 0.f, 0.f};
#pragma unroll
  for (int ks = 0; ks < 8; ++ks) {
    int k0 = ks * 32 + kg;
    float4 x0 = *reinterpret_cast<const float4*>(&p[arow][k0]);
    float4 x1 = *reinterpret_cast<const float4*>(&p[arow][k0 + 4]);
    float xv[8] = {x0.x, x0.y, x0.z, x0.w, x1.x, x1.y, x1.z, x1.w};
    bf16x8 ph, pl;
#pragma unroll
    for (int e = 0; e < 8; ++e) {
      __bf16 hh = (__bf16)xv[e];
      ph[e] = hh;
      pl[e] = (__bf16)(xv[e] - (float)hh);
    }
#pragma unroll
    for (int ni = 0; ni < 2; ++ni) {
      int d = (wn << 5) + (ni << 4) + lr;
      bf16x8 bv = *reinterpret_cast<const bf16x8*>(cvtb + ((size_t)h * 64 + d) * 256 + k0);
      pacc[ni] = __builtin_amdgcn_mfma_f32_16x16x32_bf16(ph, bv, pacc[ni], 0, 0, 0);
      pacc[ni] = __builtin_amdgcn_mfma_f32_16x16x32_bf16(pl, bv, pacc[ni], 0, 0, 0);
    }
  }
#pragma unroll
  for (int ni = 0; ni < 2; ++ni) {
    int d = (wn << 5) + (ni << 4) + lr;
#pragma unroll
    for (int r = 0; r < 4; ++r) {
      int q2 = wm * 16 + crow + r;
      c_out[((size_t)h * NTOK + i0 + q2) * DHEAD + d] = pacc[ni][r];
    }
  }
}

// ======== fused fine + sliding attention ========
// grid 4352 blocks: id<256 -> slide (MFMA-dense, dispatched first to fill CUs);
// id>=256 -> fine (gather/latency-bound). LDS shared via raw buffer.
__global__ __launch_bounds__(256) void k_fs_attn(
    const bf16* __restrict__ rqh, const bf16* __restrict__ rql,
    const bf16* __restrict__ rkh, const bf16* __restrict__ rkl,
    const bf16* __restrict__ vbh, const bf16* __restrict__ vtb,
    const int* __restrict__ sel,
    float* __restrict__ f_out, float* __restrict__ s_out) {
  __shared__ char smraw[64 * 132 * 4];   // 33792 B (slide needs all; fine ~2.4KB)
  const int blk = blockIdx.x;
  const int t = threadIdx.x;

  if (blk < 256) {
    // ================= sliding-window attention =================
    float (*p)[132] = reinterpret_cast<float(*)[132]>(smraw);
    const int h = blk >> 5, nb = blk & 31;
    const int w = t >> 6, lane = t & 63;
    const int lr = lane & 15, kg = (lane >> 4) << 3;
    const int crow = (lane >> 4) << 2;
    const int wm = w >> 1, wn = w & 1;

    bf16x8 aH[2][2], aL[2][2];
#pragma unroll
    for (int mi = 0; mi < 2; ++mi) {
      size_t qo = ((size_t)h * NTOK + nb * 64 + wm * 32 + mi * 16 + lr) * DHEAD + kg;
#pragma unroll
      for (int ks = 0; ks < 2; ++ks) {
        aH[mi][ks] = *reinterpret_cast<const bf16x8*>(rqh + qo + ks * 32);
        aL[mi][ks] = *reinterpret_cast<const bf16x8*>(rql + qo + ks * 32);
      }
    }
    f32x4 acc[2][4];
#pragma unroll
    for (int a = 0; a < 2; ++a)
#pragma unroll
      for (int b = 0; b < 4; ++b) acc[a][b] = (f32x4){0.f, 0.f, 0.f, 0.f};
#pragma unroll
    for (int ni = 0; ni < 4; ++ni) {
      int col = (wn << 6) + (ni << 4) + lr;
      size_t ko = ((size_t)h * 2112 + nb * 64 + col) * 64 + kg;
#pragma unroll
      for (int ks = 0; ks < 2; ++ks) {
        bf16x8 bH = *reinterpret_cast<const bf16x8*>(rkh + ko + ks * 32);
        bf16x8 bL = *reinterpret_cast<const bf16x8*>(rkl + ko + ks * 32);
#pragma unroll
        for (int mi = 0; mi < 2; ++mi) {
          acc[mi][ni] = __builtin_amdgcn_mfma_f32_16x16x32_bf16(aH[mi][ks], bH, acc[mi][ni], 0, 0, 0);
          acc[mi][ni] = __builtin_amdgcn_mfma_f32_16x16x32_bf16(aL[mi][ks], bH, acc[mi][ni], 0, 0, 0);
          acc[mi][ni] = __builtin_amdgcn_mfma_f32_16x16x32_bf16(aH[mi][ks], bL, acc[mi][ni], 0, 0, 0);
        }
      }
    }
#pragma unroll
    for (int mi = 0; mi < 2; ++mi)
#pragma unroll
      for (int ni = 0; ni < 4; ++ni) {
        int col = (wn << 6) + (ni << 4) + lr;
#pragma unroll
        for (int r = 0; r < 4; ++r) {
          int qi2 = wm * 32 + mi * 16 + crow + r;
          bool ok = (col >= qi2 + 1) && (col <= qi2 + 64) && (nb > 0 || col >= 64);
          p[qi2][col] = ok ? acc[mi][ni][r] * 0.125f : NEGV;
        }
      }
    __syncthreads();

    const int qi = t >> 2, s = t & 3;
    float ev[32];
    float mx = -3.0e38f;
#pragma unroll
    for (int u = 0; u < 32; ++u) { ev[u] = p[qi][s + (u << 2)]; mx = fmaxf(mx, ev[u]); }
    mx = fmaxf(mx, __shfl_xor(mx, 1));
    mx = fmaxf(mx, __shfl_xor(mx, 2));
    float sum = 0.f;
#pragma unroll
    for (int u = 0; u < 32; ++u) { float e = __expf(ev[u] - mx); ev[u] = e; sum += e; }
    sum += __shfl_xor(sum, 1); sum += __shfl_xor(sum, 2);
    float invs = 1.f / sum;
#pragma unroll
    for (int u = 0; u < 32; ++u) p[qi][s + (u << 2)] = ev[u] * invs;
    __syncthreads();

    f32x4 pacc[2][2];
#pragma unroll
    for (int a = 0; a < 2; ++a)
#pragma unroll
      for (int b = 0; b < 2; ++b) pacc[a][b] = (f32x4){0.f, 0.f, 0.f, 0.f};
#pragma unroll
    for (int ks = 0; ks < 4; ++ks) {
      int k0 = ks * 32 + kg;
      bf16x8 ph[2], pl[2];
#pragma unroll
      for (int mi = 0; mi < 2; ++mi) {
        int arow = wm * 32 + mi * 16 + lr;
        float4 x0 = *reinterpret_cast<const float4*>(&p[arow][k0]);
        float4 x1 = *reinterpret_cast<const float4*>(&p[arow][k0 + 4]);
        float xv[8] = {x0.x, x0.y, x0.z, x0.w, x1.x, x1.y, x1.z, x1.w};
#pragma unroll
        for (int e = 0; e < 8; ++e) {
          __bf16 hh = (__bf16)xv[e];
          ph[mi][e] = hh;
          pl[mi][e] = (__bf16)(xv[e] - (float)hh);
        }
      }
#pragma unroll
      for (int ni = 0; ni < 2; ++ni) {
        int d = (wn << 5) + (ni << 4) + lr;
        bf16x8 bv = *reinterpret_cast<const bf16x8*>(vtb + ((size_t)h * 64 + d) * 2112 + nb * 64 + k0);
#pragma unroll
        for (int mi = 0; mi < 2; ++mi) {
          pacc[mi][ni] = __builtin_amdgcn_mfma_f32_16x16x32_bf16(ph[mi], bv, pacc[mi][ni], 0, 0, 0);
          pacc[mi][ni] = __builtin_amdgcn_mfma_f32_16x16x32_bf16(pl[mi], bv, pacc[mi][ni], 0, 0, 0);
        }
      }
    }
#pragma unroll
    for (int mi = 0; mi < 2; ++mi)
#pragma unroll
      for (int ni = 0; ni < 2; ++ni) {
        int d = (wn << 5) + (ni << 4) + lr;
#pragma unroll
        for (int r = 0; r < 4; ++r) {
          int qi2 = wm * 32 + mi * 16 + crow + r;
          s_out[((size_t)h * NTOK + nb * 64 + qi2) * DHEAD + d] = pacc[mi][ni][r];
        }
      }
  } else {
    // ================= fine attention (1 wave/query, bf16-hi K) =================
    float (*qs)[64] = reinterpret_cast<float(*)[64]>(smraw);
    float (*pb)[80] = reinterpret_cast<float(*)[80]>(smraw + 4 * 64 * 4);
    int (*selb)[5]  = reinterpret_cast<int(*)[5]>(smraw + 4 * 64 * 4 + 4 * 80 * 4);

    const int u = blk - 256;
    const int h = u >> 9;
    const int wid = t >> 6;
    const int lane = t & 63;
    const int i = ((u & 511) << 2) | wid;

    size_t qoff = ((size_t)h * NTOK + i) * DHEAD + lane;
    qs[wid][lane] = __bfloat162float(rqh[qoff]) + __bfloat162float(rql[qoff]);
    if (lane < 5) selb[wid][lane] = sel[((h << 11) | i) * 5 + lane];
    __syncthreads();

    int sblk[5];
#pragma unroll
    for (int b = 0; b < 5; ++b) sblk[b] = selb[wid][b];

    // prefetch V into registers (latency hides under QK)
    unsigned short vreg[80];
#pragma unroll
    for (int b = 0; b < 5; ++b) {
      int kb = sblk[b] < 0 ? 0 : sblk[b];
      const unsigned short* vr = reinterpret_cast<const unsigned short*>(
          vbh + ((size_t)h * NTOK + ((size_t)kb << 4)) * DHEAD + lane);
#pragma unroll
      for (int uu = 0; uu < 16; ++uu)
        vreg[b * 16 + uu] = vr[(size_t)uu * DHEAD];
    }

    // QK with bf16-hi K: 8 x 16B loads per key (half the gather transactions)
    float sim0 = NEGV, sim1 = NEGV;
    {
      int kb = sblk[lane >> 4];
      int pos = (kb << 4) + (lane & 15);
      if (kb >= 0 && pos <= i) {
        const bf16* kp = rkh + ((size_t)h * 2112 + 64 + pos) * DHEAD;
        float d = 0.f;
#pragma unroll
        for (int e8 = 0; e8 < 8; ++e8) {
          bf16x8 kv = *reinterpret_cast<const bf16x8*>(kp + e8 * 8);
#pragma unroll
          for (int e = 0; e < 8; ++e)
            d = fmaf(qs[wid][e8 * 8 + e], (float)kv[e], d);
        }
        sim0 = d * 0.125f;
      }
    }
    if (lane < 16) {
      int kb = sblk[4];
      int pos = (kb << 4) + lane;
      if (pos <= i) {
        const bf16* kp = rkh + ((size_t)h * 2112 + 64 + pos) * DHEAD;
        float d = 0.f;
#pragma unroll
        for (int e8 = 0; e8 < 8; ++e8) {
          bf16x8 kv = *reinterpret_cast<const bf16x8*>(kp + e8 * 8);
#pragma unroll
          for (int e = 0; e < 8; ++e)
            d = fmaf(qs[wid][e8 * 8 + e], (float)kv[e], d);
        }
        sim1 = d * 0.125f;
      }
    }

    float mx = fmaxf(sim0, sim1);
#pragma unroll
    for (int o = 32; o > 0; o >>= 1) mx = fmaxf(mx, __shfl_xor(mx, o));
    float e0 = __expf(sim0 - mx);
    float e1 = __expf(sim1 - mx);
    float sum = e0 + e1;
#pragma unroll
    for (int o = 32; o > 0; o >>= 1) sum += __shfl_xor(sum, o);
    float invs = 1.f / sum;
    pb[wid][lane] = e0 * invs;
    if (lane < 16) pb[wid][64 + lane] = e1 * invs;
    // same wave writes & reads pb[wid]: DS ops wave-ordered, no barrier needed

    float acc = 0.f;
#pragma unroll
    for (int j = 0; j < 80; ++j) {
      bf16 bv;
      *reinterpret_cast<unsigned short*>(&bv) = vreg[j];
      acc = fmaf(pb[wid][j], __bfloat162float(bv), acc);
    }
    f_out[((size_t)h * NTOK + i) * DHEAD + lane] = acc;
  }
}

// ---------------- fused strat + combine: one block per token ----------------
__global__ __launch_bounds__(256) void k_combine2(
    const bf16* __restrict__ Ah, const bf16* __restrict__ Al,
    const float* __restrict__ W, const float* __restrict__ bias,
    const float* __restrict__ c_out, const float* __restrict__ f_out,
    const float* __restrict__ s_out, bf16* __restrict__ comb) {
  const int i = blockIdx.x;
  const int t = threadIdx.x;
  __shared__ float hs[DMODEL];
  __shared__ float st[24];
  size_t ro = (size_t)i * DMODEL;
#pragma unroll
  for (int u = 0; u < 2; ++u) {
    int c = t + u * 256;
    hs[c] = __bfloat162float(Ah[ro + c]) + __bfloat162float(Al[ro + c]);
  }
  __syncthreads();
  if (t < 192) {
    int c = t >> 3, s = t & 7;
    float acc = 0.f;
    for (int u = 0; u < 64; ++u) {
      int e = s * 64 + u;
      acc = fmaf(hs[e], W[(size_t)e * 24 + c], acc);
    }
    acc += __shfl_xor(acc, 1);
    acc += __shfl_xor(acc, 2);
    acc += __shfl_xor(acc, 4);
    if (s == 0) st[c] = 1.f / (1.f + expf(-(acc + bias[c])));
  }
  __syncthreads();
#pragma unroll
  for (int u = 0; u < 2; ++u) {
    int c = t + u * 256;
    int h = c >> 6, d = c & 63;
    size_t a = ((size_t)h * NTOK + i) * DHEAD + d;
    comb[ro + c] = __float2bfloat16(st[h * 3] * c_out[a] + st[h * 3 + 1] * f_out[a]
                                    + st[h * 3 + 2] * s_out[a]);
  }
}

extern "C" void kernel_launch(void* const* d_in, const int* in_sizes, int n_in,
                              void* d_out, int out_size, void* d_ws, size_t ws_size,
                              hipStream_t stream) {
  const float* x      = (const float*)d_in[0];
  const float* g_norm = (const float*)d_in[1];
  const float* w_qkv  = (const float*)d_in[2];
  const float* k_pos  = (const float*)d_in[3];
  const float* v_pos  = (const float*)d_in[4];
  const float* mem_kv = (const float*)d_in[5];
  const float* k_w1   = (const float*)d_in[6];
  const float* k_b1   = (const float*)d_in[7];
  const float* k_w2   = (const float*)d_in[8];
  const float* k_b2   = (const float*)d_in[9];
  const float* v_w1   = (const float*)d_in[10];
  const float* v_b1   = (const float*)d_in[11];
  const float* v_w2   = (const float*)d_in[12];
  const float* v_b2   = (const float*)d_in[13];
  const float* w_comb = (const float*)d_in[14];
  const float* b_comb = (const float*)d_in[15];
  const float* w_out  = (const float*)d_in[16];
  float* out = (float*)d_out;
  char* wsb = (char*)d_ws;

  bf16* WQKV_H = (bf16*)(wsb + B_WQKV_H);
  bf16* WQKV_L = (bf16*)(wsb + B_WQKV_L);
  bf16* KW1_H  = (bf16*)(wsb + B_KW1_H);
  bf16* KW1_L  = (bf16*)(wsb + B_KW1_L);
  bf16* KW2_H  = (bf16*)(wsb + B_KW2_H);
  bf16* KW2_L  = (bf16*)(wsb + B_KW2_L);
  bf16* VW1_H  = (bf16*)(wsb + B_VW1_H);
  bf16* VW2_H  = (bf16*)(wsb + B_VW2_H);
  bf16* WOUT_H = (bf16*)(wsb + B_WOUT_H);
  bf16* HB_H   = (bf16*)(wsb + B_HB_H);
  bf16* HB_L   = (bf16*)(wsb + B_HB_L);
  bf16* QBH    = (bf16*)(wsb + B_QBH);
  bf16* QBM    = (bf16*)(wsb + B_QBM);
  bf16* QBL    = (bf16*)(wsb + B_QBL);
  float* KF    = (float*)(wsb + B_KF);
  bf16* VBH    = (bf16*)(wsb + B_VBH);
  bf16* RQH    = (bf16*)(wsb + B_RQH);
  bf16* RQL    = (bf16*)(wsb + B_RQL);
  bf16* RKH    = (bf16*)(wsb + B_RKH);
  bf16* RKL    = (bf16*)(wsb + B_RKL);
  bf16* VTB    = (bf16*)(wsb + B_VTB);
  bf16* CKT_H  = (bf16*)(wsb + B_CKT_H);
  bf16* CKT_M  = (bf16*)(wsb + B_CKT_M);
  bf16* CKT_L  = (bf16*)(wsb + B_CKT_L);
  bf16* CVT    = (bf16*)(wsb + B_CVT);
  int*   SEL   = (int*)(wsb + B_SEL);
  float* COUT  = (float*)(wsb + B_COUT);
  float* FOUT  = (float*)(wsb + B_FOUT);
  float* SOUT  = (float*)(wsb + B_SOUT);
  bf16* KW_H   = (bf16*)(wsb + B_KW_H);
  bf16* KW_L   = (bf16*)(wsb + B_KW_L);
  bf16* VW_H   = (bf16*)(wsb + B_VW_H);
  bf16* HID_H  = (bf16*)(wsb + B_HID_H);
  bf16* HID_L  = (bf16*)(wsb + B_HID_L);
  bf16* HIDV   = (bf16*)(wsb + B_HIDV);
  bf16* COMBB  = (bf16*)(wsb + B_COMBB);

  // 1. setup: weight splits + pads + mem fill + rmsnorm
  k_setup<<<5378, 256, 0, stream>>>(x, g_norm, w_qkv, k_w1, k_w2, v_w1, v_w2, w_out, mem_kv,
                                    WQKV_H, WQKV_L, KW1_H, KW1_L, KW2_H, KW2_L,
                                    VW1_H, VW2_H, WOUT_H, HB_H, HB_L,
                                    RKH, RKL, VTB, CKT_H, CKT_M, CKT_L, CVT);
  // 2. qkv: LDS-staged 128x64, 384 blocks, fused split/scatter
  k_qkv<<<384, 256, 0, stream>>>(HB_H, HB_L, WQKV_H, WQKV_L, KF, QBH, QBM, QBL, VBH);
  // 3. post: rope + v-transpose + windows
  k_post<<<10432, 256, 0, stream>>>(QBH, QBM, QBL, KF, VBH, k_pos, v_pos,
                                    RQH, RQL, RKH, RKL, VTB, KW_H, KW_L, VW_H);
  // 4. merged MLP1: LDS-staged, 512 blocks; HIDV overlays dead KF
  k_mlp1<<<512, 256, 0, stream>>>(KW_H, KW_L, KW1_H, KW1_L, k_b1,
                                  VW_H, VW1_H, v_b1, HID_H, HID_L, HIDV);
  // 5. merged MLP2 -> ckT hi/mid/lo + cvT
  k_mlp2<<<dim3(1, 32, 2), 256, 0, stream>>>(HID_H, HID_L, KW2_H, KW2_L, k_b2,
                                             HIDV, VW2_H, v_b2, CKT_H, CKT_M, CKT_L, CVT);
  // 6. compression attention + selection
  k_comp_attn<<<dim3(64, 8), 256, 0, stream>>>(QBH, QBM, QBL, CKT_H, CKT_M, CKT_L, CVT, COUT, SEL);
  // 7. fused slide (256 blocks, first) + fine (4096 blocks) attention
  k_fs_attn<<<4352, 256, 0, stream>>>(RQH, RQL, RKH, RKL, VBH, VTB, SEL, FOUT, SOUT);
  // 8. fused strat + combine
  k_combine2<<<NTOK, 256, 0, stream>>>(HB_H, HB_L, w_comb, b_comb, COUT, FOUT, SOUT, COMBB);
  // 9. output projection
  k_cgemm<0, 0><<<dim3(8, 32), 256, 0, stream>>>(
      COMBB, nullptr, WOUT_H, nullptr, nullptr, out, NTOK, DMODEL, DMODEL);
}

// Round 15
// 225.560 us; speedup vs baseline: 1.3582x; 1.0191x over previous
//
#include <hip/hip_runtime.h>
#include <hip/hip_bf16.h>
#include <cstddef>

#define NTOK 2048
#define DMODEL 512
#define NHEAD 8
#define DHEAD 64
#define NWIN 254          // (2048-16)/8 + 1
#define CDIM 1024         // CB*DH
#define NEGV -1000000000.0f

typedef __attribute__((ext_vector_type(8))) __bf16 bf16x8;
typedef __attribute__((ext_vector_type(4))) float f32x4;
typedef __hip_bfloat16 bf16;

// ---------------- workspace layout (byte offsets) ----------------
static const size_t B_WQKV_H = 0;          // 1536*512*2
static const size_t B_WQKV_L = 1572864;
static const size_t B_KW1_H  = 3145728;    // 1024*1024*2
static const size_t B_KW1_L  = 5242880;
static const size_t B_KW2_H  = 7340032;    // 64*1024*2
static const size_t B_KW2_L  = 7471104;
static const size_t B_VW1_H  = 7602176;
static const size_t B_VW2_H  = 9699328;
static const size_t B_WOUT_H = 9830400;    // 512*512*2
static const size_t B_HB_H   = 10354688;   // 2048*512*2
static const size_t B_HB_L   = 12451840;
static const size_t B_QBH    = 14548992;   // 8*2048*64*2 (non-roped q, hi)
static const size_t B_QBL    = 16646144;   // (lo, 3rd term)
static const size_t B_KF     = 18743296;   // 8*2048*64*4 (k fp32; dead after k_post -> HIDV)
static const size_t B_VBH    = 22937600;   // 8*2048*64*2
static const size_t B_RQH    = 25034752;   // roped q hi/lo
static const size_t B_RQL    = 27131904;
static const size_t B_RKH    = 29229056;   // 8*2112*64*2 (roped k, 64 zero-pad rows front)
static const size_t B_RKL    = 31391744;
static const size_t B_VTB    = 33554432;   // 8*64*2112*2 (v^T, 64 zero-pad cols front)
static const size_t B_CKT_H  = 35717120;   // 8*256*64*2 (compressed k rows, j=0 mem)
static const size_t B_CKT_L  = 35979264;
static const size_t B_CVT    = 36241408;   // 8*64*256*2 (compressed v transposed)
static const size_t B_SEL    = 36700160;   // 8*2048*5*4
static const size_t B_COUT   = 37027840;   // 4194304 (overlays KW_H)
static const size_t B_FOUT   = 41222144;   // 4194304 (overlays KW_L)
static const size_t B_SOUT   = 45416448;   // 4194304 (overlays VW_H)
static const size_t B_KW_H   = B_COUT;     // 2032*1024*2 = 4161536
static const size_t B_KW_L   = B_FOUT;
static const size_t B_VW_H   = B_SOUT;
static const size_t B_HID_H  = 49610752;   // 4161536 (k hidden hi)
static const size_t B_HID_L  = 53772288;   // 4161536 (k hidden lo)
static const size_t B_QBM    = 57933824;   // 8*2048*64*2 (q mid term)
static const size_t B_CKT_M  = 60030976;   // 8*256*64*2
static const size_t B_HIDV   = B_KF;       // v hidden hi (4161536 <= 4194304, KF dead)
static const size_t B_COMBB  = B_HID_H;    // 2097152 (after MLPs dead)

// ================= 32x32-per-wave GEMM core (64x64 block tile) =================
template <int COMP>
__device__ __forceinline__ void gemm_tile(
    const bf16* __restrict__ Ah, const bf16* __restrict__ Al,
    const bf16* __restrict__ Wh, const bf16* __restrict__ Wl,
    int M, int K, int row_base, int col_base, int lr, int kg,
    f32x4 accs[2][2]) {
  int ar0 = row_base + lr;       if (ar0 > M - 1) ar0 = M - 1;
  int ar1 = row_base + 16 + lr;  if (ar1 > M - 1) ar1 = M - 1;
  const size_t a0o = (size_t)ar0 * K + kg;
  const size_t a1o = (size_t)ar1 * K + kg;
  const size_t b0o = (size_t)(col_base + lr) * K + kg;
  const size_t b1o = (size_t)(col_base + 16 + lr) * K + kg;
  f32x4 acc00 = {}, acc01 = {}, acc10 = {}, acc11 = {};
  for (int k0 = 0; k0 < K; k0 += 32) {
    bf16x8 ah0 = *reinterpret_cast<const bf16x8*>(Ah + a0o + k0);
    bf16x8 ah1 = *reinterpret_cast<const bf16x8*>(Ah + a1o + k0);
    bf16x8 bh0 = *reinterpret_cast<const bf16x8*>(Wh + b0o + k0);
    bf16x8 bh1 = *reinterpret_cast<const bf16x8*>(Wh + b1o + k0);
    acc00 = __builtin_amdgcn_mfma_f32_16x16x32_bf16(ah0, bh0, acc00, 0, 0, 0);
    acc01 = __builtin_amdgcn_mfma_f32_16x16x32_bf16(ah0, bh1, acc01, 0, 0, 0);
    acc10 = __builtin_amdgcn_mfma_f32_16x16x32_bf16(ah1, bh0, acc10, 0, 0, 0);
    acc11 = __builtin_amdgcn_mfma_f32_16x16x32_bf16(ah1, bh1, acc11, 0, 0, 0);
    if constexpr (COMP) {
      bf16x8 al0 = *reinterpret_cast<const bf16x8*>(Al + a0o + k0);
      bf16x8 al1 = *reinterpret_cast<const bf16x8*>(Al + a1o + k0);
      bf16x8 bl0 = *reinterpret_cast<const bf16x8*>(Wl + b0o + k0);
      bf16x8 bl1 = *reinterpret_cast<const bf16x8*>(Wl + b1o + k0);
      acc00 = __builtin_amdgcn_mfma_f32_16x16x32_bf16(ah0, bl0, acc00, 0, 0, 0);
      acc01 = __builtin_amdgcn_mfma_f32_16x16x32_bf16(ah0, bl1, acc01, 0, 0, 0);
      acc10 = __builtin_amdgcn_mfma_f32_16x16x32_bf16(ah1, bl0, acc10, 0, 0, 0);
      acc11 = __builtin_amdgcn_mfma_f32_16x16x32_bf16(ah1, bl1, acc11, 0, 0, 0);
      acc00 = __builtin_amdgcn_mfma_f32_16x16x32_bf16(al0, bh0, acc00, 0, 0, 0);
      acc01 = __builtin_amdgcn_mfma_f32_16x16x32_bf16(al0, bh1, acc01, 0, 0, 0);
      acc10 = __builtin_amdgcn_mfma_f32_16x16x32_bf16(al1, bh0, acc10, 0, 0, 0);
      acc11 = __builtin_amdgcn_mfma_f32_16x16x32_bf16(al1, bh1, acc11, 0, 0, 0);
    }
  }
  accs[0][0] = acc00; accs[0][1] = acc01; accs[1][0] = acc10; accs[1][1] = acc11;
}

// ---------------- generic GEMM kernel (fp32 out; out-proj) ----------------
template <int EPI, int COMP>
__global__ __launch_bounds__(256) void k_cgemm(
    const bf16* __restrict__ Ah, const bf16* __restrict__ Al,
    const bf16* __restrict__ Wh, const bf16* __restrict__ Wl,
    const float* __restrict__ bias, float* __restrict__ Cf,
    int M, int K, int N) {
  const int lane = threadIdx.x & 63;
  const int w = threadIdx.x >> 6;
  const int wr = w >> 1, wc = w & 1;
  const int row_base = (blockIdx.y << 6) + (wr << 5);
  const int col_base = (blockIdx.x << 6) + (wc << 5);
  const int lr = lane & 15;
  const int kg = (lane >> 4) << 3;
  const int crow = (lane >> 4) << 2;

  f32x4 accs[2][2];
  gemm_tile<COMP>(Ah, Al, Wh, Wl, M, K, row_base, col_base, lr, kg, accs);

#pragma unroll
  for (int mi = 0; mi < 2; ++mi) {
#pragma unroll
    for (int ni = 0; ni < 2; ++ni) {
      int col = col_base + (ni << 4) + lr;
      float bv = bias ? bias[col] : 0.f;
#pragma unroll
      for (int r = 0; r < 4; ++r) {
        int row = row_base + (mi << 4) + crow + r;
        if (row < M) {
          float vv = accs[mi][ni][r] + bv;
          if (EPI == 1) vv = fmaxf(vv, 0.f);
          Cf[(size_t)row * N + col] = vv;
        }
      }
    }
  }
}

#define LDP 40

// ---------------- qkv GEMM: LDS-staged 128x64 tile, compensated, fused scatter ----------------
__global__ __launch_bounds__(256, 2) void k_qkv(
    const bf16* __restrict__ Ah, const bf16* __restrict__ Al,
    const bf16* __restrict__ Wh, const bf16* __restrict__ Wl,
    float* __restrict__ KFo, bf16* __restrict__ QH, bf16* __restrict__ QM,
    bf16* __restrict__ QL, bf16* __restrict__ VB) {
  __shared__ bf16 sAh[128 * LDP];
  __shared__ bf16 sAl[128 * LDP];
  __shared__ bf16 sBh[64 * LDP];
  __shared__ bf16 sBl[64 * LDP];

  const int t = threadIdx.x;
  const int lane = t & 63, w = t >> 6;
  const int wr = w >> 1, wc = w & 1;
  const int lr = lane & 15;
  const int kg = (lane >> 4) << 3;
  const int crow = (lane >> 4) << 2;
  const int id = blockIdx.x;
  const int row0 = (id / 24) << 7;
  const int col0 = (id % 24) << 6;

  const int qa0 = t,        ar0s = qa0 >> 2, as0 = qa0 & 3;
  const int qa1 = t + 256,  ar1s = qa1 >> 2, as1 = qa1 & 3;
  const int gr0 = row0 + ar0s;
  const int gr1 = row0 + ar1s;
  const int br = t >> 2, bs = t & 3;
  const int gbr = col0 + br;

  f32x4 acc[4][2];
#pragma unroll
  for (int a = 0; a < 4; ++a)
#pragma unroll
    for (int b = 0; b < 2; ++b) acc[a][b] = (f32x4){0.f, 0.f, 0.f, 0.f};

  for (int k0 = 0; k0 < DMODEL; k0 += 32) {
    *reinterpret_cast<bf16x8*>(&sAh[ar0s * LDP + as0 * 8]) =
        *reinterpret_cast<const bf16x8*>(Ah + (size_t)gr0 * DMODEL + k0 + as0 * 8);
    *reinterpret_cast<bf16x8*>(&sAh[ar1s * LDP + as1 * 8]) =
        *reinterpret_cast<const bf16x8*>(Ah + (size_t)gr1 * DMODEL + k0 + as1 * 8);
    *reinterpret_cast<bf16x8*>(&sBh[br * LDP + bs * 8]) =
        *reinterpret_cast<const bf16x8*>(Wh + (size_t)gbr * DMODEL + k0 + bs * 8);
    *reinterpret_cast<bf16x8*>(&sAl[ar0s * LDP + as0 * 8]) =
        *reinterpret_cast<const bf16x8*>(Al + (size_t)gr0 * DMODEL + k0 + as0 * 8);
    *reinterpret_cast<bf16x8*>(&sAl[ar1s * LDP + as1 * 8]) =
        *reinterpret_cast<const bf16x8*>(Al + (size_t)gr1 * DMODEL + k0 + as1 * 8);
    *reinterpret_cast<bf16x8*>(&sBl[br * LDP + bs * 8]) =
        *reinterpret_cast<const bf16x8*>(Wl + (size_t)gbr * DMODEL + k0 + bs * 8);
    __syncthreads();

    bf16x8 fAh[4], fBh[2], fAl[4], fBl[2];
#pragma unroll
    for (int mi = 0; mi < 4; ++mi)
      fAh[mi] = *reinterpret_cast<const bf16x8*>(&sAh[(wr * 64 + mi * 16 + lr) * LDP + kg]);
#pragma unroll
    for (int ni = 0; ni < 2; ++ni)
      fBh[ni] = *reinterpret_cast<const bf16x8*>(&sBh[(wc * 32 + ni * 16 + lr) * LDP + kg]);
#pragma unroll
    for (int mi = 0; mi < 4; ++mi)
      fAl[mi] = *reinterpret_cast<const bf16x8*>(&sAl[(wr * 64 + mi * 16 + lr) * LDP + kg]);
#pragma unroll
    for (int ni = 0; ni < 2; ++ni)
      fBl[ni] = *reinterpret_cast<const bf16x8*>(&sBl[(wc * 32 + ni * 16 + lr) * LDP + kg]);

#pragma unroll
    for (int mi = 0; mi < 4; ++mi)
#pragma unroll
      for (int ni = 0; ni < 2; ++ni)
        acc[mi][ni] = __builtin_amdgcn_mfma_f32_16x16x32_bf16(fAh[mi], fBh[ni], acc[mi][ni], 0, 0, 0);
#pragma unroll
    for (int mi = 0; mi < 4; ++mi)
#pragma unroll
      for (int ni = 0; ni < 2; ++ni) {
        acc[mi][ni] = __builtin_amdgcn_mfma_f32_16x16x32_bf16(fAh[mi], fBl[ni], acc[mi][ni], 0, 0, 0);
        acc[mi][ni] = __builtin_amdgcn_mfma_f32_16x16x32_bf16(fAl[mi], fBh[ni], acc[mi][ni], 0, 0, 0);
      }
    __syncthreads();
  }

#pragma unroll
  for (int mi = 0; mi < 4; ++mi) {
#pragma unroll
    for (int ni = 0; ni < 2; ++ni) {
      int col = col0 + wc * 32 + ni * 16 + lr;
      int which = col >> 9, rem = col & 511;
      int hh = rem >> 6, dd = rem & 63;
#pragma unroll
      for (int r = 0; r < 4; ++r) {
        int row = row0 + wr * 64 + mi * 16 + crow + r;
        float vv = acc[mi][ni][r];
        size_t o = ((size_t)hh * NTOK + row) * DHEAD + dd;
        if (which == 0) {
          bf16 h1 = __float2bfloat16(vv);
          float r1 = vv - __bfloat162float(h1);
          bf16 m1 = __float2bfloat16(r1);
          QH[o] = h1;
          QM[o] = m1;
          QL[o] = __float2bfloat16(r1 - __bfloat162float(m1));
        } else if (which == 1) {
          KFo[o] = vv;
        } else {
          VB[o] = __float2bfloat16(vv);
        }
      }
    }
  }
}

// ---------------- merged MLP1, LDS-staged (128x64 tile, BK=32, padded LDS) ----------------
__global__ __launch_bounds__(256, 2) void k_mlp1(
    const bf16* __restrict__ KWh, const bf16* __restrict__ KWl,
    const bf16* __restrict__ W1h, const bf16* __restrict__ W1l,
    const float* __restrict__ kb1,
    const bf16* __restrict__ VWh, const bf16* __restrict__ VW1h,
    const float* __restrict__ vb1,
    bf16* __restrict__ HKh, bf16* __restrict__ HKl, bf16* __restrict__ HVh) {
  __shared__ bf16 sAh[128 * LDP];
  __shared__ bf16 sAl[128 * LDP];
  __shared__ bf16 sBh[64 * LDP];
  __shared__ bf16 sBl[64 * LDP];

  const int t = threadIdx.x;
  const int lane = t & 63, w = t >> 6;
  const int wr = w >> 1, wc = w & 1;
  const int lr = lane & 15;
  const int kg = (lane >> 4) << 3;
  const int crow = (lane >> 4) << 2;
  const int M = NHEAD * NWIN;  // 2032
  const int id = blockIdx.x;
  const bool kpath = (id < 256);
  const int u = kpath ? id : id - 256;
  const int row0 = (u >> 4) << 7;
  const int col0 = (u & 15) << 6;

  const bf16* Ah = kpath ? KWh : VWh;
  const bf16* Bh = kpath ? W1h : VW1h;

  const int qa0 = t,        ar0s = qa0 >> 2, as0 = qa0 & 3;
  const int qa1 = t + 256,  ar1s = qa1 >> 2, as1 = qa1 & 3;
  int gr0 = row0 + ar0s; if (gr0 > M - 1) gr0 = M - 1;
  int gr1 = row0 + ar1s; if (gr1 > M - 1) gr1 = M - 1;
  const int br = t >> 2, bs = t & 3;
  const int gbr = col0 + br;

  f32x4 acc[4][2];
#pragma unroll
  for (int a = 0; a < 4; ++a)
#pragma unroll
    for (int b = 0; b < 2; ++b) acc[a][b] = (f32x4){0.f, 0.f, 0.f, 0.f};

  for (int k0 = 0; k0 < CDIM; k0 += 32) {
    *reinterpret_cast<bf16x8*>(&sAh[ar0s * LDP + as0 * 8]) =
        *reinterpret_cast<const bf16x8*>(Ah + (size_t)gr0 * CDIM + k0 + as0 * 8);
    *reinterpret_cast<bf16x8*>(&sAh[ar1s * LDP + as1 * 8]) =
        *reinterpret_cast<const bf16x8*>(Ah + (size_t)gr1 * CDIM + k0 + as1 * 8);
    *reinterpret_cast<bf16x8*>(&sBh[br * LDP + bs * 8]) =
        *reinterpret_cast<const bf16x8*>(Bh + (size_t)gbr * CDIM + k0 + bs * 8);
    if (kpath) {
      *reinterpret_cast<bf16x8*>(&sAl[ar0s * LDP + as0 * 8]) =
          *reinterpret_cast<const bf16x8*>(KWl + (size_t)gr0 * CDIM + k0 + as0 * 8);
      *reinterpret_cast<bf16x8*>(&sAl[ar1s * LDP + as1 * 8]) =
          *reinterpret_cast<const bf16x8*>(KWl + (size_t)gr1 * CDIM + k0 + as1 * 8);
      *reinterpret_cast<bf16x8*>(&sBl[br * LDP + bs * 8]) =
          *reinterpret_cast<const bf16x8*>(W1l + (size_t)gbr * CDIM + k0 + bs * 8);
    }
    __syncthreads();

    bf16x8 fAh[4], fBh[2], fAl[4], fBl[2];
#pragma unroll
    for (int mi = 0; mi < 4; ++mi)
      fAh[mi] = *reinterpret_cast<const bf16x8*>(&sAh[(wr * 64 + mi * 16 + lr) * LDP + kg]);
#pragma unroll
    for (int ni = 0; ni < 2; ++ni)
      fBh[ni] = *reinterpret_cast<const bf16x8*>(&sBh[(wc * 32 + ni * 16 + lr) * LDP + kg]);
    if (kpath) {
#pragma unroll
      for (int mi = 0; mi < 4; ++mi)
        fAl[mi] = *reinterpret_cast<const bf16x8*>(&sAl[(wr * 64 + mi * 16 + lr) * LDP + kg]);
#pragma unroll
      for (int ni = 0; ni < 2; ++ni)
        fBl[ni] = *reinterpret_cast<const bf16x8*>(&sBl[(wc * 32 + ni * 16 + lr) * LDP + kg]);
    }

#pragma unroll
    for (int mi = 0; mi < 4; ++mi)
#pragma unroll
      for (int ni = 0; ni < 2; ++ni)
        acc[mi][ni] = __builtin_amdgcn_mfma_f32_16x16x32_bf16(fAh[mi], fBh[ni], acc[mi][ni], 0, 0, 0);
    if (kpath) {
#pragma unroll
      for (int mi = 0; mi < 4; ++mi)
#pragma unroll
        for (int ni = 0; ni < 2; ++ni) {
          acc[mi][ni] = __builtin_amdgcn_mfma_f32_16x16x32_bf16(fAh[mi], fBl[ni], acc[mi][ni], 0, 0, 0);
          acc[mi][ni] = __builtin_amdgcn_mfma_f32_16x16x32_bf16(fAl[mi], fBh[ni], acc[mi][ni], 0, 0, 0);
        }
    }
    __syncthreads();
  }

#pragma unroll
  for (int mi = 0; mi < 4; ++mi) {
#pragma unroll
    for (int ni = 0; ni < 2; ++ni) {
      int col = col0 + wc * 32 + ni * 16 + lr;
      float bv = kpath ? kb1[col] : vb1[col];
#pragma unroll
      for (int r = 0; r < 4; ++r) {
        int row = row0 + wr * 64 + mi * 16 + crow + r;
        if (row < M) {
          float vv = fmaxf(acc[mi][ni][r] + bv, 0.f);
          size_t o = (size_t)row * CDIM + col;
          if (kpath) {
            bf16 h1 = __float2bfloat16(vv);
            HKh[o] = h1;
            HKl[o] = __float2bfloat16(vv - __bfloat162float(h1));
          } else {
            HVh[o] = __float2bfloat16(vv);
          }
        }
      }
    }
  }
}

// ---------------- merged MLP2: z=0 k-path -> ckT hi/mid/lo, z=1 v-path -> cvT ----------------
__global__ __launch_bounds__(256) void k_mlp2(
    const bf16* __restrict__ HKh, const bf16* __restrict__ HKl,
    const bf16* __restrict__ W2h, const bf16* __restrict__ W2l,
    const float* __restrict__ kb2,
    const bf16* __restrict__ HVh, const bf16* __restrict__ VW2h,
    const float* __restrict__ vb2,
    bf16* __restrict__ ckh, bf16* __restrict__ ckm, bf16* __restrict__ ckl,
    bf16* __restrict__ cvtb) {
  const int lane = threadIdx.x & 63;
  const int w = threadIdx.x >> 6;
  const int wr = w >> 1, wc = w & 1;
  const int row_base = (blockIdx.y << 6) + (wr << 5);
  const int col_base = (wc << 5);
  const int lr = lane & 15;
  const int kg = (lane >> 4) << 3;
  const int crow = (lane >> 4) << 2;
  const int M = NHEAD * NWIN;

  f32x4 accs[2][2];
  if (blockIdx.z == 0)
    gemm_tile<1>(HKh, HKl, W2h, W2l, M, CDIM, row_base, col_base, lr, kg, accs);
  else
    gemm_tile<0>(HVh, nullptr, VW2h, nullptr, M, CDIM, row_base, col_base, lr, kg, accs);

  const float* bias = (blockIdx.z == 0) ? kb2 : vb2;
#pragma unroll
  for (int mi = 0; mi < 2; ++mi) {
#pragma unroll
    for (int ni = 0; ni < 2; ++ni) {
      int col = col_base + (ni << 4) + lr;
      float bv = bias[col];
#pragma unroll
      for (int r = 0; r < 4; ++r) {
        int row = row_base + (mi << 4) + crow + r;
        if (row < M) {
          float vv = accs[mi][ni][r] + bv;
          int hh = row / NWIN, jj = row - hh * NWIN;
          if (blockIdx.z == 0) {
            size_t o = ((size_t)hh * 256 + 1 + jj) * 64 + col;
            bf16 h1 = __float2bfloat16(vv);
            float r1 = vv - __bfloat162float(h1);
            bf16 m1 = __float2bfloat16(r1);
            ckh[o] = h1;
            ckm[o] = m1;
            ckl[o] = __float2bfloat16(r1 - __bfloat162float(m1));
          } else {
            cvtb[((size_t)hh * 64 + col) * 256 + 1 + jj] = __float2bfloat16(vv);
          }
        }
      }
    }
  }
}

// ================= k_setup: 6 weight transposes + zpad + fillmem + rmsnorm =================
__device__ __forceinline__ void wt_tile(const float* __restrict__ W,
                                        bf16* __restrict__ WTh, bf16* __restrict__ WTl,
                                        int K, int N, int bx, int by,
                                        float (*tsh)[33]) {
  const int k0 = bx << 5, n0 = by << 5;
  const int tx = threadIdx.x & 31, ty = threadIdx.x >> 5;
#pragma unroll
  for (int r = 0; r < 4; ++r)
    tsh[ty + (r << 3)][tx] = W[(size_t)(k0 + ty + (r << 3)) * N + n0 + tx];
  __syncthreads();
#pragma unroll
  for (int r = 0; r < 4; ++r) {
    float val = tsh[tx][ty + (r << 3)];
    size_t o = (size_t)(n0 + ty + (r << 3)) * K + k0 + tx;
    bf16 h1 = __float2bfloat16(val);
    WTh[o] = h1;
    if (WTl) WTl[o] = __float2bfloat16(val - __bfloat162float(h1));
  }
}

__global__ __launch_bounds__(256) void k_setup(
    const float* __restrict__ x, const float* __restrict__ g,
    const float* __restrict__ w_qkv, const float* __restrict__ k_w1,
    const float* __restrict__ k_w2, const float* __restrict__ v_w1,
    const float* __restrict__ v_w2, const float* __restrict__ w_out,
    const float* __restrict__ memkv,
    bf16* __restrict__ WQKV_H, bf16* __restrict__ WQKV_L,
    bf16* __restrict__ KW1_H, bf16* __restrict__ KW1_L,
    bf16* __restrict__ KW2_H, bf16* __restrict__ KW2_L,
    bf16* __restrict__ VW1_H, bf16* __restrict__ VW2_H, bf16* __restrict__ WOUT_H,
    bf16* __restrict__ hbh, bf16* __restrict__ hbl,
    bf16* __restrict__ rkh, bf16* __restrict__ rkl, bf16* __restrict__ vtb,
    bf16* __restrict__ ckh, bf16* __restrict__ ckm, bf16* __restrict__ ckl,
    bf16* __restrict__ cvtb) {
  __shared__ float tsh[32][33];
  __shared__ float wsum[4];
  __shared__ float scale_s;
  const int id = blockIdx.x;
  const int t = threadIdx.x;

  if (id < 768) {
    wt_tile(w_qkv, WQKV_H, WQKV_L, DMODEL, 1536, id % 16, id / 16, tsh);
  } else if (id < 1792) {
    int u = id - 768;  wt_tile(k_w1, KW1_H, KW1_L, CDIM, CDIM, u % 32, u / 32, tsh);
  } else if (id < 1856) {
    int u = id - 1792; wt_tile(k_w2, KW2_H, KW2_L, CDIM, DHEAD, u % 32, u / 32, tsh);
  } else if (id < 2880) {
    int u = id - 1856; wt_tile(v_w1, VW1_H, nullptr, CDIM, CDIM, u % 32, u / 32, tsh);
  } else if (id < 2944) {
    int u = id - 2880; wt_tile(v_w2, VW2_H, nullptr, CDIM, DHEAD, u % 32, u / 32, tsh);
  } else if (id < 3200) {
    int u = id - 2944; wt_tile(w_out, WOUT_H, nullptr, DMODEL, DMODEL, u % 16, u / 16, tsh);
  } else if (id < 3328) {
    int idx = (id - 3200) * 256 + t;   // [0, 32768)
    int h = idx >> 12, r = (idx >> 6) & 63, c = idx & 63;
    bf16 z = __float2bfloat16(0.f);
    rkh[((size_t)h * 2112 + r) * 64 + c] = z;
    rkl[((size_t)h * 2112 + r) * 64 + c] = z;
    vtb[((size_t)h * 64 + r) * 2112 + c] = z;
  } else if (id < 3330) {
    int u = (id - 3328) * 256 + t;     // [0, 512)
    if (u < 512) {
      int h = u >> 6, e = u & 63;
      float kv = memkv[(size_t)h * DHEAD + e];
      bf16 h1 = __float2bfloat16(kv);
      float r1 = kv - __bfloat162float(h1);
      bf16 m1 = __float2bfloat16(r1);
      ckh[((size_t)h * 256) * 64 + e] = h1;
      ckm[((size_t)h * 256) * 64 + e] = m1;
      ckl[((size_t)h * 256) * 64 + e] = __float2bfloat16(r1 - __bfloat162float(m1));
      bf16 z = __float2bfloat16(0.f);
      ckh[((size_t)h * 256 + 255) * 64 + e] = z;
      ckm[((size_t)h * 256 + 255) * 64 + e] = z;
      ckl[((size_t)h * 256 + 255) * 64 + e] = z;
      float vv = memkv[(size_t)(NHEAD + h) * DHEAD + e];
      cvtb[((size_t)h * 64 + e) * 256 + 0] = __float2bfloat16(vv);
      cvtb[((size_t)h * 64 + e) * 256 + 255] = z;
    }
  } else {
    const int row = id - 3330;
    const float* xr = x + (size_t)row * DMODEL;
    float s = 0.f;
    for (int c = t; c < DMODEL; c += 256) { float v = xr[c]; s += v * v; }
    for (int o = 32; o > 0; o >>= 1) s += __shfl_down(s, o);
    if ((t & 63) == 0) wsum[t >> 6] = s;
    __syncthreads();
    if (t == 0) {
      float tot = wsum[0] + wsum[1] + wsum[2] + wsum[3];
      scale_s = rsqrtf(tot * (1.f / DMODEL) + 1e-6f);
    }
    __syncthreads();
    float sc = scale_s;
    for (int c = t; c < DMODEL; c += 256) {
      float v = xr[c] * sc * g[c];
      bf16 h1 = __float2bfloat16(v);
      hbh[(size_t)row * DMODEL + c] = h1;
      hbl[(size_t)row * DMODEL + c] = __float2bfloat16(v - __bfloat162float(h1));
    }
  }
}

// ================= k_post: rope + v-transpose + compression windows =================
__global__ __launch_bounds__(256) void k_post(
    const bf16* __restrict__ qbh, const bf16* __restrict__ qbm,
    const bf16* __restrict__ qbl, const float* __restrict__ kf,
    const bf16* __restrict__ vbh,
    const float* __restrict__ kpos, const float* __restrict__ vpos,
    bf16* __restrict__ rqh, bf16* __restrict__ rql,
    bf16* __restrict__ rkh, bf16* __restrict__ rkl,
    bf16* __restrict__ vtb,
    bf16* __restrict__ kwh, bf16* __restrict__ kwl, bf16* __restrict__ vwh) {
  __shared__ bf16 tile[64][65];
  const int id = blockIdx.x;
  const int t = threadIdx.x;

  if (id < 2048) {
    int idx = id * 256 + t;
    int i = idx & 31;
    int n = (idx >> 5) & (NTOK - 1);
    int h = idx >> 16;
    float ex = (float)(2 * i) * (1.f / 64.f);
    float inv = exp2f(-ex * 13.287712379549449f);
    float ang = (float)n * inv;
    float sn, cs;
    sincosf(ang, &sn, &cs);
    size_t base = ((size_t)h * NTOK + n) * DHEAD + 2 * i;
    float q1 = __bfloat162float(qbh[base]) + __bfloat162float(qbm[base]) + __bfloat162float(qbl[base]);
    float q2 = __bfloat162float(qbh[base + 1]) + __bfloat162float(qbm[base + 1]) + __bfloat162float(qbl[base + 1]);
    float r1 = q1 * cs - q2 * sn, r2 = q1 * sn + q2 * cs;
    bf16 h1 = __float2bfloat16(r1);
    rqh[base] = h1; rql[base] = __float2bfloat16(r1 - __bfloat162float(h1));
    h1 = __float2bfloat16(r2);
    rqh[base + 1] = h1; rql[base + 1] = __float2bfloat16(r2 - __bfloat162float(h1));
    float k1 = kf[base], k2 = kf[base + 1];
    float s1 = k1 * cs - k2 * sn, s2 = k1 * sn + k2 * cs;
    size_t kb = ((size_t)h * 2112 + 64 + n) * DHEAD + 2 * i;
    h1 = __float2bfloat16(s1);
    rkh[kb] = h1; rkl[kb] = __float2bfloat16(s1 - __bfloat162float(h1));
    h1 = __float2bfloat16(s2);
    rkh[kb + 1] = h1; rkl[kb + 1] = __float2bfloat16(s2 - __bfloat162float(h1));
  } else if (id < 2304) {
    int u = id - 2048;
    int h = u >> 5, n0 = (u & 31) << 6;
    int tx = t & 63, ty = t >> 6;
    for (int r = ty; r < 64; r += 4)
      tile[r][tx] = vbh[((size_t)h * NTOK + n0 + r) * DHEAD + tx];
    __syncthreads();
    for (int r = ty; r < 64; r += 4)
      vtb[((size_t)h * 64 + r) * 2112 + 64 + n0 + tx] = tile[tx][r];
  } else {
    int idx = (id - 2304) * 256 + t;   // [0, 2080768)
    int d = idx & 63;
    int c = (idx >> 6) & 15;
    int j = (idx >> 10) % NWIN;
    int h = idx / (NWIN << 10);
    int srcpos = (j << 3) + c;
    size_t src = ((size_t)h * NTOK + srcpos) * DHEAD + d;
    size_t pp = ((size_t)h * 16 + c) * DHEAD + d;
    float kv = kf[src] + kpos[pp];
    bf16 h1 = __float2bfloat16(kv);
    kwh[idx] = h1;
    kwl[idx] = __float2bfloat16(kv - __bfloat162float(h1));
    vwh[idx] = __float2bfloat16(__bfloat162float(vbh[src]) + vpos[pp]);
  }
}

// ---------------- compression attention (MFMA, 32 queries/block) ----------------
__global__ __launch_bounds__(256) void k_comp_attn(
    const bf16* __restrict__ qbh, const bf16* __restrict__ qbm, const bf16* __restrict__ qbl,
    const bf16* __restrict__ ckh, const bf16* __restrict__ ckm, const bf16* __restrict__ ckl,
    const bf16* __restrict__ cvtb,
    float* __restrict__ c_out, int* __restrict__ sel) {
  const int h = blockIdx.y;
  const int i0 = blockIdx.x << 5;
  const int t = threadIdx.x;
  const int w = t >> 6, lane = t & 63;
  const int lr = lane & 15, kg = (lane >> 4) << 3;
  const int crow = (lane >> 4) << 2;

  __shared__ float p[32][260];

  bf16x8 aH[2][2], aM[2][2], aL[2][2];
#pragma unroll
  for (int mi = 0; mi < 2; ++mi) {
    size_t qo = ((size_t)h * NTOK + i0 + mi * 16 + lr) * DHEAD + kg;
#pragma unroll
    for (int ks = 0; ks < 2; ++ks) {
      aH[mi][ks] = *reinterpret_cast<const bf16x8*>(qbh + qo + ks * 32);
      aM[mi][ks] = *reinterpret_cast<const bf16x8*>(qbm + qo + ks * 32);
      aL[mi][ks] = *reinterpret_cast<const bf16x8*>(qbl + qo + ks * 32);
    }
  }
  f32x4 acc[2][4];
#pragma unroll
  for (int a = 0; a < 2; ++a)
#pragma unroll
    for (int b = 0; b < 4; ++b) acc[a][b] = (f32x4){0.f, 0.f, 0.f, 0.f};
#pragma unroll
  for (int ni = 0; ni < 4; ++ni) {
    int col = (w << 6) + (ni << 4) + lr;
    size_t ko = ((size_t)h * 256 + col) * 64 + kg;
#pragma unroll
    for (int ks = 0; ks < 2; ++ks) {
      bf16x8 bH = *reinterpret_cast<const bf16x8*>(ckh + ko + ks * 32);
      bf16x8 bM = *reinterpret_cast<const bf16x8*>(ckm + ko + ks * 32);
      bf16x8 bL = *reinterpret_cast<const bf16x8*>(ckl + ko + ks * 32);
#pragma unroll
      for (int mi = 0; mi < 2; ++mi) {
        acc[mi][ni] = __builtin_amdgcn_mfma_f32_16x16x32_bf16(aH[mi][ks], bH, acc[mi][ni], 0, 0, 0);
        acc[mi][ni] = __builtin_amdgcn_mfma_f32_16x16x32_bf16(aH[mi][ks], bM, acc[mi][ni], 0, 0, 0);
        acc[mi][ni] = __builtin_amdgcn_mfma_f32_16x16x32_bf16(aM[mi][ks], bH, acc[mi][ni], 0, 0, 0);
        acc[mi][ni] = __builtin_amdgcn_mfma_f32_16x16x32_bf16(aH[mi][ks], bL, acc[mi][ni], 0, 0, 0);
        acc[mi][ni] = __builtin_amdgcn_mfma_f32_16x16x32_bf16(aL[mi][ks], bH, acc[mi][ni], 0, 0, 0);
        acc[mi][ni] = __builtin_amdgcn_mfma_f32_16x16x32_bf16(aM[mi][ks], bM, acc[mi][ni], 0, 0, 0);
      }
    }
  }
#pragma unroll
  for (int mi = 0; mi < 2; ++mi)
#pragma unroll
    for (int ni = 0; ni < 4; ++ni) {
      int col = (w << 6) + (ni << 4) + lr;
      int wend = (col == 0) ? -1 : ((col - 1) << 3) + 15;
#pragma unroll
      for (int r = 0; r < 4; ++r) {
        int qi = mi * 16 + crow + r;
        bool ok = (col < 255) && (wend < i0 + qi);
        p[qi][col] = ok ? acc[mi][ni][r] * 0.125f : NEGV;
      }
    }
  __syncthreads();

  const int qi = t >> 3, s = t & 7;
  float ev[32];
  float mx = -3.0e38f;
#pragma unroll
  for (int u = 0; u < 32; ++u) { ev[u] = p[qi][s + (u << 3)]; mx = fmaxf(mx, ev[u]); }
  mx = fmaxf(mx, __shfl_xor(mx, 1));
  mx = fmaxf(mx, __shfl_xor(mx, 2));
  mx = fmaxf(mx, __shfl_xor(mx, 4));
  float sum = 0.f;
#pragma unroll
  for (int u = 0; u < 32; ++u) { float e = __expf(ev[u] - mx); ev[u] = e; sum += e; }
  sum += __shfl_xor(sum, 1); sum += __shfl_xor(sum, 2); sum += __shfl_xor(sum, 4);
  float invs = 1.f / sum;
#pragma unroll
  for (int u = 0; u < 32; ++u) p[qi][s + (u << 3)] = ev[u] * invs;

  int qblk = (i0 + qi) >> 4;
  float vals[16];
#pragma unroll
  for (int u = 0; u < 16; ++u) {
    int f = (s << 4) + u;
    float v;
    if (f >= qblk || f == 127) v = NEGV;
    else v = (p[qi][2 * f + 1] + p[qi][2 * f + 2]) * 0.5f;
    vals[u] = v;
  }
  int base = ((h << 11) | (i0 + qi)) * 5;
  for (int kk = 0; kk < 4; ++kk) {
    float bv = -3.0e38f; int bi = 0;
#pragma unroll
    for (int u = 0; u < 16; ++u) {
      if (vals[u] > bv) { bv = vals[u]; bi = (s << 4) + u; }
    }
#pragma unroll
    for (int o = 1; o < 8; o <<= 1) {
      float ov = __shfl_xor(bv, o);
      int oi = __shfl_xor(bi, o);
      if (ov > bv || (ov == bv && oi < bi)) { bv = ov; bi = oi; }
    }
    if (s == 0) sel[base + kk] = (bv > -5.0e8f) ? bi : -1;
    if ((bi >> 4) == s) vals[bi & 15] = -3.0e38f;
  }
  if (s == 0) sel[base + 4] = (i0 + qi) >> 4;
  __syncthreads();

  const int wm = w >> 1, wn = w & 1;
  const int arow = wm * 16 + lr;
  f32x4 pacc[2];
#pragma unroll
  for (int b = 0; b < 2; ++b) pacc[b] = (f32x4){0.f, 0.f, 0.f, 0.f};
#pragma unroll
  for (int ks = 0; ks < 8; ++ks) {
    int k0 = ks * 32 + kg;
    float4 x0 = *reinterpret_cast<const float4*>(&p[arow][k0]);
    float4 x1 = *reinterpret_cast<const float4*>(&p[arow][k0 + 4]);
    float xv[8] = {x0.x, x0.y, x0.z, x0.w, x1.x, x1.y, x1.z, x1.w};
    bf16x8 ph, pl;
#pragma unroll
    for (int e = 0; e < 8; ++e) {
      __bf16 hh = (__bf16)xv[e];
      ph[e] = hh;
      pl[e] = (__bf16)(xv[e] - (float)hh);
    }
#pragma unroll
    for (int ni = 0; ni < 2; ++ni) {
      int d = (wn << 5) + (ni << 4) + lr;
      bf16x8 bv = *reinterpret_cast<const bf16x8*>(cvtb + ((size_t)h * 64 + d) * 256 + k0);
      pacc[ni] = __builtin_amdgcn_mfma_f32_16x16x32_bf16(ph, bv, pacc[ni], 0, 0, 0);
      pacc[ni] = __builtin_amdgcn_mfma_f32_16x16x32_bf16(pl, bv, pacc[ni], 0, 0, 0);
    }
  }
#pragma unroll
  for (int ni = 0; ni < 2; ++ni) {
    int d = (wn << 5) + (ni << 4) + lr;
#pragma unroll
    for (int r = 0; r < 4; ++r) {
      int q2 = wm * 16 + crow + r;
      c_out[((size_t)h * NTOK + i0 + q2) * DHEAD + d] = pacc[ni][r];
    }
  }
}

// ======== fused fine + sliding attention (occupancy-tuned) ========
// grid 4608 blocks: id<512 -> slide (32 queries/block, 96-key window, 12.8KB LDS);
// id>=512 -> fine. __launch_bounds__(256,8) pins VGPR<=64 -> 8 waves/SIMD.
__global__ __launch_bounds__(256, 8) void k_fs_attn(
    const bf16* __restrict__ rqh, const bf16* __restrict__ rql,
    const bf16* __restrict__ rkh, const bf16* __restrict__ rkl,
    const bf16* __restrict__ vbh, const bf16* __restrict__ vtb,
    const int* __restrict__ sel,
    float* __restrict__ f_out, float* __restrict__ s_out) {
  __shared__ char smraw[32 * 100 * 4];   // 12800 B
  const int blk = blockIdx.x;
  const int t = threadIdx.x;

  if (blk < 512) {
    // ========== sliding-window: 32 queries, 96-key window ==========
    float (*p)[100] = reinterpret_cast<float(*)[100]>(smraw);
    const int h = blk >> 6, nb = blk & 63;
    const int w = t >> 6, lane = t & 63;
    const int lr = lane & 15, kg = (lane >> 4) << 3;
    const int crow = (lane >> 4) << 2;
    const int wr = w >> 1, wc = w & 1;

    // QK: M=32 (2x16 rows), N=96 (2x48 cols), K=64, compensated 3-term
    bf16x8 aH[2], aL[2];
    {
      size_t qo = ((size_t)h * NTOK + nb * 32 + wr * 16 + lr) * DHEAD + kg;
#pragma unroll
      for (int ks = 0; ks < 2; ++ks) {
        aH[ks] = *reinterpret_cast<const bf16x8*>(rqh + qo + ks * 32);
        aL[ks] = *reinterpret_cast<const bf16x8*>(rql + qo + ks * 32);
      }
    }
    f32x4 acc[3];
#pragma unroll
    for (int a = 0; a < 3; ++a) acc[a] = (f32x4){0.f, 0.f, 0.f, 0.f};
#pragma unroll
    for (int ni = 0; ni < 3; ++ni) {
      int col = wc * 48 + ni * 16 + lr;
      size_t ko = ((size_t)h * 2112 + nb * 32 + col) * 64 + kg;
#pragma unroll
      for (int ks = 0; ks < 2; ++ks) {
        bf16x8 bH = *reinterpret_cast<const bf16x8*>(rkh + ko + ks * 32);
        bf16x8 bL = *reinterpret_cast<const bf16x8*>(rkl + ko + ks * 32);
        acc[ni] = __builtin_amdgcn_mfma_f32_16x16x32_bf16(aH[ks], bH, acc[ni], 0, 0, 0);
        acc[ni] = __builtin_amdgcn_mfma_f32_16x16x32_bf16(aL[ks], bH, acc[ni], 0, 0, 0);
        acc[ni] = __builtin_amdgcn_mfma_f32_16x16x32_bf16(aH[ks], bL, acc[ni], 0, 0, 0);
      }
    }
    // mask: key_glob = nb*32 + col - 64, q_glob = nb*32 + q_local
    // valid: col >= q_local+1 && col <= q_local+64 && key_glob >= 0 (col >= 64 - nb*32)
    const int cmin = 64 - nb * 32;
#pragma unroll
    for (int ni = 0; ni < 3; ++ni) {
      int col = wc * 48 + ni * 16 + lr;
#pragma unroll
      for (int r = 0; r < 4; ++r) {
        int q = wr * 16 + crow + r;
        bool ok = (col >= q + 1) && (col <= q + 64) && (col >= cmin);
        p[q][col] = ok ? acc[ni][r] * 0.125f : NEGV;
      }
    }
    __syncthreads();

    // softmax: 8 threads/row, 12 cols each
    const int qi = t >> 3, s = t & 7;
    float ev[12];
    float mx = -3.0e38f;
#pragma unroll
    for (int u = 0; u < 12; ++u) { ev[u] = p[qi][s + (u << 3)]; mx = fmaxf(mx, ev[u]); }
    mx = fmaxf(mx, __shfl_xor(mx, 1));
    mx = fmaxf(mx, __shfl_xor(mx, 2));
    mx = fmaxf(mx, __shfl_xor(mx, 4));
    float sum = 0.f;
#pragma unroll
    for (int u = 0; u < 12; ++u) { float e = __expf(ev[u] - mx); ev[u] = e; sum += e; }
    sum += __shfl_xor(sum, 1); sum += __shfl_xor(sum, 2); sum += __shfl_xor(sum, 4);
    float invs = 1.f / sum;
#pragma unroll
    for (int u = 0; u < 12; ++u) p[qi][s + (u << 3)] = ev[u] * invs;
    __syncthreads();

    // PV: M=32, N=64, K=96 (3 kslices), p hi/lo split
    const int wm = w >> 1, wn = w & 1;
    const int arow = wm * 16 + lr;
    f32x4 pacc[2];
#pragma unroll
    for (int b = 0; b < 2; ++b) pacc[b] = (f32x4){0.f, 0.f, 0.f, 0.f};
#pragma unroll
    for (int ks = 0; ks < 3; ++ks) {
      int k0 = ks * 32 + kg;
      float4 x0 = *reinterpret_cast<const float4*>(&p[arow][k0]);
      float4 x1 = *reinterpret_cast<const float4*>(&p[arow][k0 + 4]);
      float xv[8] = {x0.x, x0.y, x0.z, x0.w, x1.x, x1.y, x1.z, x1.w};
      bf16x8 ph, pl;
#pragma unroll
      for (int e = 0; e < 8; ++e) {
        __bf16 hh = (__bf16)xv[e];
        ph[e] = hh;
        pl[e] = (__bf16)(xv[e] - (float)hh);
      }
#pragma unroll
      for (int ni = 0; ni < 2; ++ni) {
        int d = wn * 32 + ni * 16 + lr;
        bf16x8 bv = *reinterpret_cast<const bf16x8*>(
            vtb + ((size_t)h * 64 + d) * 2112 + nb * 32 + k0);
        pacc[ni] = __builtin_amdgcn_mfma_f32_16x16x32_bf16(ph, bv, pacc[ni], 0, 0, 0);
        pacc[ni] = __builtin_amdgcn_mfma_f32_16x16x32_bf16(pl, bv, pacc[ni], 0, 0, 0);
      }
    }
#pragma unroll
    for (int ni = 0; ni < 2; ++ni) {
      int d = wn * 32 + ni * 16 + lr;
#pragma unroll
      for (int r = 0; r < 4; ++r) {
        int q = wm * 16 + crow + r;
        s_out[((size_t)h * NTOK + nb * 32 + q) * DHEAD + d] = pacc[ni][r];
      }
    }
  } else {
    // ========== fine attention (1 wave/query, bf16-hi K) ==========
    float (*qs)[64] = reinterpret_cast<float(*)[64]>(smraw);
    float (*pb)[80] = reinterpret_cast<float(*)[80]>(smraw + 4 * 64 * 4);
    int (*selb)[5]  = reinterpret_cast<int(*)[5]>(smraw + 4 * 64 * 4 + 4 * 80 * 4);

    const int u = blk - 512;
    const int h = u >> 9;
    const int wid = t >> 6;
    const int lane = t & 63;
    const int i = ((u & 511) << 2) | wid;

    size_t qoff = ((size_t)h * NTOK + i) * DHEAD + lane;
    qs[wid][lane] = __bfloat162float(rqh[qoff]) + __bfloat162float(rql[qoff]);
    if (lane < 5) selb[wid][lane] = sel[((h << 11) | i) * 5 + lane];
    __syncthreads();

    int sblk[5];
#pragma unroll
    for (int b = 0; b < 5; ++b) sblk[b] = selb[wid][b];

    float sim0 = NEGV, sim1 = NEGV;
    {
      int kb = sblk[lane >> 4];
      int pos = (kb << 4) + (lane & 15);
      if (kb >= 0 && pos <= i) {
        const bf16* kp = rkh + ((size_t)h * 2112 + 64 + pos) * DHEAD;
        float d = 0.f;
#pragma unroll
        for (int e8 = 0; e8 < 8; ++e8) {
          bf16x8 kv = *reinterpret_cast<const bf16x8*>(kp + e8 * 8);
#pragma unroll
          for (int e = 0; e < 8; ++e)
            d = fmaf(qs[wid][e8 * 8 + e], (float)kv[e], d);
        }
        sim0 = d * 0.125f;
      }
    }
    if (lane < 16) {
      int kb = sblk[4];
      int pos = (kb << 4) + lane;
      if (pos <= i) {
        const bf16* kp = rkh + ((size_t)h * 2112 + 64 + pos) * DHEAD;
        float d = 0.f;
#pragma unroll
        for (int e8 = 0; e8 < 8; ++e8) {
          bf16x8 kv = *reinterpret_cast<const bf16x8*>(kp + e8 * 8);
#pragma unroll
          for (int e = 0; e < 8; ++e)
            d = fmaf(qs[wid][e8 * 8 + e], (float)kv[e], d);
        }
        sim1 = d * 0.125f;
      }
    }

    float mx = fmaxf(sim0, sim1);
#pragma unroll
    for (int o = 32; o > 0; o >>= 1) mx = fmaxf(mx, __shfl_xor(mx, o));
    float e0 = __expf(sim0 - mx);
    float e1 = __expf(sim1 - mx);
    float sum = e0 + e1;
#pragma unroll
    for (int o = 32; o > 0; o >>= 1) sum += __shfl_xor(sum, o);
    float invs = 1.f / sum;
    pb[wid][lane] = e0 * invs;
    if (lane < 16) pb[wid][64 + lane] = e1 * invs;
    // same wave writes & reads pb[wid]: DS ops wave-ordered, no barrier needed

    float acc = 0.f;
#pragma unroll
    for (int b = 0; b < 5; ++b) {
      int kb = sblk[b];
      if (kb < 0) continue;
      const bf16* vr = vbh + ((size_t)h * NTOK + ((size_t)kb << 4)) * DHEAD + lane;
#pragma unroll
      for (int uu = 0; uu < 16; ++uu)
        acc = fmaf(pb[wid][b * 16 + uu], __bfloat162float(vr[(size_t)uu * DHEAD]), acc);
    }
    f_out[((size_t)h * NTOK + i) * DHEAD + lane] = acc;
  }
}

// ---------------- fused strat + combine: one block per token ----------------
__global__ __launch_bounds__(256) void k_combine2(
    const bf16* __restrict__ Ah, const bf16* __restrict__ Al,
    const float* __restrict__ W, const float* __restrict__ bias,
    const float* __restrict__ c_out, const float* __restrict__ f_out,
    const float* __restrict__ s_out, bf16* __restrict__ comb) {
  const int i = blockIdx.x;
  const int t = threadIdx.x;
  __shared__ float hs[DMODEL];
  __shared__ float st[24];
  size_t ro = (size_t)i * DMODEL;
#pragma unroll
  for (int u = 0; u < 2; ++u) {
    int c = t + u * 256;
    hs[c] = __bfloat162float(Ah[ro + c]) + __bfloat162float(Al[ro + c]);
  }
  __syncthreads();
  if (t < 192) {
    int c = t >> 3, s = t & 7;
    float acc = 0.f;
    for (int u = 0; u < 64; ++u) {
      int e = s * 64 + u;
      acc = fmaf(hs[e], W[(size_t)e * 24 + c], acc);
    }
    acc += __shfl_xor(acc, 1);
    acc += __shfl_xor(acc, 2);
    acc += __shfl_xor(acc, 4);
    if (s == 0) st[c] = 1.f / (1.f + expf(-(acc + bias[c])));
  }
  __syncthreads();
#pragma unroll
  for (int u = 0; u < 2; ++u) {
    int c = t + u * 256;
    int h = c >> 6, d = c & 63;
    size_t a = ((size_t)h * NTOK + i) * DHEAD + d;
    comb[ro + c] = __float2bfloat16(st[h * 3] * c_out[a] + st[h * 3 + 1] * f_out[a]
                                    + st[h * 3 + 2] * s_out[a]);
  }
}

extern "C" void kernel_launch(void* const* d_in, const int* in_sizes, int n_in,
                              void* d_out, int out_size, void* d_ws, size_t ws_size,
                              hipStream_t stream) {
  const float* x      = (const float*)d_in[0];
  const float* g_norm = (const float*)d_in[1];
  const float* w_qkv  = (const float*)d_in[2];
  const float* k_pos  = (const float*)d_in[3];
  const float* v_pos  = (const float*)d_in[4];
  const float* mem_kv = (const float*)d_in[5];
  const float* k_w1   = (const float*)d_in[6];
  const float* k_b1   = (const float*)d_in[7];
  const float* k_w2   = (const float*)d_in[8];
  const float* k_b2   = (const float*)d_in[9];
  const float* v_w1   = (const float*)d_in[10];
  const float* v_b1   = (const float*)d_in[11];
  const float* v_w2   = (const float*)d_in[12];
  const float* v_b2   = (const float*)d_in[13];
  const float* w_comb = (const float*)d_in[14];
  const float* b_comb = (const float*)d_in[15];
  const float* w_out  = (const float*)d_in[16];
  float* out = (float*)d_out;
  char* wsb = (char*)d_ws;

  bf16* WQKV_H = (bf16*)(wsb + B_WQKV_H);
  bf16* WQKV_L = (bf16*)(wsb + B_WQKV_L);
  bf16* KW1_H  = (bf16*)(wsb + B_KW1_H);
  bf16* KW1_L  = (bf16*)(wsb + B_KW1_L);
  bf16* KW2_H  = (bf16*)(wsb + B_KW2_H);
  bf16* KW2_L  = (bf16*)(wsb + B_KW2_L);
  bf16* VW1_H  = (bf16*)(wsb + B_VW1_H);
  bf16* VW2_H  = (bf16*)(wsb + B_VW2_H);
  bf16* WOUT_H = (bf16*)(wsb + B_WOUT_H);
  bf16* HB_H   = (bf16*)(wsb + B_HB_H);
  bf16* HB_L   = (bf16*)(wsb + B_HB_L);
  bf16* QBH    = (bf16*)(wsb + B_QBH);
  bf16* QBM    = (bf16*)(wsb + B_QBM);
  bf16* QBL    = (bf16*)(wsb + B_QBL);
  float* KF    = (float*)(wsb + B_KF);
  bf16* VBH    = (bf16*)(wsb + B_VBH);
  bf16* RQH    = (bf16*)(wsb + B_RQH);
  bf16* RQL    = (bf16*)(wsb + B_RQL);
  bf16* RKH    = (bf16*)(wsb + B_RKH);
  bf16* RKL    = (bf16*)(wsb + B_RKL);
  bf16* VTB    = (bf16*)(wsb + B_VTB);
  bf16* CKT_H  = (bf16*)(wsb + B_CKT_H);
  bf16* CKT_M  = (bf16*)(wsb + B_CKT_M);
  bf16* CKT_L  = (bf16*)(wsb + B_CKT_L);
  bf16* CVT    = (bf16*)(wsb + B_CVT);
  int*   SEL   = (int*)(wsb + B_SEL);
  float* COUT  = (float*)(wsb + B_COUT);
  float* FOUT  = (float*)(wsb + B_FOUT);
  float* SOUT  = (float*)(wsb + B_SOUT);
  bf16* KW_H   = (bf16*)(wsb + B_KW_H);
  bf16* KW_L   = (bf16*)(wsb + B_KW_L);
  bf16* VW_H   = (bf16*)(wsb + B_VW_H);
  bf16* HID_H  = (bf16*)(wsb + B_HID_H);
  bf16* HID_L  = (bf16*)(wsb + B_HID_L);
  bf16* HIDV   = (bf16*)(wsb + B_HIDV);
  bf16* COMBB  = (bf16*)(wsb + B_COMBB);

  // 1. setup: weight splits + pads + mem fill + rmsnorm
  k_setup<<<5378, 256, 0, stream>>>(x, g_norm, w_qkv, k_w1, k_w2, v_w1, v_w2, w_out, mem_kv,
                                    WQKV_H, WQKV_L, KW1_H, KW1_L, KW2_H, KW2_L,
                                    VW1_H, VW2_H, WOUT_H, HB_H, HB_L,
                                    RKH, RKL, VTB, CKT_H, CKT_M, CKT_L, CVT);
  // 2. qkv: LDS-staged 128x64, 384 blocks, fused split/scatter
  k_qkv<<<384, 256, 0, stream>>>(HB_H, HB_L, WQKV_H, WQKV_L, KF, QBH, QBM, QBL, VBH);
  // 3. post: rope + v-transpose + windows
  k_post<<<10432, 256, 0, stream>>>(QBH, QBM, QBL, KF, VBH, k_pos, v_pos,
                                    RQH, RQL, RKH, RKL, VTB, KW_H, KW_L, VW_H);
  // 4. merged MLP1: LDS-staged, 512 blocks; HIDV overlays dead KF
  k_mlp1<<<512, 256, 0, stream>>>(KW_H, KW_L, KW1_H, KW1_L, k_b1,
                                  VW_H, VW1_H, v_b1, HID_H, HID_L, HIDV);
  // 5. merged MLP2 -> ckT hi/mid/lo + cvT
  k_mlp2<<<dim3(1, 32, 2), 256, 0, stream>>>(HID_H, HID_L, KW2_H, KW2_L, k_b2,
                                             HIDV, VW2_H, v_b2, CKT_H, CKT_M, CKT_L, CVT);
  // 6. compression attention + selection
  k_comp_attn<<<dim3(64, 8), 256, 0, stream>>>(QBH, QBM, QBL, CKT_H, CKT_M, CKT_L, CVT, COUT, SEL);
  // 7. fused slide (512 blocks, 32q each, first) + fine (4096 blocks) attention
  k_fs_attn<<<4608, 256, 0, stream>>>(RQH, RQL, RKH, RKL, VBH, VTB, SEL, FOUT, SOUT);
  // 8. fused strat + combine
  k_combine2<<<NTOK, 256, 0, stream>>>(HB_H, HB_L, w_comb, b_comb, COUT, FOUT, SOUT, COMBB);
  // 9. output projection
  k_cgemm<0, 0><<<dim3(8, 32), 256, 0, stream>>>(
      COMBB, nullptr, WOUT_H, nullptr, nullptr, out, NTOK, DMODEL, DMODEL);
}

// Round 16
// 217.694 us; speedup vs baseline: 1.4073x; 1.0361x over previous
//
#include <hip/hip_runtime.h>
#include <hip/hip_bf16.h>
#include <cstddef>

#define NTOK 2048
#define DMODEL 512
#define NHEAD 8
#define DHEAD 64
#define NWIN 254          // (2048-16)/8 + 1
#define CDIM 1024         // CB*DH
#define NEGV -1000000000.0f

typedef __attribute__((ext_vector_type(8))) __bf16 bf16x8;
typedef __attribute__((ext_vector_type(4))) float f32x4;
typedef __hip_bfloat16 bf16;

// ---------------- workspace layout (byte offsets) ----------------
static const size_t B_WQKV_H = 0;          // 1536*512*2
static const size_t B_WQKV_L = 1572864;
static const size_t B_KW1_H  = 3145728;    // 1024*1024*2
static const size_t B_KW1_L  = 5242880;
static const size_t B_KW2_H  = 7340032;    // 64*1024*2
static const size_t B_KW2_L  = 7471104;
static const size_t B_VW1_H  = 7602176;
static const size_t B_VW2_H  = 9699328;
static const size_t B_WOUT_H = 9830400;    // 512*512*2
static const size_t B_HB_H   = 10354688;   // 2048*512*2
static const size_t B_HB_L   = 12451840;
static const size_t B_QBH    = 14548992;   // 8*2048*64*2 (non-roped q, hi)
static const size_t B_QBL    = 16646144;   // (lo, 3rd term)
static const size_t B_KF     = 18743296;   // 8*2048*64*4 (k fp32; dead after k_post -> HIDV)
static const size_t B_VBH    = 22937600;   // 8*2048*64*2
static const size_t B_RQH    = 25034752;   // roped q hi/lo
static const size_t B_RQL    = 27131904;
static const size_t B_RKH    = 29229056;   // 8*2112*64*2 (roped k, 64 zero-pad rows front)
static const size_t B_RKL    = 31391744;
static const size_t B_VTB    = 33554432;   // 8*64*2112*2 (v^T, 64 zero-pad cols front)
static const size_t B_CKT_H  = 35717120;   // 8*256*64*2 (compressed k rows, j=0 mem)
static const size_t B_CKT_L  = 35979264;
static const size_t B_CVT    = 36241408;   // 8*64*256*2 (compressed v transposed)
static const size_t B_SEL    = 36700160;   // 8*2048*5*4
static const size_t B_COUT   = 37027840;   // 4194304 (overlays KW_H)
static const size_t B_FOUT   = 41222144;   // 4194304 (overlays KW_L)
static const size_t B_SOUT   = 45416448;   // 4194304 (overlays VW_H)
static const size_t B_KW_H   = B_COUT;     // 2032*1024*2 = 4161536
static const size_t B_KW_L   = B_FOUT;
static const size_t B_VW_H   = B_SOUT;
static const size_t B_HID_H  = 49610752;   // 4161536 (k hidden hi)
static const size_t B_HID_L  = 53772288;   // 4161536 (k hidden lo)
static const size_t B_QBM    = 57933824;   // 8*2048*64*2 (q mid term)
static const size_t B_CKT_M  = 60030976;   // 8*256*64*2
static const size_t B_HIDV   = B_KF;       // v hidden hi (4161536 <= 4194304, KF dead)
static const size_t B_COMBB  = B_HID_H;    // 2097152 (after MLPs dead)

// ================= 32x32-per-wave GEMM core (64x64 block tile) =================
template <int COMP>
__device__ __forceinline__ void gemm_tile(
    const bf16* __restrict__ Ah, const bf16* __restrict__ Al,
    const bf16* __restrict__ Wh, const bf16* __restrict__ Wl,
    int M, int K, int row_base, int col_base, int lr, int kg,
    f32x4 accs[2][2]) {
  int ar0 = row_base + lr;       if (ar0 > M - 1) ar0 = M - 1;
  int ar1 = row_base + 16 + lr;  if (ar1 > M - 1) ar1 = M - 1;
  const size_t a0o = (size_t)ar0 * K + kg;
  const size_t a1o = (size_t)ar1 * K + kg;
  const size_t b0o = (size_t)(col_base + lr) * K + kg;
  const size_t b1o = (size_t)(col_base + 16 + lr) * K + kg;
  f32x4 acc00 = {}, acc01 = {}, acc10 = {}, acc11 = {};
  for (int k0 = 0; k0 < K; k0 += 32) {
    bf16x8 ah0 = *reinterpret_cast<const bf16x8*>(Ah + a0o + k0);
    bf16x8 ah1 = *reinterpret_cast<const bf16x8*>(Ah + a1o + k0);
    bf16x8 bh0 = *reinterpret_cast<const bf16x8*>(Wh + b0o + k0);
    bf16x8 bh1 = *reinterpret_cast<const bf16x8*>(Wh + b1o + k0);
    acc00 = __builtin_amdgcn_mfma_f32_16x16x32_bf16(ah0, bh0, acc00, 0, 0, 0);
    acc01 = __builtin_amdgcn_mfma_f32_16x16x32_bf16(ah0, bh1, acc01, 0, 0, 0);
    acc10 = __builtin_amdgcn_mfma_f32_16x16x32_bf16(ah1, bh0, acc10, 0, 0, 0);
    acc11 = __builtin_amdgcn_mfma_f32_16x16x32_bf16(ah1, bh1, acc11, 0, 0, 0);
    if constexpr (COMP) {
      bf16x8 al0 = *reinterpret_cast<const bf16x8*>(Al + a0o + k0);
      bf16x8 al1 = *reinterpret_cast<const bf16x8*>(Al + a1o + k0);
      bf16x8 bl0 = *reinterpret_cast<const bf16x8*>(Wl + b0o + k0);
      bf16x8 bl1 = *reinterpret_cast<const bf16x8*>(Wl + b1o + k0);
      acc00 = __builtin_amdgcn_mfma_f32_16x16x32_bf16(ah0, bl0, acc00, 0, 0, 0);
      acc01 = __builtin_amdgcn_mfma_f32_16x16x32_bf16(ah0, bl1, acc01, 0, 0, 0);
      acc10 = __builtin_amdgcn_mfma_f32_16x16x32_bf16(ah1, bl0, acc10, 0, 0, 0);
      acc11 = __builtin_amdgcn_mfma_f32_16x16x32_bf16(ah1, bl1, acc11, 0, 0, 0);
      acc00 = __builtin_amdgcn_mfma_f32_16x16x32_bf16(al0, bh0, acc00, 0, 0, 0);
      acc01 = __builtin_amdgcn_mfma_f32_16x16x32_bf16(al0, bh1, acc01, 0, 0, 0);
      acc10 = __builtin_amdgcn_mfma_f32_16x16x32_bf16(al1, bh0, acc10, 0, 0, 0);
      acc11 = __builtin_amdgcn_mfma_f32_16x16x32_bf16(al1, bh1, acc11, 0, 0, 0);
    }
  }
  accs[0][0] = acc00; accs[0][1] = acc01; accs[1][0] = acc10; accs[1][1] = acc11;
}

// ---------------- generic GEMM kernel (fp32 out; out-proj) ----------------
template <int EPI, int COMP>
__global__ __launch_bounds__(256) void k_cgemm(
    const bf16* __restrict__ Ah, const bf16* __restrict__ Al,
    const bf16* __restrict__ Wh, const bf16* __restrict__ Wl,
    const float* __restrict__ bias, float* __restrict__ Cf,
    int M, int K, int N) {
  const int lane = threadIdx.x & 63;
  const int w = threadIdx.x >> 6;
  const int wr = w >> 1, wc = w & 1;
  const int row_base = (blockIdx.y << 6) + (wr << 5);
  const int col_base = (blockIdx.x << 6) + (wc << 5);
  const int lr = lane & 15;
  const int kg = (lane >> 4) << 3;
  const int crow = (lane >> 4) << 2;

  f32x4 accs[2][2];
  gemm_tile<COMP>(Ah, Al, Wh, Wl, M, K, row_base, col_base, lr, kg, accs);

#pragma unroll
  for (int mi = 0; mi < 2; ++mi) {
#pragma unroll
    for (int ni = 0; ni < 2; ++ni) {
      int col = col_base + (ni << 4) + lr;
      float bv = bias ? bias[col] : 0.f;
#pragma unroll
      for (int r = 0; r < 4; ++r) {
        int row = row_base + (mi << 4) + crow + r;
        if (row < M) {
          float vv = accs[mi][ni][r] + bv;
          if (EPI == 1) vv = fmaxf(vv, 0.f);
          Cf[(size_t)row * N + col] = vv;
        }
      }
    }
  }
}

#define LDP 40

// ---------------- qkv GEMM: LDS-staged 128x64 tile, compensated, fused scatter ----------------
// XCD swizzle: row-tile r = (id&7) + 8*(id>=192) -> XCD (id%8) holds 2 row panels of A.
__global__ __launch_bounds__(256, 2) void k_qkv(
    const bf16* __restrict__ Ah, const bf16* __restrict__ Al,
    const bf16* __restrict__ Wh, const bf16* __restrict__ Wl,
    float* __restrict__ KFo, bf16* __restrict__ QH, bf16* __restrict__ QM,
    bf16* __restrict__ QL, bf16* __restrict__ VB) {
  __shared__ bf16 sAh[128 * LDP];
  __shared__ bf16 sAl[128 * LDP];
  __shared__ bf16 sBh[64 * LDP];
  __shared__ bf16 sBl[64 * LDP];

  const int t = threadIdx.x;
  const int lane = t & 63, w = t >> 6;
  const int wr = w >> 1, wc = w & 1;
  const int lr = lane & 15;
  const int kg = (lane >> 4) << 3;
  const int crow = (lane >> 4) << 2;
  const int id = blockIdx.x;
  const int rt = (id & 7) + ((id >= 192) ? 8 : 0);   // row tile 0..15
  const int ct = (id >> 3) % 24;                     // col tile 0..23
  const int row0 = rt << 7;
  const int col0 = ct << 6;

  const int qa0 = t,        ar0s = qa0 >> 2, as0 = qa0 & 3;
  const int qa1 = t + 256,  ar1s = qa1 >> 2, as1 = qa1 & 3;
  const int gr0 = row0 + ar0s;
  const int gr1 = row0 + ar1s;
  const int br = t >> 2, bs = t & 3;
  const int gbr = col0 + br;

  f32x4 acc[4][2];
#pragma unroll
  for (int a = 0; a < 4; ++a)
#pragma unroll
    for (int b = 0; b < 2; ++b) acc[a][b] = (f32x4){0.f, 0.f, 0.f, 0.f};

  for (int k0 = 0; k0 < DMODEL; k0 += 32) {
    *reinterpret_cast<bf16x8*>(&sAh[ar0s * LDP + as0 * 8]) =
        *reinterpret_cast<const bf16x8*>(Ah + (size_t)gr0 * DMODEL + k0 + as0 * 8);
    *reinterpret_cast<bf16x8*>(&sAh[ar1s * LDP + as1 * 8]) =
        *reinterpret_cast<const bf16x8*>(Ah + (size_t)gr1 * DMODEL + k0 + as1 * 8);
    *reinterpret_cast<bf16x8*>(&sBh[br * LDP + bs * 8]) =
        *reinterpret_cast<const bf16x8*>(Wh + (size_t)gbr * DMODEL + k0 + bs * 8);
    *reinterpret_cast<bf16x8*>(&sAl[ar0s * LDP + as0 * 8]) =
        *reinterpret_cast<const bf16x8*>(Al + (size_t)gr0 * DMODEL + k0 + as0 * 8);
    *reinterpret_cast<bf16x8*>(&sAl[ar1s * LDP + as1 * 8]) =
        *reinterpret_cast<const bf16x8*>(Al + (size_t)gr1 * DMODEL + k0 + as1 * 8);
    *reinterpret_cast<bf16x8*>(&sBl[br * LDP + bs * 8]) =
        *reinterpret_cast<const bf16x8*>(Wl + (size_t)gbr * DMODEL + k0 + bs * 8);
    __syncthreads();

    bf16x8 fAh[4], fBh[2], fAl[4], fBl[2];
#pragma unroll
    for (int mi = 0; mi < 4; ++mi)
      fAh[mi] = *reinterpret_cast<const bf16x8*>(&sAh[(wr * 64 + mi * 16 + lr) * LDP + kg]);
#pragma unroll
    for (int ni = 0; ni < 2; ++ni)
      fBh[ni] = *reinterpret_cast<const bf16x8*>(&sBh[(wc * 32 + ni * 16 + lr) * LDP + kg]);
#pragma unroll
    for (int mi = 0; mi < 4; ++mi)
      fAl[mi] = *reinterpret_cast<const bf16x8*>(&sAl[(wr * 64 + mi * 16 + lr) * LDP + kg]);
#pragma unroll
    for (int ni = 0; ni < 2; ++ni)
      fBl[ni] = *reinterpret_cast<const bf16x8*>(&sBl[(wc * 32 + ni * 16 + lr) * LDP + kg]);

#pragma unroll
    for (int mi = 0; mi < 4; ++mi)
#pragma unroll
      for (int ni = 0; ni < 2; ++ni)
        acc[mi][ni] = __builtin_amdgcn_mfma_f32_16x16x32_bf16(fAh[mi], fBh[ni], acc[mi][ni], 0, 0, 0);
#pragma unroll
    for (int mi = 0; mi < 4; ++mi)
#pragma unroll
      for (int ni = 0; ni < 2; ++ni) {
        acc[mi][ni] = __builtin_amdgcn_mfma_f32_16x16x32_bf16(fAh[mi], fBl[ni], acc[mi][ni], 0, 0, 0);
        acc[mi][ni] = __builtin_amdgcn_mfma_f32_16x16x32_bf16(fAl[mi], fBh[ni], acc[mi][ni], 0, 0, 0);
      }
    __syncthreads();
  }

#pragma unroll
  for (int mi = 0; mi < 4; ++mi) {
#pragma unroll
    for (int ni = 0; ni < 2; ++ni) {
      int col = col0 + wc * 32 + ni * 16 + lr;
      int which = col >> 9, rem = col & 511;
      int hh = rem >> 6, dd = rem & 63;
#pragma unroll
      for (int r = 0; r < 4; ++r) {
        int row = row0 + wr * 64 + mi * 16 + crow + r;
        float vv = acc[mi][ni][r];
        size_t o = ((size_t)hh * NTOK + row) * DHEAD + dd;
        if (which == 0) {
          bf16 h1 = __float2bfloat16(vv);
          float r1 = vv - __bfloat162float(h1);
          bf16 m1 = __float2bfloat16(r1);
          QH[o] = h1;
          QM[o] = m1;
          QL[o] = __float2bfloat16(r1 - __bfloat162float(m1));
        } else if (which == 1) {
          KFo[o] = vv;
        } else {
          VB[o] = __float2bfloat16(vv);
        }
      }
    }
  }
}

// ---------------- merged MLP1, LDS-staged (128x64 tile, BK=32, padded LDS) ----------------
// XCD swizzle within each path: row tile r = (u&7) + 8*(u>=128) -> 2 A-panels per XCD.
__global__ __launch_bounds__(256, 2) void k_mlp1(
    const bf16* __restrict__ KWh, const bf16* __restrict__ KWl,
    const bf16* __restrict__ W1h, const bf16* __restrict__ W1l,
    const float* __restrict__ kb1,
    const bf16* __restrict__ VWh, const bf16* __restrict__ VW1h,
    const float* __restrict__ vb1,
    bf16* __restrict__ HKh, bf16* __restrict__ HKl, bf16* __restrict__ HVh) {
  __shared__ bf16 sAh[128 * LDP];
  __shared__ bf16 sAl[128 * LDP];
  __shared__ bf16 sBh[64 * LDP];
  __shared__ bf16 sBl[64 * LDP];

  const int t = threadIdx.x;
  const int lane = t & 63, w = t >> 6;
  const int wr = w >> 1, wc = w & 1;
  const int lr = lane & 15;
  const int kg = (lane >> 4) << 3;
  const int crow = (lane >> 4) << 2;
  const int M = NHEAD * NWIN;  // 2032
  const int id = blockIdx.x;
  const bool kpath = (id < 256);
  const int u = kpath ? id : id - 256;
  const int rt = (u & 7) + ((u >= 128) ? 8 : 0);   // row tile 0..15
  const int ct = (u >> 3) & 15;                    // col tile 0..15
  const int row0 = rt << 7;
  const int col0 = ct << 6;

  const bf16* Ah = kpath ? KWh : VWh;
  const bf16* Bh = kpath ? W1h : VW1h;

  const int qa0 = t,        ar0s = qa0 >> 2, as0 = qa0 & 3;
  const int qa1 = t + 256,  ar1s = qa1 >> 2, as1 = qa1 & 3;
  int gr0 = row0 + ar0s; if (gr0 > M - 1) gr0 = M - 1;
  int gr1 = row0 + ar1s; if (gr1 > M - 1) gr1 = M - 1;
  const int br = t >> 2, bs = t & 3;
  const int gbr = col0 + br;

  f32x4 acc[4][2];
#pragma unroll
  for (int a = 0; a < 4; ++a)
#pragma unroll
    for (int b = 0; b < 2; ++b) acc[a][b] = (f32x4){0.f, 0.f, 0.f, 0.f};

  for (int k0 = 0; k0 < CDIM; k0 += 32) {
    *reinterpret_cast<bf16x8*>(&sAh[ar0s * LDP + as0 * 8]) =
        *reinterpret_cast<const bf16x8*>(Ah + (size_t)gr0 * CDIM + k0 + as0 * 8);
    *reinterpret_cast<bf16x8*>(&sAh[ar1s * LDP + as1 * 8]) =
        *reinterpret_cast<const bf16x8*>(Ah + (size_t)gr1 * CDIM + k0 + as1 * 8);
    *reinterpret_cast<bf16x8*>(&sBh[br * LDP + bs * 8]) =
        *reinterpret_cast<const bf16x8*>(Bh + (size_t)gbr * CDIM + k0 + bs * 8);
    if (kpath) {
      *reinterpret_cast<bf16x8*>(&sAl[ar0s * LDP + as0 * 8]) =
          *reinterpret_cast<const bf16x8*>(KWl + (size_t)gr0 * CDIM + k0 + as0 * 8);
      *reinterpret_cast<bf16x8*>(&sAl[ar1s * LDP + as1 * 8]) =
          *reinterpret_cast<const bf16x8*>(KWl + (size_t)gr1 * CDIM + k0 + as1 * 8);
      *reinterpret_cast<bf16x8*>(&sBl[br * LDP + bs * 8]) =
          *reinterpret_cast<const bf16x8*>(W1l + (size_t)gbr * CDIM + k0 + bs * 8);
    }
    __syncthreads();

    bf16x8 fAh[4], fBh[2], fAl[4], fBl[2];
#pragma unroll
    for (int mi = 0; mi < 4; ++mi)
      fAh[mi] = *reinterpret_cast<const bf16x8*>(&sAh[(wr * 64 + mi * 16 + lr) * LDP + kg]);
#pragma unroll
    for (int ni = 0; ni < 2; ++ni)
      fBh[ni] = *reinterpret_cast<const bf16x8*>(&sBh[(wc * 32 + ni * 16 + lr) * LDP + kg]);
    if (kpath) {
#pragma unroll
      for (int mi = 0; mi < 4; ++mi)
        fAl[mi] = *reinterpret_cast<const bf16x8*>(&sAl[(wr * 64 + mi * 16 + lr) * LDP + kg]);
#pragma unroll
      for (int ni = 0; ni < 2; ++ni)
        fBl[ni] = *reinterpret_cast<const bf16x8*>(&sBl[(wc * 32 + ni * 16 + lr) * LDP + kg]);
    }

#pragma unroll
    for (int mi = 0; mi < 4; ++mi)
#pragma unroll
      for (int ni = 0; ni < 2; ++ni)
        acc[mi][ni] = __builtin_amdgcn_mfma_f32_16x16x32_bf16(fAh[mi], fBh[ni], acc[mi][ni], 0, 0, 0);
    if (kpath) {
#pragma unroll
      for (int mi = 0; mi < 4; ++mi)
#pragma unroll
        for (int ni = 0; ni < 2; ++ni) {
          acc[mi][ni] = __builtin_amdgcn_mfma_f32_16x16x32_bf16(fAh[mi], fBl[ni], acc[mi][ni], 0, 0, 0);
          acc[mi][ni] = __builtin_amdgcn_mfma_f32_16x16x32_bf16(fAl[mi], fBh[ni], acc[mi][ni], 0, 0, 0);
        }
    }
    __syncthreads();
  }

#pragma unroll
  for (int mi = 0; mi < 4; ++mi) {
#pragma unroll
    for (int ni = 0; ni < 2; ++ni) {
      int col = col0 + wc * 32 + ni * 16 + lr;
      float bv = kpath ? kb1[col] : vb1[col];
#pragma unroll
      for (int r = 0; r < 4; ++r) {
        int row = row0 + wr * 64 + mi * 16 + crow + r;
        if (row < M) {
          float vv = fmaxf(acc[mi][ni][r] + bv, 0.f);
          size_t o = (size_t)row * CDIM + col;
          if (kpath) {
            bf16 h1 = __float2bfloat16(vv);
            HKh[o] = h1;
            HKl[o] = __float2bfloat16(vv - __bfloat162float(h1));
          } else {
            HVh[o] = __float2bfloat16(vv);
          }
        }
      }
    }
  }
}

// ---------------- merged MLP2: z=0 k-path -> ckT hi/mid/lo, z=1 v-path -> cvT ----------------
__global__ __launch_bounds__(256) void k_mlp2(
    const bf16* __restrict__ HKh, const bf16* __restrict__ HKl,
    const bf16* __restrict__ W2h, const bf16* __restrict__ W2l,
    const float* __restrict__ kb2,
    const bf16* __restrict__ HVh, const bf16* __restrict__ VW2h,
    const float* __restrict__ vb2,
    bf16* __restrict__ ckh, bf16* __restrict__ ckm, bf16* __restrict__ ckl,
    bf16* __restrict__ cvtb) {
  const int lane = threadIdx.x & 63;
  const int w = threadIdx.x >> 6;
  const int wr = w >> 1, wc = w & 1;
  const int row_base = (blockIdx.y << 6) + (wr << 5);
  const int col_base = (wc << 5);
  const int lr = lane & 15;
  const int kg = (lane >> 4) << 3;
  const int crow = (lane >> 4) << 2;
  const int M = NHEAD * NWIN;

  f32x4 accs[2][2];
  if (blockIdx.z == 0)
    gemm_tile<1>(HKh, HKl, W2h, W2l, M, CDIM, row_base, col_base, lr, kg, accs);
  else
    gemm_tile<0>(HVh, nullptr, VW2h, nullptr, M, CDIM, row_base, col_base, lr, kg, accs);

  const float* bias = (blockIdx.z == 0) ? kb2 : vb2;
#pragma unroll
  for (int mi = 0; mi < 2; ++mi) {
#pragma unroll
    for (int ni = 0; ni < 2; ++ni) {
      int col = col_base + (ni << 4) + lr;
      float bv = bias[col];
#pragma unroll
      for (int r = 0; r < 4; ++r) {
        int row = row_base + (mi << 4) + crow + r;
        if (row < M) {
          float vv = accs[mi][ni][r] + bv;
          int hh = row / NWIN, jj = row - hh * NWIN;
          if (blockIdx.z == 0) {
            size_t o = ((size_t)hh * 256 + 1 + jj) * 64 + col;
            bf16 h1 = __float2bfloat16(vv);
            float r1 = vv - __bfloat162float(h1);
            bf16 m1 = __float2bfloat16(r1);
            ckh[o] = h1;
            ckm[o] = m1;
            ckl[o] = __float2bfloat16(r1 - __bfloat162float(m1));
          } else {
            cvtb[((size_t)hh * 64 + col) * 256 + 1 + jj] = __float2bfloat16(vv);
          }
        }
      }
    }
  }
}

// ================= k_setup: 6 weight transposes + zpad + fillmem + rmsnorm =================
__device__ __forceinline__ void wt_tile(const float* __restrict__ W,
                                        bf16* __restrict__ WTh, bf16* __restrict__ WTl,
                                        int K, int N, int bx, int by,
                                        float (*tsh)[33]) {
  const int k0 = bx << 5, n0 = by << 5;
  const int tx = threadIdx.x & 31, ty = threadIdx.x >> 5;
#pragma unroll
  for (int r = 0; r < 4; ++r)
    tsh[ty + (r << 3)][tx] = W[(size_t)(k0 + ty + (r << 3)) * N + n0 + tx];
  __syncthreads();
#pragma unroll
  for (int r = 0; r < 4; ++r) {
    float val = tsh[tx][ty + (r << 3)];
    size_t o = (size_t)(n0 + ty + (r << 3)) * K + k0 + tx;
    bf16 h1 = __float2bfloat16(val);
    WTh[o] = h1;
    if (WTl) WTl[o] = __float2bfloat16(val - __bfloat162float(h1));
  }
}

__global__ __launch_bounds__(256) void k_setup(
    const float* __restrict__ x, const float* __restrict__ g,
    const float* __restrict__ w_qkv, const float* __restrict__ k_w1,
    const float* __restrict__ k_w2, const float* __restrict__ v_w1,
    const float* __restrict__ v_w2, const float* __restrict__ w_out,
    const float* __restrict__ memkv,
    bf16* __restrict__ WQKV_H, bf16* __restrict__ WQKV_L,
    bf16* __restrict__ KW1_H, bf16* __restrict__ KW1_L,
    bf16* __restrict__ KW2_H, bf16* __restrict__ KW2_L,
    bf16* __restrict__ VW1_H, bf16* __restrict__ VW2_H, bf16* __restrict__ WOUT_H,
    bf16* __restrict__ hbh, bf16* __restrict__ hbl,
    bf16* __restrict__ rkh, bf16* __restrict__ rkl, bf16* __restrict__ vtb,
    bf16* __restrict__ ckh, bf16* __restrict__ ckm, bf16* __restrict__ ckl,
    bf16* __restrict__ cvtb) {
  __shared__ float tsh[32][33];
  __shared__ float wsum[4];
  __shared__ float scale_s;
  const int id = blockIdx.x;
  const int t = threadIdx.x;

  if (id < 768) {
    wt_tile(w_qkv, WQKV_H, WQKV_L, DMODEL, 1536, id % 16, id / 16, tsh);
  } else if (id < 1792) {
    int u = id - 768;  wt_tile(k_w1, KW1_H, KW1_L, CDIM, CDIM, u % 32, u / 32, tsh);
  } else if (id < 1856) {
    int u = id - 1792; wt_tile(k_w2, KW2_H, KW2_L, CDIM, DHEAD, u % 32, u / 32, tsh);
  } else if (id < 2880) {
    int u = id - 1856; wt_tile(v_w1, VW1_H, nullptr, CDIM, CDIM, u % 32, u / 32, tsh);
  } else if (id < 2944) {
    int u = id - 2880; wt_tile(v_w2, VW2_H, nullptr, CDIM, DHEAD, u % 32, u / 32, tsh);
  } else if (id < 3200) {
    int u = id - 2944; wt_tile(w_out, WOUT_H, nullptr, DMODEL, DMODEL, u % 16, u / 16, tsh);
  } else if (id < 3328) {
    int idx = (id - 3200) * 256 + t;   // [0, 32768)
    int h = idx >> 12, r = (idx >> 6) & 63, c = idx & 63;
    bf16 z = __float2bfloat16(0.f);
    rkh[((size_t)h * 2112 + r) * 64 + c] = z;
    rkl[((size_t)h * 2112 + r) * 64 + c] = z;
    vtb[((size_t)h * 64 + r) * 2112 + c] = z;
  } else if (id < 3330) {
    int u = (id - 3328) * 256 + t;     // [0, 512)
    if (u < 512) {
      int h = u >> 6, e = u & 63;
      float kv = memkv[(size_t)h * DHEAD + e];
      bf16 h1 = __float2bfloat16(kv);
      float r1 = kv - __bfloat162float(h1);
      bf16 m1 = __float2bfloat16(r1);
      ckh[((size_t)h * 256) * 64 + e] = h1;
      ckm[((size_t)h * 256) * 64 + e] = m1;
      ckl[((size_t)h * 256) * 64 + e] = __float2bfloat16(r1 - __bfloat162float(m1));
      bf16 z = __float2bfloat16(0.f);
      ckh[((size_t)h * 256 + 255) * 64 + e] = z;
      ckm[((size_t)h * 256 + 255) * 64 + e] = z;
      ckl[((size_t)h * 256 + 255) * 64 + e] = z;
      float vv = memkv[(size_t)(NHEAD + h) * DHEAD + e];
      cvtb[((size_t)h * 64 + e) * 256 + 0] = __float2bfloat16(vv);
      cvtb[((size_t)h * 64 + e) * 256 + 255] = z;
    }
  } else {
    const int row = id - 3330;
    const float* xr = x + (size_t)row * DMODEL;
    float s = 0.f;
    for (int c = t; c < DMODEL; c += 256) { float v = xr[c]; s += v * v; }
    for (int o = 32; o > 0; o >>= 1) s += __shfl_down(s, o);
    if ((t & 63) == 0) wsum[t >> 6] = s;
    __syncthreads();
    if (t == 0) {
      float tot = wsum[0] + wsum[1] + wsum[2] + wsum[3];
      scale_s = rsqrtf(tot * (1.f / DMODEL) + 1e-6f);
    }
    __syncthreads();
    float sc = scale_s;
    for (int c = t; c < DMODEL; c += 256) {
      float v = xr[c] * sc * g[c];
      bf16 h1 = __float2bfloat16(v);
      hbh[(size_t)row * DMODEL + c] = h1;
      hbl[(size_t)row * DMODEL + c] = __float2bfloat16(v - __bfloat162float(h1));
    }
  }
}

// ================= k_post: rope + v-transpose + compression windows =================
__global__ __launch_bounds__(256) void k_post(
    const bf16* __restrict__ qbh, const bf16* __restrict__ qbm,
    const bf16* __restrict__ qbl, const float* __restrict__ kf,
    const bf16* __restrict__ vbh,
    const float* __restrict__ kpos, const float* __restrict__ vpos,
    bf16* __restrict__ rqh, bf16* __restrict__ rql,
    bf16* __restrict__ rkh, bf16* __restrict__ rkl,
    bf16* __restrict__ vtb,
    bf16* __restrict__ kwh, bf16* __restrict__ kwl, bf16* __restrict__ vwh) {
  __shared__ bf16 tile[64][65];
  const int id = blockIdx.x;
  const int t = threadIdx.x;

  if (id < 2048) {
    int idx = id * 256 + t;
    int i = idx & 31;
    int n = (idx >> 5) & (NTOK - 1);
    int h = idx >> 16;
    float ex = (float)(2 * i) * (1.f / 64.f);
    float inv = exp2f(-ex * 13.287712379549449f);
    float ang = (float)n * inv;
    float sn, cs;
    sincosf(ang, &sn, &cs);
    size_t base = ((size_t)h * NTOK + n) * DHEAD + 2 * i;
    float q1 = __bfloat162float(qbh[base]) + __bfloat162float(qbm[base]) + __bfloat162float(qbl[base]);
    float q2 = __bfloat162float(qbh[base + 1]) + __bfloat162float(qbm[base + 1]) + __bfloat162float(qbl[base + 1]);
    float r1 = q1 * cs - q2 * sn, r2 = q1 * sn + q2 * cs;
    bf16 h1 = __float2bfloat16(r1);
    rqh[base] = h1; rql[base] = __float2bfloat16(r1 - __bfloat162float(h1));
    h1 = __float2bfloat16(r2);
    rqh[base + 1] = h1; rql[base + 1] = __float2bfloat16(r2 - __bfloat162float(h1));
    float k1 = kf[base], k2 = kf[base + 1];
    float s1 = k1 * cs - k2 * sn, s2 = k1 * sn + k2 * cs;
    size_t kb = ((size_t)h * 2112 + 64 + n) * DHEAD + 2 * i;
    h1 = __float2bfloat16(s1);
    rkh[kb] = h1; rkl[kb] = __float2bfloat16(s1 - __bfloat162float(h1));
    h1 = __float2bfloat16(s2);
    rkh[kb + 1] = h1; rkl[kb + 1] = __float2bfloat16(s2 - __bfloat162float(h1));
  } else if (id < 2304) {
    int u = id - 2048;
    int h = u >> 5, n0 = (u & 31) << 6;
    int tx = t & 63, ty = t >> 6;
    for (int r = ty; r < 64; r += 4)
      tile[r][tx] = vbh[((size_t)h * NTOK + n0 + r) * DHEAD + tx];
    __syncthreads();
    for (int r = ty; r < 64; r += 4)
      vtb[((size_t)h * 64 + r) * 2112 + 64 + n0 + tx] = tile[tx][r];
  } else {
    int idx = (id - 2304) * 256 + t;   // [0, 2080768)
    int d = idx & 63;
    int c = (idx >> 6) & 15;
    int j = (idx >> 10) % NWIN;
    int h = idx / (NWIN << 10);
    int srcpos = (j << 3) + c;
    size_t src = ((size_t)h * NTOK + srcpos) * DHEAD + d;
    size_t pp = ((size_t)h * 16 + c) * DHEAD + d;
    float kv = kf[src] + kpos[pp];
    bf16 h1 = __float2bfloat16(kv);
    kwh[idx] = h1;
    kwl[idx] = __float2bfloat16(kv - __bfloat162float(h1));
    vwh[idx] = __float2bfloat16(__bfloat162float(vbh[src]) + vpos[pp]);
  }
}

// ---------------- compression attention (MFMA, 32 queries/block) ----------------
// 1D grid 512: h = id&7 -> all blocks of head h land on XCD h (id%8).
__global__ __launch_bounds__(256) void k_comp_attn(
    const bf16* __restrict__ qbh, const bf16* __restrict__ qbm, const bf16* __restrict__ qbl,
    const bf16* __restrict__ ckh, const bf16* __restrict__ ckm, const bf16* __restrict__ ckl,
    const bf16* __restrict__ cvtb,
    float* __restrict__ c_out, int* __restrict__ sel) {
  const int h = blockIdx.x & 7;
  const int i0 = (blockIdx.x >> 3) << 5;
  const int t = threadIdx.x;
  const int w = t >> 6, lane = t & 63;
  const int lr = lane & 15, kg = (lane >> 4) << 3;
  const int crow = (lane >> 4) << 2;

  __shared__ float p[32][260];

  bf16x8 aH[2][2], aM[2][2], aL[2][2];
#pragma unroll
  for (int mi = 0; mi < 2; ++mi) {
    size_t qo = ((size_t)h * NTOK + i0 + mi * 16 + lr) * DHEAD + kg;
#pragma unroll
    for (int ks = 0; ks < 2; ++ks) {
      aH[mi][ks] = *reinterpret_cast<const bf16x8*>(qbh + qo + ks * 32);
      aM[mi][ks] = *reinterpret_cast<const bf16x8*>(qbm + qo + ks * 32);
      aL[mi][ks] = *reinterpret_cast<const bf16x8*>(qbl + qo + ks * 32);
    }
  }
  f32x4 acc[2][4];
#pragma unroll
  for (int a = 0; a < 2; ++a)
#pragma unroll
    for (int b = 0; b < 4; ++b) acc[a][b] = (f32x4){0.f, 0.f, 0.f, 0.f};
#pragma unroll
  for (int ni = 0; ni < 4; ++ni) {
    int col = (w << 6) + (ni << 4) + lr;
    size_t ko = ((size_t)h * 256 + col) * 64 + kg;
#pragma unroll
    for (int ks = 0; ks < 2; ++ks) {
      bf16x8 bH = *reinterpret_cast<const bf16x8*>(ckh + ko + ks * 32);
      bf16x8 bM = *reinterpret_cast<const bf16x8*>(ckm + ko + ks * 32);
      bf16x8 bL = *reinterpret_cast<const bf16x8*>(ckl + ko + ks * 32);
#pragma unroll
      for (int mi = 0; mi < 2; ++mi) {
        acc[mi][ni] = __builtin_amdgcn_mfma_f32_16x16x32_bf16(aH[mi][ks], bH, acc[mi][ni], 0, 0, 0);
        acc[mi][ni] = __builtin_amdgcn_mfma_f32_16x16x32_bf16(aH[mi][ks], bM, acc[mi][ni], 0, 0, 0);
        acc[mi][ni] = __builtin_amdgcn_mfma_f32_16x16x32_bf16(aM[mi][ks], bH, acc[mi][ni], 0, 0, 0);
        acc[mi][ni] = __builtin_amdgcn_mfma_f32_16x16x32_bf16(aH[mi][ks], bL, acc[mi][ni], 0, 0, 0);
        acc[mi][ni] = __builtin_amdgcn_mfma_f32_16x16x32_bf16(aL[mi][ks], bH, acc[mi][ni], 0, 0, 0);
        acc[mi][ni] = __builtin_amdgcn_mfma_f32_16x16x32_bf16(aM[mi][ks], bM, acc[mi][ni], 0, 0, 0);
      }
    }
  }
#pragma unroll
  for (int mi = 0; mi < 2; ++mi)
#pragma unroll
    for (int ni = 0; ni < 4; ++ni) {
      int col = (w << 6) + (ni << 4) + lr;
      int wend = (col == 0) ? -1 : ((col - 1) << 3) + 15;
#pragma unroll
      for (int r = 0; r < 4; ++r) {
        int qi = mi * 16 + crow + r;
        bool ok = (col < 255) && (wend < i0 + qi);
        p[qi][col] = ok ? acc[mi][ni][r] * 0.125f : NEGV;
      }
    }
  __syncthreads();

  const int qi = t >> 3, s = t & 7;
  float ev[32];
  float mx = -3.0e38f;
#pragma unroll
  for (int u = 0; u < 32; ++u) { ev[u] = p[qi][s + (u << 3)]; mx = fmaxf(mx, ev[u]); }
  mx = fmaxf(mx, __shfl_xor(mx, 1));
  mx = fmaxf(mx, __shfl_xor(mx, 2));
  mx = fmaxf(mx, __shfl_xor(mx, 4));
  float sum = 0.f;
#pragma unroll
  for (int u = 0; u < 32; ++u) { float e = __expf(ev[u] - mx); ev[u] = e; sum += e; }
  sum += __shfl_xor(sum, 1); sum += __shfl_xor(sum, 2); sum += __shfl_xor(sum, 4);
  float invs = 1.f / sum;
#pragma unroll
  for (int u = 0; u < 32; ++u) p[qi][s + (u << 3)] = ev[u] * invs;

  int qblk = (i0 + qi) >> 4;
  float vals[16];
#pragma unroll
  for (int u = 0; u < 16; ++u) {
    int f = (s << 4) + u;
    float v;
    if (f >= qblk || f == 127) v = NEGV;
    else v = (p[qi][2 * f + 1] + p[qi][2 * f + 2]) * 0.5f;
    vals[u] = v;
  }
  int base = ((h << 11) | (i0 + qi)) * 5;
  for (int kk = 0; kk < 4; ++kk) {
    float bv = -3.0e38f; int bi = 0;
#pragma unroll
    for (int u = 0; u < 16; ++u) {
      if (vals[u] > bv) { bv = vals[u]; bi = (s << 4) + u; }
    }
#pragma unroll
    for (int o = 1; o < 8; o <<= 1) {
      float ov = __shfl_xor(bv, o);
      int oi = __shfl_xor(bi, o);
      if (ov > bv || (ov == bv && oi < bi)) { bv = ov; bi = oi; }
    }
    if (s == 0) sel[base + kk] = (bv > -5.0e8f) ? bi : -1;
    if ((bi >> 4) == s) vals[bi & 15] = -3.0e38f;
  }
  if (s == 0) sel[base + 4] = (i0 + qi) >> 4;
  __syncthreads();

  const int wm = w >> 1, wn = w & 1;
  const int arow = wm * 16 + lr;
  f32x4 pacc[2];
#pragma unroll
  for (int b = 0; b < 2; ++b) pacc[b] = (f32x4){0.f, 0.f, 0.f, 0.f};
#pragma unroll
  for (int ks = 0; ks < 8; ++ks) {
    int k0 = ks * 32 + kg;
    float4 x0 = *reinterpret_cast<const float4*>(&p[arow][k0]);
    float4 x1 = *reinterpret_cast<const float4*>(&p[arow][k0 + 4]);
    float xv[8] = {x0.x, x0.y, x0.z, x0.w, x1.x, x1.y, x1.z, x1.w};
    bf16x8 ph, pl;
#pragma unroll
    for (int e = 0; e < 8; ++e) {
      __bf16 hh = (__bf16)xv[e];
      ph[e] = hh;
      pl[e] = (__bf16)(xv[e] - (float)hh);
    }
#pragma unroll
    for (int ni = 0; ni < 2; ++ni) {
      int d = (wn << 5) + (ni << 4) + lr;
      bf16x8 bv = *reinterpret_cast<const bf16x8*>(cvtb + ((size_t)h * 64 + d) * 256 + k0);
      pacc[ni] = __builtin_amdgcn_mfma_f32_16x16x32_bf16(ph, bv, pacc[ni], 0, 0, 0);
      pacc[ni] = __builtin_amdgcn_mfma_f32_16x16x32_bf16(pl, bv, pacc[ni], 0, 0, 0);
    }
  }
#pragma unroll
  for (int ni = 0; ni < 2; ++ni) {
    int d = (wn << 5) + (ni << 4) + lr;
#pragma unroll
    for (int r = 0; r < 4; ++r) {
      int q2 = wm * 16 + crow + r;
      c_out[((size_t)h * NTOK + i0 + q2) * DHEAD + d] = pacc[ni][r];
    }
  }
}

// ======== fused fine + sliding attention, head-per-XCD swizzle ========
// slide: blk<512, h = blk&7 (XCD h), nb = (blk>>3)&63.
// fine:  u = blk-512, h = u&7 (XCD h since (512+u)%8 == u%8), qq = u>>3.
__global__ __launch_bounds__(256, 8) void k_fs_attn(
    const bf16* __restrict__ rqh, const bf16* __restrict__ rql,
    const bf16* __restrict__ rkh, const bf16* __restrict__ rkl,
    const bf16* __restrict__ vbh, const bf16* __restrict__ vtb,
    const int* __restrict__ sel,
    float* __restrict__ f_out, float* __restrict__ s_out) {
  __shared__ char smraw[32 * 100 * 4];   // 12800 B
  const int blk = blockIdx.x;
  const int t = threadIdx.x;

  if (blk < 512) {
    // ========== sliding-window: 32 queries, 96-key window ==========
    float (*p)[100] = reinterpret_cast<float(*)[100]>(smraw);
    const int h = blk & 7, nb = (blk >> 3) & 63;
    const int w = t >> 6, lane = t & 63;
    const int lr = lane & 15, kg = (lane >> 4) << 3;
    const int crow = (lane >> 4) << 2;
    const int wr = w >> 1, wc = w & 1;

    bf16x8 aH[2], aL[2];
    {
      size_t qo = ((size_t)h * NTOK + nb * 32 + wr * 16 + lr) * DHEAD + kg;
#pragma unroll
      for (int ks = 0; ks < 2; ++ks) {
        aH[ks] = *reinterpret_cast<const bf16x8*>(rqh + qo + ks * 32);
        aL[ks] = *reinterpret_cast<const bf16x8*>(rql + qo + ks * 32);
      }
    }
    f32x4 acc[3];
#pragma unroll
    for (int a = 0; a < 3; ++a) acc[a] = (f32x4){0.f, 0.f, 0.f, 0.f};
#pragma unroll
    for (int ni = 0; ni < 3; ++ni) {
      int col = wc * 48 + ni * 16 + lr;
      size_t ko = ((size_t)h * 2112 + nb * 32 + col) * 64 + kg;
#pragma unroll
      for (int ks = 0; ks < 2; ++ks) {
        bf16x8 bH = *reinterpret_cast<const bf16x8*>(rkh + ko + ks * 32);
        bf16x8 bL = *reinterpret_cast<const bf16x8*>(rkl + ko + ks * 32);
        acc[ni] = __builtin_amdgcn_mfma_f32_16x16x32_bf16(aH[ks], bH, acc[ni], 0, 0, 0);
        acc[ni] = __builtin_amdgcn_mfma_f32_16x16x32_bf16(aL[ks], bH, acc[ni], 0, 0, 0);
        acc[ni] = __builtin_amdgcn_mfma_f32_16x16x32_bf16(aH[ks], bL, acc[ni], 0, 0, 0);
      }
    }
    const int cmin = 64 - nb * 32;
#pragma unroll
    for (int ni = 0; ni < 3; ++ni) {
      int col = wc * 48 + ni * 16 + lr;
#pragma unroll
      for (int r = 0; r < 4; ++r) {
        int q = wr * 16 + crow + r;
        bool ok = (col >= q + 1) && (col <= q + 64) && (col >= cmin);
        p[q][col] = ok ? acc[ni][r] * 0.125f : NEGV;
      }
    }
    __syncthreads();

    const int qi = t >> 3, s = t & 7;
    float ev[12];
    float mx = -3.0e38f;
#pragma unroll
    for (int u = 0; u < 12; ++u) { ev[u] = p[qi][s + (u << 3)]; mx = fmaxf(mx, ev[u]); }
    mx = fmaxf(mx, __shfl_xor(mx, 1));
    mx = fmaxf(mx, __shfl_xor(mx, 2));
    mx = fmaxf(mx, __shfl_xor(mx, 4));
    float sum = 0.f;
#pragma unroll
    for (int u = 0; u < 12; ++u) { float e = __expf(ev[u] - mx); ev[u] = e; sum += e; }
    sum += __shfl_xor(sum, 1); sum += __shfl_xor(sum, 2); sum += __shfl_xor(sum, 4);
    float invs = 1.f / sum;
#pragma unroll
    for (int u = 0; u < 12; ++u) p[qi][s + (u << 3)] = ev[u] * invs;
    __syncthreads();

    const int wm = w >> 1, wn = w & 1;
    const int arow = wm * 16 + lr;
    f32x4 pacc[2];
#pragma unroll
    for (int b = 0; b < 2; ++b) pacc[b] = (f32x4){0.f, 0.f, 0.f, 0.f};
#pragma unroll
    for (int ks = 0; ks < 3; ++ks) {
      int k0 = ks * 32 + kg;
      float4 x0 = *reinterpret_cast<const float4*>(&p[arow][k0]);
      float4 x1 = *reinterpret_cast<const float4*>(&p[arow][k0 + 4]);
      float xv[8] = {x0.x, x0.y, x0.z, x0.w, x1.x, x1.y, x1.z, x1.w};
      bf16x8 ph, pl;
#pragma unroll
      for (int e = 0; e < 8; ++e) {
        __bf16 hh = (__bf16)xv[e];
        ph[e] = hh;
        pl[e] = (__bf16)(xv[e] - (float)hh);
      }
#pragma unroll
      for (int ni = 0; ni < 2; ++ni) {
        int d = wn * 32 + ni * 16 + lr;
        bf16x8 bv = *reinterpret_cast<const bf16x8*>(
            vtb + ((size_t)h * 64 + d) * 2112 + nb * 32 + k0);
        pacc[ni] = __builtin_amdgcn_mfma_f32_16x16x32_bf16(ph, bv, pacc[ni], 0, 0, 0);
        pacc[ni] = __builtin_amdgcn_mfma_f32_16x16x32_bf16(pl, bv, pacc[ni], 0, 0, 0);
      }
    }
#pragma unroll
    for (int ni = 0; ni < 2; ++ni) {
      int d = wn * 32 + ni * 16 + lr;
#pragma unroll
      for (int r = 0; r < 4; ++r) {
        int q = wm * 16 + crow + r;
        s_out[((size_t)h * NTOK + nb * 32 + q) * DHEAD + d] = pacc[ni][r];
      }
    }
  } else {
    // ========== fine attention (1 wave/query, bf16-hi K) ==========
    float (*qs)[64] = reinterpret_cast<float(*)[64]>(smraw);
    float (*pb)[80] = reinterpret_cast<float(*)[80]>(smraw + 4 * 64 * 4);
    int (*selb)[5]  = reinterpret_cast<int(*)[5]>(smraw + 4 * 64 * 4 + 4 * 80 * 4);

    const int u = blk - 512;
    const int h = u & 7;
    const int qq = u >> 3;           // 0..511
    const int wid = t >> 6;
    const int lane = t & 63;
    const int i = (qq << 2) | wid;

    size_t qoff = ((size_t)h * NTOK + i) * DHEAD + lane;
    qs[wid][lane] = __bfloat162float(rqh[qoff]) + __bfloat162float(rql[qoff]);
    if (lane < 5) selb[wid][lane] = sel[((h << 11) | i) * 5 + lane];
    __syncthreads();

    int sblk[5];
#pragma unroll
    for (int b = 0; b < 5; ++b) sblk[b] = selb[wid][b];

    float sim0 = NEGV, sim1 = NEGV;
    {
      int kb = sblk[lane >> 4];
      int pos = (kb << 4) + (lane & 15);
      if (kb >= 0 && pos <= i) {
        const bf16* kp = rkh + ((size_t)h * 2112 + 64 + pos) * DHEAD;
        float d = 0.f;
#pragma unroll
        for (int e8 = 0; e8 < 8; ++e8) {
          bf16x8 kv = *reinterpret_cast<const bf16x8*>(kp + e8 * 8);
#pragma unroll
          for (int e = 0; e < 8; ++e)
            d = fmaf(qs[wid][e8 * 8 + e], (float)kv[e], d);
        }
        sim0 = d * 0.125f;
      }
    }
    if (lane < 16) {
      int kb = sblk[4];
      int pos = (kb << 4) + lane;
      if (pos <= i) {
        const bf16* kp = rkh + ((size_t)h * 2112 + 64 + pos) * DHEAD;
        float d = 0.f;
#pragma unroll
        for (int e8 = 0; e8 < 8; ++e8) {
          bf16x8 kv = *reinterpret_cast<const bf16x8*>(kp + e8 * 8);
#pragma unroll
          for (int e = 0; e < 8; ++e)
            d = fmaf(qs[wid][e8 * 8 + e], (float)kv[e], d);
        }
        sim1 = d * 0.125f;
      }
    }

    float mx = fmaxf(sim0, sim1);
#pragma unroll
    for (int o = 32; o > 0; o >>= 1) mx = fmaxf(mx, __shfl_xor(mx, o));
    float e0 = __expf(sim0 - mx);
    float e1 = __expf(sim1 - mx);
    float sum = e0 + e1;
#pragma unroll
    for (int o = 32; o > 0; o >>= 1) sum += __shfl_xor(sum, o);
    float invs = 1.f / sum;
    pb[wid][lane] = e0 * invs;
    if (lane < 16) pb[wid][64 + lane] = e1 * invs;
    // same wave writes & reads pb[wid]: DS ops wave-ordered, no barrier needed

    float acc = 0.f;
#pragma unroll
    for (int b = 0; b < 5; ++b) {
      int kb = sblk[b];
      if (kb < 0) continue;
      const bf16* vr = vbh + ((size_t)h * NTOK + ((size_t)kb << 4)) * DHEAD + lane;
#pragma unroll
      for (int uu = 0; uu < 16; ++uu)
        acc = fmaf(pb[wid][b * 16 + uu], __bfloat162float(vr[(size_t)uu * DHEAD]), acc);
    }
    f_out[((size_t)h * NTOK + i) * DHEAD + lane] = acc;
  }
}

// ---------------- fused strat + combine: one block per token ----------------
__global__ __launch_bounds__(256) void k_combine2(
    const bf16* __restrict__ Ah, const bf16* __restrict__ Al,
    const float* __restrict__ W, const float* __restrict__ bias,
    const float* __restrict__ c_out, const float* __restrict__ f_out,
    const float* __restrict__ s_out, bf16* __restrict__ comb) {
  const int i = blockIdx.x;
  const int t = threadIdx.x;
  __shared__ float hs[DMODEL];
  __shared__ float st[24];
  size_t ro = (size_t)i * DMODEL;
#pragma unroll
  for (int u = 0; u < 2; ++u) {
    int c = t + u * 256;
    hs[c] = __bfloat162float(Ah[ro + c]) + __bfloat162float(Al[ro + c]);
  }
  __syncthreads();
  if (t < 192) {
    int c = t >> 3, s = t & 7;
    float acc = 0.f;
    for (int u = 0; u < 64; ++u) {
      int e = s * 64 + u;
      acc = fmaf(hs[e], W[(size_t)e * 24 + c], acc);
    }
    acc += __shfl_xor(acc, 1);
    acc += __shfl_xor(acc, 2);
    acc += __shfl_xor(acc, 4);
    if (s == 0) st[c] = 1.f / (1.f + expf(-(acc + bias[c])));
  }
  __syncthreads();
#pragma unroll
  for (int u = 0; u < 2; ++u) {
    int c = t + u * 256;
    int h = c >> 6, d = c & 63;
    size_t a = ((size_t)h * NTOK + i) * DHEAD + d;
    comb[ro + c] = __float2bfloat16(st[h * 3] * c_out[a] + st[h * 3 + 1] * f_out[a]
                                    + st[h * 3 + 2] * s_out[a]);
  }
}

extern "C" void kernel_launch(void* const* d_in, const int* in_sizes, int n_in,
                              void* d_out, int out_size, void* d_ws, size_t ws_size,
                              hipStream_t stream) {
  const float* x      = (const float*)d_in[0];
  const float* g_norm = (const float*)d_in[1];
  const float* w_qkv  = (const float*)d_in[2];
  const float* k_pos  = (const float*)d_in[3];
  const float* v_pos  = (const float*)d_in[4];
  const float* mem_kv = (const float*)d_in[5];
  const float* k_w1   = (const float*)d_in[6];
  const float* k_b1   = (const float*)d_in[7];
  const float* k_w2   = (const float*)d_in[8];
  const float* k_b2   = (const float*)d_in[9];
  const float* v_w1   = (const float*)d_in[10];
  const float* v_b1   = (const float*)d_in[11];
  const float* v_w2   = (const float*)d_in[12];
  const float* v_b2   = (const float*)d_in[13];
  const float* w_comb = (const float*)d_in[14];
  const float* b_comb = (const float*)d_in[15];
  const float* w_out  = (const float*)d_in[16];
  float* out = (float*)d_out;
  char* wsb = (char*)d_ws;

  bf16* WQKV_H = (bf16*)(wsb + B_WQKV_H);
  bf16* WQKV_L = (bf16*)(wsb + B_WQKV_L);
  bf16* KW1_H  = (bf16*)(wsb + B_KW1_H);
  bf16* KW1_L  = (bf16*)(wsb + B_KW1_L);
  bf16* KW2_H  = (bf16*)(wsb + B_KW2_H);
  bf16* KW2_L  = (bf16*)(wsb + B_KW2_L);
  bf16* VW1_H  = (bf16*)(wsb + B_VW1_H);
  bf16* VW2_H  = (bf16*)(wsb + B_VW2_H);
  bf16* WOUT_H = (bf16*)(wsb + B_WOUT_H);
  bf16* HB_H   = (bf16*)(wsb + B_HB_H);
  bf16* HB_L   = (bf16*)(wsb + B_HB_L);
  bf16* QBH    = (bf16*)(wsb + B_QBH);
  bf16* QBM    = (bf16*)(wsb + B_QBM);
  bf16* QBL    = (bf16*)(wsb + B_QBL);
  float* KF    = (float*)(wsb + B_KF);
  bf16* VBH    = (bf16*)(wsb + B_VBH);
  bf16* RQH    = (bf16*)(wsb + B_RQH);
  bf16* RQL    = (bf16*)(wsb + B_RQL);
  bf16* RKH    = (bf16*)(wsb + B_RKH);
  bf16* RKL    = (bf16*)(wsb + B_RKL);
  bf16* VTB    = (bf16*)(wsb + B_VTB);
  bf16* CKT_H  = (bf16*)(wsb + B_CKT_H);
  bf16* CKT_M  = (bf16*)(wsb + B_CKT_M);
  bf16* CKT_L  = (bf16*)(wsb + B_CKT_L);
  bf16* CVT    = (bf16*)(wsb + B_CVT);
  int*   SEL   = (int*)(wsb + B_SEL);
  float* COUT  = (float*)(wsb + B_COUT);
  float* FOUT  = (float*)(wsb + B_FOUT);
  float* SOUT  = (float*)(wsb + B_SOUT);
  bf16* KW_H   = (bf16*)(wsb + B_KW_H);
  bf16* KW_L   = (bf16*)(wsb + B_KW_L);
  bf16* VW_H   = (bf16*)(wsb + B_VW_H);
  bf16* HID_H  = (bf16*)(wsb + B_HID_H);
  bf16* HID_L  = (bf16*)(wsb + B_HID_L);
  bf16* HIDV   = (bf16*)(wsb + B_HIDV);
  bf16* COMBB  = (bf16*)(wsb + B_COMBB);

  // 1. setup: weight splits + pads + mem fill + rmsnorm
  k_setup<<<5378, 256, 0, stream>>>(x, g_norm, w_qkv, k_w1, k_w2, v_w1, v_w2, w_out, mem_kv,
                                    WQKV_H, WQKV_L, KW1_H, KW1_L, KW2_H, KW2_L,
                                    VW1_H, VW2_H, WOUT_H, HB_H, HB_L,
                                    RKH, RKL, VTB, CKT_H, CKT_M, CKT_L, CVT);
  // 2. qkv: LDS-staged 128x64, 384 blocks (XCD row-grouped), fused split/scatter
  k_qkv<<<384, 256, 0, stream>>>(HB_H, HB_L, WQKV_H, WQKV_L, KF, QBH, QBM, QBL, VBH);
  // 3. post: rope + v-transpose + windows
  k_post<<<10432, 256, 0, stream>>>(QBH, QBM, QBL, KF, VBH, k_pos, v_pos,
                                    RQH, RQL, RKH, RKL, VTB, KW_H, KW_L, VW_H);
  // 4. merged MLP1: LDS-staged, 512 blocks (XCD row-grouped); HIDV overlays dead KF
  k_mlp1<<<512, 256, 0, stream>>>(KW_H, KW_L, KW1_H, KW1_L, k_b1,
                                  VW_H, VW1_H, v_b1, HID_H, HID_L, HIDV);
  // 5. merged MLP2 -> ckT hi/mid/lo + cvT
  k_mlp2<<<dim3(1, 32, 2), 256, 0, stream>>>(HID_H, HID_L, KW2_H, KW2_L, k_b2,
                                             HIDV, VW2_H, v_b2, CKT_H, CKT_M, CKT_L, CVT);
  // 6. compression attention + selection (head-per-XCD, 512 blocks)
  k_comp_attn<<<512, 256, 0, stream>>>(QBH, QBM, QBL, CKT_H, CKT_M, CKT_L, CVT, COUT, SEL);
  // 7. fused slide + fine attention (head-per-XCD)
  k_fs_attn<<<4608, 256, 0, stream>>>(RQH, RQL, RKH, RKL, VBH, VTB, SEL, FOUT, SOUT);
  // 8. fused strat + combine
  k_combine2<<<NTOK, 256, 0, stream>>>(HB_H, HB_L, w_comb, b_comb, COUT, FOUT, SOUT, COMBB);
  // 9. output projection
  k_cgemm<0, 0><<<dim3(8, 32), 256, 0, stream>>>(
      COMBB, nullptr, WOUT_H, nullptr, nullptr, out, NTOK, DMODEL, DMODEL);
}

// Round 17
// 205.393 us; speedup vs baseline: 1.4916x; 1.0599x over previous
//
#include <hip/hip_runtime.h>
#include <hip/hip_bf16.h>
#include <cstddef>

#define NTOK 2048
#define DMODEL 512
#define NHEAD 8
#define DHEAD 64
#define NWIN 254          // (2048-16)/8 + 1
#define CDIM 1024         // CB*DH
#define NEGV -1000000000.0f

typedef __attribute__((ext_vector_type(8))) __bf16 bf16x8;
typedef __attribute__((ext_vector_type(4))) float f32x4;
typedef __hip_bfloat16 bf16;

// ---------------- workspace layout (byte offsets) ----------------
static const size_t B_WQKV_H = 0;          // 1536*512*2
static const size_t B_WQKV_L = 1572864;
static const size_t B_KW1_H  = 3145728;    // 1024*1024*2
static const size_t B_KW1_L  = 5242880;
static const size_t B_KW2_H  = 7340032;    // 64*1024*2
static const size_t B_KW2_L  = 7471104;
static const size_t B_VW1_H  = 7602176;
static const size_t B_VW2_H  = 9699328;
static const size_t B_WOUT_H = 9830400;    // 512*512*2
static const size_t B_HB_H   = 10354688;   // 2048*512*2
static const size_t B_HB_L   = 12451840;
static const size_t B_QBH    = 14548992;   // 8*2048*64*2 (non-roped q, hi)
static const size_t B_QBL    = 16646144;   // (lo, 3rd term)
static const size_t B_KF     = 18743296;   // 8*2048*64*4 (k fp32; dead after k_post -> HIDV)
static const size_t B_VBH    = 22937600;   // 8*2048*64*2
static const size_t B_RQH    = 25034752;   // roped q hi/lo
static const size_t B_RQL    = 27131904;
static const size_t B_RKH    = 29229056;   // 8*2112*64*2 (roped k, 64 zero-pad rows front)
static const size_t B_RKL    = 31391744;
static const size_t B_VTB    = 33554432;   // 8*64*2112*2 (v^T, 64 zero-pad cols front)
static const size_t B_CKT_H  = 35717120;   // 8*256*64*2 (compressed k rows, j=0 mem)
static const size_t B_CKT_L  = 35979264;
static const size_t B_CVT    = 36241408;   // 8*64*256*2 (compressed v transposed)
static const size_t B_SEL    = 36700160;   // 8*2048*5*4
static const size_t B_COUT   = 37027840;   // 4194304 (overlays KW_H)
static const size_t B_FOUT   = 41222144;   // 4194304 (overlays KW_L)
static const size_t B_SOUT   = 45416448;   // 4194304 (overlays VW_H)
static const size_t B_KW_H   = B_COUT;     // 2032*1024*2 = 4161536
static const size_t B_KW_L   = B_FOUT;
static const size_t B_VW_H   = B_SOUT;
static const size_t B_HID_H  = 49610752;   // 4161536 (k hidden hi)
static const size_t B_HID_L  = 53772288;   // 4161536 (k hidden lo)
static const size_t B_QBM    = 57933824;   // 8*2048*64*2 (q mid term)
static const size_t B_CKT_M  = 60030976;   // 8*256*64*2
static const size_t B_HIDV   = B_KF;       // v hidden hi (4161536 <= 4194304, KF dead)
static const size_t B_COMBB  = B_HID_H;    // 2097152 (after MLPs dead)

// ================= 32x32-per-wave GEMM core (64x64 block tile) =================
template <int COMP>
__device__ __forceinline__ void gemm_tile(
    const bf16* __restrict__ Ah, const bf16* __restrict__ Al,
    const bf16* __restrict__ Wh, const bf16* __restrict__ Wl,
    int M, int K, int row_base, int col_base, int lr, int kg,
    f32x4 accs[2][2]) {
  int ar0 = row_base + lr;       if (ar0 > M - 1) ar0 = M - 1;
  int ar1 = row_base + 16 + lr;  if (ar1 > M - 1) ar1 = M - 1;
  const size_t a0o = (size_t)ar0 * K + kg;
  const size_t a1o = (size_t)ar1 * K + kg;
  const size_t b0o = (size_t)(col_base + lr) * K + kg;
  const size_t b1o = (size_t)(col_base + 16 + lr) * K + kg;
  f32x4 acc00 = {}, acc01 = {}, acc10 = {}, acc11 = {};
  for (int k0 = 0; k0 < K; k0 += 32) {
    bf16x8 ah0 = *reinterpret_cast<const bf16x8*>(Ah + a0o + k0);
    bf16x8 ah1 = *reinterpret_cast<const bf16x8*>(Ah + a1o + k0);
    bf16x8 bh0 = *reinterpret_cast<const bf16x8*>(Wh + b0o + k0);
    bf16x8 bh1 = *reinterpret_cast<const bf16x8*>(Wh + b1o + k0);
    acc00 = __builtin_amdgcn_mfma_f32_16x16x32_bf16(ah0, bh0, acc00, 0, 0, 0);
    acc01 = __builtin_amdgcn_mfma_f32_16x16x32_bf16(ah0, bh1, acc01, 0, 0, 0);
    acc10 = __builtin_amdgcn_mfma_f32_16x16x32_bf16(ah1, bh0, acc10, 0, 0, 0);
    acc11 = __builtin_amdgcn_mfma_f32_16x16x32_bf16(ah1, bh1, acc11, 0, 0, 0);
    if constexpr (COMP) {
      bf16x8 al0 = *reinterpret_cast<const bf16x8*>(Al + a0o + k0);
      bf16x8 al1 = *reinterpret_cast<const bf16x8*>(Al + a1o + k0);
      bf16x8 bl0 = *reinterpret_cast<const bf16x8*>(Wl + b0o + k0);
      bf16x8 bl1 = *reinterpret_cast<const bf16x8*>(Wl + b1o + k0);
      acc00 = __builtin_amdgcn_mfma_f32_16x16x32_bf16(ah0, bl0, acc00, 0, 0, 0);
      acc01 = __builtin_amdgcn_mfma_f32_16x16x32_bf16(ah0, bl1, acc01, 0, 0, 0);
      acc10 = __builtin_amdgcn_mfma_f32_16x16x32_bf16(ah1, bl0, acc10, 0, 0, 0);
      acc11 = __builtin_amdgcn_mfma_f32_16x16x32_bf16(ah1, bl1, acc11, 0, 0, 0);
      acc00 = __builtin_amdgcn_mfma_f32_16x16x32_bf16(al0, bh0, acc00, 0, 0, 0);
      acc01 = __builtin_amdgcn_mfma_f32_16x16x32_bf16(al0, bh1, acc01, 0, 0, 0);
      acc10 = __builtin_amdgcn_mfma_f32_16x16x32_bf16(al1, bh0, acc10, 0, 0, 0);
      acc11 = __builtin_amdgcn_mfma_f32_16x16x32_bf16(al1, bh1, acc11, 0, 0, 0);
    }
  }
  accs[0][0] = acc00; accs[0][1] = acc01; accs[1][0] = acc10; accs[1][1] = acc11;
}

// ---------------- generic GEMM kernel (fp32 out; out-proj) ----------------
template <int EPI, int COMP>
__global__ __launch_bounds__(256) void k_cgemm(
    const bf16* __restrict__ Ah, const bf16* __restrict__ Al,
    const bf16* __restrict__ Wh, const bf16* __restrict__ Wl,
    const float* __restrict__ bias, float* __restrict__ Cf,
    int M, int K, int N) {
  const int lane = threadIdx.x & 63;
  const int w = threadIdx.x >> 6;
  const int wr = w >> 1, wc = w & 1;
  const int row_base = (blockIdx.y << 6) + (wr << 5);
  const int col_base = (blockIdx.x << 6) + (wc << 5);
  const int lr = lane & 15;
  const int kg = (lane >> 4) << 3;
  const int crow = (lane >> 4) << 2;

  f32x4 accs[2][2];
  gemm_tile<COMP>(Ah, Al, Wh, Wl, M, K, row_base, col_base, lr, kg, accs);

#pragma unroll
  for (int mi = 0; mi < 2; ++mi) {
#pragma unroll
    for (int ni = 0; ni < 2; ++ni) {
      int col = col_base + (ni << 4) + lr;
      float bv = bias ? bias[col] : 0.f;
#pragma unroll
      for (int r = 0; r < 4; ++r) {
        int row = row_base + (mi << 4) + crow + r;
        if (row < M) {
          float vv = accs[mi][ni][r] + bv;
          if (EPI == 1) vv = fmaxf(vv, 0.f);
          Cf[(size_t)row * N + col] = vv;
        }
      }
    }
  }
}

#define LDP 40

// ---------------- qkv GEMM: LDS-staged 128x64, XOR chunk swizzle + T14 split ----------------
// XCD swizzle: row-tile r = (id&7) + 8*(id>=192). Chunk c of row r stored at c^(r&3).
__global__ __launch_bounds__(256, 2) void k_qkv(
    const bf16* __restrict__ Ah, const bf16* __restrict__ Al,
    const bf16* __restrict__ Wh, const bf16* __restrict__ Wl,
    float* __restrict__ KFo, bf16* __restrict__ QH, bf16* __restrict__ QM,
    bf16* __restrict__ QL, bf16* __restrict__ VB) {
  __shared__ bf16 sAh[128 * LDP];
  __shared__ bf16 sAl[128 * LDP];
  __shared__ bf16 sBh[64 * LDP];
  __shared__ bf16 sBl[64 * LDP];

  const int t = threadIdx.x;
  const int lane = t & 63, w = t >> 6;
  const int wr = w >> 1, wc = w & 1;
  const int lr = lane & 15;
  const int kg = (lane >> 4) << 3;
  const int crow = (lane >> 4) << 2;
  const int id = blockIdx.x;
  const int rt = (id & 7) + ((id >= 192) ? 8 : 0);
  const int ct = (id >> 3) % 24;
  const int row0 = rt << 7;
  const int col0 = ct << 6;

  const int qa0 = t,        ar0s = qa0 >> 2, as0 = qa0 & 3;
  const int qa1 = t + 256,  ar1s = qa1 >> 2, as1 = qa1 & 3;
  const int gr0 = row0 + ar0s;
  const int gr1 = row0 + ar1s;
  const int br = t >> 2, bs = t & 3;
  const int gbr = col0 + br;
  // swizzled write slots (elements)
  const int wA0 = (as0 ^ (ar0s & 3)) << 3;
  const int wA1 = (as1 ^ (ar1s & 3)) << 3;
  const int wB  = (bs ^ (br & 3)) << 3;
  // swizzled fragment-read chunk (rows of a fragment differ by 16 -> same row&3 = lr&3)
  const int rc = (((lane >> 4) ^ (lr & 3)) << 3);

  f32x4 acc[4][2];
#pragma unroll
  for (int a = 0; a < 4; ++a)
#pragma unroll
    for (int b = 0; b < 2; ++b) acc[a][b] = (f32x4){0.f, 0.f, 0.f, 0.f};

  // preload k0 = 0
  bf16x8 rAh0 = *reinterpret_cast<const bf16x8*>(Ah + (size_t)gr0 * DMODEL + as0 * 8);
  bf16x8 rAh1 = *reinterpret_cast<const bf16x8*>(Ah + (size_t)gr1 * DMODEL + as1 * 8);
  bf16x8 rBh  = *reinterpret_cast<const bf16x8*>(Wh + (size_t)gbr * DMODEL + bs * 8);
  bf16x8 rAl0 = *reinterpret_cast<const bf16x8*>(Al + (size_t)gr0 * DMODEL + as0 * 8);
  bf16x8 rAl1 = *reinterpret_cast<const bf16x8*>(Al + (size_t)gr1 * DMODEL + as1 * 8);
  bf16x8 rBl  = *reinterpret_cast<const bf16x8*>(Wl + (size_t)gbr * DMODEL + bs * 8);

  for (int k0 = 0; k0 < DMODEL; k0 += 32) {
    *reinterpret_cast<bf16x8*>(&sAh[ar0s * LDP + wA0]) = rAh0;
    *reinterpret_cast<bf16x8*>(&sAh[ar1s * LDP + wA1]) = rAh1;
    *reinterpret_cast<bf16x8*>(&sBh[br * LDP + wB]) = rBh;
    *reinterpret_cast<bf16x8*>(&sAl[ar0s * LDP + wA0]) = rAl0;
    *reinterpret_cast<bf16x8*>(&sAl[ar1s * LDP + wA1]) = rAl1;
    *reinterpret_cast<bf16x8*>(&sBl[br * LDP + wB]) = rBl;
    __syncthreads();

    // T14: issue next-step global loads; latency hides under MFMA phase
    if (k0 + 32 < DMODEL) {
      const int kn = k0 + 32;
      rAh0 = *reinterpret_cast<const bf16x8*>(Ah + (size_t)gr0 * DMODEL + kn + as0 * 8);
      rAh1 = *reinterpret_cast<const bf16x8*>(Ah + (size_t)gr1 * DMODEL + kn + as1 * 8);
      rBh  = *reinterpret_cast<const bf16x8*>(Wh + (size_t)gbr * DMODEL + kn + bs * 8);
      rAl0 = *reinterpret_cast<const bf16x8*>(Al + (size_t)gr0 * DMODEL + kn + as0 * 8);
      rAl1 = *reinterpret_cast<const bf16x8*>(Al + (size_t)gr1 * DMODEL + kn + as1 * 8);
      rBl  = *reinterpret_cast<const bf16x8*>(Wl + (size_t)gbr * DMODEL + kn + bs * 8);
    }

    bf16x8 fAh[4], fBh[2], fAl[4], fBl[2];
#pragma unroll
    for (int mi = 0; mi < 4; ++mi)
      fAh[mi] = *reinterpret_cast<const bf16x8*>(&sAh[(wr * 64 + mi * 16 + lr) * LDP + rc]);
#pragma unroll
    for (int ni = 0; ni < 2; ++ni)
      fBh[ni] = *reinterpret_cast<const bf16x8*>(&sBh[(wc * 32 + ni * 16 + lr) * LDP + rc]);
#pragma unroll
    for (int mi = 0; mi < 4; ++mi)
      fAl[mi] = *reinterpret_cast<const bf16x8*>(&sAl[(wr * 64 + mi * 16 + lr) * LDP + rc]);
#pragma unroll
    for (int ni = 0; ni < 2; ++ni)
      fBl[ni] = *reinterpret_cast<const bf16x8*>(&sBl[(wc * 32 + ni * 16 + lr) * LDP + rc]);

#pragma unroll
    for (int mi = 0; mi < 4; ++mi)
#pragma unroll
      for (int ni = 0; ni < 2; ++ni)
        acc[mi][ni] = __builtin_amdgcn_mfma_f32_16x16x32_bf16(fAh[mi], fBh[ni], acc[mi][ni], 0, 0, 0);
#pragma unroll
    for (int mi = 0; mi < 4; ++mi)
#pragma unroll
      for (int ni = 0; ni < 2; ++ni) {
        acc[mi][ni] = __builtin_amdgcn_mfma_f32_16x16x32_bf16(fAh[mi], fBl[ni], acc[mi][ni], 0, 0, 0);
        acc[mi][ni] = __builtin_amdgcn_mfma_f32_16x16x32_bf16(fAl[mi], fBh[ni], acc[mi][ni], 0, 0, 0);
      }
    __syncthreads();
  }

#pragma unroll
  for (int mi = 0; mi < 4; ++mi) {
#pragma unroll
    for (int ni = 0; ni < 2; ++ni) {
      int col = col0 + wc * 32 + ni * 16 + lr;
      int which = col >> 9, rem = col & 511;
      int hh = rem >> 6, dd = rem & 63;
#pragma unroll
      for (int r = 0; r < 4; ++r) {
        int row = row0 + wr * 64 + mi * 16 + crow + r;
        float vv = acc[mi][ni][r];
        size_t o = ((size_t)hh * NTOK + row) * DHEAD + dd;
        if (which == 0) {
          bf16 h1 = __float2bfloat16(vv);
          float r1 = vv - __bfloat162float(h1);
          bf16 m1 = __float2bfloat16(r1);
          QH[o] = h1;
          QM[o] = m1;
          QL[o] = __float2bfloat16(r1 - __bfloat162float(m1));
        } else if (which == 1) {
          KFo[o] = vv;
        } else {
          VB[o] = __float2bfloat16(vv);
        }
      }
    }
  }
}

// ---------------- merged MLP1: LDS-staged + XOR chunk swizzle + T14 split ----------------
__global__ __launch_bounds__(256, 2) void k_mlp1(
    const bf16* __restrict__ KWh, const bf16* __restrict__ KWl,
    const bf16* __restrict__ W1h, const bf16* __restrict__ W1l,
    const float* __restrict__ kb1,
    const bf16* __restrict__ VWh, const bf16* __restrict__ VW1h,
    const float* __restrict__ vb1,
    bf16* __restrict__ HKh, bf16* __restrict__ HKl, bf16* __restrict__ HVh) {
  __shared__ bf16 sAh[128 * LDP];
  __shared__ bf16 sAl[128 * LDP];
  __shared__ bf16 sBh[64 * LDP];
  __shared__ bf16 sBl[64 * LDP];

  const int t = threadIdx.x;
  const int lane = t & 63, w = t >> 6;
  const int wr = w >> 1, wc = w & 1;
  const int lr = lane & 15;
  const int kg = (lane >> 4) << 3;
  const int crow = (lane >> 4) << 2;
  const int M = NHEAD * NWIN;  // 2032
  const int id = blockIdx.x;
  const bool kpath = (id < 256);
  const int u = kpath ? id : id - 256;
  const int rt = (u & 7) + ((u >= 128) ? 8 : 0);
  const int ct = (u >> 3) & 15;
  const int row0 = rt << 7;
  const int col0 = ct << 6;

  const bf16* Ah = kpath ? KWh : VWh;
  const bf16* Bh = kpath ? W1h : VW1h;

  const int qa0 = t,        ar0s = qa0 >> 2, as0 = qa0 & 3;
  const int qa1 = t + 256,  ar1s = qa1 >> 2, as1 = qa1 & 3;
  int gr0 = row0 + ar0s; if (gr0 > M - 1) gr0 = M - 1;
  int gr1 = row0 + ar1s; if (gr1 > M - 1) gr1 = M - 1;
  const int br = t >> 2, bs = t & 3;
  const int gbr = col0 + br;
  const int wA0 = (as0 ^ (ar0s & 3)) << 3;
  const int wA1 = (as1 ^ (ar1s & 3)) << 3;
  const int wB  = (bs ^ (br & 3)) << 3;
  const int rc = (((lane >> 4) ^ (lr & 3)) << 3);

  f32x4 acc[4][2];
#pragma unroll
  for (int a = 0; a < 4; ++a)
#pragma unroll
    for (int b = 0; b < 2; ++b) acc[a][b] = (f32x4){0.f, 0.f, 0.f, 0.f};

  bf16x8 rAh0 = *reinterpret_cast<const bf16x8*>(Ah + (size_t)gr0 * CDIM + as0 * 8);
  bf16x8 rAh1 = *reinterpret_cast<const bf16x8*>(Ah + (size_t)gr1 * CDIM + as1 * 8);
  bf16x8 rBh  = *reinterpret_cast<const bf16x8*>(Bh + (size_t)gbr * CDIM + bs * 8);
  bf16x8 rAl0, rAl1, rBl;
  if (kpath) {
    rAl0 = *reinterpret_cast<const bf16x8*>(KWl + (size_t)gr0 * CDIM + as0 * 8);
    rAl1 = *reinterpret_cast<const bf16x8*>(KWl + (size_t)gr1 * CDIM + as1 * 8);
    rBl  = *reinterpret_cast<const bf16x8*>(W1l + (size_t)gbr * CDIM + bs * 8);
  }

  for (int k0 = 0; k0 < CDIM; k0 += 32) {
    *reinterpret_cast<bf16x8*>(&sAh[ar0s * LDP + wA0]) = rAh0;
    *reinterpret_cast<bf16x8*>(&sAh[ar1s * LDP + wA1]) = rAh1;
    *reinterpret_cast<bf16x8*>(&sBh[br * LDP + wB]) = rBh;
    if (kpath) {
      *reinterpret_cast<bf16x8*>(&sAl[ar0s * LDP + wA0]) = rAl0;
      *reinterpret_cast<bf16x8*>(&sAl[ar1s * LDP + wA1]) = rAl1;
      *reinterpret_cast<bf16x8*>(&sBl[br * LDP + wB]) = rBl;
    }
    __syncthreads();

    if (k0 + 32 < CDIM) {
      const int kn = k0 + 32;
      rAh0 = *reinterpret_cast<const bf16x8*>(Ah + (size_t)gr0 * CDIM + kn + as0 * 8);
      rAh1 = *reinterpret_cast<const bf16x8*>(Ah + (size_t)gr1 * CDIM + kn + as1 * 8);
      rBh  = *reinterpret_cast<const bf16x8*>(Bh + (size_t)gbr * CDIM + kn + bs * 8);
      if (kpath) {
        rAl0 = *reinterpret_cast<const bf16x8*>(KWl + (size_t)gr0 * CDIM + kn + as0 * 8);
        rAl1 = *reinterpret_cast<const bf16x8*>(KWl + (size_t)gr1 * CDIM + kn + as1 * 8);
        rBl  = *reinterpret_cast<const bf16x8*>(W1l + (size_t)gbr * CDIM + kn + bs * 8);
      }
    }

    bf16x8 fAh[4], fBh[2], fAl[4], fBl[2];
#pragma unroll
    for (int mi = 0; mi < 4; ++mi)
      fAh[mi] = *reinterpret_cast<const bf16x8*>(&sAh[(wr * 64 + mi * 16 + lr) * LDP + rc]);
#pragma unroll
    for (int ni = 0; ni < 2; ++ni)
      fBh[ni] = *reinterpret_cast<const bf16x8*>(&sBh[(wc * 32 + ni * 16 + lr) * LDP + rc]);
    if (kpath) {
#pragma unroll
      for (int mi = 0; mi < 4; ++mi)
        fAl[mi] = *reinterpret_cast<const bf16x8*>(&sAl[(wr * 64 + mi * 16 + lr) * LDP + rc]);
#pragma unroll
      for (int ni = 0; ni < 2; ++ni)
        fBl[ni] = *reinterpret_cast<const bf16x8*>(&sBl[(wc * 32 + ni * 16 + lr) * LDP + rc]);
    }

#pragma unroll
    for (int mi = 0; mi < 4; ++mi)
#pragma unroll
      for (int ni = 0; ni < 2; ++ni)
        acc[mi][ni] = __builtin_amdgcn_mfma_f32_16x16x32_bf16(fAh[mi], fBh[ni], acc[mi][ni], 0, 0, 0);
    if (kpath) {
#pragma unroll
      for (int mi = 0; mi < 4; ++mi)
#pragma unroll
        for (int ni = 0; ni < 2; ++ni) {
          acc[mi][ni] = __builtin_amdgcn_mfma_f32_16x16x32_bf16(fAh[mi], fBl[ni], acc[mi][ni], 0, 0, 0);
          acc[mi][ni] = __builtin_amdgcn_mfma_f32_16x16x32_bf16(fAl[mi], fBh[ni], acc[mi][ni], 0, 0, 0);
        }
    }
    __syncthreads();
  }

#pragma unroll
  for (int mi = 0; mi < 4; ++mi) {
#pragma unroll
    for (int ni = 0; ni < 2; ++ni) {
      int col = col0 + wc * 32 + ni * 16 + lr;
      float bv = kpath ? kb1[col] : vb1[col];
#pragma unroll
      for (int r = 0; r < 4; ++r) {
        int row = row0 + wr * 64 + mi * 16 + crow + r;
        if (row < M) {
          float vv = fmaxf(acc[mi][ni][r] + bv, 0.f);
          size_t o = (size_t)row * CDIM + col;
          if (kpath) {
            bf16 h1 = __float2bfloat16(vv);
            HKh[o] = h1;
            HKl[o] = __float2bfloat16(vv - __bfloat162float(h1));
          } else {
            HVh[o] = __float2bfloat16(vv);
          }
        }
      }
    }
  }
}

// ---------------- merged MLP2: z=0 k-path -> ckT hi/mid/lo, z=1 v-path -> cvT ----------------
__global__ __launch_bounds__(256) void k_mlp2(
    const bf16* __restrict__ HKh, const bf16* __restrict__ HKl,
    const bf16* __restrict__ W2h, const bf16* __restrict__ W2l,
    const float* __restrict__ kb2,
    const bf16* __restrict__ HVh, const bf16* __restrict__ VW2h,
    const float* __restrict__ vb2,
    bf16* __restrict__ ckh, bf16* __restrict__ ckm, bf16* __restrict__ ckl,
    bf16* __restrict__ cvtb) {
  const int lane = threadIdx.x & 63;
  const int w = threadIdx.x >> 6;
  const int wr = w >> 1, wc = w & 1;
  const int row_base = (blockIdx.y << 6) + (wr << 5);
  const int col_base = (wc << 5);
  const int lr = lane & 15;
  const int kg = (lane >> 4) << 3;
  const int crow = (lane >> 4) << 2;
  const int M = NHEAD * NWIN;

  f32x4 accs[2][2];
  if (blockIdx.z == 0)
    gemm_tile<1>(HKh, HKl, W2h, W2l, M, CDIM, row_base, col_base, lr, kg, accs);
  else
    gemm_tile<0>(HVh, nullptr, VW2h, nullptr, M, CDIM, row_base, col_base, lr, kg, accs);

  const float* bias = (blockIdx.z == 0) ? kb2 : vb2;
#pragma unroll
  for (int mi = 0; mi < 2; ++mi) {
#pragma unroll
    for (int ni = 0; ni < 2; ++ni) {
      int col = col_base + (ni << 4) + lr;
      float bv = bias[col];
#pragma unroll
      for (int r = 0; r < 4; ++r) {
        int row = row_base + (mi << 4) + crow + r;
        if (row < M) {
          float vv = accs[mi][ni][r] + bv;
          int hh = row / NWIN, jj = row - hh * NWIN;
          if (blockIdx.z == 0) {
            size_t o = ((size_t)hh * 256 + 1 + jj) * 64 + col;
            bf16 h1 = __float2bfloat16(vv);
            float r1 = vv - __bfloat162float(h1);
            bf16 m1 = __float2bfloat16(r1);
            ckh[o] = h1;
            ckm[o] = m1;
            ckl[o] = __float2bfloat16(r1 - __bfloat162float(m1));
          } else {
            cvtb[((size_t)hh * 64 + col) * 256 + 1 + jj] = __float2bfloat16(vv);
          }
        }
      }
    }
  }
}

// ================= k_setup: 6 weight transposes + zpad + fillmem + rmsnorm =================
__device__ __forceinline__ void wt_tile(const float* __restrict__ W,
                                        bf16* __restrict__ WTh, bf16* __restrict__ WTl,
                                        int K, int N, int bx, int by,
                                        float (*tsh)[33]) {
  const int k0 = bx << 5, n0 = by << 5;
  const int tx = threadIdx.x & 31, ty = threadIdx.x >> 5;
#pragma unroll
  for (int r = 0; r < 4; ++r)
    tsh[ty + (r << 3)][tx] = W[(size_t)(k0 + ty + (r << 3)) * N + n0 + tx];
  __syncthreads();
#pragma unroll
  for (int r = 0; r < 4; ++r) {
    float val = tsh[tx][ty + (r << 3)];
    size_t o = (size_t)(n0 + ty + (r << 3)) * K + k0 + tx;
    bf16 h1 = __float2bfloat16(val);
    WTh[o] = h1;
    if (WTl) WTl[o] = __float2bfloat16(val - __bfloat162float(h1));
  }
}

__global__ __launch_bounds__(256) void k_setup(
    const float* __restrict__ x, const float* __restrict__ g,
    const float* __restrict__ w_qkv, const float* __restrict__ k_w1,
    const float* __restrict__ k_w2, const float* __restrict__ v_w1,
    const float* __restrict__ v_w2, const float* __restrict__ w_out,
    const float* __restrict__ memkv,
    bf16* __restrict__ WQKV_H, bf16* __restrict__ WQKV_L,
    bf16* __restrict__ KW1_H, bf16* __restrict__ KW1_L,
    bf16* __restrict__ KW2_H, bf16* __restrict__ KW2_L,
    bf16* __restrict__ VW1_H, bf16* __restrict__ VW2_H, bf16* __restrict__ WOUT_H,
    bf16* __restrict__ hbh, bf16* __restrict__ hbl,
    bf16* __restrict__ rkh, bf16* __restrict__ rkl, bf16* __restrict__ vtb,
    bf16* __restrict__ ckh, bf16* __restrict__ ckm, bf16* __restrict__ ckl,
    bf16* __restrict__ cvtb) {
  __shared__ float tsh[32][33];
  __shared__ float wsum[4];
  __shared__ float scale_s;
  const int id = blockIdx.x;
  const int t = threadIdx.x;

  if (id < 768) {
    wt_tile(w_qkv, WQKV_H, WQKV_L, DMODEL, 1536, id % 16, id / 16, tsh);
  } else if (id < 1792) {
    int u = id - 768;  wt_tile(k_w1, KW1_H, KW1_L, CDIM, CDIM, u % 32, u / 32, tsh);
  } else if (id < 1856) {
    int u = id - 1792; wt_tile(k_w2, KW2_H, KW2_L, CDIM, DHEAD, u % 32, u / 32, tsh);
  } else if (id < 2880) {
    int u = id - 1856; wt_tile(v_w1, VW1_H, nullptr, CDIM, CDIM, u % 32, u / 32, tsh);
  } else if (id < 2944) {
    int u = id - 2880; wt_tile(v_w2, VW2_H, nullptr, CDIM, DHEAD, u % 32, u / 32, tsh);
  } else if (id < 3200) {
    int u = id - 2944; wt_tile(w_out, WOUT_H, nullptr, DMODEL, DMODEL, u % 16, u / 16, tsh);
  } else if (id < 3328) {
    int idx = (id - 3200) * 256 + t;   // [0, 32768)
    int h = idx >> 12, r = (idx >> 6) & 63, c = idx & 63;
    bf16 z = __float2bfloat16(0.f);
    rkh[((size_t)h * 2112 + r) * 64 + c] = z;
    rkl[((size_t)h * 2112 + r) * 64 + c] = z;
    vtb[((size_t)h * 64 + r) * 2112 + c] = z;
  } else if (id < 3330) {
    int u = (id - 3328) * 256 + t;     // [0, 512)
    if (u < 512) {
      int h = u >> 6, e = u & 63;
      float kv = memkv[(size_t)h * DHEAD + e];
      bf16 h1 = __float2bfloat16(kv);
      float r1 = kv - __bfloat162float(h1);
      bf16 m1 = __float2bfloat16(r1);
      ckh[((size_t)h * 256) * 64 + e] = h1;
      ckm[((size_t)h * 256) * 64 + e] = m1;
      ckl[((size_t)h * 256) * 64 + e] = __float2bfloat16(r1 - __bfloat162float(m1));
      bf16 z = __float2bfloat16(0.f);
      ckh[((size_t)h * 256 + 255) * 64 + e] = z;
      ckm[((size_t)h * 256 + 255) * 64 + e] = z;
      ckl[((size_t)h * 256 + 255) * 64 + e] = z;
      float vv = memkv[(size_t)(NHEAD + h) * DHEAD + e];
      cvtb[((size_t)h * 64 + e) * 256 + 0] = __float2bfloat16(vv);
      cvtb[((size_t)h * 64 + e) * 256 + 255] = z;
    }
  } else {
    const int row = id - 3330;
    const float* xr = x + (size_t)row * DMODEL;
    float s = 0.f;
    for (int c = t; c < DMODEL; c += 256) { float v = xr[c]; s += v * v; }
    for (int o = 32; o > 0; o >>= 1) s += __shfl_down(s, o);
    if ((t & 63) == 0) wsum[t >> 6] = s;
    __syncthreads();
    if (t == 0) {
      float tot = wsum[0] + wsum[1] + wsum[2] + wsum[3];
      scale_s = rsqrtf(tot * (1.f / DMODEL) + 1e-6f);
    }
    __syncthreads();
    float sc = scale_s;
    for (int c = t; c < DMODEL; c += 256) {
      float v = xr[c] * sc * g[c];
      bf16 h1 = __float2bfloat16(v);
      hbh[(size_t)row * DMODEL + c] = h1;
      hbl[(size_t)row * DMODEL + c] = __float2bfloat16(v - __bfloat162float(h1));
    }
  }
}

// ================= k_post: rope + v-transpose + compression windows =================
__global__ __launch_bounds__(256) void k_post(
    const bf16* __restrict__ qbh, const bf16* __restrict__ qbm,
    const bf16* __restrict__ qbl, const float* __restrict__ kf,
    const bf16* __restrict__ vbh,
    const float* __restrict__ kpos, const float* __restrict__ vpos,
    bf16* __restrict__ rqh, bf16* __restrict__ rql,
    bf16* __restrict__ rkh, bf16* __restrict__ rkl,
    bf16* __restrict__ vtb,
    bf16* __restrict__ kwh, bf16* __restrict__ kwl, bf16* __restrict__ vwh) {
  __shared__ bf16 tile[64][65];
  const int id = blockIdx.x;
  const int t = threadIdx.x;

  if (id < 2048) {
    int idx = id * 256 + t;
    int i = idx & 31;
    int n = (idx >> 5) & (NTOK - 1);
    int h = idx >> 16;
    float ex = (float)(2 * i) * (1.f / 64.f);
    float inv = exp2f(-ex * 13.287712379549449f);
    float ang = (float)n * inv;
    float sn, cs;
    sincosf(ang, &sn, &cs);
    size_t base = ((size_t)h * NTOK + n) * DHEAD + 2 * i;
    float q1 = __bfloat162float(qbh[base]) + __bfloat162float(qbm[base]) + __bfloat162float(qbl[base]);
    float q2 = __bfloat162float(qbh[base + 1]) + __bfloat162float(qbm[base + 1]) + __bfloat162float(qbl[base + 1]);
    float r1 = q1 * cs - q2 * sn, r2 = q1 * sn + q2 * cs;
    bf16 h1 = __float2bfloat16(r1);
    rqh[base] = h1; rql[base] = __float2bfloat16(r1 - __bfloat162float(h1));
    h1 = __float2bfloat16(r2);
    rqh[base + 1] = h1; rql[base + 1] = __float2bfloat16(r2 - __bfloat162float(h1));
    float k1 = kf[base], k2 = kf[base + 1];
    float s1 = k1 * cs - k2 * sn, s2 = k1 * sn + k2 * cs;
    size_t kb = ((size_t)h * 2112 + 64 + n) * DHEAD + 2 * i;
    h1 = __float2bfloat16(s1);
    rkh[kb] = h1; rkl[kb] = __float2bfloat16(s1 - __bfloat162float(h1));
    h1 = __float2bfloat16(s2);
    rkh[kb + 1] = h1; rkl[kb + 1] = __float2bfloat16(s2 - __bfloat162float(h1));
  } else if (id < 2304) {
    int u = id - 2048;
    int h = u >> 5, n0 = (u & 31) << 6;
    int tx = t & 63, ty = t >> 6;
    for (int r = ty; r < 64; r += 4)
      tile[r][tx] = vbh[((size_t)h * NTOK + n0 + r) * DHEAD + tx];
    __syncthreads();
    for (int r = ty; r < 64; r += 4)
      vtb[((size_t)h * 64 + r) * 2112 + 64 + n0 + tx] = tile[tx][r];
  } else {
    int idx = (id - 2304) * 256 + t;   // [0, 2080768)
    int d = idx & 63;
    int c = (idx >> 6) & 15;
    int j = (idx >> 10) % NWIN;
    int h = idx / (NWIN << 10);
    int srcpos = (j << 3) + c;
    size_t src = ((size_t)h * NTOK + srcpos) * DHEAD + d;
    size_t pp = ((size_t)h * 16 + c) * DHEAD + d;
    float kv = kf[src] + kpos[pp];
    bf16 h1 = __float2bfloat16(kv);
    kwh[idx] = h1;
    kwl[idx] = __float2bfloat16(kv - __bfloat162float(h1));
    vwh[idx] = __float2bfloat16(__bfloat162float(vbh[src]) + vpos[pp]);
  }
}

// ---------------- compression attention (MFMA, 32 queries/block) ----------------
// 1D grid 512: h = id&7 -> all blocks of head h land on XCD h.
__global__ __launch_bounds__(256) void k_comp_attn(
    const bf16* __restrict__ qbh, const bf16* __restrict__ qbm, const bf16* __restrict__ qbl,
    const bf16* __restrict__ ckh, const bf16* __restrict__ ckm, const bf16* __restrict__ ckl,
    const bf16* __restrict__ cvtb,
    float* __restrict__ c_out, int* __restrict__ sel) {
  const int h = blockIdx.x & 7;
  const int i0 = (blockIdx.x >> 3) << 5;
  const int t = threadIdx.x;
  const int w = t >> 6, lane = t & 63;
  const int lr = lane & 15, kg = (lane >> 4) << 3;
  const int crow = (lane >> 4) << 2;

  __shared__ float p[32][260];

  bf16x8 aH[2][2], aM[2][2], aL[2][2];
#pragma unroll
  for (int mi = 0; mi < 2; ++mi) {
    size_t qo = ((size_t)h * NTOK + i0 + mi * 16 + lr) * DHEAD + kg;
#pragma unroll
    for (int ks = 0; ks < 2; ++ks) {
      aH[mi][ks] = *reinterpret_cast<const bf16x8*>(qbh + qo + ks * 32);
      aM[mi][ks] = *reinterpret_cast<const bf16x8*>(qbm + qo + ks * 32);
      aL[mi][ks] = *reinterpret_cast<const bf16x8*>(qbl + qo + ks * 32);
    }
  }
  f32x4 acc[2][4];
#pragma unroll
  for (int a = 0; a < 2; ++a)
#pragma unroll
    for (int b = 0; b < 4; ++b) acc[a][b] = (f32x4){0.f, 0.f, 0.f, 0.f};
#pragma unroll
  for (int ni = 0; ni < 4; ++ni) {
    int col = (w << 6) + (ni << 4) + lr;
    size_t ko = ((size_t)h * 256 + col) * 64 + kg;
#pragma unroll
    for (int ks = 0; ks < 2; ++ks) {
      bf16x8 bH = *reinterpret_cast<const bf16x8*>(ckh + ko + ks * 32);
      bf16x8 bM = *reinterpret_cast<const bf16x8*>(ckm + ko + ks * 32);
      bf16x8 bL = *reinterpret_cast<const bf16x8*>(ckl + ko + ks * 32);
#pragma unroll
      for (int mi = 0; mi < 2; ++mi) {
        acc[mi][ni] = __builtin_amdgcn_mfma_f32_16x16x32_bf16(aH[mi][ks], bH, acc[mi][ni], 0, 0, 0);
        acc[mi][ni] = __builtin_amdgcn_mfma_f32_16x16x32_bf16(aH[mi][ks], bM, acc[mi][ni], 0, 0, 0);
        acc[mi][ni] = __builtin_amdgcn_mfma_f32_16x16x32_bf16(aM[mi][ks], bH, acc[mi][ni], 0, 0, 0);
        acc[mi][ni] = __builtin_amdgcn_mfma_f32_16x16x32_bf16(aH[mi][ks], bL, acc[mi][ni], 0, 0, 0);
        acc[mi][ni] = __builtin_amdgcn_mfma_f32_16x16x32_bf16(aL[mi][ks], bH, acc[mi][ni], 0, 0, 0);
        acc[mi][ni] = __builtin_amdgcn_mfma_f32_16x16x32_bf16(aM[mi][ks], bM, acc[mi][ni], 0, 0, 0);
      }
    }
  }
#pragma unroll
  for (int mi = 0; mi < 2; ++mi)
#pragma unroll
    for (int ni = 0; ni < 4; ++ni) {
      int col = (w << 6) + (ni << 4) + lr;
      int wend = (col == 0) ? -1 : ((col - 1) << 3) + 15;
#pragma unroll
      for (int r = 0; r < 4; ++r) {
        int qi = mi * 16 + crow + r;
        bool ok = (col < 255) && (wend < i0 + qi);
        p[qi][col] = ok ? acc[mi][ni][r] * 0.125f : NEGV;
      }
    }
  __syncthreads();

  const int qi = t >> 3, s = t & 7;
  float ev[32];
  float mx = -3.0e38f;
#pragma unroll
  for (int u = 0; u < 32; ++u) { ev[u] = p[qi][s + (u << 3)]; mx = fmaxf(mx, ev[u]); }
  mx = fmaxf(mx, __shfl_xor(mx, 1));
  mx = fmaxf(mx, __shfl_xor(mx, 2));
  mx = fmaxf(mx, __shfl_xor(mx, 4));
  float sum = 0.f;
#pragma unroll
  for (int u = 0; u < 32; ++u) { float e = __expf(ev[u] - mx); ev[u] = e; sum += e; }
  sum += __shfl_xor(sum, 1); sum += __shfl_xor(sum, 2); sum += __shfl_xor(sum, 4);
  float invs = 1.f / sum;
#pragma unroll
  for (int u = 0; u < 32; ++u) p[qi][s + (u << 3)] = ev[u] * invs;

  int qblk = (i0 + qi) >> 4;
  float vals[16];
#pragma unroll
  for (int u = 0; u < 16; ++u) {
    int f = (s << 4) + u;
    float v;
    if (f >= qblk || f == 127) v = NEGV;
    else v = (p[qi][2 * f + 1] + p[qi][2 * f + 2]) * 0.5f;
    vals[u] = v;
  }
  int base = ((h << 11) | (i0 + qi)) * 5;
  for (int kk = 0; kk < 4; ++kk) {
    float bv = -3.0e38f; int bi = 0;
#pragma unroll
    for (int u = 0; u < 16; ++u) {
      if (vals[u] > bv) { bv = vals[u]; bi = (s << 4) + u; }
    }
#pragma unroll
    for (int o = 1; o < 8; o <<= 1) {
      float ov = __shfl_xor(bv, o);
      int oi = __shfl_xor(bi, o);
      if (ov > bv || (ov == bv && oi < bi)) { bv = ov; bi = oi; }
    }
    if (s == 0) sel[base + kk] = (bv > -5.0e8f) ? bi : -1;
    if ((bi >> 4) == s) vals[bi & 15] = -3.0e38f;
  }
  if (s == 0) sel[base + 4] = (i0 + qi) >> 4;
  __syncthreads();

  const int wm = w >> 1, wn = w & 1;
  const int arow = wm * 16 + lr;
  f32x4 pacc[2];
#pragma unroll
  for (int b = 0; b < 2; ++b) pacc[b] = (f32x4){0.f, 0.f, 0.f, 0.f};
#pragma unroll
  for (int ks = 0; ks < 8; ++ks) {
    int k0 = ks * 32 + kg;
    float4 x0 = *reinterpret_cast<const float4*>(&p[arow][k0]);
    float4 x1 = *reinterpret_cast<const float4*>(&p[arow][k0 + 4]);
    float xv[8] = {x0.x, x0.y, x0.z, x0.w, x1.x, x1.y, x1.z, x1.w};
    bf16x8 ph, pl;
#pragma unroll
    for (int e = 0; e < 8; ++e) {
      __bf16 hh = (__bf16)xv[e];
      ph[e] = hh;
      pl[e] = (__bf16)(xv[e] - (float)hh);
    }
#pragma unroll
    for (int ni = 0; ni < 2; ++ni) {
      int d = (wn << 5) + (ni << 4) + lr;
      bf16x8 bv = *reinterpret_cast<const bf16x8*>(cvtb + ((size_t)h * 64 + d) * 256 + k0);
      pacc[ni] = __builtin_amdgcn_mfma_f32_16x16x32_bf16(ph, bv, pacc[ni], 0, 0, 0);
      pacc[ni] = __builtin_amdgcn_mfma_f32_16x16x32_bf16(pl, bv, pacc[ni], 0, 0, 0);
    }
  }
#pragma unroll
  for (int ni = 0; ni < 2; ++ni) {
    int d = (wn << 5) + (ni << 4) + lr;
#pragma unroll
    for (int r = 0; r < 4; ++r) {
      int q2 = wm * 16 + crow + r;
      c_out[((size_t)h * NTOK + i0 + q2) * DHEAD + d] = pacc[ni][r];
    }
  }
}

// ======== fused fine + sliding attention, head-per-XCD swizzle ========
__global__ __launch_bounds__(256, 8) void k_fs_attn(
    const bf16* __restrict__ rqh, const bf16* __restrict__ rql,
    const bf16* __restrict__ rkh, const bf16* __restrict__ rkl,
    const bf16* __restrict__ vbh, const bf16* __restrict__ vtb,
    const int* __restrict__ sel,
    float* __restrict__ f_out, float* __restrict__ s_out) {
  __shared__ char smraw[32 * 100 * 4];   // 12800 B
  const int blk = blockIdx.x;
  const int t = threadIdx.x;

  if (blk < 512) {
    // ========== sliding-window: 32 queries, 96-key window ==========
    float (*p)[100] = reinterpret_cast<float(*)[100]>(smraw);
    const int h = blk & 7, nb = (blk >> 3) & 63;
    const int w = t >> 6, lane = t & 63;
    const int lr = lane & 15, kg = (lane >> 4) << 3;
    const int crow = (lane >> 4) << 2;
    const int wr = w >> 1, wc = w & 1;

    bf16x8 aH[2], aL[2];
    {
      size_t qo = ((size_t)h * NTOK + nb * 32 + wr * 16 + lr) * DHEAD + kg;
#pragma unroll
      for (int ks = 0; ks < 2; ++ks) {
        aH[ks] = *reinterpret_cast<const bf16x8*>(rqh + qo + ks * 32);
        aL[ks] = *reinterpret_cast<const bf16x8*>(rql + qo + ks * 32);
      }
    }
    f32x4 acc[3];
#pragma unroll
    for (int a = 0; a < 3; ++a) acc[a] = (f32x4){0.f, 0.f, 0.f, 0.f};
#pragma unroll
    for (int ni = 0; ni < 3; ++ni) {
      int col = wc * 48 + ni * 16 + lr;
      size_t ko = ((size_t)h * 2112 + nb * 32 + col) * 64 + kg;
#pragma unroll
      for (int ks = 0; ks < 2; ++ks) {
        bf16x8 bH = *reinterpret_cast<const bf16x8*>(rkh + ko + ks * 32);
        bf16x8 bL = *reinterpret_cast<const bf16x8*>(rkl + ko + ks * 32);
        acc[ni] = __builtin_amdgcn_mfma_f32_16x16x32_bf16(aH[ks], bH, acc[ni], 0, 0, 0);
        acc[ni] = __builtin_amdgcn_mfma_f32_16x16x32_bf16(aL[ks], bH, acc[ni], 0, 0, 0);
        acc[ni] = __builtin_amdgcn_mfma_f32_16x16x32_bf16(aH[ks], bL, acc[ni], 0, 0, 0);
      }
    }
    const int cmin = 64 - nb * 32;
#pragma unroll
    for (int ni = 0; ni < 3; ++ni) {
      int col = wc * 48 + ni * 16 + lr;
#pragma unroll
      for (int r = 0; r < 4; ++r) {
        int q = wr * 16 + crow + r;
        bool ok = (col >= q + 1) && (col <= q + 64) && (col >= cmin);
        p[q][col] = ok ? acc[ni][r] * 0.125f : NEGV;
      }
    }
    __syncthreads();

    const int qi = t >> 3, s = t & 7;
    float ev[12];
    float mx = -3.0e38f;
#pragma unroll
    for (int u = 0; u < 12; ++u) { ev[u] = p[qi][s + (u << 3)]; mx = fmaxf(mx, ev[u]); }
    mx = fmaxf(mx, __shfl_xor(mx, 1));
    mx = fmaxf(mx, __shfl_xor(mx, 2));
    mx = fmaxf(mx, __shfl_xor(mx, 4));
    float sum = 0.f;
#pragma unroll
    for (int u = 0; u < 12; ++u) { float e = __expf(ev[u] - mx); ev[u] = e; sum += e; }
    sum += __shfl_xor(sum, 1); sum += __shfl_xor(sum, 2); sum += __shfl_xor(sum, 4);
    float invs = 1.f / sum;
#pragma unroll
    for (int u = 0; u < 12; ++u) p[qi][s + (u << 3)] = ev[u] * invs;
    __syncthreads();

    const int wm = w >> 1, wn = w & 1;
    const int arow = wm * 16 + lr;
    f32x4 pacc[2];
#pragma unroll
    for (int b = 0; b < 2; ++b) pacc[b] = (f32x4){0.f, 0.f, 0.f, 0.f};
#pragma unroll
    for (int ks = 0; ks < 3; ++ks) {
      int k0 = ks * 32 + kg;
      float4 x0 = *reinterpret_cast<const float4*>(&p[arow][k0]);
      float4 x1 = *reinterpret_cast<const float4*>(&p[arow][k0 + 4]);
      float xv[8] = {x0.x, x0.y, x0.z, x0.w, x1.x, x1.y, x1.z, x1.w};
      bf16x8 ph, pl;
#pragma unroll
      for (int e = 0; e < 8; ++e) {
        __bf16 hh = (__bf16)xv[e];
        ph[e] = hh;
        pl[e] = (__bf16)(xv[e] - (float)hh);
      }
#pragma unroll
      for (int ni = 0; ni < 2; ++ni) {
        int d = wn * 32 + ni * 16 + lr;
        bf16x8 bv = *reinterpret_cast<const bf16x8*>(
            vtb + ((size_t)h * 64 + d) * 2112 + nb * 32 + k0);
        pacc[ni] = __builtin_amdgcn_mfma_f32_16x16x32_bf16(ph, bv, pacc[ni], 0, 0, 0);
        pacc[ni] = __builtin_amdgcn_mfma_f32_16x16x32_bf16(pl, bv, pacc[ni], 0, 0, 0);
      }
    }
#pragma unroll
    for (int ni = 0; ni < 2; ++ni) {
      int d = wn * 32 + ni * 16 + lr;
#pragma unroll
      for (int r = 0; r < 4; ++r) {
        int q = wm * 16 + crow + r;
        s_out[((size_t)h * NTOK + nb * 32 + q) * DHEAD + d] = pacc[ni][r];
      }
    }
  } else {
    // ========== fine attention (1 wave/query, bf16-hi K) ==========
    float (*qs)[64] = reinterpret_cast<float(*)[64]>(smraw);
    float (*pb)[80] = reinterpret_cast<float(*)[80]>(smraw + 4 * 64 * 4);
    int (*selb)[5]  = reinterpret_cast<int(*)[5]>(smraw + 4 * 64 * 4 + 4 * 80 * 4);

    const int u = blk - 512;
    const int h = u & 7;
    const int qq = u >> 3;
    const int wid = t >> 6;
    const int lane = t & 63;
    const int i = (qq << 2) | wid;

    size_t qoff = ((size_t)h * NTOK + i) * DHEAD + lane;
    qs[wid][lane] = __bfloat162float(rqh[qoff]) + __bfloat162float(rql[qoff]);
    if (lane < 5) selb[wid][lane] = sel[((h << 11) | i) * 5 + lane];
    __syncthreads();

    int sblk[5];
#pragma unroll
    for (int b = 0; b < 5; ++b) sblk[b] = selb[wid][b];

    float sim0 = NEGV, sim1 = NEGV;
    {
      int kb = sblk[lane >> 4];
      int pos = (kb << 4) + (lane & 15);
      if (kb >= 0 && pos <= i) {
        const bf16* kp = rkh + ((size_t)h * 2112 + 64 + pos) * DHEAD;
        float d = 0.f;
#pragma unroll
        for (int e8 = 0; e8 < 8; ++e8) {
          bf16x8 kv = *reinterpret_cast<const bf16x8*>(kp + e8 * 8);
#pragma unroll
          for (int e = 0; e < 8; ++e)
            d = fmaf(qs[wid][e8 * 8 + e], (float)kv[e], d);
        }
        sim0 = d * 0.125f;
      }
    }
    if (lane < 16) {
      int kb = sblk[4];
      int pos = (kb << 4) + lane;
      if (pos <= i) {
        const bf16* kp = rkh + ((size_t)h * 2112 + 64 + pos) * DHEAD;
        float d = 0.f;
#pragma unroll
        for (int e8 = 0; e8 < 8; ++e8) {
          bf16x8 kv = *reinterpret_cast<const bf16x8*>(kp + e8 * 8);
#pragma unroll
          for (int e = 0; e < 8; ++e)
            d = fmaf(qs[wid][e8 * 8 + e], (float)kv[e], d);
        }
        sim1 = d * 0.125f;
      }
    }

    float mx = fmaxf(sim0, sim1);
#pragma unroll
    for (int o = 32; o > 0; o >>= 1) mx = fmaxf(mx, __shfl_xor(mx, o));
    float e0 = __expf(sim0 - mx);
    float e1 = __expf(sim1 - mx);
    float sum = e0 + e1;
#pragma unroll
    for (int o = 32; o > 0; o >>= 1) sum += __shfl_xor(sum, o);
    float invs = 1.f / sum;
    pb[wid][lane] = e0 * invs;
    if (lane < 16) pb[wid][64 + lane] = e1 * invs;
    // same wave writes & reads pb[wid]: DS ops wave-ordered, no barrier needed

    float acc = 0.f;
#pragma unroll
    for (int b = 0; b < 5; ++b) {
      int kb = sblk[b];
      if (kb < 0) continue;
      const bf16* vr = vbh + ((size_t)h * NTOK + ((size_t)kb << 4)) * DHEAD + lane;
#pragma unroll
      for (int uu = 0; uu < 16; ++uu)
        acc = fmaf(pb[wid][b * 16 + uu], __bfloat162float(vr[(size_t)uu * DHEAD]), acc);
    }
    f_out[((size_t)h * NTOK + i) * DHEAD + lane] = acc;
  }
}

// ---------------- fused strat + combine: one block per token ----------------
__global__ __launch_bounds__(256) void k_combine2(
    const bf16* __restrict__ Ah, const bf16* __restrict__ Al,
    const float* __restrict__ W, const float* __restrict__ bias,
    const float* __restrict__ c_out, const float* __restrict__ f_out,
    const float* __restrict__ s_out, bf16* __restrict__ comb) {
  const int i = blockIdx.x;
  const int t = threadIdx.x;
  __shared__ float hs[DMODEL];
  __shared__ float st[24];
  size_t ro = (size_t)i * DMODEL;
#pragma unroll
  for (int u = 0; u < 2; ++u) {
    int c = t + u * 256;
    hs[c] = __bfloat162float(Ah[ro + c]) + __bfloat162float(Al[ro + c]);
  }
  __syncthreads();
  if (t < 192) {
    int c = t >> 3, s = t & 7;
    float acc = 0.f;
    for (int u = 0; u < 64; ++u) {
      int e = s * 64 + u;
      acc = fmaf(hs[e], W[(size_t)e * 24 + c], acc);
    }
    acc += __shfl_xor(acc, 1);
    acc += __shfl_xor(acc, 2);
    acc += __shfl_xor(acc, 4);
    if (s == 0) st[c] = 1.f / (1.f + expf(-(acc + bias[c])));
  }
  __syncthreads();
#pragma unroll
  for (int u = 0; u < 2; ++u) {
    int c = t + u * 256;
    int h = c >> 6, d = c & 63;
    size_t a = ((size_t)h * NTOK + i) * DHEAD + d;
    comb[ro + c] = __float2bfloat16(st[h * 3] * c_out[a] + st[h * 3 + 1] * f_out[a]
                                    + st[h * 3 + 2] * s_out[a]);
  }
}

extern "C" void kernel_launch(void* const* d_in, const int* in_sizes, int n_in,
                              void* d_out, int out_size, void* d_ws, size_t ws_size,
                              hipStream_t stream) {
  const float* x      = (const float*)d_in[0];
  const float* g_norm = (const float*)d_in[1];
  const float* w_qkv  = (const float*)d_in[2];
  const float* k_pos  = (const float*)d_in[3];
  const float* v_pos  = (const float*)d_in[4];
  const float* mem_kv = (const float*)d_in[5];
  const float* k_w1   = (const float*)d_in[6];
  const float* k_b1   = (const float*)d_in[7];
  const float* k_w2   = (const float*)d_in[8];
  const float* k_b2   = (const float*)d_in[9];
  const float* v_w1   = (const float*)d_in[10];
  const float* v_b1   = (const float*)d_in[11];
  const float* v_w2   = (const float*)d_in[12];
  const float* v_b2   = (const float*)d_in[13];
  const float* w_comb = (const float*)d_in[14];
  const float* b_comb = (const float*)d_in[15];
  const float* w_out  = (const float*)d_in[16];
  float* out = (float*)d_out;
  char* wsb = (char*)d_ws;

  bf16* WQKV_H = (bf16*)(wsb + B_WQKV_H);
  bf16* WQKV_L = (bf16*)(wsb + B_WQKV_L);
  bf16* KW1_H  = (bf16*)(wsb + B_KW1_H);
  bf16* KW1_L  = (bf16*)(wsb + B_KW1_L);
  bf16* KW2_H  = (bf16*)(wsb + B_KW2_H);
  bf16* KW2_L  = (bf16*)(wsb + B_KW2_L);
  bf16* VW1_H  = (bf16*)(wsb + B_VW1_H);
  bf16* VW2_H  = (bf16*)(wsb + B_VW2_H);
  bf16* WOUT_H = (bf16*)(wsb + B_WOUT_H);
  bf16* HB_H   = (bf16*)(wsb + B_HB_H);
  bf16* HB_L   = (bf16*)(wsb + B_HB_L);
  bf16* QBH    = (bf16*)(wsb + B_QBH);
  bf16* QBM    = (bf16*)(wsb + B_QBM);
  bf16* QBL    = (bf16*)(wsb + B_QBL);
  float* KF    = (float*)(wsb + B_KF);
  bf16* VBH    = (bf16*)(wsb + B_VBH);
  bf16* RQH    = (bf16*)(wsb + B_RQH);
  bf16* RQL    = (bf16*)(wsb + B_RQL);
  bf16* RKH    = (bf16*)(wsb + B_RKH);
  bf16* RKL    = (bf16*)(wsb + B_RKL);
  bf16* VTB    = (bf16*)(wsb + B_VTB);
  bf16* CKT_H  = (bf16*)(wsb + B_CKT_H);
  bf16* CKT_M  = (bf16*)(wsb + B_CKT_M);
  bf16* CKT_L  = (bf16*)(wsb + B_CKT_L);
  bf16* CVT    = (bf16*)(wsb + B_CVT);
  int*   SEL   = (int*)(wsb + B_SEL);
  float* COUT  = (float*)(wsb + B_COUT);
  float* FOUT  = (float*)(wsb + B_FOUT);
  float* SOUT  = (float*)(wsb + B_SOUT);
  bf16* KW_H   = (bf16*)(wsb + B_KW_H);
  bf16* KW_L   = (bf16*)(wsb + B_KW_L);
  bf16* VW_H   = (bf16*)(wsb + B_VW_H);
  bf16* HID_H  = (bf16*)(wsb + B_HID_H);
  bf16* HID_L  = (bf16*)(wsb + B_HID_L);
  bf16* HIDV   = (bf16*)(wsb + B_HIDV);
  bf16* COMBB  = (bf16*)(wsb + B_COMBB);

  // 1. setup: weight splits + pads + mem fill + rmsnorm
  k_setup<<<5378, 256, 0, stream>>>(x, g_norm, w_qkv, k_w1, k_w2, v_w1, v_w2, w_out, mem_kv,
                                    WQKV_H, WQKV_L, KW1_H, KW1_L, KW2_H, KW2_L,
                                    VW1_H, VW2_H, WOUT_H, HB_H, HB_L,
                                    RKH, RKL, VTB, CKT_H, CKT_M, CKT_L, CVT);
  // 2. qkv: LDS-staged 128x64, swizzled + T14, fused split/scatter
  k_qkv<<<384, 256, 0, stream>>>(HB_H, HB_L, WQKV_H, WQKV_L, KF, QBH, QBM, QBL, VBH);
  // 3. post: rope + v-transpose + windows
  k_post<<<10432, 256, 0, stream>>>(QBH, QBM, QBL, KF, VBH, k_pos, v_pos,
                                    RQH, RQL, RKH, RKL, VTB, KW_H, KW_L, VW_H);
  // 4. merged MLP1: LDS-staged, swizzled + T14; HIDV overlays dead KF
  k_mlp1<<<512, 256, 0, stream>>>(KW_H, KW_L, KW1_H, KW1_L, k_b1,
                                  VW_H, VW1_H, v_b1, HID_H, HID_L, HIDV);
  // 5. merged MLP2 -> ckT hi/mid/lo + cvT
  k_mlp2<<<dim3(1, 32, 2), 256, 0, stream>>>(HID_H, HID_L, KW2_H, KW2_L, k_b2,
                                             HIDV, VW2_H, v_b2, CKT_H, CKT_M, CKT_L, CVT);
  // 6. compression attention + selection (head-per-XCD, 512 blocks)
  k_comp_attn<<<512, 256, 0, stream>>>(QBH, QBM, QBL, CKT_H, CKT_M, CKT_L, CVT, COUT, SEL);
  // 7. fused slide + fine attention (head-per-XCD)
  k_fs_attn<<<4608, 256, 0, stream>>>(RQH, RQL, RKH, RKL, VBH, VTB, SEL, FOUT, SOUT);
  // 8. fused strat + combine
  k_combine2<<<NTOK, 256, 0, stream>>>(HB_H, HB_L, w_comb, b_comb, COUT, FOUT, SOUT, COMBB);
  // 9. output projection
  k_cgemm<0, 0><<<dim3(8, 32), 256, 0, stream>>>(
      COMBB, nullptr, WOUT_H, nullptr, nullptr, out, NTOK, DMODEL, DMODEL);
}

// Round 18
// 193.070 us; speedup vs baseline: 1.5868x; 1.0638x over previous
//
#include <hip/hip_runtime.h>
#include <hip/hip_bf16.h>
#include <cstddef>

#define NTOK 2048
#define DMODEL 512
#define NHEAD 8
#define DHEAD 64
#define NWIN 254          // (2048-16)/8 + 1
#define CDIM 1024         // CB*DH
#define NEGV -1000000000.0f

typedef __attribute__((ext_vector_type(8))) __bf16 bf16x8;
typedef __attribute__((ext_vector_type(4))) float f32x4;
typedef __hip_bfloat16 bf16;

// ---------------- workspace layout (byte offsets) ----------------
static const size_t B_WQKV_H = 0;          // 1536*512*2
static const size_t B_WQKV_L = 1572864;
static const size_t B_KW1_H  = 3145728;    // 1024*1024*2
static const size_t B_KW1_L  = 5242880;
static const size_t B_KW2_H  = 7340032;    // 64*1024*2
static const size_t B_KW2_L  = 7471104;
static const size_t B_VW1_H  = 7602176;
static const size_t B_VW2_H  = 9699328;
static const size_t B_WOUT_H = 9830400;    // 512*512*2
static const size_t B_HB_H   = 10354688;   // 2048*512*2
static const size_t B_HB_L   = 12451840;
static const size_t B_QBH    = 14548992;   // 8*2048*64*2 (non-roped q, hi)
static const size_t B_QBL    = 16646144;   // (lo, 3rd term)
static const size_t B_KF     = 18743296;   // 8*2048*64*4 (k fp32; dead after k_post -> HIDV)
static const size_t B_VBH    = 22937600;   // 8*2048*64*2
static const size_t B_RQH    = 25034752;   // roped q hi/lo
static const size_t B_RQL    = 27131904;
static const size_t B_RKH    = 29229056;   // 8*2112*64*2 (roped k, 64 zero-pad rows front)
static const size_t B_RKL    = 31391744;
static const size_t B_VTB    = 33554432;   // 8*64*2112*2 (v^T, 64 zero-pad cols front)
static const size_t B_CKT_H  = 35717120;   // 8*256*64*2 (compressed k rows, j=0 mem)
static const size_t B_CKT_L  = 35979264;
static const size_t B_CVT    = 36241408;   // 8*64*256*2 (compressed v transposed)
static const size_t B_SEL    = 36700160;   // 8*2048*5*4
static const size_t B_COUT   = 37027840;   // 4194304 (overlays KW_H)
static const size_t B_FOUT   = 41222144;   // 4194304 (overlays KW_L)
static const size_t B_SOUT   = 45416448;   // 4194304 (overlays VW_H)
static const size_t B_KW_H   = B_COUT;     // 2032*1024*2 = 4161536
static const size_t B_KW_L   = B_FOUT;
static const size_t B_VW_H   = B_SOUT;
static const size_t B_HID_H  = 49610752;   // 4161536 (k hidden hi)
static const size_t B_HID_L  = 53772288;   // 4161536 (k hidden lo)
static const size_t B_QBM    = 57933824;   // 8*2048*64*2 (q mid term)
static const size_t B_CKT_M  = 60030976;   // 8*256*64*2
static const size_t B_HIDV   = B_KF;       // v hidden hi (4161536 <= 4194304, KF dead)
static const size_t B_COMBB  = B_HID_H;    // 2097152 (after MLPs dead)

// ================= 32x32-per-wave GEMM core (64x64 block tile) =================
template <int COMP>
__device__ __forceinline__ void gemm_tile(
    const bf16* __restrict__ Ah, const bf16* __restrict__ Al,
    const bf16* __restrict__ Wh, const bf16* __restrict__ Wl,
    int M, int K, int row_base, int col_base, int lr, int kg,
    f32x4 accs[2][2]) {
  int ar0 = row_base + lr;       if (ar0 > M - 1) ar0 = M - 1;
  int ar1 = row_base + 16 + lr;  if (ar1 > M - 1) ar1 = M - 1;
  const size_t a0o = (size_t)ar0 * K + kg;
  const size_t a1o = (size_t)ar1 * K + kg;
  const size_t b0o = (size_t)(col_base + lr) * K + kg;
  const size_t b1o = (size_t)(col_base + 16 + lr) * K + kg;
  f32x4 acc00 = {}, acc01 = {}, acc10 = {}, acc11 = {};
  for (int k0 = 0; k0 < K; k0 += 32) {
    bf16x8 ah0 = *reinterpret_cast<const bf16x8*>(Ah + a0o + k0);
    bf16x8 ah1 = *reinterpret_cast<const bf16x8*>(Ah + a1o + k0);
    bf16x8 bh0 = *reinterpret_cast<const bf16x8*>(Wh + b0o + k0);
    bf16x8 bh1 = *reinterpret_cast<const bf16x8*>(Wh + b1o + k0);
    acc00 = __builtin_amdgcn_mfma_f32_16x16x32_bf16(ah0, bh0, acc00, 0, 0, 0);
    acc01 = __builtin_amdgcn_mfma_f32_16x16x32_bf16(ah0, bh1, acc01, 0, 0, 0);
    acc10 = __builtin_amdgcn_mfma_f32_16x16x32_bf16(ah1, bh0, acc10, 0, 0, 0);
    acc11 = __builtin_amdgcn_mfma_f32_16x16x32_bf16(ah1, bh1, acc11, 0, 0, 0);
    if constexpr (COMP) {
      bf16x8 al0 = *reinterpret_cast<const bf16x8*>(Al + a0o + k0);
      bf16x8 al1 = *reinterpret_cast<const bf16x8*>(Al + a1o + k0);
      bf16x8 bl0 = *reinterpret_cast<const bf16x8*>(Wl + b0o + k0);
      bf16x8 bl1 = *reinterpret_cast<const bf16x8*>(Wl + b1o + k0);
      acc00 = __builtin_amdgcn_mfma_f32_16x16x32_bf16(ah0, bl0, acc00, 0, 0, 0);
      acc01 = __builtin_amdgcn_mfma_f32_16x16x32_bf16(ah0, bl1, acc01, 0, 0, 0);
      acc10 = __builtin_amdgcn_mfma_f32_16x16x32_bf16(ah1, bl0, acc10, 0, 0, 0);
      acc11 = __builtin_amdgcn_mfma_f32_16x16x32_bf16(ah1, bl1, acc11, 0, 0, 0);
      acc00 = __builtin_amdgcn_mfma_f32_16x16x32_bf16(al0, bh0, acc00, 0, 0, 0);
      acc01 = __builtin_amdgcn_mfma_f32_16x16x32_bf16(al0, bh1, acc01, 0, 0, 0);
      acc10 = __builtin_amdgcn_mfma_f32_16x16x32_bf16(al1, bh0, acc10, 0, 0, 0);
      acc11 = __builtin_amdgcn_mfma_f32_16x16x32_bf16(al1, bh1, acc11, 0, 0, 0);
    }
  }
  accs[0][0] = acc00; accs[0][1] = acc01; accs[1][0] = acc10; accs[1][1] = acc11;
}

// ---------------- generic GEMM kernel (fp32 out; out-proj) ----------------
template <int EPI, int COMP>
__global__ __launch_bounds__(256) void k_cgemm(
    const bf16* __restrict__ Ah, const bf16* __restrict__ Al,
    const bf16* __restrict__ Wh, const bf16* __restrict__ Wl,
    const float* __restrict__ bias, float* __restrict__ Cf,
    int M, int K, int N) {
  const int lane = threadIdx.x & 63;
  const int w = threadIdx.x >> 6;
  const int wr = w >> 1, wc = w & 1;
  const int row_base = (blockIdx.y << 6) + (wr << 5);
  const int col_base = (blockIdx.x << 6) + (wc << 5);
  const int lr = lane & 15;
  const int kg = (lane >> 4) << 3;
  const int crow = (lane >> 4) << 2;

  f32x4 accs[2][2];
  gemm_tile<COMP>(Ah, Al, Wh, Wl, M, K, row_base, col_base, lr, kg, accs);

#pragma unroll
  for (int mi = 0; mi < 2; ++mi) {
#pragma unroll
    for (int ni = 0; ni < 2; ++ni) {
      int col = col_base + (ni << 4) + lr;
      float bv = bias ? bias[col] : 0.f;
#pragma unroll
      for (int r = 0; r < 4; ++r) {
        int row = row_base + (mi << 4) + crow + r;
        if (row < M) {
          float vv = accs[mi][ni][r] + bv;
          if (EPI == 1) vv = fmaxf(vv, 0.f);
          Cf[(size_t)row * N + col] = vv;
        }
      }
    }
  }
}

#define LDP 40

// ---------------- qkv GEMM: LDS-staged 128x64, XOR chunk swizzle + T14 split ----------------
__global__ __launch_bounds__(256, 2) void k_qkv(
    const bf16* __restrict__ Ah, const bf16* __restrict__ Al,
    const bf16* __restrict__ Wh, const bf16* __restrict__ Wl,
    float* __restrict__ KFo, bf16* __restrict__ QH, bf16* __restrict__ QM,
    bf16* __restrict__ QL, bf16* __restrict__ VB) {
  __shared__ bf16 sAh[128 * LDP];
  __shared__ bf16 sAl[128 * LDP];
  __shared__ bf16 sBh[64 * LDP];
  __shared__ bf16 sBl[64 * LDP];

  const int t = threadIdx.x;
  const int lane = t & 63, w = t >> 6;
  const int wr = w >> 1, wc = w & 1;
  const int lr = lane & 15;
  const int kg = (lane >> 4) << 3;
  const int crow = (lane >> 4) << 2;
  const int id = blockIdx.x;
  const int rt = (id & 7) + ((id >= 192) ? 8 : 0);
  const int ct = (id >> 3) % 24;
  const int row0 = rt << 7;
  const int col0 = ct << 6;

  const int qa0 = t,        ar0s = qa0 >> 2, as0 = qa0 & 3;
  const int qa1 = t + 256,  ar1s = qa1 >> 2, as1 = qa1 & 3;
  const int gr0 = row0 + ar0s;
  const int gr1 = row0 + ar1s;
  const int br = t >> 2, bs = t & 3;
  const int gbr = col0 + br;
  const int wA0 = (as0 ^ (ar0s & 3)) << 3;
  const int wA1 = (as1 ^ (ar1s & 3)) << 3;
  const int wB  = (bs ^ (br & 3)) << 3;
  const int rc = (((lane >> 4) ^ (lr & 3)) << 3);

  f32x4 acc[4][2];
#pragma unroll
  for (int a = 0; a < 4; ++a)
#pragma unroll
    for (int b = 0; b < 2; ++b) acc[a][b] = (f32x4){0.f, 0.f, 0.f, 0.f};

  bf16x8 rAh0 = *reinterpret_cast<const bf16x8*>(Ah + (size_t)gr0 * DMODEL + as0 * 8);
  bf16x8 rAh1 = *reinterpret_cast<const bf16x8*>(Ah + (size_t)gr1 * DMODEL + as1 * 8);
  bf16x8 rBh  = *reinterpret_cast<const bf16x8*>(Wh + (size_t)gbr * DMODEL + bs * 8);
  bf16x8 rAl0 = *reinterpret_cast<const bf16x8*>(Al + (size_t)gr0 * DMODEL + as0 * 8);
  bf16x8 rAl1 = *reinterpret_cast<const bf16x8*>(Al + (size_t)gr1 * DMODEL + as1 * 8);
  bf16x8 rBl  = *reinterpret_cast<const bf16x8*>(Wl + (size_t)gbr * DMODEL + bs * 8);

  for (int k0 = 0; k0 < DMODEL; k0 += 32) {
    *reinterpret_cast<bf16x8*>(&sAh[ar0s * LDP + wA0]) = rAh0;
    *reinterpret_cast<bf16x8*>(&sAh[ar1s * LDP + wA1]) = rAh1;
    *reinterpret_cast<bf16x8*>(&sBh[br * LDP + wB]) = rBh;
    *reinterpret_cast<bf16x8*>(&sAl[ar0s * LDP + wA0]) = rAl0;
    *reinterpret_cast<bf16x8*>(&sAl[ar1s * LDP + wA1]) = rAl1;
    *reinterpret_cast<bf16x8*>(&sBl[br * LDP + wB]) = rBl;
    __syncthreads();

    if (k0 + 32 < DMODEL) {
      const int kn = k0 + 32;
      rAh0 = *reinterpret_cast<const bf16x8*>(Ah + (size_t)gr0 * DMODEL + kn + as0 * 8);
      rAh1 = *reinterpret_cast<const bf16x8*>(Ah + (size_t)gr1 * DMODEL + kn + as1 * 8);
      rBh  = *reinterpret_cast<const bf16x8*>(Wh + (size_t)gbr * DMODEL + kn + bs * 8);
      rAl0 = *reinterpret_cast<const bf16x8*>(Al + (size_t)gr0 * DMODEL + kn + as0 * 8);
      rAl1 = *reinterpret_cast<const bf16x8*>(Al + (size_t)gr1 * DMODEL + kn + as1 * 8);
      rBl  = *reinterpret_cast<const bf16x8*>(Wl + (size_t)gbr * DMODEL + kn + bs * 8);
    }

    bf16x8 fAh[4], fBh[2], fAl[4], fBl[2];
#pragma unroll
    for (int mi = 0; mi < 4; ++mi)
      fAh[mi] = *reinterpret_cast<const bf16x8*>(&sAh[(wr * 64 + mi * 16 + lr) * LDP + rc]);
#pragma unroll
    for (int ni = 0; ni < 2; ++ni)
      fBh[ni] = *reinterpret_cast<const bf16x8*>(&sBh[(wc * 32 + ni * 16 + lr) * LDP + rc]);
#pragma unroll
    for (int mi = 0; mi < 4; ++mi)
      fAl[mi] = *reinterpret_cast<const bf16x8*>(&sAl[(wr * 64 + mi * 16 + lr) * LDP + rc]);
#pragma unroll
    for (int ni = 0; ni < 2; ++ni)
      fBl[ni] = *reinterpret_cast<const bf16x8*>(&sBl[(wc * 32 + ni * 16 + lr) * LDP + rc]);

#pragma unroll
    for (int mi = 0; mi < 4; ++mi)
#pragma unroll
      for (int ni = 0; ni < 2; ++ni)
        acc[mi][ni] = __builtin_amdgcn_mfma_f32_16x16x32_bf16(fAh[mi], fBh[ni], acc[mi][ni], 0, 0, 0);
#pragma unroll
    for (int mi = 0; mi < 4; ++mi)
#pragma unroll
      for (int ni = 0; ni < 2; ++ni) {
        acc[mi][ni] = __builtin_amdgcn_mfma_f32_16x16x32_bf16(fAh[mi], fBl[ni], acc[mi][ni], 0, 0, 0);
        acc[mi][ni] = __builtin_amdgcn_mfma_f32_16x16x32_bf16(fAl[mi], fBh[ni], acc[mi][ni], 0, 0, 0);
      }
    __syncthreads();
  }

#pragma unroll
  for (int mi = 0; mi < 4; ++mi) {
#pragma unroll
    for (int ni = 0; ni < 2; ++ni) {
      int col = col0 + wc * 32 + ni * 16 + lr;
      int which = col >> 9, rem = col & 511;
      int hh = rem >> 6, dd = rem & 63;
#pragma unroll
      for (int r = 0; r < 4; ++r) {
        int row = row0 + wr * 64 + mi * 16 + crow + r;
        float vv = acc[mi][ni][r];
        size_t o = ((size_t)hh * NTOK + row) * DHEAD + dd;
        if (which == 0) {
          bf16 h1 = __float2bfloat16(vv);
          float r1 = vv - __bfloat162float(h1);
          bf16 m1 = __float2bfloat16(r1);
          QH[o] = h1;
          QM[o] = m1;
          QL[o] = __float2bfloat16(r1 - __bfloat162float(m1));
        } else if (which == 1) {
          KFo[o] = vv;
        } else {
          VB[o] = __float2bfloat16(vv);
        }
      }
    }
  }
}

// ---------------- merged MLP1: LDS-staged + XOR chunk swizzle + T14 split ----------------
__global__ __launch_bounds__(256, 2) void k_mlp1(
    const bf16* __restrict__ KWh, const bf16* __restrict__ KWl,
    const bf16* __restrict__ W1h, const bf16* __restrict__ W1l,
    const float* __restrict__ kb1,
    const bf16* __restrict__ VWh, const bf16* __restrict__ VW1h,
    const float* __restrict__ vb1,
    bf16* __restrict__ HKh, bf16* __restrict__ HKl, bf16* __restrict__ HVh) {
  __shared__ bf16 sAh[128 * LDP];
  __shared__ bf16 sAl[128 * LDP];
  __shared__ bf16 sBh[64 * LDP];
  __shared__ bf16 sBl[64 * LDP];

  const int t = threadIdx.x;
  const int lane = t & 63, w = t >> 6;
  const int wr = w >> 1, wc = w & 1;
  const int lr = lane & 15;
  const int kg = (lane >> 4) << 3;
  const int crow = (lane >> 4) << 2;
  const int M = NHEAD * NWIN;  // 2032
  const int id = blockIdx.x;
  const bool kpath = (id < 256);
  const int u = kpath ? id : id - 256;
  const int rt = (u & 7) + ((u >= 128) ? 8 : 0);
  const int ct = (u >> 3) & 15;
  const int row0 = rt << 7;
  const int col0 = ct << 6;

  const bf16* Ah = kpath ? KWh : VWh;
  const bf16* Bh = kpath ? W1h : VW1h;

  const int qa0 = t,        ar0s = qa0 >> 2, as0 = qa0 & 3;
  const int qa1 = t + 256,  ar1s = qa1 >> 2, as1 = qa1 & 3;
  int gr0 = row0 + ar0s; if (gr0 > M - 1) gr0 = M - 1;
  int gr1 = row0 + ar1s; if (gr1 > M - 1) gr1 = M - 1;
  const int br = t >> 2, bs = t & 3;
  const int gbr = col0 + br;
  const int wA0 = (as0 ^ (ar0s & 3)) << 3;
  const int wA1 = (as1 ^ (ar1s & 3)) << 3;
  const int wB  = (bs ^ (br & 3)) << 3;
  const int rc = (((lane >> 4) ^ (lr & 3)) << 3);

  f32x4 acc[4][2];
#pragma unroll
  for (int a = 0; a < 4; ++a)
#pragma unroll
    for (int b = 0; b < 2; ++b) acc[a][b] = (f32x4){0.f, 0.f, 0.f, 0.f};

  bf16x8 rAh0 = *reinterpret_cast<const bf16x8*>(Ah + (size_t)gr0 * CDIM + as0 * 8);
  bf16x8 rAh1 = *reinterpret_cast<const bf16x8*>(Ah + (size_t)gr1 * CDIM + as1 * 8);
  bf16x8 rBh  = *reinterpret_cast<const bf16x8*>(Bh + (size_t)gbr * CDIM + bs * 8);
  bf16x8 rAl0, rAl1, rBl;
  if (kpath) {
    rAl0 = *reinterpret_cast<const bf16x8*>(KWl + (size_t)gr0 * CDIM + as0 * 8);
    rAl1 = *reinterpret_cast<const bf16x8*>(KWl + (size_t)gr1 * CDIM + as1 * 8);
    rBl  = *reinterpret_cast<const bf16x8*>(W1l + (size_t)gbr * CDIM + bs * 8);
  }

  for (int k0 = 0; k0 < CDIM; k0 += 32) {
    *reinterpret_cast<bf16x8*>(&sAh[ar0s * LDP + wA0]) = rAh0;
    *reinterpret_cast<bf16x8*>(&sAh[ar1s * LDP + wA1]) = rAh1;
    *reinterpret_cast<bf16x8*>(&sBh[br * LDP + wB]) = rBh;
    if (kpath) {
      *reinterpret_cast<bf16x8*>(&sAl[ar0s * LDP + wA0]) = rAl0;
      *reinterpret_cast<bf16x8*>(&sAl[ar1s * LDP + wA1]) = rAl1;
      *reinterpret_cast<bf16x8*>(&sBl[br * LDP + wB]) = rBl;
    }
    __syncthreads();

    if (k0 + 32 < CDIM) {
      const int kn = k0 + 32;
      rAh0 = *reinterpret_cast<const bf16x8*>(Ah + (size_t)gr0 * CDIM + kn + as0 * 8);
      rAh1 = *reinterpret_cast<const bf16x8*>(Ah + (size_t)gr1 * CDIM + kn + as1 * 8);
      rBh  = *reinterpret_cast<const bf16x8*>(Bh + (size_t)gbr * CDIM + kn + bs * 8);
      if (kpath) {
        rAl0 = *reinterpret_cast<const bf16x8*>(KWl + (size_t)gr0 * CDIM + kn + as0 * 8);
        rAl1 = *reinterpret_cast<const bf16x8*>(KWl + (size_t)gr1 * CDIM + kn + as1 * 8);
        rBl  = *reinterpret_cast<const bf16x8*>(W1l + (size_t)gbr * CDIM + kn + bs * 8);
      }
    }

    bf16x8 fAh[4], fBh[2], fAl[4], fBl[2];
#pragma unroll
    for (int mi = 0; mi < 4; ++mi)
      fAh[mi] = *reinterpret_cast<const bf16x8*>(&sAh[(wr * 64 + mi * 16 + lr) * LDP + rc]);
#pragma unroll
    for (int ni = 0; ni < 2; ++ni)
      fBh[ni] = *reinterpret_cast<const bf16x8*>(&sBh[(wc * 32 + ni * 16 + lr) * LDP + rc]);
    if (kpath) {
#pragma unroll
      for (int mi = 0; mi < 4; ++mi)
        fAl[mi] = *reinterpret_cast<const bf16x8*>(&sAl[(wr * 64 + mi * 16 + lr) * LDP + rc]);
#pragma unroll
      for (int ni = 0; ni < 2; ++ni)
        fBl[ni] = *reinterpret_cast<const bf16x8*>(&sBl[(wc * 32 + ni * 16 + lr) * LDP + rc]);
    }

#pragma unroll
    for (int mi = 0; mi < 4; ++mi)
#pragma unroll
      for (int ni = 0; ni < 2; ++ni)
        acc[mi][ni] = __builtin_amdgcn_mfma_f32_16x16x32_bf16(fAh[mi], fBh[ni], acc[mi][ni], 0, 0, 0);
    if (kpath) {
#pragma unroll
      for (int mi = 0; mi < 4; ++mi)
#pragma unroll
        for (int ni = 0; ni < 2; ++ni) {
          acc[mi][ni] = __builtin_amdgcn_mfma_f32_16x16x32_bf16(fAh[mi], fBl[ni], acc[mi][ni], 0, 0, 0);
          acc[mi][ni] = __builtin_amdgcn_mfma_f32_16x16x32_bf16(fAl[mi], fBh[ni], acc[mi][ni], 0, 0, 0);
        }
    }
    __syncthreads();
  }

#pragma unroll
  for (int mi = 0; mi < 4; ++mi) {
#pragma unroll
    for (int ni = 0; ni < 2; ++ni) {
      int col = col0 + wc * 32 + ni * 16 + lr;
      float bv = kpath ? kb1[col] : vb1[col];
#pragma unroll
      for (int r = 0; r < 4; ++r) {
        int row = row0 + wr * 64 + mi * 16 + crow + r;
        if (row < M) {
          float vv = fmaxf(acc[mi][ni][r] + bv, 0.f);
          size_t o = (size_t)row * CDIM + col;
          if (kpath) {
            bf16 h1 = __float2bfloat16(vv);
            HKh[o] = h1;
            HKl[o] = __float2bfloat16(vv - __bfloat162float(h1));
          } else {
            HVh[o] = __float2bfloat16(vv);
          }
        }
      }
    }
  }
}

// ---------------- merged MLP2: z=0 k-path -> ckT hi/mid/lo, z=1 v-path -> cvT ----------------
__global__ __launch_bounds__(256) void k_mlp2(
    const bf16* __restrict__ HKh, const bf16* __restrict__ HKl,
    const bf16* __restrict__ W2h, const bf16* __restrict__ W2l,
    const float* __restrict__ kb2,
    const bf16* __restrict__ HVh, const bf16* __restrict__ VW2h,
    const float* __restrict__ vb2,
    bf16* __restrict__ ckh, bf16* __restrict__ ckm, bf16* __restrict__ ckl,
    bf16* __restrict__ cvtb) {
  const int lane = threadIdx.x & 63;
  const int w = threadIdx.x >> 6;
  const int wr = w >> 1, wc = w & 1;
  const int row_base = (blockIdx.y << 6) + (wr << 5);
  const int col_base = (wc << 5);
  const int lr = lane & 15;
  const int kg = (lane >> 4) << 3;
  const int crow = (lane >> 4) << 2;
  const int M = NHEAD * NWIN;

  f32x4 accs[2][2];
  if (blockIdx.z == 0)
    gemm_tile<1>(HKh, HKl, W2h, W2l, M, CDIM, row_base, col_base, lr, kg, accs);
  else
    gemm_tile<0>(HVh, nullptr, VW2h, nullptr, M, CDIM, row_base, col_base, lr, kg, accs);

  const float* bias = (blockIdx.z == 0) ? kb2 : vb2;
#pragma unroll
  for (int mi = 0; mi < 2; ++mi) {
#pragma unroll
    for (int ni = 0; ni < 2; ++ni) {
      int col = col_base + (ni << 4) + lr;
      float bv = bias[col];
#pragma unroll
      for (int r = 0; r < 4; ++r) {
        int row = row_base + (mi << 4) + crow + r;
        if (row < M) {
          float vv = accs[mi][ni][r] + bv;
          int hh = row / NWIN, jj = row - hh * NWIN;
          if (blockIdx.z == 0) {
            size_t o = ((size_t)hh * 256 + 1 + jj) * 64 + col;
            bf16 h1 = __float2bfloat16(vv);
            float r1 = vv - __bfloat162float(h1);
            bf16 m1 = __float2bfloat16(r1);
            ckh[o] = h1;
            ckm[o] = m1;
            ckl[o] = __float2bfloat16(r1 - __bfloat162float(m1));
          } else {
            cvtb[((size_t)hh * 64 + col) * 256 + 1 + jj] = __float2bfloat16(vv);
          }
        }
      }
    }
  }
}

// ================= k_setup: 6 weight transposes + zpad + fillmem + rmsnorm =================
__device__ __forceinline__ void wt_tile(const float* __restrict__ W,
                                        bf16* __restrict__ WTh, bf16* __restrict__ WTl,
                                        int K, int N, int bx, int by,
                                        float (*tsh)[33]) {
  const int k0 = bx << 5, n0 = by << 5;
  const int tx = threadIdx.x & 31, ty = threadIdx.x >> 5;
#pragma unroll
  for (int r = 0; r < 4; ++r)
    tsh[ty + (r << 3)][tx] = W[(size_t)(k0 + ty + (r << 3)) * N + n0 + tx];
  __syncthreads();
#pragma unroll
  for (int r = 0; r < 4; ++r) {
    float val = tsh[tx][ty + (r << 3)];
    size_t o = (size_t)(n0 + ty + (r << 3)) * K + k0 + tx;
    bf16 h1 = __float2bfloat16(val);
    WTh[o] = h1;
    if (WTl) WTl[o] = __float2bfloat16(val - __bfloat162float(h1));
  }
}

__global__ __launch_bounds__(256) void k_setup(
    const float* __restrict__ x, const float* __restrict__ g,
    const float* __restrict__ w_qkv, const float* __restrict__ k_w1,
    const float* __restrict__ k_w2, const float* __restrict__ v_w1,
    const float* __restrict__ v_w2, const float* __restrict__ w_out,
    const float* __restrict__ memkv,
    bf16* __restrict__ WQKV_H, bf16* __restrict__ WQKV_L,
    bf16* __restrict__ KW1_H, bf16* __restrict__ KW1_L,
    bf16* __restrict__ KW2_H, bf16* __restrict__ KW2_L,
    bf16* __restrict__ VW1_H, bf16* __restrict__ VW2_H, bf16* __restrict__ WOUT_H,
    bf16* __restrict__ hbh, bf16* __restrict__ hbl,
    bf16* __restrict__ rkh, bf16* __restrict__ rkl, bf16* __restrict__ vtb,
    bf16* __restrict__ ckh, bf16* __restrict__ ckm, bf16* __restrict__ ckl,
    bf16* __restrict__ cvtb) {
  __shared__ float tsh[32][33];
  __shared__ float wsum[4];
  __shared__ float scale_s;
  const int id = blockIdx.x;
  const int t = threadIdx.x;

  if (id < 768) {
    wt_tile(w_qkv, WQKV_H, WQKV_L, DMODEL, 1536, id % 16, id / 16, tsh);
  } else if (id < 1792) {
    int u = id - 768;  wt_tile(k_w1, KW1_H, KW1_L, CDIM, CDIM, u % 32, u / 32, tsh);
  } else if (id < 1856) {
    int u = id - 1792; wt_tile(k_w2, KW2_H, KW2_L, CDIM, DHEAD, u % 32, u / 32, tsh);
  } else if (id < 2880) {
    int u = id - 1856; wt_tile(v_w1, VW1_H, nullptr, CDIM, CDIM, u % 32, u / 32, tsh);
  } else if (id < 2944) {
    int u = id - 2880; wt_tile(v_w2, VW2_H, nullptr, CDIM, DHEAD, u % 32, u / 32, tsh);
  } else if (id < 3200) {
    int u = id - 2944; wt_tile(w_out, WOUT_H, nullptr, DMODEL, DMODEL, u % 16, u / 16, tsh);
  } else if (id < 3328) {
    int idx = (id - 3200) * 256 + t;   // [0, 32768)
    int h = idx >> 12, r = (idx >> 6) & 63, c = idx & 63;
    bf16 z = __float2bfloat16(0.f);
    rkh[((size_t)h * 2112 + r) * 64 + c] = z;
    rkl[((size_t)h * 2112 + r) * 64 + c] = z;
    vtb[((size_t)h * 64 + r) * 2112 + c] = z;
  } else if (id < 3330) {
    int u = (id - 3328) * 256 + t;     // [0, 512)
    if (u < 512) {
      int h = u >> 6, e = u & 63;
      float kv = memkv[(size_t)h * DHEAD + e];
      bf16 h1 = __float2bfloat16(kv);
      float r1 = kv - __bfloat162float(h1);
      bf16 m1 = __float2bfloat16(r1);
      ckh[((size_t)h * 256) * 64 + e] = h1;
      ckm[((size_t)h * 256) * 64 + e] = m1;
      ckl[((size_t)h * 256) * 64 + e] = __float2bfloat16(r1 - __bfloat162float(m1));
      bf16 z = __float2bfloat16(0.f);
      ckh[((size_t)h * 256 + 255) * 64 + e] = z;
      ckm[((size_t)h * 256 + 255) * 64 + e] = z;
      ckl[((size_t)h * 256 + 255) * 64 + e] = z;
      float vv = memkv[(size_t)(NHEAD + h) * DHEAD + e];
      cvtb[((size_t)h * 64 + e) * 256 + 0] = __float2bfloat16(vv);
      cvtb[((size_t)h * 64 + e) * 256 + 255] = z;
    }
  } else {
    const int row = id - 3330;
    const float* xr = x + (size_t)row * DMODEL;
    float s = 0.f;
    for (int c = t; c < DMODEL; c += 256) { float v = xr[c]; s += v * v; }
    for (int o = 32; o > 0; o >>= 1) s += __shfl_down(s, o);
    if ((t & 63) == 0) wsum[t >> 6] = s;
    __syncthreads();
    if (t == 0) {
      float tot = wsum[0] + wsum[1] + wsum[2] + wsum[3];
      scale_s = rsqrtf(tot * (1.f / DMODEL) + 1e-6f);
    }
    __syncthreads();
    float sc = scale_s;
    for (int c = t; c < DMODEL; c += 256) {
      float v = xr[c] * sc * g[c];
      bf16 h1 = __float2bfloat16(v);
      hbh[(size_t)row * DMODEL + c] = h1;
      hbl[(size_t)row * DMODEL + c] = __float2bfloat16(v - __bfloat162float(h1));
    }
  }
}

// ================= k_post: rope + v-transpose + compression windows =================
__global__ __launch_bounds__(256) void k_post(
    const bf16* __restrict__ qbh, const bf16* __restrict__ qbm,
    const bf16* __restrict__ qbl, const float* __restrict__ kf,
    const bf16* __restrict__ vbh,
    const float* __restrict__ kpos, const float* __restrict__ vpos,
    bf16* __restrict__ rqh, bf16* __restrict__ rql,
    bf16* __restrict__ rkh, bf16* __restrict__ rkl,
    bf16* __restrict__ vtb,
    bf16* __restrict__ kwh, bf16* __restrict__ kwl, bf16* __restrict__ vwh) {
  __shared__ bf16 tile[64][65];
  const int id = blockIdx.x;
  const int t = threadIdx.x;

  if (id < 2048) {
    int idx = id * 256 + t;
    int i = idx & 31;
    int n = (idx >> 5) & (NTOK - 1);
    int h = idx >> 16;
    float ex = (float)(2 * i) * (1.f / 64.f);
    float inv = exp2f(-ex * 13.287712379549449f);
    float ang = (float)n * inv;
    float sn, cs;
    sincosf(ang, &sn, &cs);
    size_t base = ((size_t)h * NTOK + n) * DHEAD + 2 * i;
    float q1 = __bfloat162float(qbh[base]) + __bfloat162float(qbm[base]) + __bfloat162float(qbl[base]);
    float q2 = __bfloat162float(qbh[base + 1]) + __bfloat162float(qbm[base + 1]) + __bfloat162float(qbl[base + 1]);
    float r1 = q1 * cs - q2 * sn, r2 = q1 * sn + q2 * cs;
    bf16 h1 = __float2bfloat16(r1);
    rqh[base] = h1; rql[base] = __float2bfloat16(r1 - __bfloat162float(h1));
    h1 = __float2bfloat16(r2);
    rqh[base + 1] = h1; rql[base + 1] = __float2bfloat16(r2 - __bfloat162float(h1));
    float k1 = kf[base], k2 = kf[base + 1];
    float s1 = k1 * cs - k2 * sn, s2 = k1 * sn + k2 * cs;
    size_t kb = ((size_t)h * 2112 + 64 + n) * DHEAD + 2 * i;
    h1 = __float2bfloat16(s1);
    rkh[kb] = h1; rkl[kb] = __float2bfloat16(s1 - __bfloat162float(h1));
    h1 = __float2bfloat16(s2);
    rkh[kb + 1] = h1; rkl[kb + 1] = __float2bfloat16(s2 - __bfloat162float(h1));
  } else if (id < 2304) {
    int u = id - 2048;
    int h = u >> 5, n0 = (u & 31) << 6;
    int tx = t & 63, ty = t >> 6;
    for (int r = ty; r < 64; r += 4)
      tile[r][tx] = vbh[((size_t)h * NTOK + n0 + r) * DHEAD + tx];
    __syncthreads();
    for (int r = ty; r < 64; r += 4)
      vtb[((size_t)h * 64 + r) * 2112 + 64 + n0 + tx] = tile[tx][r];
  } else {
    int idx = (id - 2304) * 256 + t;   // [0, 2080768)
    int d = idx & 63;
    int c = (idx >> 6) & 15;
    int j = (idx >> 10) % NWIN;
    int h = idx / (NWIN << 10);
    int srcpos = (j << 3) + c;
    size_t src = ((size_t)h * NTOK + srcpos) * DHEAD + d;
    size_t pp = ((size_t)h * 16 + c) * DHEAD + d;
    float kv = kf[src] + kpos[pp];
    bf16 h1 = __float2bfloat16(kv);
    kwh[idx] = h1;
    kwl[idx] = __float2bfloat16(kv - __bfloat162float(h1));
    vwh[idx] = __float2bfloat16(__bfloat162float(vbh[src]) + vpos[pp]);
  }
}

// ---------------- compression attention (MFMA, 32 queries/block) ----------------
__global__ __launch_bounds__(256) void k_comp_attn(
    const bf16* __restrict__ qbh, const bf16* __restrict__ qbm, const bf16* __restrict__ qbl,
    const bf16* __restrict__ ckh, const bf16* __restrict__ ckm, const bf16* __restrict__ ckl,
    const bf16* __restrict__ cvtb,
    float* __restrict__ c_out, int* __restrict__ sel) {
  const int h = blockIdx.x & 7;
  const int i0 = (blockIdx.x >> 3) << 5;
  const int t = threadIdx.x;
  const int w = t >> 6, lane = t & 63;
  const int lr = lane & 15, kg = (lane >> 4) << 3;
  const int crow = (lane >> 4) << 2;

  __shared__ float p[32][260];

  bf16x8 aH[2][2], aM[2][2], aL[2][2];
#pragma unroll
  for (int mi = 0; mi < 2; ++mi) {
    size_t qo = ((size_t)h * NTOK + i0 + mi * 16 + lr) * DHEAD + kg;
#pragma unroll
    for (int ks = 0; ks < 2; ++ks) {
      aH[mi][ks] = *reinterpret_cast<const bf16x8*>(qbh + qo + ks * 32);
      aM[mi][ks] = *reinterpret_cast<const bf16x8*>(qbm + qo + ks * 32);
      aL[mi][ks] = *reinterpret_cast<const bf16x8*>(qbl + qo + ks * 32);
    }
  }
  f32x4 acc[2][4];
#pragma unroll
  for (int a = 0; a < 2; ++a)
#pragma unroll
    for (int b = 0; b < 4; ++b) acc[a][b] = (f32x4){0.f, 0.f, 0.f, 0.f};
#pragma unroll
  for (int ni = 0; ni < 4; ++ni) {
    int col = (w << 6) + (ni << 4) + lr;
    size_t ko = ((size_t)h * 256 + col) * 64 + kg;
#pragma unroll
    for (int ks = 0; ks < 2; ++ks) {
      bf16x8 bH = *reinterpret_cast<const bf16x8*>(ckh + ko + ks * 32);
      bf16x8 bM = *reinterpret_cast<const bf16x8*>(ckm + ko + ks * 32);
      bf16x8 bL = *reinterpret_cast<const bf16x8*>(ckl + ko + ks * 32);
#pragma unroll
      for (int mi = 0; mi < 2; ++mi) {
        acc[mi][ni] = __builtin_amdgcn_mfma_f32_16x16x32_bf16(aH[mi][ks], bH, acc[mi][ni], 0, 0, 0);
        acc[mi][ni] = __builtin_amdgcn_mfma_f32_16x16x32_bf16(aH[mi][ks], bM, acc[mi][ni], 0, 0, 0);
        acc[mi][ni] = __builtin_amdgcn_mfma_f32_16x16x32_bf16(aM[mi][ks], bH, acc[mi][ni], 0, 0, 0);
        acc[mi][ni] = __builtin_amdgcn_mfma_f32_16x16x32_bf16(aH[mi][ks], bL, acc[mi][ni], 0, 0, 0);
        acc[mi][ni] = __builtin_amdgcn_mfma_f32_16x16x32_bf16(aL[mi][ks], bH, acc[mi][ni], 0, 0, 0);
        acc[mi][ni] = __builtin_amdgcn_mfma_f32_16x16x32_bf16(aM[mi][ks], bM, acc[mi][ni], 0, 0, 0);
      }
    }
  }
#pragma unroll
  for (int mi = 0; mi < 2; ++mi)
#pragma unroll
    for (int ni = 0; ni < 4; ++ni) {
      int col = (w << 6) + (ni << 4) + lr;
      int wend = (col == 0) ? -1 : ((col - 1) << 3) + 15;
#pragma unroll
      for (int r = 0; r < 4; ++r) {
        int qi = mi * 16 + crow + r;
        bool ok = (col < 255) && (wend < i0 + qi);
        p[qi][col] = ok ? acc[mi][ni][r] * 0.125f : NEGV;
      }
    }
  __syncthreads();

  const int qi = t >> 3, s = t & 7;
  float ev[32];
  float mx = -3.0e38f;
#pragma unroll
  for (int u = 0; u < 32; ++u) { ev[u] = p[qi][s + (u << 3)]; mx = fmaxf(mx, ev[u]); }
  mx = fmaxf(mx, __shfl_xor(mx, 1));
  mx = fmaxf(mx, __shfl_xor(mx, 2));
  mx = fmaxf(mx, __shfl_xor(mx, 4));
  float sum = 0.f;
#pragma unroll
  for (int u = 0; u < 32; ++u) { float e = __expf(ev[u] - mx); ev[u] = e; sum += e; }
  sum += __shfl_xor(sum, 1); sum += __shfl_xor(sum, 2); sum += __shfl_xor(sum, 4);
  float invs = 1.f / sum;
#pragma unroll
  for (int u = 0; u < 32; ++u) p[qi][s + (u << 3)] = ev[u] * invs;

  int qblk = (i0 + qi) >> 4;
  float vals[16];
#pragma unroll
  for (int u = 0; u < 16; ++u) {
    int f = (s << 4) + u;
    float v;
    if (f >= qblk || f == 127) v = NEGV;
    else v = (p[qi][2 * f + 1] + p[qi][2 * f + 2]) * 0.5f;
    vals[u] = v;
  }
  int base = ((h << 11) | (i0 + qi)) * 5;
  for (int kk = 0; kk < 4; ++kk) {
    float bv = -3.0e38f; int bi = 0;
#pragma unroll
    for (int u = 0; u < 16; ++u) {
      if (vals[u] > bv) { bv = vals[u]; bi = (s << 4) + u; }
    }
#pragma unroll
    for (int o = 1; o < 8; o <<= 1) {
      float ov = __shfl_xor(bv, o);
      int oi = __shfl_xor(bi, o);
      if (ov > bv || (ov == bv && oi < bi)) { bv = ov; bi = oi; }
    }
    if (s == 0) sel[base + kk] = (bv > -5.0e8f) ? bi : -1;
    if ((bi >> 4) == s) vals[bi & 15] = -3.0e38f;
  }
  if (s == 0) sel[base + 4] = (i0 + qi) >> 4;
  __syncthreads();

  const int wm = w >> 1, wn = w & 1;
  const int arow = wm * 16 + lr;
  f32x4 pacc[2];
#pragma unroll
  for (int b = 0; b < 2; ++b) pacc[b] = (f32x4){0.f, 0.f, 0.f, 0.f};
#pragma unroll
  for (int ks = 0; ks < 8; ++ks) {
    int k0 = ks * 32 + kg;
    float4 x0 = *reinterpret_cast<const float4*>(&p[arow][k0]);
    float4 x1 = *reinterpret_cast<const float4*>(&p[arow][k0 + 4]);
    float xv[8] = {x0.x, x0.y, x0.z, x0.w, x1.x, x1.y, x1.z, x1.w};
    bf16x8 ph, pl;
#pragma unroll
    for (int e = 0; e < 8; ++e) {
      __bf16 hh = (__bf16)xv[e];
      ph[e] = hh;
      pl[e] = (__bf16)(xv[e] - (float)hh);
    }
#pragma unroll
    for (int ni = 0; ni < 2; ++ni) {
      int d = (wn << 5) + (ni << 4) + lr;
      bf16x8 bv = *reinterpret_cast<const bf16x8*>(cvtb + ((size_t)h * 64 + d) * 256 + k0);
      pacc[ni] = __builtin_amdgcn_mfma_f32_16x16x32_bf16(ph, bv, pacc[ni], 0, 0, 0);
      pacc[ni] = __builtin_amdgcn_mfma_f32_16x16x32_bf16(pl, bv, pacc[ni], 0, 0, 0);
    }
  }
#pragma unroll
  for (int ni = 0; ni < 2; ++ni) {
    int d = (wn << 5) + (ni << 4) + lr;
#pragma unroll
    for (int r = 0; r < 4; ++r) {
      int q2 = wm * 16 + crow + r;
      c_out[((size_t)h * NTOK + i0 + q2) * DHEAD + d] = pacc[ni][r];
    }
  }
}

// ======== fused fine + sliding attention, head-per-XCD swizzle ========
// fine: 4-lanes-per-key QK (lane = (key-slot, dim-chunk)); 4x fewer divergent lines.
__global__ __launch_bounds__(256, 8) void k_fs_attn(
    const bf16* __restrict__ rqh, const bf16* __restrict__ rql,
    const bf16* __restrict__ rkh, const bf16* __restrict__ rkl,
    const bf16* __restrict__ vbh, const bf16* __restrict__ vtb,
    const int* __restrict__ sel,
    float* __restrict__ f_out, float* __restrict__ s_out) {
  __shared__ char smraw[32 * 100 * 4];   // 12800 B
  const int blk = blockIdx.x;
  const int t = threadIdx.x;

  if (blk < 512) {
    // ========== sliding-window: 32 queries, 96-key window ==========
    float (*p)[100] = reinterpret_cast<float(*)[100]>(smraw);
    const int h = blk & 7, nb = (blk >> 3) & 63;
    const int w = t >> 6, lane = t & 63;
    const int lr = lane & 15, kg = (lane >> 4) << 3;
    const int crow = (lane >> 4) << 2;
    const int wr = w >> 1, wc = w & 1;

    bf16x8 aH[2], aL[2];
    {
      size_t qo = ((size_t)h * NTOK + nb * 32 + wr * 16 + lr) * DHEAD + kg;
#pragma unroll
      for (int ks = 0; ks < 2; ++ks) {
        aH[ks] = *reinterpret_cast<const bf16x8*>(rqh + qo + ks * 32);
        aL[ks] = *reinterpret_cast<const bf16x8*>(rql + qo + ks * 32);
      }
    }
    f32x4 acc[3];
#pragma unroll
    for (int a = 0; a < 3; ++a) acc[a] = (f32x4){0.f, 0.f, 0.f, 0.f};
#pragma unroll
    for (int ni = 0; ni < 3; ++ni) {
      int col = wc * 48 + ni * 16 + lr;
      size_t ko = ((size_t)h * 2112 + nb * 32 + col) * 64 + kg;
#pragma unroll
      for (int ks = 0; ks < 2; ++ks) {
        bf16x8 bH = *reinterpret_cast<const bf16x8*>(rkh + ko + ks * 32);
        bf16x8 bL = *reinterpret_cast<const bf16x8*>(rkl + ko + ks * 32);
        acc[ni] = __builtin_amdgcn_mfma_f32_16x16x32_bf16(aH[ks], bH, acc[ni], 0, 0, 0);
        acc[ni] = __builtin_amdgcn_mfma_f32_16x16x32_bf16(aL[ks], bH, acc[ni], 0, 0, 0);
        acc[ni] = __builtin_amdgcn_mfma_f32_16x16x32_bf16(aH[ks], bL, acc[ni], 0, 0, 0);
      }
    }
    const int cmin = 64 - nb * 32;
#pragma unroll
    for (int ni = 0; ni < 3; ++ni) {
      int col = wc * 48 + ni * 16 + lr;
#pragma unroll
      for (int r = 0; r < 4; ++r) {
        int q = wr * 16 + crow + r;
        bool ok = (col >= q + 1) && (col <= q + 64) && (col >= cmin);
        p[q][col] = ok ? acc[ni][r] * 0.125f : NEGV;
      }
    }
    __syncthreads();

    const int qi = t >> 3, s = t & 7;
    float ev[12];
    float mx = -3.0e38f;
#pragma unroll
    for (int u = 0; u < 12; ++u) { ev[u] = p[qi][s + (u << 3)]; mx = fmaxf(mx, ev[u]); }
    mx = fmaxf(mx, __shfl_xor(mx, 1));
    mx = fmaxf(mx, __shfl_xor(mx, 2));
    mx = fmaxf(mx, __shfl_xor(mx, 4));
    float sum = 0.f;
#pragma unroll
    for (int u = 0; u < 12; ++u) { float e = __expf(ev[u] - mx); ev[u] = e; sum += e; }
    sum += __shfl_xor(sum, 1); sum += __shfl_xor(sum, 2); sum += __shfl_xor(sum, 4);
    float invs = 1.f / sum;
#pragma unroll
    for (int u = 0; u < 12; ++u) p[qi][s + (u << 3)] = ev[u] * invs;
    __syncthreads();

    const int wm = w >> 1, wn = w & 1;
    const int arow = wm * 16 + lr;
    f32x4 pacc[2];
#pragma unroll
    for (int b = 0; b < 2; ++b) pacc[b] = (f32x4){0.f, 0.f, 0.f, 0.f};
#pragma unroll
    for (int ks = 0; ks < 3; ++ks) {
      int k0 = ks * 32 + kg;
      float4 x0 = *reinterpret_cast<const float4*>(&p[arow][k0]);
      float4 x1 = *reinterpret_cast<const float4*>(&p[arow][k0 + 4]);
      float xv[8] = {x0.x, x0.y, x0.z, x0.w, x1.x, x1.y, x1.z, x1.w};
      bf16x8 ph, pl;
#pragma unroll
      for (int e = 0; e < 8; ++e) {
        __bf16 hh = (__bf16)xv[e];
        ph[e] = hh;
        pl[e] = (__bf16)(xv[e] - (float)hh);
      }
#pragma unroll
      for (int ni = 0; ni < 2; ++ni) {
        int d = wn * 32 + ni * 16 + lr;
        bf16x8 bv = *reinterpret_cast<const bf16x8*>(
            vtb + ((size_t)h * 64 + d) * 2112 + nb * 32 + k0);
        pacc[ni] = __builtin_amdgcn_mfma_f32_16x16x32_bf16(ph, bv, pacc[ni], 0, 0, 0);
        pacc[ni] = __builtin_amdgcn_mfma_f32_16x16x32_bf16(pl, bv, pacc[ni], 0, 0, 0);
      }
    }
#pragma unroll
    for (int ni = 0; ni < 2; ++ni) {
      int d = wn * 32 + ni * 16 + lr;
#pragma unroll
      for (int r = 0; r < 4; ++r) {
        int q = wm * 16 + crow + r;
        s_out[((size_t)h * NTOK + nb * 32 + q) * DHEAD + d] = pacc[ni][r];
      }
    }
  } else {
    // ========== fine attention: 1 wave/query, 4-lanes-per-key QK ==========
    float (*pb)[80] = reinterpret_cast<float(*)[80]>(smraw);
    int (*selb)[5]  = reinterpret_cast<int(*)[5]>(smraw + 4 * 80 * 4);

    const int u = blk - 512;
    const int h = u & 7;
    const int qq = u >> 3;
    const int wid = t >> 6;
    const int lane = t & 63;
    const int i = (qq << 2) | wid;
    const int ks = lane >> 2;        // key slot 0..15
    const int c = lane & 3;          // dim chunk 0..3 (16 elems each)

    if (lane < 5) selb[wid][lane] = sel[((h << 11) | i) * 5 + lane];
    // selb written+read by same wave: DS wave-ordered, no barrier needed

    // q chunk (16 elems) in registers; 16-way duplicated loads coalesce to 4 lines
    float qreg[16];
    {
      const bf16* qh = rqh + ((size_t)h * NTOK + i) * DHEAD + c * 16;
      const bf16* ql = rql + ((size_t)h * NTOK + i) * DHEAD + c * 16;
      bf16x8 qh0 = *reinterpret_cast<const bf16x8*>(qh);
      bf16x8 qh1 = *reinterpret_cast<const bf16x8*>(qh + 8);
      bf16x8 ql0 = *reinterpret_cast<const bf16x8*>(ql);
      bf16x8 ql1 = *reinterpret_cast<const bf16x8*>(ql + 8);
#pragma unroll
      for (int e = 0; e < 8; ++e) {
        qreg[e] = (float)qh0[e] + (float)ql0[e];
        qreg[8 + e] = (float)qh1[e] + (float)ql1[e];
      }
    }

    int sblk[5];
#pragma unroll
    for (int b = 0; b < 5; ++b) sblk[b] = selb[wid][b];

    // QK: pass b handles keys sblk[b]*16 + ks; lane loads 32B contiguous of one row
    float sims[5];
#pragma unroll
    for (int b = 0; b < 5; ++b) {
      int kb = sblk[b];
      int kbc = kb < 0 ? 0 : kb;
      int pos = (kbc << 4) + ks;
      const bf16* kp = rkh + ((size_t)h * 2112 + 64 + pos) * DHEAD + c * 16;
      bf16x8 k0v = *reinterpret_cast<const bf16x8*>(kp);
      bf16x8 k1v = *reinterpret_cast<const bf16x8*>(kp + 8);
      float d = 0.f;
#pragma unroll
      for (int e = 0; e < 8; ++e) {
        d = fmaf(qreg[e], (float)k0v[e], d);
        d = fmaf(qreg[8 + e], (float)k1v[e], d);
      }
      d += __shfl_xor(d, 1);
      d += __shfl_xor(d, 2);
      bool valid = (kb >= 0) && (((kb << 4) + ks) <= i);
      sims[b] = valid ? d * 0.125f : NEGV;
    }

    // softmax over 80: xor 4/8/16/32 covers all 16 key-slots without duplication
    float mx = sims[0];
#pragma unroll
    for (int b = 1; b < 5; ++b) mx = fmaxf(mx, sims[b]);
    mx = fmaxf(mx, __shfl_xor(mx, 4));
    mx = fmaxf(mx, __shfl_xor(mx, 8));
    mx = fmaxf(mx, __shfl_xor(mx, 16));
    mx = fmaxf(mx, __shfl_xor(mx, 32));
    float ex[5], S = 0.f;
#pragma unroll
    for (int b = 0; b < 5; ++b) { ex[b] = __expf(sims[b] - mx); S += ex[b]; }
    S += __shfl_xor(S, 4);
    S += __shfl_xor(S, 8);
    S += __shfl_xor(S, 16);
    S += __shfl_xor(S, 32);
    float invs = 1.f / S;
    if (c == 0) {
#pragma unroll
      for (int b = 0; b < 5; ++b) pb[wid][b * 16 + ks] = ex[b] * invs;
    }
    // same wave writes & reads pb[wid]: DS ops wave-ordered, no barrier needed

    // PV: lane = dim d; p broadcast from LDS, coalesced v loads
    float acc = 0.f;
#pragma unroll
    for (int b = 0; b < 5; ++b) {
      int kb = sblk[b];
      if (kb < 0) continue;
      const bf16* vr = vbh + ((size_t)h * NTOK + ((size_t)kb << 4)) * DHEAD + lane;
#pragma unroll
      for (int uu = 0; uu < 16; ++uu)
        acc = fmaf(pb[wid][b * 16 + uu], __bfloat162float(vr[(size_t)uu * DHEAD]), acc);
    }
    f_out[((size_t)h * NTOK + i) * DHEAD + lane] = acc;
  }
}

// ---------------- fused strat + combine: one block per token ----------------
__global__ __launch_bounds__(256) void k_combine2(
    const bf16* __restrict__ Ah, const bf16* __restrict__ Al,
    const float* __restrict__ W, const float* __restrict__ bias,
    const float* __restrict__ c_out, const float* __restrict__ f_out,
    const float* __restrict__ s_out, bf16* __restrict__ comb) {
  const int i = blockIdx.x;
  const int t = threadIdx.x;
  __shared__ float hs[DMODEL];
  __shared__ float st[24];
  size_t ro = (size_t)i * DMODEL;
#pragma unroll
  for (int u = 0; u < 2; ++u) {
    int c = t + u * 256;
    hs[c] = __bfloat162float(Ah[ro + c]) + __bfloat162float(Al[ro + c]);
  }
  __syncthreads();
  if (t < 192) {
    int c = t >> 3, s = t & 7;
    float acc = 0.f;
    for (int u = 0; u < 64; ++u) {
      int e = s * 64 + u;
      acc = fmaf(hs[e], W[(size_t)e * 24 + c], acc);
    }
    acc += __shfl_xor(acc, 1);
    acc += __shfl_xor(acc, 2);
    acc += __shfl_xor(acc, 4);
    if (s == 0) st[c] = 1.f / (1.f + expf(-(acc + bias[c])));
  }
  __syncthreads();
#pragma unroll
  for (int u = 0; u < 2; ++u) {
    int c = t + u * 256;
    int h = c >> 6, d = c & 63;
    size_t a = ((size_t)h * NTOK + i) * DHEAD + d;
    comb[ro + c] = __float2bfloat16(st[h * 3] * c_out[a] + st[h * 3 + 1] * f_out[a]
                                    + st[h * 3 + 2] * s_out[a]);
  }
}

extern "C" void kernel_launch(void* const* d_in, const int* in_sizes, int n_in,
                              void* d_out, int out_size, void* d_ws, size_t ws_size,
                              hipStream_t stream) {
  const float* x      = (const float*)d_in[0];
  const float* g_norm = (const float*)d_in[1];
  const float* w_qkv  = (const float*)d_in[2];
  const float* k_pos  = (const float*)d_in[3];
  const float* v_pos  = (const float*)d_in[4];
  const float* mem_kv = (const float*)d_in[5];
  const float* k_w1   = (const float*)d_in[6];
  const float* k_b1   = (const float*)d_in[7];
  const float* k_w2   = (const float*)d_in[8];
  const float* k_b2   = (const float*)d_in[9];
  const float* v_w1   = (const float*)d_in[10];
  const float* v_b1   = (const float*)d_in[11];
  const float* v_w2   = (const float*)d_in[12];
  const float* v_b2   = (const float*)d_in[13];
  const float* w_comb = (const float*)d_in[14];
  const float* b_comb = (const float*)d_in[15];
  const float* w_out  = (const float*)d_in[16];
  float* out = (float*)d_out;
  char* wsb = (char*)d_ws;

  bf16* WQKV_H = (bf16*)(wsb + B_WQKV_H);
  bf16* WQKV_L = (bf16*)(wsb + B_WQKV_L);
  bf16* KW1_H  = (bf16*)(wsb + B_KW1_H);
  bf16* KW1_L  = (bf16*)(wsb + B_KW1_L);
  bf16* KW2_H  = (bf16*)(wsb + B_KW2_H);
  bf16* KW2_L  = (bf16*)(wsb + B_KW2_L);
  bf16* VW1_H  = (bf16*)(wsb + B_VW1_H);
  bf16* VW2_H  = (bf16*)(wsb + B_VW2_H);
  bf16* WOUT_H = (bf16*)(wsb + B_WOUT_H);
  bf16* HB_H   = (bf16*)(wsb + B_HB_H);
  bf16* HB_L   = (bf16*)(wsb + B_HB_L);
  bf16* QBH    = (bf16*)(wsb + B_QBH);
  bf16* QBM    = (bf16*)(wsb + B_QBM);
  bf16* QBL    = (bf16*)(wsb + B_QBL);
  float* KF    = (float*)(wsb + B_KF);
  bf16* VBH    = (bf16*)(wsb + B_VBH);
  bf16* RQH    = (bf16*)(wsb + B_RQH);
  bf16* RQL    = (bf16*)(wsb + B_RQL);
  bf16* RKH    = (bf16*)(wsb + B_RKH);
  bf16* RKL    = (bf16*)(wsb + B_RKL);
  bf16* VTB    = (bf16*)(wsb + B_VTB);
  bf16* CKT_H  = (bf16*)(wsb + B_CKT_H);
  bf16* CKT_M  = (bf16*)(wsb + B_CKT_M);
  bf16* CKT_L  = (bf16*)(wsb + B_CKT_L);
  bf16* CVT    = (bf16*)(wsb + B_CVT);
  int*   SEL   = (int*)(wsb + B_SEL);
  float* COUT  = (float*)(wsb + B_COUT);
  float* FOUT  = (float*)(wsb + B_FOUT);
  float* SOUT  = (float*)(wsb + B_SOUT);
  bf16* KW_H   = (bf16*)(wsb + B_KW_H);
  bf16* KW_L   = (bf16*)(wsb + B_KW_L);
  bf16* VW_H   = (bf16*)(wsb + B_VW_H);
  bf16* HID_H  = (bf16*)(wsb + B_HID_H);
  bf16* HID_L  = (bf16*)(wsb + B_HID_L);
  bf16* HIDV   = (bf16*)(wsb + B_HIDV);
  bf16* COMBB  = (bf16*)(wsb + B_COMBB);

  // 1. setup: weight splits + pads + mem fill + rmsnorm
  k_setup<<<5378, 256, 0, stream>>>(x, g_norm, w_qkv, k_w1, k_w2, v_w1, v_w2, w_out, mem_kv,
                                    WQKV_H, WQKV_L, KW1_H, KW1_L, KW2_H, KW2_L,
                                    VW1_H, VW2_H, WOUT_H, HB_H, HB_L,
                                    RKH, RKL, VTB, CKT_H, CKT_M, CKT_L, CVT);
  // 2. qkv: LDS-staged 128x64, swizzled + T14, fused split/scatter
  k_qkv<<<384, 256, 0, stream>>>(HB_H, HB_L, WQKV_H, WQKV_L, KF, QBH, QBM, QBL, VBH);
  // 3. post: rope + v-transpose + windows
  k_post<<<10432, 256, 0, stream>>>(QBH, QBM, QBL, KF, VBH, k_pos, v_pos,
                                    RQH, RQL, RKH, RKL, VTB, KW_H, KW_L, VW_H);
  // 4. merged MLP1: LDS-staged, swizzled + T14; HIDV overlays dead KF
  k_mlp1<<<512, 256, 0, stream>>>(KW_H, KW_L, KW1_H, KW1_L, k_b1,
                                  VW_H, VW1_H, v_b1, HID_H, HID_L, HIDV);
  // 5. merged MLP2 -> ckT hi/mid/lo + cvT
  k_mlp2<<<dim3(1, 32, 2), 256, 0, stream>>>(HID_H, HID_L, KW2_H, KW2_L, k_b2,
                                             HIDV, VW2_H, v_b2, CKT_H, CKT_M, CKT_L, CVT);
  // 6. compression attention + selection (head-per-XCD, 512 blocks)
  k_comp_attn<<<512, 256, 0, stream>>>(QBH, QBM, QBL, CKT_H, CKT_M, CKT_L, CVT, COUT, SEL);
  // 7. fused slide + fine attention (head-per-XCD, 4-lane-per-key fine QK)
  k_fs_attn<<<4608, 256, 0, stream>>>(RQH, RQL, RKH, RKL, VBH, VTB, SEL, FOUT, SOUT);
  // 8. fused strat + combine
  k_combine2<<<NTOK, 256, 0, stream>>>(HB_H, HB_L, w_comb, b_comb, COUT, FOUT, SOUT, COMBB);
  // 9. output projection
  k_cgemm<0, 0><<<dim3(8, 32), 256, 0, stream>>>(
      COMBB, nullptr, WOUT_H, nullptr, nullptr, out, NTOK, DMODEL, DMODEL);
}

// Round 19
// 189.225 us; speedup vs baseline: 1.6190x; 1.0203x over previous
//
#include <hip/hip_runtime.h>
#include <hip/hip_bf16.h>
#include <cstddef>

#define NTOK 2048
#define DMODEL 512
#define NHEAD 8
#define DHEAD 64
#define NWIN 254          // (2048-16)/8 + 1
#define CDIM 1024         // CB*DH
#define NEGV -1000000000.0f

typedef __attribute__((ext_vector_type(8))) __bf16 bf16x8;
typedef __attribute__((ext_vector_type(4))) float f32x4;
typedef __hip_bfloat16 bf16;

// ---------------- workspace layout (byte offsets) ----------------
static const size_t B_WQKV_H = 0;          // 1536*512*2
static const size_t B_WQKV_L = 1572864;
static const size_t B_KW1_H  = 3145728;    // 1024*1024*2
static const size_t B_KW1_L  = 5242880;
static const size_t B_KW2_H  = 7340032;    // 64*1024*2
static const size_t B_KW2_L  = 7471104;
static const size_t B_VW1_H  = 7602176;
static const size_t B_VW2_H  = 9699328;
static const size_t B_WOUT_H = 9830400;    // 512*512*2
static const size_t B_HB_H   = 10354688;   // 2048*512*2
static const size_t B_HB_L   = 12451840;
static const size_t B_QBH    = 14548992;   // 8*2048*64*2 (non-roped q, hi)
static const size_t B_QBL    = 16646144;   // (lo, 3rd term)
static const size_t B_KF     = 18743296;   // 8*2048*64*4 (k fp32; dead after k_post -> HIDV)
static const size_t B_VBH    = 22937600;   // 8*2048*64*2
static const size_t B_RQH    = 25034752;   // roped q hi/lo
static const size_t B_RQL    = 27131904;
static const size_t B_RKH    = 29229056;   // 8*2112*64*2 (roped k, 64 zero-pad rows front)
static const size_t B_RKL    = 31391744;
static const size_t B_VTB    = 33554432;   // 8*64*2112*2 (v^T, 64 zero-pad cols front)
static const size_t B_CKT_H  = 35717120;   // 8*256*64*2 (compressed k rows, j=0 mem)
static const size_t B_CKT_L  = 35979264;
static const size_t B_CVT    = 36241408;   // 8*64*256*2 (compressed v transposed)
static const size_t B_SEL    = 36700160;   // 8*2048*5*4
static const size_t B_COUT   = 37027840;   // 4194304 (overlays KW_H)
static const size_t B_FOUT   = 41222144;   // 4194304 (overlays KW_L)
static const size_t B_SOUT   = 45416448;   // 4194304 (overlays VW_H)
static const size_t B_KW_H   = B_COUT;     // 2032*1024*2 = 4161536
static const size_t B_KW_L   = B_FOUT;
static const size_t B_VW_H   = B_SOUT;
static const size_t B_HID_H  = 49610752;   // 4161536 (k hidden hi)
static const size_t B_HID_L  = 53772288;   // 4161536 (k hidden lo)
static const size_t B_QBM    = 57933824;   // 8*2048*64*2 (q mid term)
static const size_t B_CKT_M  = 60030976;   // 8*256*64*2
static const size_t B_HIDV   = B_KF;       // v hidden hi (4161536 <= 4194304, KF dead)
static const size_t B_COMBB  = B_HID_H;    // 2097152 (after MLPs dead)

// ================= 32x32-per-wave GEMM core (64x64 block tile, K sub-range) =================
template <int COMP>
__device__ __forceinline__ void gemm_tile(
    const bf16* __restrict__ Ah, const bf16* __restrict__ Al,
    const bf16* __restrict__ Wh, const bf16* __restrict__ Wl,
    int M, int K, int kbeg, int kend, int row_base, int col_base, int lr, int kg,
    f32x4 accs[2][2]) {
  int ar0 = row_base + lr;       if (ar0 > M - 1) ar0 = M - 1;
  int ar1 = row_base + 16 + lr;  if (ar1 > M - 1) ar1 = M - 1;
  const size_t a0o = (size_t)ar0 * K + kg;
  const size_t a1o = (size_t)ar1 * K + kg;
  const size_t b0o = (size_t)(col_base + lr) * K + kg;
  const size_t b1o = (size_t)(col_base + 16 + lr) * K + kg;
  f32x4 acc00 = {}, acc01 = {}, acc10 = {}, acc11 = {};
  for (int k0 = kbeg; k0 < kend; k0 += 32) {
    bf16x8 ah0 = *reinterpret_cast<const bf16x8*>(Ah + a0o + k0);
    bf16x8 ah1 = *reinterpret_cast<const bf16x8*>(Ah + a1o + k0);
    bf16x8 bh0 = *reinterpret_cast<const bf16x8*>(Wh + b0o + k0);
    bf16x8 bh1 = *reinterpret_cast<const bf16x8*>(Wh + b1o + k0);
    acc00 = __builtin_amdgcn_mfma_f32_16x16x32_bf16(ah0, bh0, acc00, 0, 0, 0);
    acc01 = __builtin_amdgcn_mfma_f32_16x16x32_bf16(ah0, bh1, acc01, 0, 0, 0);
    acc10 = __builtin_amdgcn_mfma_f32_16x16x32_bf16(ah1, bh0, acc10, 0, 0, 0);
    acc11 = __builtin_amdgcn_mfma_f32_16x16x32_bf16(ah1, bh1, acc11, 0, 0, 0);
    if constexpr (COMP) {
      bf16x8 al0 = *reinterpret_cast<const bf16x8*>(Al + a0o + k0);
      bf16x8 al1 = *reinterpret_cast<const bf16x8*>(Al + a1o + k0);
      bf16x8 bl0 = *reinterpret_cast<const bf16x8*>(Wl + b0o + k0);
      bf16x8 bl1 = *reinterpret_cast<const bf16x8*>(Wl + b1o + k0);
      acc00 = __builtin_amdgcn_mfma_f32_16x16x32_bf16(ah0, bl0, acc00, 0, 0, 0);
      acc01 = __builtin_amdgcn_mfma_f32_16x16x32_bf16(ah0, bl1, acc01, 0, 0, 0);
      acc10 = __builtin_amdgcn_mfma_f32_16x16x32_bf16(ah1, bl0, acc10, 0, 0, 0);
      acc11 = __builtin_amdgcn_mfma_f32_16x16x32_bf16(ah1, bl1, acc11, 0, 0, 0);
      acc00 = __builtin_amdgcn_mfma_f32_16x16x32_bf16(al0, bh0, acc00, 0, 0, 0);
      acc01 = __builtin_amdgcn_mfma_f32_16x16x32_bf16(al0, bh1, acc01, 0, 0, 0);
      acc10 = __builtin_amdgcn_mfma_f32_16x16x32_bf16(al1, bh0, acc10, 0, 0, 0);
      acc11 = __builtin_amdgcn_mfma_f32_16x16x32_bf16(al1, bh1, acc11, 0, 0, 0);
    }
  }
  accs[0][0] = acc00; accs[0][1] = acc01; accs[1][0] = acc10; accs[1][1] = acc11;
}

// ---------------- generic GEMM kernel (fp32 out; out-proj) ----------------
template <int EPI, int COMP>
__global__ __launch_bounds__(256) void k_cgemm(
    const bf16* __restrict__ Ah, const bf16* __restrict__ Al,
    const bf16* __restrict__ Wh, const bf16* __restrict__ Wl,
    const float* __restrict__ bias, float* __restrict__ Cf,
    int M, int K, int N) {
  const int lane = threadIdx.x & 63;
  const int w = threadIdx.x >> 6;
  const int wr = w >> 1, wc = w & 1;
  const int row_base = (blockIdx.y << 6) + (wr << 5);
  const int col_base = (blockIdx.x << 6) + (wc << 5);
  const int lr = lane & 15;
  const int kg = (lane >> 4) << 3;
  const int crow = (lane >> 4) << 2;

  f32x4 accs[2][2];
  gemm_tile<COMP>(Ah, Al, Wh, Wl, M, K, 0, K, row_base, col_base, lr, kg, accs);

#pragma unroll
  for (int mi = 0; mi < 2; ++mi) {
#pragma unroll
    for (int ni = 0; ni < 2; ++ni) {
      int col = col_base + (ni << 4) + lr;
      float bv = bias ? bias[col] : 0.f;
#pragma unroll
      for (int r = 0; r < 4; ++r) {
        int row = row_base + (mi << 4) + crow + r;
        if (row < M) {
          float vv = accs[mi][ni][r] + bv;
          if (EPI == 1) vv = fmaxf(vv, 0.f);
          Cf[(size_t)row * N + col] = vv;
        }
      }
    }
  }
}

#define LDP 40

// ---------------- qkv GEMM: LDS-staged 128x64, XOR chunk swizzle + T14 split ----------------
__global__ __launch_bounds__(256, 2) void k_qkv(
    const bf16* __restrict__ Ah, const bf16* __restrict__ Al,
    const bf16* __restrict__ Wh, const bf16* __restrict__ Wl,
    float* __restrict__ KFo, bf16* __restrict__ QH, bf16* __restrict__ QM,
    bf16* __restrict__ QL, bf16* __restrict__ VB) {
  __shared__ bf16 sAh[128 * LDP];
  __shared__ bf16 sAl[128 * LDP];
  __shared__ bf16 sBh[64 * LDP];
  __shared__ bf16 sBl[64 * LDP];

  const int t = threadIdx.x;
  const int lane = t & 63, w = t >> 6;
  const int wr = w >> 1, wc = w & 1;
  const int lr = lane & 15;
  const int kg = (lane >> 4) << 3;
  const int crow = (lane >> 4) << 2;
  const int id = blockIdx.x;
  const int rt = (id & 7) + ((id >= 192) ? 8 : 0);
  const int ct = (id >> 3) % 24;
  const int row0 = rt << 7;
  const int col0 = ct << 6;

  const int qa0 = t,        ar0s = qa0 >> 2, as0 = qa0 & 3;
  const int qa1 = t + 256,  ar1s = qa1 >> 2, as1 = qa1 & 3;
  const int gr0 = row0 + ar0s;
  const int gr1 = row0 + ar1s;
  const int br = t >> 2, bs = t & 3;
  const int gbr = col0 + br;
  const int wA0 = (as0 ^ (ar0s & 3)) << 3;
  const int wA1 = (as1 ^ (ar1s & 3)) << 3;
  const int wB  = (bs ^ (br & 3)) << 3;
  const int rc = (((lane >> 4) ^ (lr & 3)) << 3);

  f32x4 acc[4][2];
#pragma unroll
  for (int a = 0; a < 4; ++a)
#pragma unroll
    for (int b = 0; b < 2; ++b) acc[a][b] = (f32x4){0.f, 0.f, 0.f, 0.f};

  bf16x8 rAh0 = *reinterpret_cast<const bf16x8*>(Ah + (size_t)gr0 * DMODEL + as0 * 8);
  bf16x8 rAh1 = *reinterpret_cast<const bf16x8*>(Ah + (size_t)gr1 * DMODEL + as1 * 8);
  bf16x8 rBh  = *reinterpret_cast<const bf16x8*>(Wh + (size_t)gbr * DMODEL + bs * 8);
  bf16x8 rAl0 = *reinterpret_cast<const bf16x8*>(Al + (size_t)gr0 * DMODEL + as0 * 8);
  bf16x8 rAl1 = *reinterpret_cast<const bf16x8*>(Al + (size_t)gr1 * DMODEL + as1 * 8);
  bf16x8 rBl  = *reinterpret_cast<const bf16x8*>(Wl + (size_t)gbr * DMODEL + bs * 8);

  for (int k0 = 0; k0 < DMODEL; k0 += 32) {
    *reinterpret_cast<bf16x8*>(&sAh[ar0s * LDP + wA0]) = rAh0;
    *reinterpret_cast<bf16x8*>(&sAh[ar1s * LDP + wA1]) = rAh1;
    *reinterpret_cast<bf16x8*>(&sBh[br * LDP + wB]) = rBh;
    *reinterpret_cast<bf16x8*>(&sAl[ar0s * LDP + wA0]) = rAl0;
    *reinterpret_cast<bf16x8*>(&sAl[ar1s * LDP + wA1]) = rAl1;
    *reinterpret_cast<bf16x8*>(&sBl[br * LDP + wB]) = rBl;
    __syncthreads();

    if (k0 + 32 < DMODEL) {
      const int kn = k0 + 32;
      rAh0 = *reinterpret_cast<const bf16x8*>(Ah + (size_t)gr0 * DMODEL + kn + as0 * 8);
      rAh1 = *reinterpret_cast<const bf16x8*>(Ah + (size_t)gr1 * DMODEL + kn + as1 * 8);
      rBh  = *reinterpret_cast<const bf16x8*>(Wh + (size_t)gbr * DMODEL + kn + bs * 8);
      rAl0 = *reinterpret_cast<const bf16x8*>(Al + (size_t)gr0 * DMODEL + kn + as0 * 8);
      rAl1 = *reinterpret_cast<const bf16x8*>(Al + (size_t)gr1 * DMODEL + kn + as1 * 8);
      rBl  = *reinterpret_cast<const bf16x8*>(Wl + (size_t)gbr * DMODEL + kn + bs * 8);
    }

    bf16x8 fAh[4], fBh[2], fAl[4], fBl[2];
#pragma unroll
    for (int mi = 0; mi < 4; ++mi)
      fAh[mi] = *reinterpret_cast<const bf16x8*>(&sAh[(wr * 64 + mi * 16 + lr) * LDP + rc]);
#pragma unroll
    for (int ni = 0; ni < 2; ++ni)
      fBh[ni] = *reinterpret_cast<const bf16x8*>(&sBh[(wc * 32 + ni * 16 + lr) * LDP + rc]);
#pragma unroll
    for (int mi = 0; mi < 4; ++mi)
      fAl[mi] = *reinterpret_cast<const bf16x8*>(&sAl[(wr * 64 + mi * 16 + lr) * LDP + rc]);
#pragma unroll
    for (int ni = 0; ni < 2; ++ni)
      fBl[ni] = *reinterpret_cast<const bf16x8*>(&sBl[(wc * 32 + ni * 16 + lr) * LDP + rc]);

#pragma unroll
    for (int mi = 0; mi < 4; ++mi)
#pragma unroll
      for (int ni = 0; ni < 2; ++ni)
        acc[mi][ni] = __builtin_amdgcn_mfma_f32_16x16x32_bf16(fAh[mi], fBh[ni], acc[mi][ni], 0, 0, 0);
#pragma unroll
    for (int mi = 0; mi < 4; ++mi)
#pragma unroll
      for (int ni = 0; ni < 2; ++ni) {
        acc[mi][ni] = __builtin_amdgcn_mfma_f32_16x16x32_bf16(fAh[mi], fBl[ni], acc[mi][ni], 0, 0, 0);
        acc[mi][ni] = __builtin_amdgcn_mfma_f32_16x16x32_bf16(fAl[mi], fBh[ni], acc[mi][ni], 0, 0, 0);
      }
    __syncthreads();
  }

#pragma unroll
  for (int mi = 0; mi < 4; ++mi) {
#pragma unroll
    for (int ni = 0; ni < 2; ++ni) {
      int col = col0 + wc * 32 + ni * 16 + lr;
      int which = col >> 9, rem = col & 511;
      int hh = rem >> 6, dd = rem & 63;
#pragma unroll
      for (int r = 0; r < 4; ++r) {
        int row = row0 + wr * 64 + mi * 16 + crow + r;
        float vv = acc[mi][ni][r];
        size_t o = ((size_t)hh * NTOK + row) * DHEAD + dd;
        if (which == 0) {
          bf16 h1 = __float2bfloat16(vv);
          float r1 = vv - __bfloat162float(h1);
          bf16 m1 = __float2bfloat16(r1);
          QH[o] = h1;
          QM[o] = m1;
          QL[o] = __float2bfloat16(r1 - __bfloat162float(m1));
        } else if (which == 1) {
          KFo[o] = vv;
        } else {
          VB[o] = __float2bfloat16(vv);
        }
      }
    }
  }
}

// ---------------- merged MLP1: LDS-staged + XOR chunk swizzle + T14 split ----------------
__global__ __launch_bounds__(256, 2) void k_mlp1(
    const bf16* __restrict__ KWh, const bf16* __restrict__ KWl,
    const bf16* __restrict__ W1h, const bf16* __restrict__ W1l,
    const float* __restrict__ kb1,
    const bf16* __restrict__ VWh, const bf16* __restrict__ VW1h,
    const float* __restrict__ vb1,
    bf16* __restrict__ HKh, bf16* __restrict__ HKl, bf16* __restrict__ HVh) {
  __shared__ bf16 sAh[128 * LDP];
  __shared__ bf16 sAl[128 * LDP];
  __shared__ bf16 sBh[64 * LDP];
  __shared__ bf16 sBl[64 * LDP];

  const int t = threadIdx.x;
  const int lane = t & 63, w = t >> 6;
  const int wr = w >> 1, wc = w & 1;
  const int lr = lane & 15;
  const int kg = (lane >> 4) << 3;
  const int crow = (lane >> 4) << 2;
  const int M = NHEAD * NWIN;  // 2032
  const int id = blockIdx.x;
  const bool kpath = (id < 256);
  const int u = kpath ? id : id - 256;
  const int rt = (u & 7) + ((u >= 128) ? 8 : 0);
  const int ct = (u >> 3) & 15;
  const int row0 = rt << 7;
  const int col0 = ct << 6;

  const bf16* Ah = kpath ? KWh : VWh;
  const bf16* Bh = kpath ? W1h : VW1h;

  const int qa0 = t,        ar0s = qa0 >> 2, as0 = qa0 & 3;
  const int qa1 = t + 256,  ar1s = qa1 >> 2, as1 = qa1 & 3;
  int gr0 = row0 + ar0s; if (gr0 > M - 1) gr0 = M - 1;
  int gr1 = row0 + ar1s; if (gr1 > M - 1) gr1 = M - 1;
  const int br = t >> 2, bs = t & 3;
  const int gbr = col0 + br;
  const int wA0 = (as0 ^ (ar0s & 3)) << 3;
  const int wA1 = (as1 ^ (ar1s & 3)) << 3;
  const int wB  = (bs ^ (br & 3)) << 3;
  const int rc = (((lane >> 4) ^ (lr & 3)) << 3);

  f32x4 acc[4][2];
#pragma unroll
  for (int a = 0; a < 4; ++a)
#pragma unroll
    for (int b = 0; b < 2; ++b) acc[a][b] = (f32x4){0.f, 0.f, 0.f, 0.f};

  bf16x8 rAh0 = *reinterpret_cast<const bf16x8*>(Ah + (size_t)gr0 * CDIM + as0 * 8);
  bf16x8 rAh1 = *reinterpret_cast<const bf16x8*>(Ah + (size_t)gr1 * CDIM + as1 * 8);
  bf16x8 rBh  = *reinterpret_cast<const bf16x8*>(Bh + (size_t)gbr * CDIM + bs * 8);
  bf16x8 rAl0, rAl1, rBl;
  if (kpath) {
    rAl0 = *reinterpret_cast<const bf16x8*>(KWl + (size_t)gr0 * CDIM + as0 * 8);
    rAl1 = *reinterpret_cast<const bf16x8*>(KWl + (size_t)gr1 * CDIM + as1 * 8);
    rBl  = *reinterpret_cast<const bf16x8*>(W1l + (size_t)gbr * CDIM + bs * 8);
  }

  for (int k0 = 0; k0 < CDIM; k0 += 32) {
    *reinterpret_cast<bf16x8*>(&sAh[ar0s * LDP + wA0]) = rAh0;
    *reinterpret_cast<bf16x8*>(&sAh[ar1s * LDP + wA1]) = rAh1;
    *reinterpret_cast<bf16x8*>(&sBh[br * LDP + wB]) = rBh;
    if (kpath) {
      *reinterpret_cast<bf16x8*>(&sAl[ar0s * LDP + wA0]) = rAl0;
      *reinterpret_cast<bf16x8*>(&sAl[ar1s * LDP + wA1]) = rAl1;
      *reinterpret_cast<bf16x8*>(&sBl[br * LDP + wB]) = rBl;
    }
    __syncthreads();

    if (k0 + 32 < CDIM) {
      const int kn = k0 + 32;
      rAh0 = *reinterpret_cast<const bf16x8*>(Ah + (size_t)gr0 * CDIM + kn + as0 * 8);
      rAh1 = *reinterpret_cast<const bf16x8*>(Ah + (size_t)gr1 * CDIM + kn + as1 * 8);
      rBh  = *reinterpret_cast<const bf16x8*>(Bh + (size_t)gbr * CDIM + kn + bs * 8);
      if (kpath) {
        rAl0 = *reinterpret_cast<const bf16x8*>(KWl + (size_t)gr0 * CDIM + kn + as0 * 8);
        rAl1 = *reinterpret_cast<const bf16x8*>(KWl + (size_t)gr1 * CDIM + kn + as1 * 8);
        rBl  = *reinterpret_cast<const bf16x8*>(W1l + (size_t)gbr * CDIM + kn + bs * 8);
      }
    }

    bf16x8 fAh[4], fBh[2], fAl[4], fBl[2];
#pragma unroll
    for (int mi = 0; mi < 4; ++mi)
      fAh[mi] = *reinterpret_cast<const bf16x8*>(&sAh[(wr * 64 + mi * 16 + lr) * LDP + rc]);
#pragma unroll
    for (int ni = 0; ni < 2; ++ni)
      fBh[ni] = *reinterpret_cast<const bf16x8*>(&sBh[(wc * 32 + ni * 16 + lr) * LDP + rc]);
    if (kpath) {
#pragma unroll
      for (int mi = 0; mi < 4; ++mi)
        fAl[mi] = *reinterpret_cast<const bf16x8*>(&sAl[(wr * 64 + mi * 16 + lr) * LDP + rc]);
#pragma unroll
      for (int ni = 0; ni < 2; ++ni)
        fBl[ni] = *reinterpret_cast<const bf16x8*>(&sBl[(wc * 32 + ni * 16 + lr) * LDP + rc]);
    }

#pragma unroll
    for (int mi = 0; mi < 4; ++mi)
#pragma unroll
      for (int ni = 0; ni < 2; ++ni)
        acc[mi][ni] = __builtin_amdgcn_mfma_f32_16x16x32_bf16(fAh[mi], fBh[ni], acc[mi][ni], 0, 0, 0);
    if (kpath) {
#pragma unroll
      for (int mi = 0; mi < 4; ++mi)
#pragma unroll
        for (int ni = 0; ni < 2; ++ni) {
          acc[mi][ni] = __builtin_amdgcn_mfma_f32_16x16x32_bf16(fAh[mi], fBl[ni], acc[mi][ni], 0, 0, 0);
          acc[mi][ni] = __builtin_amdgcn_mfma_f32_16x16x32_bf16(fAl[mi], fBh[ni], acc[mi][ni], 0, 0, 0);
        }
    }
    __syncthreads();
  }

#pragma unroll
  for (int mi = 0; mi < 4; ++mi) {
#pragma unroll
    for (int ni = 0; ni < 2; ++ni) {
      int col = col0 + wc * 32 + ni * 16 + lr;
      float bv = kpath ? kb1[col] : vb1[col];
#pragma unroll
      for (int r = 0; r < 4; ++r) {
        int row = row0 + wr * 64 + mi * 16 + crow + r;
        if (row < M) {
          float vv = fmaxf(acc[mi][ni][r] + bv, 0.f);
          size_t o = (size_t)row * CDIM + col;
          if (kpath) {
            bf16 h1 = __float2bfloat16(vv);
            HKh[o] = h1;
            HKl[o] = __float2bfloat16(vv - __bfloat162float(h1));
          } else {
            HVh[o] = __float2bfloat16(vv);
          }
        }
      }
    }
  }
}

// ------- merged MLP2, split-K: waves 0-3 K[0:512], waves 4-7 K[512:1024], LDS reduce -------
__global__ __launch_bounds__(512) void k_mlp2(
    const bf16* __restrict__ HKh, const bf16* __restrict__ HKl,
    const bf16* __restrict__ W2h, const bf16* __restrict__ W2l,
    const float* __restrict__ kb2,
    const bf16* __restrict__ HVh, const bf16* __restrict__ VW2h,
    const float* __restrict__ vb2,
    bf16* __restrict__ ckh, bf16* __restrict__ ckm, bf16* __restrict__ ckl,
    bf16* __restrict__ cvtb) {
  __shared__ float red[4][64][16];   // 16 KB partials
  const int t = threadIdx.x;
  const int lane = t & 63;
  const int w = t >> 6;            // 0..7
  const int kh = w >> 2;           // K-half
  const int sub = w & 3;
  const int wr = sub >> 1, wc = sub & 1;
  const int row_base = (blockIdx.y << 6) + (wr << 5);
  const int col_base = (wc << 5);
  const int lr = lane & 15;
  const int kg = (lane >> 4) << 3;
  const int crow = (lane >> 4) << 2;
  const int M = NHEAD * NWIN;
  const int kb = kh << 9, ke = kb + 512;

  f32x4 accs[2][2];
  if (blockIdx.z == 0)
    gemm_tile<1>(HKh, HKl, W2h, W2l, M, CDIM, kb, ke, row_base, col_base, lr, kg, accs);
  else
    gemm_tile<0>(HVh, nullptr, VW2h, nullptr, M, CDIM, kb, ke, row_base, col_base, lr, kg, accs);

  if (kh == 1) {
#pragma unroll
    for (int mi = 0; mi < 2; ++mi)
#pragma unroll
      for (int ni = 0; ni < 2; ++ni)
#pragma unroll
        for (int r = 0; r < 4; ++r)
          red[sub][lane][mi * 8 + ni * 4 + r] = accs[mi][ni][r];
  }
  __syncthreads();
  if (kh == 1) return;
#pragma unroll
  for (int mi = 0; mi < 2; ++mi)
#pragma unroll
    for (int ni = 0; ni < 2; ++ni)
#pragma unroll
      for (int r = 0; r < 4; ++r)
        accs[mi][ni][r] += red[sub][lane][mi * 8 + ni * 4 + r];

  const float* bias = (blockIdx.z == 0) ? kb2 : vb2;
#pragma unroll
  for (int mi = 0; mi < 2; ++mi) {
#pragma unroll
    for (int ni = 0; ni < 2; ++ni) {
      int col = col_base + (ni << 4) + lr;
      float bv = bias[col];
#pragma unroll
      for (int r = 0; r < 4; ++r) {
        int row = row_base + (mi << 4) + crow + r;
        if (row < M) {
          float vv = accs[mi][ni][r] + bv;
          int hh = row / NWIN, jj = row - hh * NWIN;
          if (blockIdx.z == 0) {
            size_t o = ((size_t)hh * 256 + 1 + jj) * 64 + col;
            bf16 h1 = __float2bfloat16(vv);
            float r1 = vv - __bfloat162float(h1);
            bf16 m1 = __float2bfloat16(r1);
            ckh[o] = h1;
            ckm[o] = m1;
            ckl[o] = __float2bfloat16(r1 - __bfloat162float(m1));
          } else {
            cvtb[((size_t)hh * 64 + col) * 256 + 1 + jj] = __float2bfloat16(vv);
          }
        }
      }
    }
  }
}

// ================= k_setup: 6 weight transposes + zpad + fillmem + rmsnorm =================
__device__ __forceinline__ void wt_tile(const float* __restrict__ W,
                                        bf16* __restrict__ WTh, bf16* __restrict__ WTl,
                                        int K, int N, int bx, int by,
                                        float (*tsh)[33]) {
  const int k0 = bx << 5, n0 = by << 5;
  const int tx = threadIdx.x & 31, ty = threadIdx.x >> 5;
#pragma unroll
  for (int r = 0; r < 4; ++r)
    tsh[ty + (r << 3)][tx] = W[(size_t)(k0 + ty + (r << 3)) * N + n0 + tx];
  __syncthreads();
#pragma unroll
  for (int r = 0; r < 4; ++r) {
    float val = tsh[tx][ty + (r << 3)];
    size_t o = (size_t)(n0 + ty + (r << 3)) * K + k0 + tx;
    bf16 h1 = __float2bfloat16(val);
    WTh[o] = h1;
    if (WTl) WTl[o] = __float2bfloat16(val - __bfloat162float(h1));
  }
}

__global__ __launch_bounds__(256) void k_setup(
    const float* __restrict__ x, const float* __restrict__ g,
    const float* __restrict__ w_qkv, const float* __restrict__ k_w1,
    const float* __restrict__ k_w2, const float* __restrict__ v_w1,
    const float* __restrict__ v_w2, const float* __restrict__ w_out,
    const float* __restrict__ memkv,
    bf16* __restrict__ WQKV_H, bf16* __restrict__ WQKV_L,
    bf16* __restrict__ KW1_H, bf16* __restrict__ KW1_L,
    bf16* __restrict__ KW2_H, bf16* __restrict__ KW2_L,
    bf16* __restrict__ VW1_H, bf16* __restrict__ VW2_H, bf16* __restrict__ WOUT_H,
    bf16* __restrict__ hbh, bf16* __restrict__ hbl,
    bf16* __restrict__ rkh, bf16* __restrict__ rkl, bf16* __restrict__ vtb,
    bf16* __restrict__ ckh, bf16* __restrict__ ckm, bf16* __restrict__ ckl,
    bf16* __restrict__ cvtb) {
  __shared__ float tsh[32][33];
  __shared__ float wsum[4];
  __shared__ float scale_s;
  const int id = blockIdx.x;
  const int t = threadIdx.x;

  if (id < 768) {
    wt_tile(w_qkv, WQKV_H, WQKV_L, DMODEL, 1536, id % 16, id / 16, tsh);
  } else if (id < 1792) {
    int u = id - 768;  wt_tile(k_w1, KW1_H, KW1_L, CDIM, CDIM, u % 32, u / 32, tsh);
  } else if (id < 1856) {
    int u = id - 1792; wt_tile(k_w2, KW2_H, KW2_L, CDIM, DHEAD, u % 32, u / 32, tsh);
  } else if (id < 2880) {
    int u = id - 1856; wt_tile(v_w1, VW1_H, nullptr, CDIM, CDIM, u % 32, u / 32, tsh);
  } else if (id < 2944) {
    int u = id - 2880; wt_tile(v_w2, VW2_H, nullptr, CDIM, DHEAD, u % 32, u / 32, tsh);
  } else if (id < 3200) {
    int u = id - 2944; wt_tile(w_out, WOUT_H, nullptr, DMODEL, DMODEL, u % 16, u / 16, tsh);
  } else if (id < 3328) {
    int idx = (id - 3200) * 256 + t;   // [0, 32768)
    int h = idx >> 12, r = (idx >> 6) & 63, c = idx & 63;
    bf16 z = __float2bfloat16(0.f);
    rkh[((size_t)h * 2112 + r) * 64 + c] = z;
    rkl[((size_t)h * 2112 + r) * 64 + c] = z;
    vtb[((size_t)h * 64 + r) * 2112 + c] = z;
  } else if (id < 3330) {
    int u = (id - 3328) * 256 + t;     // [0, 512)
    if (u < 512) {
      int h = u >> 6, e = u & 63;
      float kv = memkv[(size_t)h * DHEAD + e];
      bf16 h1 = __float2bfloat16(kv);
      float r1 = kv - __bfloat162float(h1);
      bf16 m1 = __float2bfloat16(r1);
      ckh[((size_t)h * 256) * 64 + e] = h1;
      ckm[((size_t)h * 256) * 64 + e] = m1;
      ckl[((size_t)h * 256) * 64 + e] = __float2bfloat16(r1 - __bfloat162float(m1));
      bf16 z = __float2bfloat16(0.f);
      ckh[((size_t)h * 256 + 255) * 64 + e] = z;
      ckm[((size_t)h * 256 + 255) * 64 + e] = z;
      ckl[((size_t)h * 256 + 255) * 64 + e] = z;
      float vv = memkv[(size_t)(NHEAD + h) * DHEAD + e];
      cvtb[((size_t)h * 64 + e) * 256 + 0] = __float2bfloat16(vv);
      cvtb[((size_t)h * 64 + e) * 256 + 255] = z;
    }
  } else {
    const int row = id - 3330;
    const float* xr = x + (size_t)row * DMODEL;
    float s = 0.f;
    for (int c = t; c < DMODEL; c += 256) { float v = xr[c]; s += v * v; }
    for (int o = 32; o > 0; o >>= 1) s += __shfl_down(s, o);
    if ((t & 63) == 0) wsum[t >> 6] = s;
    __syncthreads();
    if (t == 0) {
      float tot = wsum[0] + wsum[1] + wsum[2] + wsum[3];
      scale_s = rsqrtf(tot * (1.f / DMODEL) + 1e-6f);
    }
    __syncthreads();
    float sc = scale_s;
    for (int c = t; c < DMODEL; c += 256) {
      float v = xr[c] * sc * g[c];
      bf16 h1 = __float2bfloat16(v);
      hbh[(size_t)row * DMODEL + c] = h1;
      hbl[(size_t)row * DMODEL + c] = __float2bfloat16(v - __bfloat162float(h1));
    }
  }
}

// ================= k_post: rope + v-transpose + compression windows =================
__global__ __launch_bounds__(256) void k_post(
    const bf16* __restrict__ qbh, const bf16* __restrict__ qbm,
    const bf16* __restrict__ qbl, const float* __restrict__ kf,
    const bf16* __restrict__ vbh,
    const float* __restrict__ kpos, const float* __restrict__ vpos,
    bf16* __restrict__ rqh, bf16* __restrict__ rql,
    bf16* __restrict__ rkh, bf16* __restrict__ rkl,
    bf16* __restrict__ vtb,
    bf16* __restrict__ kwh, bf16* __restrict__ kwl, bf16* __restrict__ vwh) {
  __shared__ bf16 tile[64][65];
  const int id = blockIdx.x;
  const int t = threadIdx.x;

  if (id < 2048) {
    int idx = id * 256 + t;
    int i = idx & 31;
    int n = (idx >> 5) & (NTOK - 1);
    int h = idx >> 16;
    float ex = (float)(2 * i) * (1.f / 64.f);
    float inv = exp2f(-ex * 13.287712379549449f);
    float ang = (float)n * inv;
    float sn, cs;
    sincosf(ang, &sn, &cs);
    size_t base = ((size_t)h * NTOK + n) * DHEAD + 2 * i;
    float q1 = __bfloat162float(qbh[base]) + __bfloat162float(qbm[base]) + __bfloat162float(qbl[base]);
    float q2 = __bfloat162float(qbh[base + 1]) + __bfloat162float(qbm[base + 1]) + __bfloat162float(qbl[base + 1]);
    float r1 = q1 * cs - q2 * sn, r2 = q1 * sn + q2 * cs;
    bf16 h1 = __float2bfloat16(r1);
    rqh[base] = h1; rql[base] = __float2bfloat16(r1 - __bfloat162float(h1));
    h1 = __float2bfloat16(r2);
    rqh[base + 1] = h1; rql[base + 1] = __float2bfloat16(r2 - __bfloat162float(h1));
    float k1 = kf[base], k2 = kf[base + 1];
    float s1 = k1 * cs - k2 * sn, s2 = k1 * sn + k2 * cs;
    size_t kb = ((size_t)h * 2112 + 64 + n) * DHEAD + 2 * i;
    h1 = __float2bfloat16(s1);
    rkh[kb] = h1; rkl[kb] = __float2bfloat16(s1 - __bfloat162float(h1));
    h1 = __float2bfloat16(s2);
    rkh[kb + 1] = h1; rkl[kb + 1] = __float2bfloat16(s2 - __bfloat162float(h1));
  } else if (id < 2304) {
    int u = id - 2048;
    int h = u >> 5, n0 = (u & 31) << 6;
    int tx = t & 63, ty = t >> 6;
    for (int r = ty; r < 64; r += 4)
      tile[r][tx] = vbh[((size_t)h * NTOK + n0 + r) * DHEAD + tx];
    __syncthreads();
    for (int r = ty; r < 64; r += 4)
      vtb[((size_t)h * 64 + r) * 2112 + 64 + n0 + tx] = tile[tx][r];
  } else {
    int idx = (id - 2304) * 256 + t;   // [0, 2080768)
    int d = idx & 63;
    int c = (idx >> 6) & 15;
    int j = (idx >> 10) % NWIN;
    int h = idx / (NWIN << 10);
    int srcpos = (j << 3) + c;
    size_t src = ((size_t)h * NTOK + srcpos) * DHEAD + d;
    size_t pp = ((size_t)h * 16 + c) * DHEAD + d;
    float kv = kf[src] + kpos[pp];
    bf16 h1 = __float2bfloat16(kv);
    kwh[idx] = h1;
    kwl[idx] = __float2bfloat16(kv - __bfloat162float(h1));
    vwh[idx] = __float2bfloat16(__bfloat162float(vbh[src]) + vpos[pp]);
  }
}

// ======== merged compression + sliding attention (head-per-XCD) ========
// blk<512: compression attn + selection; blk>=512: sliding window.
// Both depend only on qkv/post/mlp2 outputs; slide fills comp's idle CUs.
__global__ __launch_bounds__(256) void k_comp_attn(
    const bf16* __restrict__ qbh, const bf16* __restrict__ qbm, const bf16* __restrict__ qbl,
    const bf16* __restrict__ ckh, const bf16* __restrict__ ckm, const bf16* __restrict__ ckl,
    const bf16* __restrict__ cvtb,
    const bf16* __restrict__ rqh, const bf16* __restrict__ rql,
    const bf16* __restrict__ rkh, const bf16* __restrict__ rkl,
    const bf16* __restrict__ vtb,
    float* __restrict__ c_out, int* __restrict__ sel, float* __restrict__ s_out) {
  __shared__ char smraw[32 * 260 * 4];   // 33280 B (comp needs all; slide 12.8KB)
  const int blk = blockIdx.x;
  const int t = threadIdx.x;

  if (blk < 512) {
    // ================= compression attention =================
    float (*p)[260] = reinterpret_cast<float(*)[260]>(smraw);
    const int h = blk & 7;
    const int i0 = (blk >> 3) << 5;
    const int w = t >> 6, lane = t & 63;
    const int lr = lane & 15, kg = (lane >> 4) << 3;
    const int crow = (lane >> 4) << 2;

    bf16x8 aH[2][2], aM[2][2], aL[2][2];
#pragma unroll
    for (int mi = 0; mi < 2; ++mi) {
      size_t qo = ((size_t)h * NTOK + i0 + mi * 16 + lr) * DHEAD + kg;
#pragma unroll
      for (int ks = 0; ks < 2; ++ks) {
        aH[mi][ks] = *reinterpret_cast<const bf16x8*>(qbh + qo + ks * 32);
        aM[mi][ks] = *reinterpret_cast<const bf16x8*>(qbm + qo + ks * 32);
        aL[mi][ks] = *reinterpret_cast<const bf16x8*>(qbl + qo + ks * 32);
      }
    }
    f32x4 acc[2][4];
#pragma unroll
    for (int a = 0; a < 2; ++a)
#pragma unroll
      for (int b = 0; b < 4; ++b) acc[a][b] = (f32x4){0.f, 0.f, 0.f, 0.f};
#pragma unroll
    for (int ni = 0; ni < 4; ++ni) {
      int col = (w << 6) + (ni << 4) + lr;
      size_t ko = ((size_t)h * 256 + col) * 64 + kg;
#pragma unroll
      for (int ks = 0; ks < 2; ++ks) {
        bf16x8 bH = *reinterpret_cast<const bf16x8*>(ckh + ko + ks * 32);
        bf16x8 bM = *reinterpret_cast<const bf16x8*>(ckm + ko + ks * 32);
        bf16x8 bL = *reinterpret_cast<const bf16x8*>(ckl + ko + ks * 32);
#pragma unroll
        for (int mi = 0; mi < 2; ++mi) {
          acc[mi][ni] = __builtin_amdgcn_mfma_f32_16x16x32_bf16(aH[mi][ks], bH, acc[mi][ni], 0, 0, 0);
          acc[mi][ni] = __builtin_amdgcn_mfma_f32_16x16x32_bf16(aH[mi][ks], bM, acc[mi][ni], 0, 0, 0);
          acc[mi][ni] = __builtin_amdgcn_mfma_f32_16x16x32_bf16(aM[mi][ks], bH, acc[mi][ni], 0, 0, 0);
          acc[mi][ni] = __builtin_amdgcn_mfma_f32_16x16x32_bf16(aH[mi][ks], bL, acc[mi][ni], 0, 0, 0);
          acc[mi][ni] = __builtin_amdgcn_mfma_f32_16x16x32_bf16(aL[mi][ks], bH, acc[mi][ni], 0, 0, 0);
          acc[mi][ni] = __builtin_amdgcn_mfma_f32_16x16x32_bf16(aM[mi][ks], bM, acc[mi][ni], 0, 0, 0);
        }
      }
    }
#pragma unroll
    for (int mi = 0; mi < 2; ++mi)
#pragma unroll
      for (int ni = 0; ni < 4; ++ni) {
        int col = (w << 6) + (ni << 4) + lr;
        int wend = (col == 0) ? -1 : ((col - 1) << 3) + 15;
#pragma unroll
        for (int r = 0; r < 4; ++r) {
          int qi = mi * 16 + crow + r;
          bool ok = (col < 255) && (wend < i0 + qi);
          p[qi][col] = ok ? acc[mi][ni][r] * 0.125f : NEGV;
        }
      }
    __syncthreads();

    const int qi = t >> 3, s = t & 7;
    float ev[32];
    float mx = -3.0e38f;
#pragma unroll
    for (int u = 0; u < 32; ++u) { ev[u] = p[qi][s + (u << 3)]; mx = fmaxf(mx, ev[u]); }
    mx = fmaxf(mx, __shfl_xor(mx, 1));
    mx = fmaxf(mx, __shfl_xor(mx, 2));
    mx = fmaxf(mx, __shfl_xor(mx, 4));
    float sum = 0.f;
#pragma unroll
    for (int u = 0; u < 32; ++u) { float e = __expf(ev[u] - mx); ev[u] = e; sum += e; }
    sum += __shfl_xor(sum, 1); sum += __shfl_xor(sum, 2); sum += __shfl_xor(sum, 4);
    float invs = 1.f / sum;
#pragma unroll
    for (int u = 0; u < 32; ++u) p[qi][s + (u << 3)] = ev[u] * invs;

    int qblk = (i0 + qi) >> 4;
    float vals[16];
#pragma unroll
    for (int u = 0; u < 16; ++u) {
      int f = (s << 4) + u;
      float v;
      if (f >= qblk || f == 127) v = NEGV;
      else v = (p[qi][2 * f + 1] + p[qi][2 * f + 2]) * 0.5f;
      vals[u] = v;
    }
    int base = ((h << 11) | (i0 + qi)) * 5;
    for (int kk = 0; kk < 4; ++kk) {
      float bv = -3.0e38f; int bi = 0;
#pragma unroll
      for (int u = 0; u < 16; ++u) {
        if (vals[u] > bv) { bv = vals[u]; bi = (s << 4) + u; }
      }
#pragma unroll
      for (int o = 1; o < 8; o <<= 1) {
        float ov = __shfl_xor(bv, o);
        int oi = __shfl_xor(bi, o);
        if (ov > bv || (ov == bv && oi < bi)) { bv = ov; bi = oi; }
      }
      if (s == 0) sel[base + kk] = (bv > -5.0e8f) ? bi : -1;
      if ((bi >> 4) == s) vals[bi & 15] = -3.0e38f;
    }
    if (s == 0) sel[base + 4] = (i0 + qi) >> 4;
    __syncthreads();

    const int wm = w >> 1, wn = w & 1;
    const int arow = wm * 16 + lr;
    f32x4 pacc[2];
#pragma unroll
    for (int b = 0; b < 2; ++b) pacc[b] = (f32x4){0.f, 0.f, 0.f, 0.f};
#pragma unroll
    for (int ks = 0; ks < 8; ++ks) {
      int k0 = ks * 32 + kg;
      float4 x0 = *reinterpret_cast<const float4*>(&p[arow][k0]);
      float4 x1 = *reinterpret_cast<const float4*>(&p[arow][k0 + 4]);
      float xv[8] = {x0.x, x0.y, x0.z, x0.w, x1.x, x1.y, x1.z, x1.w};
      bf16x8 ph, pl;
#pragma unroll
      for (int e = 0; e < 8; ++e) {
        __bf16 hh = (__bf16)xv[e];
        ph[e] = hh;
        pl[e] = (__bf16)(xv[e] - (float)hh);
      }
#pragma unroll
      for (int ni = 0; ni < 2; ++ni) {
        int d = (wn << 5) + (ni << 4) + lr;
        bf16x8 bv = *reinterpret_cast<const bf16x8*>(cvtb + ((size_t)h * 64 + d) * 256 + k0);
        pacc[ni] = __builtin_amdgcn_mfma_f32_16x16x32_bf16(ph, bv, pacc[ni], 0, 0, 0);
        pacc[ni] = __builtin_amdgcn_mfma_f32_16x16x32_bf16(pl, bv, pacc[ni], 0, 0, 0);
      }
    }
#pragma unroll
    for (int ni = 0; ni < 2; ++ni) {
      int d = (wn << 5) + (ni << 4) + lr;
#pragma unroll
      for (int r = 0; r < 4; ++r) {
        int q2 = wm * 16 + crow + r;
        c_out[((size_t)h * NTOK + i0 + q2) * DHEAD + d] = pacc[ni][r];
      }
    }
  } else {
    // ================= sliding-window: 32 queries, 96-key window =================
    float (*p)[100] = reinterpret_cast<float(*)[100]>(smraw);
    const int u = blk - 512;
    const int h = u & 7, nb = (u >> 3) & 63;
    const int w = t >> 6, lane = t & 63;
    const int lr = lane & 15, kg = (lane >> 4) << 3;
    const int crow = (lane >> 4) << 2;
    const int wr = w >> 1, wc = w & 1;

    bf16x8 aH[2], aL[2];
    {
      size_t qo = ((size_t)h * NTOK + nb * 32 + wr * 16 + lr) * DHEAD + kg;
#pragma unroll
      for (int ks = 0; ks < 2; ++ks) {
        aH[ks] = *reinterpret_cast<const bf16x8*>(rqh + qo + ks * 32);
        aL[ks] = *reinterpret_cast<const bf16x8*>(rql + qo + ks * 32);
      }
    }
    f32x4 acc[3];
#pragma unroll
    for (int a = 0; a < 3; ++a) acc[a] = (f32x4){0.f, 0.f, 0.f, 0.f};
#pragma unroll
    for (int ni = 0; ni < 3; ++ni) {
      int col = wc * 48 + ni * 16 + lr;
      size_t ko = ((size_t)h * 2112 + nb * 32 + col) * 64 + kg;
#pragma unroll
      for (int ks = 0; ks < 2; ++ks) {
        bf16x8 bH = *reinterpret_cast<const bf16x8*>(rkh + ko + ks * 32);
        bf16x8 bL = *reinterpret_cast<const bf16x8*>(rkl + ko + ks * 32);
        acc[ni] = __builtin_amdgcn_mfma_f32_16x16x32_bf16(aH[ks], bH, acc[ni], 0, 0, 0);
        acc[ni] = __builtin_amdgcn_mfma_f32_16x16x32_bf16(aL[ks], bH, acc[ni], 0, 0, 0);
        acc[ni] = __builtin_amdgcn_mfma_f32_16x16x32_bf16(aH[ks], bL, acc[ni], 0, 0, 0);
      }
    }
    const int cmin = 64 - nb * 32;
#pragma unroll
    for (int ni = 0; ni < 3; ++ni) {
      int col = wc * 48 + ni * 16 + lr;
#pragma unroll
      for (int r = 0; r < 4; ++r) {
        int q = wr * 16 + crow + r;
        bool ok = (col >= q + 1) && (col <= q + 64) && (col >= cmin);
        p[q][col] = ok ? acc[ni][r] * 0.125f : NEGV;
      }
    }
    __syncthreads();

    const int qi = t >> 3, s = t & 7;
    float ev[12];
    float mx = -3.0e38f;
#pragma unroll
    for (int uu = 0; uu < 12; ++uu) { ev[uu] = p[qi][s + (uu << 3)]; mx = fmaxf(mx, ev[uu]); }
    mx = fmaxf(mx, __shfl_xor(mx, 1));
    mx = fmaxf(mx, __shfl_xor(mx, 2));
    mx = fmaxf(mx, __shfl_xor(mx, 4));
    float sum = 0.f;
#pragma unroll
    for (int uu = 0; uu < 12; ++uu) { float e = __expf(ev[uu] - mx); ev[uu] = e; sum += e; }
    sum += __shfl_xor(sum, 1); sum += __shfl_xor(sum, 2); sum += __shfl_xor(sum, 4);
    float invs = 1.f / sum;
#pragma unroll
    for (int uu = 0; uu < 12; ++uu) p[qi][s + (uu << 3)] = ev[uu] * invs;
    __syncthreads();

    const int wm = w >> 1, wn = w & 1;
    const int arow = wm * 16 + lr;
    f32x4 pacc[2];
#pragma unroll
    for (int b = 0; b < 2; ++b) pacc[b] = (f32x4){0.f, 0.f, 0.f, 0.f};
#pragma unroll
    for (int ks = 0; ks < 3; ++ks) {
      int k0 = ks * 32 + kg;
      float4 x0 = *reinterpret_cast<const float4*>(&p[arow][k0]);
      float4 x1 = *reinterpret_cast<const float4*>(&p[arow][k0 + 4]);
      float xv[8] = {x0.x, x0.y, x0.z, x0.w, x1.x, x1.y, x1.z, x1.w};
      bf16x8 ph, pl;
#pragma unroll
      for (int e = 0; e < 8; ++e) {
        __bf16 hh = (__bf16)xv[e];
        ph[e] = hh;
        pl[e] = (__bf16)(xv[e] - (float)hh);
      }
#pragma unroll
      for (int ni = 0; ni < 2; ++ni) {
        int d = wn * 32 + ni * 16 + lr;
        bf16x8 bv = *reinterpret_cast<const bf16x8*>(
            vtb + ((size_t)h * 64 + d) * 2112 + nb * 32 + k0);
        pacc[ni] = __builtin_amdgcn_mfma_f32_16x16x32_bf16(ph, bv, pacc[ni], 0, 0, 0);
        pacc[ni] = __builtin_amdgcn_mfma_f32_16x16x32_bf16(pl, bv, pacc[ni], 0, 0, 0);
      }
    }
#pragma unroll
    for (int ni = 0; ni < 2; ++ni) {
      int d = wn * 32 + ni * 16 + lr;
#pragma unroll
      for (int r = 0; r < 4; ++r) {
        int q = wm * 16 + crow + r;
        s_out[((size_t)h * NTOK + nb * 32 + q) * DHEAD + d] = pacc[ni][r];
      }
    }
  }
}

// ======== fine attention only: 1 wave/query, 4-lanes-per-key QK, head-per-XCD ========
__global__ __launch_bounds__(256, 8) void k_fs_attn(
    const bf16* __restrict__ rqh, const bf16* __restrict__ rql,
    const bf16* __restrict__ rkh, const bf16* __restrict__ vbh,
    const int* __restrict__ sel, float* __restrict__ f_out) {
  __shared__ float pb[4][80];
  __shared__ int selb[4][5];
  const int blk = blockIdx.x;
  const int t = threadIdx.x;
  const int h = blk & 7;
  const int qq = blk >> 3;
  const int wid = t >> 6;
  const int lane = t & 63;
  const int i = (qq << 2) | wid;
  const int ks = lane >> 2;        // key slot 0..15
  const int c = lane & 3;          // dim chunk 0..3 (16 elems each)

  if (lane < 5) selb[wid][lane] = sel[((h << 11) | i) * 5 + lane];
  // selb written+read by same wave: DS wave-ordered, no barrier needed

  float qreg[16];
  {
    const bf16* qh = rqh + ((size_t)h * NTOK + i) * DHEAD + c * 16;
    const bf16* ql = rql + ((size_t)h * NTOK + i) * DHEAD + c * 16;
    bf16x8 qh0 = *reinterpret_cast<const bf16x8*>(qh);
    bf16x8 qh1 = *reinterpret_cast<const bf16x8*>(qh + 8);
    bf16x8 ql0 = *reinterpret_cast<const bf16x8*>(ql);
    bf16x8 ql1 = *reinterpret_cast<const bf16x8*>(ql + 8);
#pragma unroll
    for (int e = 0; e < 8; ++e) {
      qreg[e] = (float)qh0[e] + (float)ql0[e];
      qreg[8 + e] = (float)qh1[e] + (float)ql1[e];
    }
  }

  int sblk[5];
#pragma unroll
  for (int b = 0; b < 5; ++b) sblk[b] = selb[wid][b];

  float sims[5];
#pragma unroll
  for (int b = 0; b < 5; ++b) {
    int kb = sblk[b];
    int kbc = kb < 0 ? 0 : kb;
    int pos = (kbc << 4) + ks;
    const bf16* kp = rkh + ((size_t)h * 2112 + 64 + pos) * DHEAD + c * 16;
    bf16x8 k0v = *reinterpret_cast<const bf16x8*>(kp);
    bf16x8 k1v = *reinterpret_cast<const bf16x8*>(kp + 8);
    float d = 0.f;
#pragma unroll
    for (int e = 0; e < 8; ++e) {
      d = fmaf(qreg[e], (float)k0v[e], d);
      d = fmaf(qreg[8 + e], (float)k1v[e], d);
    }
    d += __shfl_xor(d, 1);
    d += __shfl_xor(d, 2);
    bool valid = (kb >= 0) && (((kb << 4) + ks) <= i);
    sims[b] = valid ? d * 0.125f : NEGV;
  }

  float mx = sims[0];
#pragma unroll
  for (int b = 1; b < 5; ++b) mx = fmaxf(mx, sims[b]);
  mx = fmaxf(mx, __shfl_xor(mx, 4));
  mx = fmaxf(mx, __shfl_xor(mx, 8));
  mx = fmaxf(mx, __shfl_xor(mx, 16));
  mx = fmaxf(mx, __shfl_xor(mx, 32));
  float ex[5], S = 0.f;
#pragma unroll
  for (int b = 0; b < 5; ++b) { ex[b] = __expf(sims[b] - mx); S += ex[b]; }
  S += __shfl_xor(S, 4);
  S += __shfl_xor(S, 8);
  S += __shfl_xor(S, 16);
  S += __shfl_xor(S, 32);
  float invs = 1.f / S;
  if (c == 0) {
#pragma unroll
    for (int b = 0; b < 5; ++b) pb[wid][b * 16 + ks] = ex[b] * invs;
  }
  // same wave writes & reads pb[wid]: DS ops wave-ordered, no barrier needed

  float acc = 0.f;
#pragma unroll
  for (int b = 0; b < 5; ++b) {
    int kb = sblk[b];
    if (kb < 0) continue;
    const bf16* vr = vbh + ((size_t)h * NTOK + ((size_t)kb << 4)) * DHEAD + lane;
#pragma unroll
    for (int uu = 0; uu < 16; ++uu)
      acc = fmaf(pb[wid][b * 16 + uu], __bfloat162float(vr[(size_t)uu * DHEAD]), acc);
  }
  f_out[((size_t)h * NTOK + i) * DHEAD + lane] = acc;
}

// ---------------- fused strat + combine: one block per token ----------------
__global__ __launch_bounds__(256) void k_combine2(
    const bf16* __restrict__ Ah, const bf16* __restrict__ Al,
    const float* __restrict__ W, const float* __restrict__ bias,
    const float* __restrict__ c_out, const float* __restrict__ f_out,
    const float* __restrict__ s_out, bf16* __restrict__ comb) {
  const int i = blockIdx.x;
  const int t = threadIdx.x;
  __shared__ float hs[DMODEL];
  __shared__ float st[24];
  size_t ro = (size_t)i * DMODEL;
#pragma unroll
  for (int u = 0; u < 2; ++u) {
    int c = t + u * 256;
    hs[c] = __bfloat162float(Ah[ro + c]) + __bfloat162float(Al[ro + c]);
  }
  __syncthreads();
  if (t < 192) {
    int c = t >> 3, s = t & 7;
    float acc = 0.f;
    for (int u = 0; u < 64; ++u) {
      int e = s * 64 + u;
      acc = fmaf(hs[e], W[(size_t)e * 24 + c], acc);
    }
    acc += __shfl_xor(acc, 1);
    acc += __shfl_xor(acc, 2);
    acc += __shfl_xor(acc, 4);
    if (s == 0) st[c] = 1.f / (1.f + expf(-(acc + bias[c])));
  }
  __syncthreads();
#pragma unroll
  for (int u = 0; u < 2; ++u) {
    int c = t + u * 256;
    int h = c >> 6, d = c & 63;
    size_t a = ((size_t)h * NTOK + i) * DHEAD + d;
    comb[ro + c] = __float2bfloat16(st[h * 3] * c_out[a] + st[h * 3 + 1] * f_out[a]
                                    + st[h * 3 + 2] * s_out[a]);
  }
}

extern "C" void kernel_launch(void* const* d_in, const int* in_sizes, int n_in,
                              void* d_out, int out_size, void* d_ws, size_t ws_size,
                              hipStream_t stream) {
  const float* x      = (const float*)d_in[0];
  const float* g_norm = (const float*)d_in[1];
  const float* w_qkv  = (const float*)d_in[2];
  const float* k_pos  = (const float*)d_in[3];
  const float* v_pos  = (const float*)d_in[4];
  const float* mem_kv = (const float*)d_in[5];
  const float* k_w1   = (const float*)d_in[6];
  const float* k_b1   = (const float*)d_in[7];
  const float* k_w2   = (const float*)d_in[8];
  const float* k_b2   = (const float*)d_in[9];
  const float* v_w1   = (const float*)d_in[10];
  const float* v_b1   = (const float*)d_in[11];
  const float* v_w2   = (const float*)d_in[12];
  const float* v_b2   = (const float*)d_in[13];
  const float* w_comb = (const float*)d_in[14];
  const float* b_comb = (const float*)d_in[15];
  const float* w_out  = (const float*)d_in[16];
  float* out = (float*)d_out;
  char* wsb = (char*)d_ws;

  bf16* WQKV_H = (bf16*)(wsb + B_WQKV_H);
  bf16* WQKV_L = (bf16*)(wsb + B_WQKV_L);
  bf16* KW1_H  = (bf16*)(wsb + B_KW1_H);
  bf16* KW1_L  = (bf16*)(wsb + B_KW1_L);
  bf16* KW2_H  = (bf16*)(wsb + B_KW2_H);
  bf16* KW2_L  = (bf16*)(wsb + B_KW2_L);
  bf16* VW1_H  = (bf16*)(wsb + B_VW1_H);
  bf16* VW2_H  = (bf16*)(wsb + B_VW2_H);
  bf16* WOUT_H = (bf16*)(wsb + B_WOUT_H);
  bf16* HB_H   = (bf16*)(wsb + B_HB_H);
  bf16* HB_L   = (bf16*)(wsb + B_HB_L);
  bf16* QBH    = (bf16*)(wsb + B_QBH);
  bf16* QBM    = (bf16*)(wsb + B_QBM);
  bf16* QBL    = (bf16*)(wsb + B_QBL);
  float* KF    = (float*)(wsb + B_KF);
  bf16* VBH    = (bf16*)(wsb + B_VBH);
  bf16* RQH    = (bf16*)(wsb + B_RQH);
  bf16* RQL    = (bf16*)(wsb + B_RQL);
  bf16* RKH    = (bf16*)(wsb + B_RKH);
  bf16* RKL    = (bf16*)(wsb + B_RKL);
  bf16* VTB    = (bf16*)(wsb + B_VTB);
  bf16* CKT_H  = (bf16*)(wsb + B_CKT_H);
  bf16* CKT_M  = (bf16*)(wsb + B_CKT_M);
  bf16* CKT_L  = (bf16*)(wsb + B_CKT_L);
  bf16* CVT    = (bf16*)(wsb + B_CVT);
  int*   SEL   = (int*)(wsb + B_SEL);
  float* COUT  = (float*)(wsb + B_COUT);
  float* FOUT  = (float*)(wsb + B_FOUT);
  float* SOUT  = (float*)(wsb + B_SOUT);
  bf16* KW_H   = (bf16*)(wsb + B_KW_H);
  bf16* KW_L   = (bf16*)(wsb + B_KW_L);
  bf16* VW_H   = (bf16*)(wsb + B_VW_H);
  bf16* HID_H  = (bf16*)(wsb + B_HID_H);
  bf16* HID_L  = (bf16*)(wsb + B_HID_L);
  bf16* HIDV   = (bf16*)(wsb + B_HIDV);
  bf16* COMBB  = (bf16*)(wsb + B_COMBB);

  // 1. setup: weight splits + pads + mem fill + rmsnorm
  k_setup<<<5378, 256, 0, stream>>>(x, g_norm, w_qkv, k_w1, k_w2, v_w1, v_w2, w_out, mem_kv,
                                    WQKV_H, WQKV_L, KW1_H, KW1_L, KW2_H, KW2_L,
                                    VW1_H, VW2_H, WOUT_H, HB_H, HB_L,
                                    RKH, RKL, VTB, CKT_H, CKT_M, CKT_L, CVT);
  // 2. qkv: LDS-staged 128x64, swizzled + T14, fused split/scatter
  k_qkv<<<384, 256, 0, stream>>>(HB_H, HB_L, WQKV_H, WQKV_L, KF, QBH, QBM, QBL, VBH);
  // 3. post: rope + v-transpose + windows
  k_post<<<10432, 256, 0, stream>>>(QBH, QBM, QBL, KF, VBH, k_pos, v_pos,
                                    RQH, RQL, RKH, RKL, VTB, KW_H, KW_L, VW_H);
  // 4. merged MLP1: LDS-staged, swizzled + T14; HIDV overlays dead KF
  k_mlp1<<<512, 256, 0, stream>>>(KW_H, KW_L, KW1_H, KW1_L, k_b1,
                                  VW_H, VW1_H, v_b1, HID_H, HID_L, HIDV);
  // 5. merged MLP2 (split-K, 8 waves) -> ckT hi/mid/lo + cvT
  k_mlp2<<<dim3(1, 32, 2), 512, 0, stream>>>(HID_H, HID_L, KW2_H, KW2_L, k_b2,
                                             HIDV, VW2_H, v_b2, CKT_H, CKT_M, CKT_L, CVT);
  // 6. merged compression attn + selection (blocks 0-511) + sliding window (512-1023)
  k_comp_attn<<<1024, 256, 0, stream>>>(QBH, QBM, QBL, CKT_H, CKT_M, CKT_L, CVT,
                                        RQH, RQL, RKH, RKL, VTB, COUT, SEL, SOUT);
  // 7. fine attention only (head-per-XCD, 4-lane-per-key QK)
  k_fs_attn<<<4096, 256, 0, stream>>>(RQH, RQL, RKH, VBH, SEL, FOUT);
  // 8. fused strat + combine
  k_combine2<<<NTOK, 256, 0, stream>>>(HB_H, HB_L, w_comb, b_comb, COUT, FOUT, SOUT, COMBB);
  // 9. output projection
  k_cgemm<0, 0><<<dim3(8, 32), 256, 0, stream>>>(
      COMBB, nullptr, WOUT_H, nullptr, nullptr, out, NTOK, DMODEL, DMODEL);
}